// Round 1
// baseline (6250.112 us; speedup 1.0000x reference)
//
#include <hip/hip_runtime.h>
#include <math.h>

// ESMMimicryModule: B=8 S=2048 H=8 NL=128 DF=VF=64 NF=1280 HS=33 FEAT=1313
// Round 0: fp32 correctness baseline. Structure:
//  k_orig: softmax(latent)*mask concat x_embeds -> orig (B,S,1313)
//  per layer:
//    k_gemm  x4: Eq,Ek,Ev,proj (bias=row 1312 of W, scaled in epilogue)
//    k_segmean x2: q_land,k_land ; k_possel/k_possel2: analytic pos means
//    k_kernel2: softmax(q_land@k_land^T+possel2) + per-(b,h) colsum max
//    k_kernel3: flash-style scores->softmax->@Ev => kv3 (B,H,NL,VF)
//    k_inverse: 6-iter Newton-Schulz in LDS, then m2 = inv @ kv3
//    k_k1attn: kernel_1 logits+softmax, @m2, +proj, write transposed merged
//    k_gemm: merged @ collect -> next values / final output (*mask)
// ws usage ~272 MB (merged aliases Ev).

namespace {

constexpr int B = 8, S = 2048, H = 8, NL = 128, DF = 64, VF = 64;
constexpr int NF = 1280, HS = 33, FEAT = 1313, FEATP = 1314;
constexpr int SEG = 16, HV = H * VF;                 // 512
constexpr float INV_SCALE = 0.35355339059327373f;    // DF^-0.25

// ---------------------------------------------------------------- orig
__global__ __launch_bounds__(256) void k_orig(
    const float* __restrict__ lat, const float* __restrict__ masks,
    const float* __restrict__ xemb, float* __restrict__ orig)
{
  long row = blockIdx.x;            // b*S+s
  int t = threadIdx.x;
  const float* xr = xemb + row * (long)NF;
  float* og = orig + row * (long)FEAT;
  for (int i = t; i < NF; i += 256) og[i] = xr[i];
  __shared__ float sm[HS];
  if (t < 64) {
    float v = (t < HS) ? lat[row * (long)HS + t] : -INFINITY;
    float m = v;
    #pragma unroll
    for (int o = 32; o; o >>= 1) m = fmaxf(m, __shfl_xor(m, o));
    float e = (t < HS) ? expf(v - m) : 0.f;
    float s = e;
    #pragma unroll
    for (int o = 32; o; o >>= 1) s += __shfl_xor(s, o);
    if (t < HS) sm[t] = e / s * masks[row];
  }
  __syncthreads();
  if (t < HS) og[NF + t] = sm[t];
}

// ---------------------------------------------------------------- generic GEMM
// C[z][m][n] = scale*( sum_k A[z][m][k]*W[z][k][n] + W[z][biasRow][n] ) * mask?
// per z: A += (z/aDiv)*aStride ; W += (z%wMod)*wStride ; C += z*cStride
__global__ __launch_bounds__(256) void k_gemm(
    const float* __restrict__ A, const float* __restrict__ W,
    const float* __restrict__ mask, float* __restrict__ C,
    int M, int N, int K,
    long aStride, int aDiv, long wStride, int wMod,
    long cStride, int biasRow, float scale)
{
  int z = blockIdx.z;
  const float* Ap = A + (long)(z / aDiv) * aStride;
  const float* Wp = W + (long)(z % wMod) * wStride;
  float* Cp = C + (long)z * cStride;
  int m0 = blockIdx.y * 64;
  int n0 = blockIdx.x * 64;
  __shared__ float Ast[16][68];   // [kk][m]  (transposed A tile)
  __shared__ float Ws[16][68];    // [kk][n]
  int tid = threadIdx.x;
  int tx = tid & 15, ty = tid >> 4;
  float acc[4][4] = {};
  int nK = (K + 15) / 16;
  for (int kb = 0; kb < nK; kb++) {
    int k0 = kb * 16;
    for (int idx = tid; idx < 64 * 16; idx += 256) {
      int m = idx >> 4, kk = idx & 15;
      int gm = m0 + m, gk = k0 + kk;
      Ast[kk][m] = (gm < M && gk < K) ? Ap[(long)gm * K + gk] : 0.f;
    }
    for (int idx = tid; idx < 16 * 64; idx += 256) {
      int kk = idx >> 6, n = idx & 63;
      int gk = k0 + kk, gn = n0 + n;
      Ws[kk][n] = (gk < K && gn < N) ? Wp[(long)gk * N + gn] : 0.f;
    }
    __syncthreads();
    #pragma unroll
    for (int kk = 0; kk < 16; kk++) {
      float4 a4 = *(const float4*)&Ast[kk][ty * 4];
      float4 w4 = *(const float4*)&Ws[kk][tx * 4];
      float av[4] = {a4.x, a4.y, a4.z, a4.w};
      float wv[4] = {w4.x, w4.y, w4.z, w4.w};
      #pragma unroll
      for (int i = 0; i < 4; i++)
        #pragma unroll
        for (int j = 0; j < 4; j++)
          acc[i][j] += av[i] * wv[j];
    }
    __syncthreads();
  }
  #pragma unroll
  for (int i = 0; i < 4; i++) {
    int gm = m0 + ty * 4 + i;
    if (gm >= M) continue;
    float mv = mask ? mask[(long)z * M + gm] : 1.f;
    #pragma unroll
    for (int j = 0; j < 4; j++) {
      int gn = n0 + tx * 4 + j;
      if (gn >= N) continue;
      float v = acc[i][j];
      if (biasRow >= 0) v += Wp[(long)biasRow * N + gn];
      Cp[(long)gm * N + gn] = v * scale * mv;
    }
  }
}

// ---------------------------------------------------------------- landmarks
// in (Z,S,DF) -> out (Z,NL,DF): mean over SEG consecutive rows
__global__ void k_segmean(const float* __restrict__ in, float* __restrict__ out)
{
  long zl = blockIdx.x;
  long z = zl / NL, l = zl % NL;
  int d = threadIdx.x; // 64
  const float* p = in + (z * S + l * SEG) * (long)DF + d;
  float s = 0.f;
  #pragma unroll
  for (int i = 0; i < SEG; i++) s += p[(long)i * DF];
  out[(z * NL + l) * (long)DF + d] = s * (1.f / SEG);
}

// possel[h,l,j] = -sigma_h * mean_{i in block l} |i-j|
__global__ void k_possel(const float* __restrict__ agg, float* __restrict__ possel)
{
  int hl = blockIdx.x; int h = hl / NL; int l = hl % NL;
  float sigma = fabsf(agg[h]) + 0.001f;
  int base = l * SEG;
  for (int j = threadIdx.x; j < S; j += blockDim.x) {
    float s = 0.f;
    #pragma unroll
    for (int i = 0; i < SEG; i++) s += fabsf((float)(base + i - j));
    possel[((long)h * NL + l) * S + j] = -sigma * s * (1.f / SEG);
  }
}

// possel2[h,l,m] = mean over j-window m of possel
__global__ void k_possel2(const float* __restrict__ possel, float* __restrict__ possel2)
{
  int hl = blockIdx.x;
  for (int m = threadIdx.x; m < NL; m += blockDim.x) {
    const float* p = possel + (long)hl * S + m * SEG;
    float s = 0.f;
    #pragma unroll
    for (int i = 0; i < SEG; i++) s += p[i];
    possel2[(long)hl * NL + m] = s * (1.f / SEG);
  }
}

// ---------------------------------------------------------------- kernel_2
// k2 = softmax(q_land@k_land^T + possel2) ; colmax[z] = max_m sum_l k2[l,m]
__global__ __launch_bounds__(256) void k_kernel2(
    const float* __restrict__ qland, const float* __restrict__ kland,
    const float* __restrict__ possel2, float* __restrict__ k2,
    float* __restrict__ colmax)
{
  int z = blockIdx.x; int b = z / H; int h = z % H;
  __shared__ float qs[NL][68];
  __shared__ float ks[NL][68];
  __shared__ float lg[NL][NL + 1];
  int tid = threadIdx.x;
  for (int idx = tid; idx < NL * DF; idx += 256) {
    int r = idx >> 6, d = idx & 63;
    qs[r][d] = qland[((long)z * NL + r) * DF + d];
    ks[r][d] = kland[((long)b * NL + r) * DF + d];
  }
  __syncthreads();
  int r = tid >> 1, half = tid & 1;
  const float* p2 = possel2 + ((long)h * NL + r) * NL;
  float lmax = -INFINITY;
  for (int c = 0; c < 64; c++) {
    int m = half * 64 + c;
    float s = 0.f;
    #pragma unroll
    for (int d = 0; d < DF; d += 4) {
      float4 q = *(const float4*)&qs[r][d];
      float4 k4 = *(const float4*)&ks[m][d];
      s += q.x * k4.x + q.y * k4.y + q.z * k4.z + q.w * k4.w;
    }
    s += p2[m];
    lg[r][m] = s;
    lmax = fmaxf(lmax, s);
  }
  lmax = fmaxf(lmax, __shfl_xor(lmax, 1));
  float lsum = 0.f;
  for (int c = 0; c < 64; c++) {
    int m = half * 64 + c;
    float e = expf(lg[r][m] - lmax);
    lg[r][m] = e; lsum += e;
  }
  lsum += __shfl_xor(lsum, 1);
  float inv = 1.f / lsum;
  for (int c = 0; c < 64; c++) {
    int m = half * 64 + c;
    float p = lg[r][m] * inv;
    lg[r][m] = p;
    k2[((long)z * NL + r) * NL + m] = p;
  }
  __syncthreads();
  float myc = 0.f;
  if (tid < NL) {
    for (int rr = 0; rr < NL; rr++) myc += lg[rr][tid];
  }
  float wm = myc;
  #pragma unroll
  for (int o = 32; o; o >>= 1) wm = fmaxf(wm, __shfl_xor(wm, o));
  __shared__ float wred[4];
  if ((tid & 63) == 0) wred[tid >> 6] = wm;
  __syncthreads();
  if (tid == 0)
    colmax[z] = fmaxf(fmaxf(wred[0], wred[1]), fmaxf(wred[2], wred[3]));
}

// ---------------------------------------------------------------- kernel_3
// scores = q_land@Ek^T + mask + possel ; softmax over S ; kv3 = P @ Ev
// block = (b,h, 8-row landmark tile)
__global__ __launch_bounds__(256) void k_kernel3(
    const float* __restrict__ qland, const float* __restrict__ Ek,
    const float* __restrict__ Ev, const float* __restrict__ possel,
    const float* __restrict__ masks, float* __restrict__ kv3)
{
  int zz = blockIdx.x; int z = zz / (NL / 8); int lt = zz % (NL / 8);
  int b = z / H, h = z % H;
  int l0 = lt * 8;
  __shared__ float qld[8][68];
  __shared__ float P[8][S];        // 64 KB
  __shared__ float evs[128][68];   // staging (Ek then Ev chunks)
  int tid = threadIdx.x;
  for (int idx = tid; idx < 8 * DF; idx += 256) {
    int r = idx >> 6, d = idx & 63;
    qld[r][d] = qland[((long)z * NL + l0 + r) * DF + d];
  }
  __syncthreads();
  int r = tid >> 5, tc = tid & 31;
  const float* ekb = Ek + (long)b * S * DF;
  const float* pp = possel + ((long)h * NL + l0 + r) * S;
  const float* mrow = masks + (long)b * S;
  for (int j0 = 0; j0 < S; j0 += 128) {
    for (int idx = tid; idx < 128 * DF; idx += 256) {
      int k = idx >> 6, d = idx & 63;
      evs[k][d] = ekb[(long)(j0 + k) * DF + d];
    }
    __syncthreads();
    #pragma unroll
    for (int jj = 0; jj < 4; jj++) {
      int jl = tc + jj * 32; int j = j0 + jl;
      float s = 0.f;
      #pragma unroll
      for (int d = 0; d < DF; d += 4) {
        float4 e = *(const float4*)&evs[jl][d];
        float4 q = *(const float4*)&qld[r][d];
        s += e.x * q.x + e.y * q.y + e.z * q.z + e.w * q.w;
      }
      s += pp[j] + ((mrow[j] == 0.f) ? -1e6f : 0.f);
      P[r][j] = s;
    }
    __syncthreads();
  }
  // softmax over 2048 per row (32 threads / row)
  float m = -INFINITY;
  for (int i = 0; i < 64; i++) m = fmaxf(m, P[r][tc + i * 32]);
  #pragma unroll
  for (int o = 16; o; o >>= 1) m = fmaxf(m, __shfl_xor(m, o));
  float ssum = 0.f;
  for (int i = 0; i < 64; i++) {
    float e = expf(P[r][tc + i * 32] - m);
    P[r][tc + i * 32] = e; ssum += e;
  }
  #pragma unroll
  for (int o = 16; o; o >>= 1) ssum += __shfl_xor(ssum, o);
  float inv = 1.f / ssum;
  __syncthreads();
  // PV
  const float* evb = Ev + (long)z * S * DF;
  int c0 = tc * 2;
  float a0 = 0.f, a1 = 0.f;
  for (int k0 = 0; k0 < S; k0 += 128) {
    for (int idx = tid; idx < 128 * DF; idx += 256) {
      int k = idx >> 6, d = idx & 63;
      evs[k][d] = evb[(long)(k0 + k) * DF + d];
    }
    __syncthreads();
    #pragma unroll 8
    for (int kk = 0; kk < 128; kk++) {
      float p = P[r][k0 + kk];
      a0 += p * evs[kk][c0];
      a1 += p * evs[kk][c0 + 1];
    }
    __syncthreads();
  }
  long o = ((long)z * NL + l0 + r) * VF + c0;
  kv3[o] = a0 * inv;
  kv3[o + 1] = a1 * inv;
}

// ---------------------------------------------------------------- inverse
// value0 = recip*key^T ; 6x Newton-Schulz ; m2 = value @ kv3
__global__ __launch_bounds__(512) void k_inverse(
    const float* __restrict__ k2g, const float* __restrict__ colmax,
    float* __restrict__ ubuf, const float* __restrict__ kv3,
    float* __restrict__ m2)
{
  int z = blockIdx.x;
  __shared__ float V[NL][NL + 1];
  __shared__ float KV[NL][NL + 1];
  __shared__ float chunk[2176];
  int tid = threadIdx.x;
  int tx = tid & 15, ty = tid >> 4;   // tx 0..15, ty 0..31
  int r0 = ty * 4, c0 = tx * 8;
  float gmax = 0.f;
  for (int i = 0; i < B * H; i++) gmax = fmaxf(gmax, colmax[i]);
  float recip = 1.f / gmax;
  const float* key = k2g + (long)z * NL * NL;
  float* ub = ubuf + (long)z * NL * NL;
  for (int idx = tid; idx < NL * NL; idx += 512) {
    int rr = idx >> 7, cc = idx & 127;
    V[cc][rr] = recip * key[idx];
  }
  __syncthreads();
  float acc[4][8];
  for (int it = 0; it < 6; it++) {
    // KV = key @ V
    #pragma unroll
    for (int i = 0; i < 4; i++)
      #pragma unroll
      for (int j = 0; j < 8; j++) acc[i][j] = 0.f;
    for (int kb = 0; kb < 8; kb++) {
      for (int idx = tid; idx < NL * 16; idx += 512) {
        int i = idx >> 4, kk = idx & 15;
        chunk[i * 17 + kk] = key[i * NL + kb * 16 + kk];
      }
      __syncthreads();
      #pragma unroll
      for (int kk = 0; kk < 16; kk++) {
        float a[4], bb[8];
        #pragma unroll
        for (int i = 0; i < 4; i++) a[i] = chunk[(r0 + i) * 17 + kk];
        #pragma unroll
        for (int j = 0; j < 8; j++) bb[j] = V[kb * 16 + kk][c0 + j];
        #pragma unroll
        for (int i = 0; i < 4; i++)
          #pragma unroll
          for (int j = 0; j < 8; j++) acc[i][j] += a[i] * bb[j];
      }
      __syncthreads();
    }
    #pragma unroll
    for (int i = 0; i < 4; i++)
      #pragma unroll
      for (int j = 0; j < 8; j++) KV[r0 + i][c0 + j] = acc[i][j];
    __syncthreads();
    // u = 7KV - KV@KV -> global ub
    #pragma unroll
    for (int i = 0; i < 4; i++)
      #pragma unroll
      for (int j = 0; j < 8; j++) acc[i][j] = 0.f;
    for (int k = 0; k < NL; k++) {
      float a[4], bb[8];
      #pragma unroll
      for (int i = 0; i < 4; i++) a[i] = KV[r0 + i][k];
      #pragma unroll
      for (int j = 0; j < 8; j++) bb[j] = KV[k][c0 + j];
      #pragma unroll
      for (int i = 0; i < 4; i++)
        #pragma unroll
        for (int j = 0; j < 8; j++) acc[i][j] += a[i] * bb[j];
    }
    #pragma unroll
    for (int i = 0; i < 4; i++)
      #pragma unroll
      for (int j = 0; j < 8; j++)
        ub[(long)(r0 + i) * NL + c0 + j] = 7.f * KV[r0 + i][c0 + j] - acc[i][j];
    __syncthreads();
    // x = 15KV - KV@u -> KV
    #pragma unroll
    for (int i = 0; i < 4; i++)
      #pragma unroll
      for (int j = 0; j < 8; j++) acc[i][j] = 0.f;
    for (int kb = 0; kb < 8; kb++) {
      for (int idx = tid; idx < 16 * NL; idx += 512) {
        int kk = idx >> 7, j = idx & 127;
        chunk[kk * 136 + j] = ub[(long)(kb * 16 + kk) * NL + j];
      }
      __syncthreads();
      #pragma unroll
      for (int kk = 0; kk < 16; kk++) {
        float a[4], bb[8];
        #pragma unroll
        for (int i = 0; i < 4; i++) a[i] = KV[r0 + i][kb * 16 + kk];
        #pragma unroll
        for (int j = 0; j < 8; j++) bb[j] = chunk[kk * 136 + c0 + j];
        #pragma unroll
        for (int i = 0; i < 4; i++)
          #pragma unroll
          for (int j = 0; j < 8; j++) acc[i][j] += a[i] * bb[j];
      }
      __syncthreads();
    }
    #pragma unroll
    for (int i = 0; i < 4; i++)
      #pragma unroll
      for (int j = 0; j < 8; j++)
        acc[i][j] = 15.f * KV[r0 + i][c0 + j] - acc[i][j];
    __syncthreads();
    #pragma unroll
    for (int i = 0; i < 4; i++)
      #pragma unroll
      for (int j = 0; j < 8; j++) KV[r0 + i][c0 + j] = acc[i][j];
    __syncthreads();
    // V = 0.25*(13V - V@KV)
    #pragma unroll
    for (int i = 0; i < 4; i++)
      #pragma unroll
      for (int j = 0; j < 8; j++) acc[i][j] = 0.f;
    for (int k = 0; k < NL; k++) {
      float a[4], bb[8];
      #pragma unroll
      for (int i = 0; i < 4; i++) a[i] = V[r0 + i][k];
      #pragma unroll
      for (int j = 0; j < 8; j++) bb[j] = KV[k][c0 + j];
      #pragma unroll
      for (int i = 0; i < 4; i++)
        #pragma unroll
        for (int j = 0; j < 8; j++) acc[i][j] += a[i] * bb[j];
    }
    #pragma unroll
    for (int i = 0; i < 4; i++)
      #pragma unroll
      for (int j = 0; j < 8; j++)
        acc[i][j] = 0.25f * (13.f * V[r0 + i][c0 + j] - acc[i][j]);
    __syncthreads();
    #pragma unroll
    for (int i = 0; i < 4; i++)
      #pragma unroll
      for (int j = 0; j < 8; j++) V[r0 + i][c0 + j] = acc[i][j];
    __syncthreads();
  }
  // m2 = V @ kv3[z]
  const float* kp = kv3 + (long)z * NL * VF;
  float am[4][4] = {};
  for (int k = 0; k < NL; k++) {
    float4 b4 = *(const float4*)&kp[(long)k * VF + tx * 4];
    float bb[4] = {b4.x, b4.y, b4.z, b4.w};
    #pragma unroll
    for (int i = 0; i < 4; i++) {
      float a = V[r0 + i][k];
      #pragma unroll
      for (int j = 0; j < 4; j++) am[i][j] += a * bb[j];
    }
  }
  float* mp = m2 + (long)z * NL * VF;
  #pragma unroll
  for (int i = 0; i < 4; i++)
    #pragma unroll
    for (int j = 0; j < 4; j++)
      mp[(long)(r0 + i) * VF + tx * 4 + j] = am[i][j];
}

// ---------------------------------------------------------------- kernel_1 + attn + merge
// logits = Eq@k_land^T + possel^T ; softmax over NL ; out = P@m2 + proj
// written transposed into merged (B,S,H*VF)
__global__ __launch_bounds__(256) void k_k1attn(
    const float* __restrict__ Eq, const float* __restrict__ kland,
    const float* __restrict__ possel, const float* __restrict__ m2,
    const float* __restrict__ proj, float* __restrict__ merged)
{
  int zz = blockIdx.x; int z = zz / (S / 16); int st = zz % (S / 16);
  int b = z / H, h = z % H;
  int s0 = st * 16;
  __shared__ float ks[NL][68];
  __shared__ float ms[NL][64];
  __shared__ float eqs[16][68];
  __shared__ float P[16][132];
  int tid = threadIdx.x;
  for (int idx = tid; idx < NL * DF; idx += 256) {
    int rr = idx >> 6, d = idx & 63;
    ks[rr][d] = kland[((long)b * NL + rr) * DF + d];
    ms[rr][d] = m2[((long)z * NL + rr) * DF + d];
  }
  for (int idx = tid; idx < 16 * DF; idx += 256) {
    int rr = idx >> 6, d = idx & 63;
    eqs[rr][d] = Eq[((long)z * S + s0 + rr) * DF + d];
  }
  __syncthreads();
  int r = tid >> 4, li = tid & 15;
  const float* pp = possel + (long)h * NL * S;
  float vals[8]; float lmax = -INFINITY;
  #pragma unroll
  for (int jj = 0; jj < 8; jj++) {
    int l = li + jj * 16;
    float s = 0.f;
    #pragma unroll
    for (int d = 0; d < DF; d += 4) {
      float4 e = *(const float4*)&eqs[r][d];
      float4 k4 = *(const float4*)&ks[l][d];
      s += e.x * k4.x + e.y * k4.y + e.z * k4.z + e.w * k4.w;
    }
    s += pp[(long)l * S + s0 + r];
    vals[jj] = s; lmax = fmaxf(lmax, s);
  }
  #pragma unroll
  for (int o = 8; o; o >>= 1) lmax = fmaxf(lmax, __shfl_xor(lmax, o));
  float ssum = 0.f;
  #pragma unroll
  for (int jj = 0; jj < 8; jj++) { vals[jj] = expf(vals[jj] - lmax); ssum += vals[jj]; }
  #pragma unroll
  for (int o = 8; o; o >>= 1) ssum += __shfl_xor(ssum, o);
  float inv = 1.f / ssum;
  #pragma unroll
  for (int jj = 0; jj < 8; jj++) P[r][li + jj * 16] = vals[jj] * inv;
  __syncthreads();
  // out tile (16 x 64) = P @ ms  (+ proj)
  float acc[4] = {};
  for (int l = 0; l < NL; l++) {
    float p = P[r][l];
    float4 m4 = *(const float4*)&ms[l][li * 4];
    acc[0] += p * m4.x; acc[1] += p * m4.y; acc[2] += p * m4.z; acc[3] += p * m4.w;
  }
  long srow = (long)b * S + s0 + r;
  float4 pj = *(const float4*)&proj[srow * VF + li * 4];
  float4 o4;
  o4.x = acc[0] + pj.x; o4.y = acc[1] + pj.y;
  o4.z = acc[2] + pj.z; o4.w = acc[3] + pj.w;
  *(float4*)&merged[srow * (long)HV + h * VF + li * 4] = o4;
}

} // namespace

extern "C" void kernel_launch(void* const* d_in, const int* in_sizes, int n_in,
                              void* d_out, int out_size, void* d_ws, size_t ws_size,
                              hipStream_t stream)
{
  const float* lat   = (const float*)d_in[0];
  const float* masks = (const float*)d_in[1];
  const float* xemb  = (const float*)d_in[2];
  // d_in[3] pos_embed: unused by the reference
  const float* ccls  = (const float*)d_in[4];
  const float* qlin  = (const float*)d_in[5];
  const float* klin  = (const float*)d_in[6];
  const float* vlin  = (const float*)d_in[7];
  const float* plin  = (const float*)d_in[8];
  const float* agg   = (const float*)d_in[9];
  const float* cfeat = (const float*)d_in[10];
  float* out = (float*)d_out;
  float* ws = (float*)d_ws;

  long off = 0;
  auto alloc = [&](long n) { float* p = ws + off; off += n; return p; };
  float* orig   = alloc((long)B * S * FEAT);
  float* vbuf   = alloc((long)B * S * FEAT);
  float* Eq     = alloc((long)B * H * S * DF);
  float* EkB    = alloc((long)B * S * DF);
  float* Ev     = alloc((long)B * H * S * DF);  // merged aliases this
  float* projb  = alloc((long)B * S * VF);
  float* qland  = alloc((long)B * H * NL * DF);
  float* kland  = alloc((long)B * NL * DF);
  float* possel = alloc((long)H * NL * S);
  float* possel2= alloc((long)H * NL * NL);
  float* k2b    = alloc((long)B * H * NL * NL);
  float* ubuf   = alloc((long)B * H * NL * NL);
  float* kv3    = alloc((long)B * H * NL * VF);
  float* m2b    = alloc((long)B * H * NL * VF);
  float* colmax = alloc(64);
  float* merged = Ev;  // lifetime-disjoint alias: Ev dead after k_kernel3

  k_orig<<<B * S, 256, 0, stream>>>(lat, masks, xemb, orig);

  const float* values = orig;
  for (int layer = 0; layer < 2; layer++) {
    const float* qw = qlin + (long)layer * H * FEATP * DF;
    const float* kw = klin + (long)layer * FEATP * DF;
    const float* vw = vlin + (long)layer * H * FEATP * DF;
    const float* pw = plin + (long)layer * FEATP * DF;
    const float* ag = agg + layer * H;

    dim3 gEq(1, S / 64, B * H);
    dim3 gEk(1, S / 64, B);
    k_gemm<<<gEq, 256, 0, stream>>>(values, qw, nullptr, Eq, S, DF, FEAT,
        (long)S * FEAT, H, (long)FEATP * DF, H, (long)S * DF, FEAT - 1, INV_SCALE);
    k_gemm<<<gEk, 256, 0, stream>>>(values, kw, nullptr, EkB, S, DF, FEAT,
        (long)S * FEAT, 1, 0L, 1, (long)S * DF, FEAT - 1, INV_SCALE);
    k_gemm<<<gEq, 256, 0, stream>>>(values, vw, nullptr, Ev, S, DF, FEAT,
        (long)S * FEAT, H, (long)FEATP * DF, H, (long)S * DF, FEAT - 1, 1.0f);
    k_gemm<<<gEk, 256, 0, stream>>>(orig, pw, nullptr, projb, S, VF, FEAT,
        (long)S * FEAT, 1, 0L, 1, (long)S * VF, FEAT - 1, 0.5f);

    k_segmean<<<B * H * NL, 64, 0, stream>>>(Eq, qland);
    k_segmean<<<B * NL, 64, 0, stream>>>(EkB, kland);
    k_possel<<<H * NL, 256, 0, stream>>>(ag, possel);
    k_possel2<<<H * NL, 128, 0, stream>>>(possel, possel2);

    k_kernel2<<<B * H, 256, 0, stream>>>(qland, kland, possel2, k2b, colmax);
    k_kernel3<<<B * H * (NL / 8), 256, 0, stream>>>(qland, EkB, Ev, possel, masks, kv3);
    k_inverse<<<B * H, 512, 0, stream>>>(k2b, colmax, ubuf, kv3, m2b);
    k_k1attn<<<B * H * (S / 16), 256, 0, stream>>>(Eq, kland, possel, m2b, projb, merged);

    if (layer == 0) {
      dim3 gF((FEAT + 63) / 64, S / 64, B);
      k_gemm<<<gF, 256, 0, stream>>>(merged, cfeat, nullptr, vbuf, S, FEAT, HV,
          (long)S * HV, 1, 0L, 1, (long)S * FEAT, -1, 1.0f);
      values = vbuf;
    } else {
      dim3 gF(1, S / 64, B);
      k_gemm<<<gF, 256, 0, stream>>>(merged, ccls, masks, out, S, HS, HV,
          (long)S * HV, 1, 0L, 1, (long)S * HS, -1, 1.0f);
    }
  }
  (void)in_sizes; (void)n_in; (void)out_size; (void)ws_size;
}

// Round 2
// 2529.478 us; speedup vs baseline: 2.4709x; 2.4709x over previous
//
#include <hip/hip_runtime.h>
#include <math.h>

// ESMMimicryModule: B=8 S=2048 H=8 NL=128 DF=VF=64 NF=1280 HS=33 FEAT=1313
// Round 1: (a) fp16 MFMA GEMMs (pre-swizzled fp16 arenas, global_load_lds,
// double-buffered, counted vmcnt), (b) k_inverse rewritten: row-local Horner
// polynomial, V/X only in LDS, conflict-free mappings, no global bounce.

namespace {

constexpr int B = 8, S = 2048, H = 8, NL = 128, DF = 64, VF = 64;
constexpr int NF = 1280, HS = 33, FEAT = 1313, FEATP = 1314;
constexpr int SEG = 16, HV = H * VF;            // 512
constexpr int KSF = 1344;                        // padded feature-K (21*64)
constexpr long ROWS = (long)B * S;               // 16384
constexpr float INV_SCALE = 0.35355339059327373f;

typedef _Float16 f16;
typedef _Float16 f16x8 __attribute__((ext_vector_type(8)));
typedef _Float16 f16x4 __attribute__((ext_vector_type(4)));
typedef float f32x4 __attribute__((ext_vector_type(4)));

// ---------------------------------------------------------------- cl = softmax(latent)*mask
__global__ __launch_bounds__(256) void k_cl(
    const float* __restrict__ lat, const float* __restrict__ masks,
    float* __restrict__ cl)
{
  long row = (long)blockIdx.x * 4 + (threadIdx.x >> 6);
  int l = threadIdx.x & 63;
  float v = (l < HS) ? lat[row * HS + l] : -INFINITY;
  float m = v;
  #pragma unroll
  for (int o = 32; o; o >>= 1) m = fmaxf(m, __shfl_xor(m, o));
  float e = (l < HS) ? expf(v - m) : 0.f;
  float s = e;
  #pragma unroll
  for (int o = 32; o; o >>= 1) s += __shfl_xor(s, o);
  if (l < HS) cl[row * HS + l] = e / s * masks[row];
}

// ---------------------------------------------------------------- origA fp16 arena (swizzled)
// arena[row][t*64 + cs*8 + i] = data[row][t*64 + (cs^(row&7))*8 + i]
__global__ __launch_bounds__(256) void k_cvta(
    const float* __restrict__ xemb, const float* __restrict__ cl,
    f16* __restrict__ dst)
{
  long idx = (long)blockIdx.x * 256 + threadIdx.x;  // chunk id (row,c)
  long row = idx / 168;
  int c = (int)(idx - row * 168);
  int t = c >> 3, cs = c & 7;
  int cd = cs ^ ((int)row & 7);
  int k0 = t * 64 + cd * 8;
  f16x8 v;
  #pragma unroll
  for (int i = 0; i < 8; ++i) {
    int k = k0 + i;
    float f = 0.f;
    if (k < NF) f = xemb[row * NF + k];
    else if (k < FEAT) f = cl[row * HS + (k - NF)];
    v[i] = (f16)f;
  }
  *(f16x8*)&dst[idx * 8] = v;
}

// ---------------------------------------------------------------- weight -> Wt fp16 arena
// dst[z][n][t*64 + cs*8 + i] = src[z][t*64+(cs^(n&7))*8+i][n]  (0 beyond K/N)
__global__ __launch_bounds__(256) void k_cvtw(
    const float* __restrict__ src, f16* __restrict__ dst,
    int K, int N, int Npad, int KS, long srcZ, long total)
{
  long idx = (long)blockIdx.x * 256 + threadIdx.x;
  if (idx >= total) return;
  long cpz = (long)Npad * (KS >> 3);
  long z = idx / cpz;
  long rem = idx - z * cpz;
  int n = (int)(rem / (KS >> 3));
  int c = (int)(rem - (long)n * (KS >> 3));
  int t = c >> 3, cs = c & 7;
  int cd = cs ^ (n & 7);
  int k0 = t * 64 + cd * 8;
  const float* sp = src + z * srcZ;
  f16x8 v;
  #pragma unroll
  for (int i = 0; i < 8; ++i) {
    int k = k0 + i;
    v[i] = (f16)((k < K && n < N) ? sp[(long)k * N + n] : 0.f);
  }
  *(f16x8*)&dst[idx * 8] = v;
}

// ---------------------------------------------------------------- fp16 MFMA GEMM
// C[z] = A[z] (M x K) @ W[z]^T-arena (K x 64-per-n-tile), BM=256 BN=64 BK=64,
// 4 waves x (64x64), double-buffered LDS via global_load_lds.
// mode 0: fp32 C = (acc + bias)*scale ; mode 1: fp16 swizzled arena (KSF row
// stride, zero-fill col>=NR) ; mode 2: fp32 out * mask, col<NR, ld=ldC.
__global__ __launch_bounds__(256, 2) void k_mgemm(
    const f16* __restrict__ A, long aZOff, int aDiv,
    const f16* __restrict__ Wt, long wZOff, int wMod,
    int KT, int mode,
    float* __restrict__ C, long cZOff, int ldC,
    const float* __restrict__ biasBase, long biasZOff, float scale,
    f16* __restrict__ outA, int NR, const float* __restrict__ mask)
{
  const long KS = (long)KT * 64;
  int z = blockIdx.z;
  const f16* Ap = A + (long)(z / aDiv) * aZOff;
  const f16* Wp = Wt + (long)(z % wMod) * wZOff;
  long m0 = (long)blockIdx.x * 256;
  int n0 = blockIdx.y * 64;
  constexpr int BOFF = 256 * 64;
  __shared__ f16 lds[2][(256 + 64) * 64];
  int tid = threadIdx.x;
  int wv = tid >> 6, l = tid & 63;

  const f16* aW = Ap + (m0 + wv * 64 + (l >> 3)) * KS + (l & 7) * 8;
  const f16* bW = Wp + ((long)(n0 + wv * 16 + (l >> 3))) * KS + (l & 7) * 8;

  f32x4 acc[4][4];
  #pragma unroll
  for (int i = 0; i < 4; ++i)
    #pragma unroll
    for (int j = 0; j < 4; ++j) acc[i][j] = (f32x4){0.f, 0.f, 0.f, 0.f};

  auto stage = [&](int buf, int t) {
    f16* la = &lds[buf][(wv * 64) * 64];
    const f16* ga = aW + (long)t * 64;
    #pragma unroll
    for (int j = 0; j < 8; ++j)
      __builtin_amdgcn_global_load_lds(
          (const __attribute__((address_space(1))) void*)(ga + (long)j * 8 * KS),
          (__attribute__((address_space(3))) void*)(la + j * 8 * 64), 16, 0, 0);
    f16* lb = &lds[buf][BOFF + (wv * 16) * 64];
    const f16* gb = bW + (long)t * 64;
    #pragma unroll
    for (int j = 0; j < 2; ++j)
      __builtin_amdgcn_global_load_lds(
          (const __attribute__((address_space(1))) void*)(gb + (long)j * 8 * KS),
          (__attribute__((address_space(3))) void*)(lb + j * 8 * 64), 16, 0, 0);
  };

  stage(0, 0);
  int rA = (wv * 64 + (l & 15)) * 64;
  int rB = BOFF + (l & 15) * 64;
  int lc = l >> 4, lx = l & 7;
  for (int t = 0; t < KT; ++t) {
    int nb = t & 1;
    if (t + 1 < KT) {
      stage(nb ^ 1, t + 1);
      asm volatile("s_waitcnt vmcnt(10)" ::: "memory");
    } else {
      asm volatile("s_waitcnt vmcnt(0)" ::: "memory");
    }
    __syncthreads();
    const f16* base = &lds[nb][0];
    f16x8 af[4][2], bf[4][2];
    #pragma unroll
    for (int mi = 0; mi < 4; ++mi)
      #pragma unroll
      for (int kh = 0; kh < 2; ++kh)
        af[mi][kh] = *(const f16x8*)&base[rA + mi * 16 * 64 + (((kh * 4 + lc) ^ lx) << 3)];
    #pragma unroll
    for (int ni = 0; ni < 4; ++ni)
      #pragma unroll
      for (int kh = 0; kh < 2; ++kh)
        bf[ni][kh] = *(const f16x8*)&base[rB + ni * 16 * 64 + (((kh * 4 + lc) ^ lx) << 3)];
    #pragma unroll
    for (int mi = 0; mi < 4; ++mi)
      #pragma unroll
      for (int ni = 0; ni < 4; ++ni) {
        acc[mi][ni] = __builtin_amdgcn_mfma_f32_16x16x32_f16(af[mi][0], bf[ni][0], acc[mi][ni], 0, 0, 0);
        acc[mi][ni] = __builtin_amdgcn_mfma_f32_16x16x32_f16(af[mi][1], bf[ni][1], acc[mi][ni], 0, 0, 0);
      }
    __syncthreads();
  }

  int lr = (l >> 4) * 4;
  int lcn = l & 15;
  if (mode == 0) {
    float* Cp = C + (long)z * cZOff;
    const float* bp = biasBase ? biasBase + (long)(z % wMod) * biasZOff : nullptr;
    #pragma unroll
    for (int ni = 0; ni < 4; ++ni) {
      int col = n0 + ni * 16 + lcn;
      float bv = bp ? bp[col] : 0.f;
      #pragma unroll
      for (int mi = 0; mi < 4; ++mi) {
        long row = m0 + wv * 64 + mi * 16 + lr;
        #pragma unroll
        for (int r = 0; r < 4; ++r)
          Cp[(row + r) * (long)ldC + col] = (acc[mi][ni][r] + bv) * scale;
      }
    }
  } else if (mode == 1) {
    #pragma unroll
    for (int mi = 0; mi < 4; ++mi) {
      #pragma unroll
      for (int r = 0; r < 4; ++r) {
        long row = m0 + wv * 64 + mi * 16 + lr + r;
        int r7 = (int)row & 7;
        #pragma unroll
        for (int ni = 0; ni < 4; ++ni) {
          int col = n0 + ni * 16 + lcn;
          int tt = col >> 6, kk = col & 63;
          int cd = kk >> 3, wi = kk & 7;
          float v = (col < NR) ? acc[mi][ni][r] : 0.f;
          outA[row * KSF + tt * 64 + (((cd ^ r7)) << 3) + wi] = (f16)v;
        }
      }
    }
  } else {
    #pragma unroll
    for (int mi = 0; mi < 4; ++mi) {
      #pragma unroll
      for (int r = 0; r < 4; ++r) {
        long row = m0 + wv * 64 + mi * 16 + lr + r;
        float mv = mask[row];
        #pragma unroll
        for (int ni = 0; ni < 4; ++ni) {
          int col = n0 + ni * 16 + lcn;
          if (col < NR) C[row * (long)ldC + col] = acc[mi][ni][r] * mv;
        }
      }
    }
  }
}

// ---------------------------------------------------------------- landmarks
__global__ void k_segmean(const float* __restrict__ in, float* __restrict__ out)
{
  long zl = blockIdx.x;
  long z = zl / NL, lm = zl % NL;
  int d = threadIdx.x;
  const float* p = in + (z * S + lm * SEG) * (long)DF + d;
  float s = 0.f;
  #pragma unroll
  for (int i = 0; i < SEG; i++) s += p[(long)i * DF];
  out[(z * NL + lm) * (long)DF + d] = s * (1.f / SEG);
}

__global__ void k_possel(const float* __restrict__ agg, float* __restrict__ possel)
{
  int hl = blockIdx.x; int h = hl / NL; int lm = hl % NL;
  float sigma = fabsf(agg[h]) + 0.001f;
  int base = lm * SEG;
  for (int j = threadIdx.x; j < S; j += blockDim.x) {
    float s = 0.f;
    #pragma unroll
    for (int i = 0; i < SEG; i++) s += fabsf((float)(base + i - j));
    possel[((long)h * NL + lm) * S + j] = -sigma * s * (1.f / SEG);
  }
}

__global__ void k_possel2(const float* __restrict__ possel, float* __restrict__ possel2)
{
  int hl = blockIdx.x;
  for (int m = threadIdx.x; m < NL; m += blockDim.x) {
    const float* p = possel + (long)hl * S + m * SEG;
    float s = 0.f;
    #pragma unroll
    for (int i = 0; i < SEG; i++) s += p[i];
    possel2[(long)hl * NL + m] = s * (1.f / SEG);
  }
}

// ---------------------------------------------------------------- kernel_2
__global__ __launch_bounds__(256) void k_kernel2(
    const float* __restrict__ qland, const float* __restrict__ kland,
    const float* __restrict__ possel2, float* __restrict__ k2,
    float* __restrict__ colmax)
{
  int z = blockIdx.x; int b = z / H; int h = z % H;
  __shared__ float qs[NL][68];
  __shared__ float ks[NL][68];
  __shared__ float lg[NL][NL + 1];
  int tid = threadIdx.x;
  for (int idx = tid; idx < NL * DF; idx += 256) {
    int r = idx >> 6, d = idx & 63;
    qs[r][d] = qland[((long)z * NL + r) * DF + d];
    ks[r][d] = kland[((long)b * NL + r) * DF + d];
  }
  __syncthreads();
  int r = tid >> 1, half = tid & 1;
  const float* p2 = possel2 + ((long)h * NL + r) * NL;
  float lmax = -INFINITY;
  for (int c = 0; c < 64; c++) {
    int m = half * 64 + c;
    float s = 0.f;
    #pragma unroll
    for (int d = 0; d < DF; d += 4) {
      float4 q = *(const float4*)&qs[r][d];
      float4 k4 = *(const float4*)&ks[m][d];
      s += q.x * k4.x + q.y * k4.y + q.z * k4.z + q.w * k4.w;
    }
    s += p2[m];
    lg[r][m] = s;
    lmax = fmaxf(lmax, s);
  }
  lmax = fmaxf(lmax, __shfl_xor(lmax, 1));
  float lsum = 0.f;
  for (int c = 0; c < 64; c++) {
    int m = half * 64 + c;
    float e = expf(lg[r][m] - lmax);
    lg[r][m] = e; lsum += e;
  }
  lsum += __shfl_xor(lsum, 1);
  float inv = 1.f / lsum;
  for (int c = 0; c < 64; c++) {
    int m = half * 64 + c;
    float p = lg[r][m] * inv;
    lg[r][m] = p;
    k2[((long)z * NL + r) * NL + m] = p;
  }
  __syncthreads();
  float myc = 0.f;
  if (tid < NL) {
    for (int rr = 0; rr < NL; rr++) myc += lg[rr][tid];
  }
  float wm = myc;
  #pragma unroll
  for (int o = 32; o; o >>= 1) wm = fmaxf(wm, __shfl_xor(wm, o));
  __shared__ float wred[4];
  if ((tid & 63) == 0) wred[tid >> 6] = wm;
  __syncthreads();
  if (tid == 0)
    colmax[z] = fmaxf(fmaxf(wred[0], wred[1]), fmaxf(wred[2], wred[3]));
}

// ---------------------------------------------------------------- kernel_3
__global__ __launch_bounds__(256) void k_kernel3(
    const float* __restrict__ qland, const float* __restrict__ Ek,
    const float* __restrict__ Ev, const float* __restrict__ possel,
    const float* __restrict__ masks, float* __restrict__ kv3)
{
  int zz = blockIdx.x; int z = zz / (NL / 8); int lt = zz % (NL / 8);
  int b = z / H, h = z % H;
  int l0 = lt * 8;
  __shared__ float qld[8][68];
  __shared__ float P[8][S];
  __shared__ float evs[128][68];
  int tid = threadIdx.x;
  for (int idx = tid; idx < 8 * DF; idx += 256) {
    int r = idx >> 6, d = idx & 63;
    qld[r][d] = qland[((long)z * NL + l0 + r) * DF + d];
  }
  __syncthreads();
  int r = tid >> 5, tc = tid & 31;
  const float* ekb = Ek + (long)b * S * DF;
  const float* pp = possel + ((long)h * NL + l0 + r) * S;
  const float* mrow = masks + (long)b * S;
  for (int j0 = 0; j0 < S; j0 += 128) {
    for (int idx = tid; idx < 128 * DF; idx += 256) {
      int k = idx >> 6, d = idx & 63;
      evs[k][d] = ekb[(long)(j0 + k) * DF + d];
    }
    __syncthreads();
    #pragma unroll
    for (int jj = 0; jj < 4; jj++) {
      int jl = tc + jj * 32; int j = j0 + jl;
      float s = 0.f;
      #pragma unroll
      for (int d = 0; d < DF; d += 4) {
        float4 e = *(const float4*)&evs[jl][d];
        float4 q = *(const float4*)&qld[r][d];
        s += e.x * q.x + e.y * q.y + e.z * q.z + e.w * q.w;
      }
      s += pp[j] + ((mrow[j] == 0.f) ? -1e6f : 0.f);
      P[r][j] = s;
    }
    __syncthreads();
  }
  float m = -INFINITY;
  for (int i = 0; i < 64; i++) m = fmaxf(m, P[r][tc + i * 32]);
  #pragma unroll
  for (int o = 16; o; o >>= 1) m = fmaxf(m, __shfl_xor(m, o));
  float ssum = 0.f;
  for (int i = 0; i < 64; i++) {
    float e = expf(P[r][tc + i * 32] - m);
    P[r][tc + i * 32] = e; ssum += e;
  }
  #pragma unroll
  for (int o = 16; o; o >>= 1) ssum += __shfl_xor(ssum, o);
  float inv = 1.f / ssum;
  __syncthreads();
  const float* evb = Ev + (long)z * S * DF;
  int c0 = tc * 2;
  float a0 = 0.f, a1 = 0.f;
  for (int k0 = 0; k0 < S; k0 += 128) {
    for (int idx = tid; idx < 128 * DF; idx += 256) {
      int k = idx >> 6, d = idx & 63;
      evs[k][d] = evb[(long)(k0 + k) * DF + d];
    }
    __syncthreads();
    #pragma unroll 8
    for (int kk = 0; kk < 128; kk++) {
      float p = P[r][k0 + kk];
      a0 += p * evs[kk][c0];
      a1 += p * evs[kk][c0 + 1];
    }
    __syncthreads();
  }
  long o = ((long)z * NL + l0 + r) * VF + c0;
  kv3[o] = a0 * inv;
  kv3[o + 1] = a1 * inv;
}

// ---------------------------------------------------------------- inverse (rewritten)
// V = recip*key^T; 6x: X = key@V; V <- 0.25*(13V - 15 V@X + 7 V@X^2 - V@X^3)
// row-local chains overwrite V rows in place; then m2 = V @ kv3.
__global__ __launch_bounds__(512) void k_inverse(
    const float* __restrict__ k2g, const float* __restrict__ colmax,
    const float* __restrict__ kv3, float* __restrict__ m2)
{
  __shared__ float V[128][132];
  __shared__ float X[128][132];
  int z = blockIdx.x;
  int tid = threadIdx.x;
  int wv = tid >> 6, l = tid & 63;
  float gmax = colmax[0];
  for (int i = 1; i < 64; ++i) gmax = fmaxf(gmax, colmax[i]);
  float recip = 1.f / gmax;
  const float* key = k2g + (long)z * NL * NL;
  for (int idx = tid; idx < NL * NL; idx += 512) {
    int r = idx >> 7, c = idx & 127;
    V[c][r] = recip * key[idx];
  }
  __syncthreads();
  int rA1 = wv * 16 + (l >> 4) * 4;   // step1: 4 rows
  int cB = (l & 15) * 8;              // 8 cols
  for (int it = 0; it < 6; ++it) {
    // X = key @ V
    float acc[4][8];
    #pragma unroll
    for (int i = 0; i < 4; ++i)
      #pragma unroll
      for (int j = 0; j < 8; ++j) acc[i][j] = 0.f;
    for (int k4 = 0; k4 < 128; k4 += 4) {
      float4 a4[4];
      #pragma unroll
      for (int i = 0; i < 4; ++i)
        a4[i] = *(const float4*)&key[(long)(rA1 + i) * 128 + k4];
      #pragma unroll
      for (int kk = 0; kk < 4; ++kk) {
        float bb[8];
        *(float4*)&bb[0] = *(const float4*)&V[k4 + kk][cB];
        *(float4*)&bb[4] = *(const float4*)&V[k4 + kk][cB + 4];
        #pragma unroll
        for (int i = 0; i < 4; ++i) {
          float a = ((const float*)&a4[i])[kk];
          #pragma unroll
          for (int j = 0; j < 8; ++j) acc[i][j] += a * bb[j];
        }
      }
    }
    #pragma unroll
    for (int i = 0; i < 4; ++i) {
      *(float4*)&X[rA1 + i][cB] = make_float4(acc[i][0], acc[i][1], acc[i][2], acc[i][3]);
      *(float4*)&X[rA1 + i][cB + 4] = make_float4(acc[i][4], acc[i][5], acc[i][6], acc[i][7]);
    }
    __syncthreads();
    // polynomial, two 64-row half-blocks; P-chain in place over V rows
    for (int hb = 0; hb < 2; ++hb) {
      int r0 = hb * 64 + wv * 8 + (l >> 4) * 2;   // 2 rows
      float a2[2][8], tmp[2][8];
      auto mm = [&]() {
        #pragma unroll
        for (int i = 0; i < 2; ++i)
          #pragma unroll
          for (int j = 0; j < 8; ++j) a2[i][j] = 0.f;
        for (int k = 0; k < 128; ++k) {
          float bb[8];
          *(float4*)&bb[0] = *(const float4*)&X[k][cB];
          *(float4*)&bb[4] = *(const float4*)&X[k][cB + 4];
          float av0 = V[r0][k], av1 = V[r0 + 1][k];
          #pragma unroll
          for (int j = 0; j < 8; ++j) {
            a2[0][j] += av0 * bb[j];
            a2[1][j] += av1 * bb[j];
          }
        }
      };
      mm();  // P1
      #pragma unroll
      for (int i = 0; i < 2; ++i) {
        float4 v0 = *(const float4*)&V[r0 + i][cB];
        float4 v1 = *(const float4*)&V[r0 + i][cB + 4];
        tmp[i][0] = 13.f * v0.x - 15.f * a2[i][0];
        tmp[i][1] = 13.f * v0.y - 15.f * a2[i][1];
        tmp[i][2] = 13.f * v0.z - 15.f * a2[i][2];
        tmp[i][3] = 13.f * v0.w - 15.f * a2[i][3];
        tmp[i][4] = 13.f * v1.x - 15.f * a2[i][4];
        tmp[i][5] = 13.f * v1.y - 15.f * a2[i][5];
        tmp[i][6] = 13.f * v1.z - 15.f * a2[i][6];
        tmp[i][7] = 13.f * v1.w - 15.f * a2[i][7];
      }
      __syncthreads();
      #pragma unroll
      for (int i = 0; i < 2; ++i) {
        *(float4*)&V[r0 + i][cB] = make_float4(a2[i][0], a2[i][1], a2[i][2], a2[i][3]);
        *(float4*)&V[r0 + i][cB + 4] = make_float4(a2[i][4], a2[i][5], a2[i][6], a2[i][7]);
      }
      __syncthreads();
      mm();  // P2
      #pragma unroll
      for (int i = 0; i < 2; ++i)
        #pragma unroll
        for (int j = 0; j < 8; ++j) tmp[i][j] += 7.f * a2[i][j];
      __syncthreads();
      #pragma unroll
      for (int i = 0; i < 2; ++i) {
        *(float4*)&V[r0 + i][cB] = make_float4(a2[i][0], a2[i][1], a2[i][2], a2[i][3]);
        *(float4*)&V[r0 + i][cB + 4] = make_float4(a2[i][4], a2[i][5], a2[i][6], a2[i][7]);
      }
      __syncthreads();
      mm();  // P3
      __syncthreads();
      #pragma unroll
      for (int i = 0; i < 2; ++i) {
        float o0 = 0.25f * (tmp[i][0] - a2[i][0]);
        float o1 = 0.25f * (tmp[i][1] - a2[i][1]);
        float o2 = 0.25f * (tmp[i][2] - a2[i][2]);
        float o3 = 0.25f * (tmp[i][3] - a2[i][3]);
        float o4 = 0.25f * (tmp[i][4] - a2[i][4]);
        float o5 = 0.25f * (tmp[i][5] - a2[i][5]);
        float o6 = 0.25f * (tmp[i][6] - a2[i][6]);
        float o7 = 0.25f * (tmp[i][7] - a2[i][7]);
        *(float4*)&V[r0 + i][cB] = make_float4(o0, o1, o2, o3);
        *(float4*)&V[r0 + i][cB + 4] = make_float4(o4, o5, o6, o7);
      }
      __syncthreads();
    }
  }
  // m2 = V @ kv3[z]
  const float* kp = kv3 + (long)z * NL * VF;
  for (int idx = tid; idx < NL * VF; idx += 512)
    X[idx >> 6][idx & 63] = kp[idx];
  __syncthreads();
  int rM = wv * 16 + (l >> 4) * 4;
  int cM = (l & 15) * 4;
  float am[4][4] = {};
  for (int k = 0; k < 128; ++k) {
    float4 b4 = *(const float4*)&X[k][cM];
    #pragma unroll
    for (int i = 0; i < 4; ++i) {
      float a = V[rM + i][k];
      am[i][0] += a * b4.x; am[i][1] += a * b4.y;
      am[i][2] += a * b4.z; am[i][3] += a * b4.w;
    }
  }
  float* mp = m2 + (long)z * NL * VF;
  #pragma unroll
  for (int i = 0; i < 4; ++i)
    *(float4*)&mp[(long)(rM + i) * VF + cM] =
        make_float4(am[i][0], am[i][1], am[i][2], am[i][3]);
}

// ---------------------------------------------------------------- kernel_1 + attn + merge
__global__ __launch_bounds__(256) void k_k1attn(
    const float* __restrict__ Eq, const float* __restrict__ kland,
    const float* __restrict__ possel, const float* __restrict__ m2,
    const float* __restrict__ proj, f16* __restrict__ merged)
{
  int zz = blockIdx.x; int z = zz / (S / 16); int st = zz % (S / 16);
  int b = z / H, h = z % H;
  int s0 = st * 16;
  __shared__ float ks[NL][68];
  __shared__ float ms[NL][64];
  __shared__ float eqs[16][68];
  __shared__ float P[16][132];
  int tid = threadIdx.x;
  for (int idx = tid; idx < NL * DF; idx += 256) {
    int rr = idx >> 6, d = idx & 63;
    ks[rr][d] = kland[((long)b * NL + rr) * DF + d];
    ms[rr][d] = m2[((long)z * NL + rr) * DF + d];
  }
  for (int idx = tid; idx < 16 * DF; idx += 256) {
    int rr = idx >> 6, d = idx & 63;
    eqs[rr][d] = Eq[((long)z * S + s0 + rr) * DF + d];
  }
  __syncthreads();
  int r = tid >> 4, li = tid & 15;
  const float* pp = possel + (long)h * NL * S;
  float vals[8]; float lmax = -INFINITY;
  #pragma unroll
  for (int jj = 0; jj < 8; jj++) {
    int lm = li + jj * 16;
    float s = 0.f;
    #pragma unroll
    for (int d = 0; d < DF; d += 4) {
      float4 e = *(const float4*)&eqs[r][d];
      float4 k4 = *(const float4*)&ks[lm][d];
      s += e.x * k4.x + e.y * k4.y + e.z * k4.z + e.w * k4.w;
    }
    s += pp[(long)lm * S + s0 + r];
    vals[jj] = s; lmax = fmaxf(lmax, s);
  }
  #pragma unroll
  for (int o = 8; o; o >>= 1) lmax = fmaxf(lmax, __shfl_xor(lmax, o));
  float ssum = 0.f;
  #pragma unroll
  for (int jj = 0; jj < 8; jj++) { vals[jj] = expf(vals[jj] - lmax); ssum += vals[jj]; }
  #pragma unroll
  for (int o = 8; o; o >>= 1) ssum += __shfl_xor(ssum, o);
  float inv = 1.f / ssum;
  #pragma unroll
  for (int jj = 0; jj < 8; jj++) P[r][li + jj * 16] = vals[jj] * inv;
  __syncthreads();
  float acc[4] = {};
  for (int lm = 0; lm < NL; lm++) {
    float p = P[r][lm];
    float4 m4 = *(const float4*)&ms[lm][li * 4];
    acc[0] += p * m4.x; acc[1] += p * m4.y; acc[2] += p * m4.z; acc[3] += p * m4.w;
  }
  long srow = (long)b * S + s0 + r;
  float4 pj = *(const float4*)&proj[srow * VF + li * 4];
  f16x4 h4;
  h4[0] = (f16)(acc[0] + pj.x); h4[1] = (f16)(acc[1] + pj.y);
  h4[2] = (f16)(acc[2] + pj.z); h4[3] = (f16)(acc[3] + pj.w);
  int r7 = (int)(srow & 7);
  long off = srow * (long)HV + h * 64 + (((li >> 1) ^ r7) << 3) + ((li & 1) << 2);
  *(f16x4*)&merged[off] = h4;
}

} // namespace

extern "C" void kernel_launch(void* const* d_in, const int* in_sizes, int n_in,
                              void* d_out, int out_size, void* d_ws, size_t ws_size,
                              hipStream_t stream)
{
  const float* lat   = (const float*)d_in[0];
  const float* masks = (const float*)d_in[1];
  const float* xemb  = (const float*)d_in[2];
  const float* ccls  = (const float*)d_in[4];
  const float* qlin  = (const float*)d_in[5];
  const float* klin  = (const float*)d_in[6];
  const float* vlin  = (const float*)d_in[7];
  const float* plin  = (const float*)d_in[8];
  const float* agg   = (const float*)d_in[9];
  const float* cfeat = (const float*)d_in[10];
  float* out = (float*)d_out;
  float* ws = (float*)d_ws;

  long off = 0;
  auto allocF = [&](long n) { float* p = ws + off; off += (n + 3) & ~3L; return p; };
  auto allocH = [&](long n) { f16* p = (f16*)(ws + off); off += ((n + 1) / 2 + 3) & ~3L; return p; };

  f16* origA = allocH(ROWS * KSF);
  f16* vbufA = allocH(ROWS * KSF);
  f16* merged = allocH(ROWS * (long)HV);
  f16* WQt = allocH(16L * 64 * KSF);
  f16* WKt = allocH(2L * 64 * KSF);
  f16* WVt = allocH(16L * 64 * KSF);
  f16* WPt = allocH(2L * 64 * KSF);
  f16* WCFt = allocH((long)KSF * 512);
  f16* WCCt = allocH(64L * 512);
  float* cl     = allocF(ROWS * HS);
  float* Eq     = allocF((long)B * H * S * DF);
  float* EkB    = allocF((long)B * S * DF);
  float* Ev     = allocF((long)B * H * S * DF);
  float* projb  = allocF((long)B * S * VF);
  float* qland  = allocF((long)B * H * NL * DF);
  float* kland  = allocF((long)B * NL * DF);
  float* possel = allocF((long)H * NL * S);
  float* possel2= allocF((long)H * NL * NL);
  float* k2b    = allocF((long)B * H * NL * NL);
  float* kv3    = allocF((long)B * H * NL * VF);
  float* m2b    = allocF((long)B * H * NL * VF);
  float* colmax = allocF(64);

  k_cl<<<(int)(ROWS / 4), 256, 0, stream>>>(lat, masks, cl);
  k_cvta<<<(int)(ROWS * 168 / 256), 256, 0, stream>>>(xemb, cl, origA);

  auto cvtw = [&](const float* src, f16* dst, int K, int N, int Npad, int KS, long srcZ, int nz) {
    long total = (long)nz * Npad * (KS / 8);
    k_cvtw<<<(int)((total + 255) / 256), 256, 0, stream>>>(src, dst, K, N, Npad, KS, srcZ, total);
  };
  cvtw(qlin, WQt, FEAT, 64, 64, KSF, (long)FEATP * 64, 16);
  cvtw(klin, WKt, FEAT, 64, 64, KSF, (long)FEATP * 64, 2);
  cvtw(vlin, WVt, FEAT, 64, 64, KSF, (long)FEATP * 64, 16);
  cvtw(plin, WPt, FEAT, 64, 64, KSF, (long)FEATP * 64, 2);
  cvtw(cfeat, WCFt, 512, FEAT, KSF, 512, 0, 1);
  cvtw(ccls, WCCt, 512, HS, 64, 512, 0, 1);

  const f16* Aact = origA;
  for (int layer = 0; layer < 2; ++layer) {
    const f16* wq = WQt + (long)layer * 8 * 64 * KSF;
    const f16* wk = WKt + (long)layer * 64 * KSF;
    const f16* wvv = WVt + (long)layer * 8 * 64 * KSF;
    const f16* wp = WPt + (long)layer * 64 * KSF;
    const float* bq = qlin + (long)layer * 8 * FEATP * 64 + (long)(FEATP - 2) * 64;
    const float* bk = klin + (long)layer * FEATP * 64 + (long)(FEATP - 2) * 64;
    const float* bv = vlin + (long)layer * 8 * FEATP * 64 + (long)(FEATP - 2) * 64;
    const float* bp = plin + (long)layer * FEATP * 64 + (long)(FEATP - 2) * 64;
    const float* ag = agg + layer * H;

    dim3 gQ(8, 1, 64), gK(8, 1, 8);
    k_mgemm<<<gQ, 256, 0, stream>>>(Aact, (long)S * KSF, 8, wq, 64L * KSF, 8, 21, 0,
        Eq, (long)S * 64, 64, bq, (long)FEATP * 64, INV_SCALE, nullptr, 64, nullptr);
    k_mgemm<<<gK, 256, 0, stream>>>(Aact, (long)S * KSF, 1, wk, 0, 1, 21, 0,
        EkB, (long)S * 64, 64, bk, 0, INV_SCALE, nullptr, 64, nullptr);
    k_mgemm<<<gQ, 256, 0, stream>>>(Aact, (long)S * KSF, 8, wvv, 64L * KSF, 8, 21, 0,
        Ev, (long)S * 64, 64, bv, (long)FEATP * 64, 1.0f, nullptr, 64, nullptr);
    k_mgemm<<<gK, 256, 0, stream>>>(origA, (long)S * KSF, 1, wp, 0, 1, 21, 0,
        projb, (long)S * 64, 64, bp, 0, 0.5f, nullptr, 64, nullptr);

    k_segmean<<<B * H * NL, 64, 0, stream>>>(Eq, qland);
    k_segmean<<<B * NL, 64, 0, stream>>>(EkB, kland);
    k_possel<<<H * NL, 256, 0, stream>>>(ag, possel);
    k_possel2<<<H * NL, 128, 0, stream>>>(possel, possel2);

    k_kernel2<<<B * H, 256, 0, stream>>>(qland, kland, possel2, k2b, colmax);
    k_kernel3<<<B * H * (NL / 8), 256, 0, stream>>>(qland, EkB, Ev, possel, masks, kv3);
    k_inverse<<<B * H, 512, 0, stream>>>(k2b, colmax, kv3, m2b);
    k_k1attn<<<B * H * (S / 16), 256, 0, stream>>>(Eq, kland, possel, m2b, projb, merged);

    if (layer == 0) {
      dim3 gC(64, 21, 1);
      k_mgemm<<<gC, 256, 0, stream>>>(merged, 0, 1, WCFt, 0, 1, 8, 1,
          nullptr, 0, 0, nullptr, 0, 1.0f, vbufA, FEAT, nullptr);
      Aact = vbufA;
    } else {
      dim3 gO(64, 1, 1);
      k_mgemm<<<gO, 256, 0, stream>>>(merged, 0, 1, WCCt, 0, 1, 8, 2,
          out, 0, HS, nullptr, 0, 1.0f, nullptr, HS, masks);
    }
  }
  (void)in_sizes; (void)n_in; (void)out_size; (void)ws_size;
}

// Round 3
// 1721.710 us; speedup vs baseline: 3.6302x; 1.4692x over previous
//
#include <hip/hip_runtime.h>
#include <math.h>

// ESMMimicryModule: B=8 S=2048 H=8 NL=128 DF=VF=64 NF=1280 HS=33 FEAT=1313
// Round 2: k_kernel3 rewritten as flash-style MFMA fp16 kernel (analytic pos
// term, XOR-swizzled LDS tiles, online softmax, P@V via mfma). Ev now fp16-only
// (mgemm mode 3), Ek dual fp32+fp16 (mode 4), qland dual via k_segmean.

namespace {

constexpr int B = 8, S = 2048, H = 8, NL = 128, DF = 64, VF = 64;
constexpr int NF = 1280, HS = 33, FEAT = 1313, FEATP = 1314;
constexpr int SEG = 16, HV = H * VF;            // 512
constexpr int KSF = 1344;                        // padded feature-K (21*64)
constexpr long ROWS = (long)B * S;               // 16384
constexpr float INV_SCALE = 0.35355339059327373f;

typedef _Float16 f16;
typedef _Float16 f16x8 __attribute__((ext_vector_type(8)));
typedef _Float16 f16x4 __attribute__((ext_vector_type(4)));
typedef float f32x4 __attribute__((ext_vector_type(4)));

// ---------------------------------------------------------------- cl = softmax(latent)*mask
__global__ __launch_bounds__(256) void k_cl(
    const float* __restrict__ lat, const float* __restrict__ masks,
    float* __restrict__ cl)
{
  long row = (long)blockIdx.x * 4 + (threadIdx.x >> 6);
  int l = threadIdx.x & 63;
  float v = (l < HS) ? lat[row * HS + l] : -INFINITY;
  float m = v;
  #pragma unroll
  for (int o = 32; o; o >>= 1) m = fmaxf(m, __shfl_xor(m, o));
  float e = (l < HS) ? expf(v - m) : 0.f;
  float s = e;
  #pragma unroll
  for (int o = 32; o; o >>= 1) s += __shfl_xor(s, o);
  if (l < HS) cl[row * HS + l] = e / s * masks[row];
}

// ---------------------------------------------------------------- origA fp16 arena (swizzled)
__global__ __launch_bounds__(256) void k_cvta(
    const float* __restrict__ xemb, const float* __restrict__ cl,
    f16* __restrict__ dst)
{
  long idx = (long)blockIdx.x * 256 + threadIdx.x;  // chunk id (row,c)
  long row = idx / 168;
  int c = (int)(idx - row * 168);
  int t = c >> 3, cs = c & 7;
  int cd = cs ^ ((int)row & 7);
  int k0 = t * 64 + cd * 8;
  f16x8 v;
  #pragma unroll
  for (int i = 0; i < 8; ++i) {
    int k = k0 + i;
    float f = 0.f;
    if (k < NF) f = xemb[row * NF + k];
    else if (k < FEAT) f = cl[row * HS + (k - NF)];
    v[i] = (f16)f;
  }
  *(f16x8*)&dst[idx * 8] = v;
}

// ---------------------------------------------------------------- weight -> Wt fp16 arena
__global__ __launch_bounds__(256) void k_cvtw(
    const float* __restrict__ src, f16* __restrict__ dst,
    int K, int N, int Npad, int KS, long srcZ, long total)
{
  long idx = (long)blockIdx.x * 256 + threadIdx.x;
  if (idx >= total) return;
  long cpz = (long)Npad * (KS >> 3);
  long z = idx / cpz;
  long rem = idx - z * cpz;
  int n = (int)(rem / (KS >> 3));
  int c = (int)(rem - (long)n * (KS >> 3));
  int t = c >> 3, cs = c & 7;
  int cd = cs ^ (n & 7);
  int k0 = t * 64 + cd * 8;
  const float* sp = src + z * srcZ;
  f16x8 v;
  #pragma unroll
  for (int i = 0; i < 8; ++i) {
    int k = k0 + i;
    v[i] = (f16)((k < K && n < N) ? sp[(long)k * N + n] : 0.f);
  }
  *(f16x8*)&dst[idx * 8] = v;
}

// ---------------------------------------------------------------- fp16 MFMA GEMM
// mode 0: fp32 C = (acc + bias)*scale
// mode 1: fp16 swizzled arena (KSF stride, zero-fill col>=NR)
// mode 2: fp32 out * mask, col<NR
// mode 3: fp16 row-major out (64 cols), (acc+bias)*scale
// mode 4: mode 0 fp32 + fp16 row-major copy
__global__ __launch_bounds__(256, 2) void k_mgemm(
    const f16* __restrict__ A, long aZOff, int aDiv,
    const f16* __restrict__ Wt, long wZOff, int wMod,
    int KT, int mode,
    float* __restrict__ C, long cZOff, int ldC,
    const float* __restrict__ biasBase, long biasZOff, float scale,
    f16* __restrict__ outA, int NR, const float* __restrict__ mask)
{
  const long KS = (long)KT * 64;
  int z = blockIdx.z;
  const f16* Ap = A + (long)(z / aDiv) * aZOff;
  const f16* Wp = Wt + (long)(z % wMod) * wZOff;
  long m0 = (long)blockIdx.x * 256;
  int n0 = blockIdx.y * 64;
  constexpr int BOFF = 256 * 64;
  __shared__ f16 lds[2][(256 + 64) * 64];
  int tid = threadIdx.x;
  int wv = tid >> 6, l = tid & 63;

  const f16* aW = Ap + (m0 + wv * 64 + (l >> 3)) * KS + (l & 7) * 8;
  const f16* bW = Wp + ((long)(n0 + wv * 16 + (l >> 3))) * KS + (l & 7) * 8;

  f32x4 acc[4][4];
  #pragma unroll
  for (int i = 0; i < 4; ++i)
    #pragma unroll
    for (int j = 0; j < 4; ++j) acc[i][j] = (f32x4){0.f, 0.f, 0.f, 0.f};

  auto stage = [&](int buf, int t) {
    f16* la = &lds[buf][(wv * 64) * 64];
    const f16* ga = aW + (long)t * 64;
    #pragma unroll
    for (int j = 0; j < 8; ++j)
      __builtin_amdgcn_global_load_lds(
          (const __attribute__((address_space(1))) void*)(ga + (long)j * 8 * KS),
          (__attribute__((address_space(3))) void*)(la + j * 8 * 64), 16, 0, 0);
    f16* lb = &lds[buf][BOFF + (wv * 16) * 64];
    const f16* gb = bW + (long)t * 64;
    #pragma unroll
    for (int j = 0; j < 2; ++j)
      __builtin_amdgcn_global_load_lds(
          (const __attribute__((address_space(1))) void*)(gb + (long)j * 8 * KS),
          (__attribute__((address_space(3))) void*)(lb + j * 8 * 64), 16, 0, 0);
  };

  stage(0, 0);
  int rA = (wv * 64 + (l & 15)) * 64;
  int rB = BOFF + (l & 15) * 64;
  int lc = l >> 4, lx = l & 7;
  for (int t = 0; t < KT; ++t) {
    int nb = t & 1;
    if (t + 1 < KT) {
      stage(nb ^ 1, t + 1);
      asm volatile("s_waitcnt vmcnt(10)" ::: "memory");
    } else {
      asm volatile("s_waitcnt vmcnt(0)" ::: "memory");
    }
    __syncthreads();
    const f16* base = &lds[nb][0];
    f16x8 af[4][2], bf[4][2];
    #pragma unroll
    for (int mi = 0; mi < 4; ++mi)
      #pragma unroll
      for (int kh = 0; kh < 2; ++kh)
        af[mi][kh] = *(const f16x8*)&base[rA + mi * 16 * 64 + (((kh * 4 + lc) ^ lx) << 3)];
    #pragma unroll
    for (int ni = 0; ni < 4; ++ni)
      #pragma unroll
      for (int kh = 0; kh < 2; ++kh)
        bf[ni][kh] = *(const f16x8*)&base[rB + ni * 16 * 64 + (((kh * 4 + lc) ^ lx) << 3)];
    #pragma unroll
    for (int mi = 0; mi < 4; ++mi)
      #pragma unroll
      for (int ni = 0; ni < 4; ++ni) {
        acc[mi][ni] = __builtin_amdgcn_mfma_f32_16x16x32_f16(af[mi][0], bf[ni][0], acc[mi][ni], 0, 0, 0);
        acc[mi][ni] = __builtin_amdgcn_mfma_f32_16x16x32_f16(af[mi][1], bf[ni][1], acc[mi][ni], 0, 0, 0);
      }
    __syncthreads();
  }

  int lr = (l >> 4) * 4;
  int lcn = l & 15;
  if (mode == 0) {
    float* Cp = C + (long)z * cZOff;
    const float* bp = biasBase ? biasBase + (long)(z % wMod) * biasZOff : nullptr;
    #pragma unroll
    for (int ni = 0; ni < 4; ++ni) {
      int col = n0 + ni * 16 + lcn;
      float bv = bp ? bp[col] : 0.f;
      #pragma unroll
      for (int mi = 0; mi < 4; ++mi) {
        long row = m0 + wv * 64 + mi * 16 + lr;
        #pragma unroll
        for (int r = 0; r < 4; ++r)
          Cp[(row + r) * (long)ldC + col] = (acc[mi][ni][r] + bv) * scale;
      }
    }
  } else if (mode == 1) {
    #pragma unroll
    for (int mi = 0; mi < 4; ++mi) {
      #pragma unroll
      for (int r = 0; r < 4; ++r) {
        long row = m0 + wv * 64 + mi * 16 + lr + r;
        int r7 = (int)row & 7;
        #pragma unroll
        for (int ni = 0; ni < 4; ++ni) {
          int col = n0 + ni * 16 + lcn;
          int tt = col >> 6, kk = col & 63;
          int cd = kk >> 3, wi = kk & 7;
          float v = (col < NR) ? acc[mi][ni][r] : 0.f;
          outA[row * KSF + tt * 64 + (((cd ^ r7)) << 3) + wi] = (f16)v;
        }
      }
    }
  } else if (mode == 2) {
    #pragma unroll
    for (int mi = 0; mi < 4; ++mi) {
      #pragma unroll
      for (int r = 0; r < 4; ++r) {
        long row = m0 + wv * 64 + mi * 16 + lr + r;
        float mv = mask[row];
        #pragma unroll
        for (int ni = 0; ni < 4; ++ni) {
          int col = n0 + ni * 16 + lcn;
          if (col < NR) C[row * (long)ldC + col] = acc[mi][ni][r] * mv;
        }
      }
    }
  } else {  // mode 3 / 4
    const float* bp = biasBase ? biasBase + (long)(z % wMod) * biasZOff : nullptr;
    f16* o16 = outA + (long)z * cZOff;
    float* Cp = C ? C + (long)z * cZOff : nullptr;
    #pragma unroll
    for (int ni = 0; ni < 4; ++ni) {
      int col = n0 + ni * 16 + lcn;
      float bv = bp ? bp[col] : 0.f;
      #pragma unroll
      for (int mi = 0; mi < 4; ++mi) {
        long row = m0 + wv * 64 + mi * 16 + lr;
        #pragma unroll
        for (int r = 0; r < 4; ++r) {
          float v = (acc[mi][ni][r] + bv) * scale;
          if (mode == 4) Cp[(row + r) * 64 + col] = v;
          o16[(row + r) * 64 + col] = (f16)v;
        }
      }
    }
  }
}

// ---------------------------------------------------------------- landmarks
__global__ void k_segmean(const float* __restrict__ in, float* __restrict__ out,
                          f16* __restrict__ out16)
{
  long zl = blockIdx.x;
  long z = zl / NL, lm = zl % NL;
  int d = threadIdx.x;
  const float* p = in + (z * S + lm * SEG) * (long)DF + d;
  float s = 0.f;
  #pragma unroll
  for (int i = 0; i < SEG; i++) s += p[(long)i * DF];
  float v = s * (1.f / SEG);
  out[(z * NL + lm) * (long)DF + d] = v;
  if (out16) out16[(z * NL + lm) * (long)DF + d] = (f16)v;
}

__global__ void k_possel(const float* __restrict__ agg, float* __restrict__ possel)
{
  int hl = blockIdx.x; int h = hl / NL; int lm = hl % NL;
  float sigma = fabsf(agg[h]) + 0.001f;
  int base = lm * SEG;
  for (int j = threadIdx.x; j < S; j += blockDim.x) {
    float s = 0.f;
    #pragma unroll
    for (int i = 0; i < SEG; i++) s += fabsf((float)(base + i - j));
    possel[((long)h * NL + lm) * S + j] = -sigma * s * (1.f / SEG);
  }
}

__global__ void k_possel2(const float* __restrict__ possel, float* __restrict__ possel2)
{
  int hl = blockIdx.x;
  for (int m = threadIdx.x; m < NL; m += blockDim.x) {
    const float* p = possel + (long)hl * S + m * SEG;
    float s = 0.f;
    #pragma unroll
    for (int i = 0; i < SEG; i++) s += p[i];
    possel2[(long)hl * NL + m] = s * (1.f / SEG);
  }
}

// ---------------------------------------------------------------- kernel_2
__global__ __launch_bounds__(256) void k_kernel2(
    const float* __restrict__ qland, const float* __restrict__ kland,
    const float* __restrict__ possel2, float* __restrict__ k2,
    float* __restrict__ colmax)
{
  int z = blockIdx.x; int b = z / H; int h = z % H;
  __shared__ float qs[NL][68];
  __shared__ float ks[NL][68];
  __shared__ float lg[NL][NL + 1];
  int tid = threadIdx.x;
  for (int idx = tid; idx < NL * DF; idx += 256) {
    int r = idx >> 6, d = idx & 63;
    qs[r][d] = qland[((long)z * NL + r) * DF + d];
    ks[r][d] = kland[((long)b * NL + r) * DF + d];
  }
  __syncthreads();
  int r = tid >> 1, half = tid & 1;
  const float* p2 = possel2 + ((long)h * NL + r) * NL;
  float lmax = -INFINITY;
  for (int c = 0; c < 64; c++) {
    int m = half * 64 + c;
    float s = 0.f;
    #pragma unroll
    for (int d = 0; d < DF; d += 4) {
      float4 q = *(const float4*)&qs[r][d];
      float4 k4 = *(const float4*)&ks[m][d];
      s += q.x * k4.x + q.y * k4.y + q.z * k4.z + q.w * k4.w;
    }
    s += p2[m];
    lg[r][m] = s;
    lmax = fmaxf(lmax, s);
  }
  lmax = fmaxf(lmax, __shfl_xor(lmax, 1));
  float lsum = 0.f;
  for (int c = 0; c < 64; c++) {
    int m = half * 64 + c;
    float e = expf(lg[r][m] - lmax);
    lg[r][m] = e; lsum += e;
  }
  lsum += __shfl_xor(lsum, 1);
  float inv = 1.f / lsum;
  for (int c = 0; c < 64; c++) {
    int m = half * 64 + c;
    float p = lg[r][m] * inv;
    lg[r][m] = p;
    k2[((long)z * NL + r) * NL + m] = p;
  }
  __syncthreads();
  float myc = 0.f;
  if (tid < NL) {
    for (int rr = 0; rr < NL; rr++) myc += lg[rr][tid];
  }
  float wm = myc;
  #pragma unroll
  for (int o = 32; o; o >>= 1) wm = fmaxf(wm, __shfl_xor(wm, o));
  __shared__ float wred[4];
  if ((tid & 63) == 0) wred[tid >> 6] = wm;
  __syncthreads();
  if (tid == 0)
    colmax[z] = fmaxf(fmaxf(wred[0], wred[1]), fmaxf(wred[2], wred[3]));
}

// ---------------------------------------------------------------- kernel_3 (flash MFMA)
// block = (b,h,half): 64 queries (landmarks), 4 waves x 16 queries.
// per 128-key tile: stage Ek[128][64], EvT[64][128] fp16 swizzled; QK^T mfma;
// analytic pos + mask; online softmax; P fp16 -> LDS; PV mfma. kv3 fp32.
__global__ __launch_bounds__(256, 2) void k_kernel3(
    const f16* __restrict__ qland16, const f16* __restrict__ Ek16,
    const f16* __restrict__ Ev16, const float* __restrict__ aggL,
    const float* __restrict__ masks, float* __restrict__ kv3)
{
  __shared__ __align__(16) f16 Qs[64 * 64];
  __shared__ __align__(16) f16 Ks[128 * 64];
  __shared__ __align__(16) f16 Vt[64 * 128];
  __shared__ __align__(16) f16 Pb[4 * 16 * 128];
  __shared__ float Ms[128];
  int z2 = blockIdx.x;
  int z = z2 >> 1, half = z2 & 1;
  int b = z >> 3, h = z & 7;
  int q0 = half * 64;
  int tid = threadIdx.x;
  int w = tid >> 6, l = tid & 63;
  float sigma = fabsf(aggL[h]) + 0.001f;
  float cpos = -sigma * (1.f / 16.f);

  // stage Q (64 x 64), swizzled
  for (int c = tid; c < 64 * 8; c += 256) {
    int q = c >> 3, kc = c & 7;
    f16x8 v = *(const f16x8*)&qland16[((long)z * NL + q0 + q) * 64 + kc * 8];
    *(f16x8*)&Qs[q * 64 + ((kc ^ (q & 7)) << 3)] = v;
  }

  f16* Pw = &Pb[w * 16 * 128];
  int l15 = l & 15, lg4 = l >> 4, l7 = l & 7;
  f32x4 Oa[4];
  #pragma unroll
  for (int i = 0; i < 4; ++i) Oa[i] = (f32x4){0.f, 0.f, 0.f, 0.f};
  float mrun[4] = {-INFINITY, -INFINITY, -INFINITY, -INFINITY};
  float lrun[4] = {0.f, 0.f, 0.f, 0.f};

  for (int t0 = 0; t0 < S / 128; ++t0) {
    __syncthreads();
    // stage Ek tile
    for (int c = tid; c < 1024; c += 256) {
      int k = c >> 3, kc = c & 7;
      f16x8 v = *(const f16x8*)&Ek16[((long)b * S + t0 * 128 + k) * 64 + kc * 8];
      *(f16x8*)&Ks[k * 64 + ((kc ^ (k & 7)) << 3)] = v;
    }
    // stage Ev tile transposed
    for (int c = tid; c < 1024; c += 256) {
      int k = c & 127, dc = c >> 7;
      f16x8 v = *(const f16x8*)&Ev16[((long)z * S + t0 * 128 + k) * 64 + dc * 8];
      int kc = k >> 3, ki = k & 7;
      #pragma unroll
      for (int j = 0; j < 8; ++j) {
        int d = dc * 8 + j;
        Vt[d * 128 + ((kc ^ (d & 7)) << 3) + ki] = v[j];
      }
    }
    if (tid < 128)
      Ms[tid] = (masks[(long)b * S + t0 * 128 + tid] == 0.f) ? -1e6f : 0.f;
    __syncthreads();

    // QK^T: 16 queries x 128 keys per wave
    f16x8 af[2];
    #pragma unroll
    for (int kh = 0; kh < 2; ++kh)
      af[kh] = *(const f16x8*)&Qs[(w * 16 + l15) * 64 + (((kh * 4 + lg4) ^ l7) << 3)];
    f32x4 sc[8];
    #pragma unroll
    for (int ct = 0; ct < 8; ++ct) {
      int n = ct * 16 + l15;
      f16x8 b0 = *(const f16x8*)&Ks[n * 64 + (((lg4) ^ (n & 7)) << 3)];
      f16x8 b1 = *(const f16x8*)&Ks[n * 64 + (((4 + lg4) ^ (n & 7)) << 3)];
      f32x4 zz = (f32x4){0.f, 0.f, 0.f, 0.f};
      zz = __builtin_amdgcn_mfma_f32_16x16x32_f16(af[0], b0, zz, 0, 0, 0);
      sc[ct] = __builtin_amdgcn_mfma_f32_16x16x32_f16(af[1], b1, zz, 0, 0, 0);
    }
    // pos + mask, row maxima
    float tmax[4] = {-INFINITY, -INFINITY, -INFINITY, -INFINITY};
    #pragma unroll
    for (int ct = 0; ct < 8; ++ct) {
      float mk = Ms[ct * 16 + l15];
      int key = t0 * 128 + ct * 16 + l15;
      #pragma unroll
      for (int r = 0; r < 4; ++r) {
        int qg = q0 + w * 16 + lg4 * 4 + r;
        float a = (float)(key - 16 * qg);
        float ac = fminf(fmaxf(a, 0.f), 15.f);
        float dd = fabsf(a - ac);
        float sum = ac * ac - 15.f * ac + 120.f + 16.f * dd;
        float s = sc[ct][r] + cpos * sum + mk;
        sc[ct][r] = s;
        tmax[r] = fmaxf(tmax[r], s);
      }
    }
    #pragma unroll
    for (int r = 0; r < 4; ++r) {
      #pragma unroll
      for (int o = 1; o < 16; o <<= 1)
        tmax[r] = fmaxf(tmax[r], __shfl_xor(tmax[r], o));
    }
    float fr[4], lsum[4];
    #pragma unroll
    for (int r = 0; r < 4; ++r) {
      float mnew = fmaxf(mrun[r], tmax[r]);
      fr[r] = expf(mrun[r] - mnew);
      mrun[r] = mnew;
      lsum[r] = 0.f;
    }
    #pragma unroll
    for (int ct = 0; ct < 8; ++ct) {
      #pragma unroll
      for (int r = 0; r < 4; ++r) {
        float p = expf(sc[ct][r] - mrun[r]);
        sc[ct][r] = p;
        lsum[r] += p;
      }
    }
    #pragma unroll
    for (int r = 0; r < 4; ++r) {
      #pragma unroll
      for (int o = 1; o < 16; o <<= 1)
        lsum[r] += __shfl_xor(lsum[r], o);
      lrun[r] = lrun[r] * fr[r] + lsum[r];
    }
    f32x4 fv = (f32x4){fr[0], fr[1], fr[2], fr[3]};
    #pragma unroll
    for (int dt = 0; dt < 4; ++dt) Oa[dt] *= fv;
    // write P (fp16, swizzled) to wave-private LDS
    #pragma unroll
    for (int ct = 0; ct < 8; ++ct) {
      int kc = ct * 2 + (l15 >> 3);
      int ki = l15 & 7;
      #pragma unroll
      for (int r = 0; r < 4; ++r) {
        int row = lg4 * 4 + r;
        Pw[row * 128 + ((kc ^ (row & 7)) << 3) + ki] = (f16)sc[ct][r];
      }
    }
    // PV
    #pragma unroll
    for (int ks = 0; ks < 4; ++ks) {
      f16x8 pa = *(const f16x8*)&Pw[l15 * 128 + (((ks * 4 + lg4) ^ l7) << 3)];
      #pragma unroll
      for (int dt = 0; dt < 4; ++dt) {
        int n = dt * 16 + l15;
        f16x8 bv = *(const f16x8*)&Vt[n * 128 + (((ks * 4 + lg4) ^ (n & 7)) << 3)];
        Oa[dt] = __builtin_amdgcn_mfma_f32_16x16x32_f16(pa, bv, Oa[dt], 0, 0, 0);
      }
    }
  }
  // epilogue: divide by lrun, write kv3 fp32
  #pragma unroll
  for (int r = 0; r < 4; ++r) {
    float inv = 1.f / lrun[r];
    long qg = q0 + w * 16 + lg4 * 4 + r;
    #pragma unroll
    for (int dt = 0; dt < 4; ++dt)
      kv3[((long)z * NL + qg) * VF + dt * 16 + l15] = Oa[dt][r] * inv;
  }
}

// ---------------------------------------------------------------- inverse
__global__ __launch_bounds__(512) void k_inverse(
    const float* __restrict__ k2g, const float* __restrict__ colmax,
    const float* __restrict__ kv3, float* __restrict__ m2)
{
  __shared__ float V[128][132];
  __shared__ float X[128][132];
  int z = blockIdx.x;
  int tid = threadIdx.x;
  int wv = tid >> 6, l = tid & 63;
  float gmax = colmax[0];
  for (int i = 1; i < 64; ++i) gmax = fmaxf(gmax, colmax[i]);
  float recip = 1.f / gmax;
  const float* key = k2g + (long)z * NL * NL;
  for (int idx = tid; idx < NL * NL; idx += 512) {
    int r = idx >> 7, c = idx & 127;
    V[c][r] = recip * key[idx];
  }
  __syncthreads();
  int rA1 = wv * 16 + (l >> 4) * 4;
  int cB = (l & 15) * 8;
  for (int it = 0; it < 6; ++it) {
    float acc[4][8];
    #pragma unroll
    for (int i = 0; i < 4; ++i)
      #pragma unroll
      for (int j = 0; j < 8; ++j) acc[i][j] = 0.f;
    for (int k4 = 0; k4 < 128; k4 += 4) {
      float4 a4[4];
      #pragma unroll
      for (int i = 0; i < 4; ++i)
        a4[i] = *(const float4*)&key[(long)(rA1 + i) * 128 + k4];
      #pragma unroll
      for (int kk = 0; kk < 4; ++kk) {
        float bb[8];
        *(float4*)&bb[0] = *(const float4*)&V[k4 + kk][cB];
        *(float4*)&bb[4] = *(const float4*)&V[k4 + kk][cB + 4];
        #pragma unroll
        for (int i = 0; i < 4; ++i) {
          float a = ((const float*)&a4[i])[kk];
          #pragma unroll
          for (int j = 0; j < 8; ++j) acc[i][j] += a * bb[j];
        }
      }
    }
    #pragma unroll
    for (int i = 0; i < 4; ++i) {
      *(float4*)&X[rA1 + i][cB] = make_float4(acc[i][0], acc[i][1], acc[i][2], acc[i][3]);
      *(float4*)&X[rA1 + i][cB + 4] = make_float4(acc[i][4], acc[i][5], acc[i][6], acc[i][7]);
    }
    __syncthreads();
    for (int hb = 0; hb < 2; ++hb) {
      int r0 = hb * 64 + wv * 8 + (l >> 4) * 2;
      float a2[2][8], tmp[2][8];
      auto mm = [&]() {
        #pragma unroll
        for (int i = 0; i < 2; ++i)
          #pragma unroll
          for (int j = 0; j < 8; ++j) a2[i][j] = 0.f;
        for (int k = 0; k < 128; ++k) {
          float bb[8];
          *(float4*)&bb[0] = *(const float4*)&X[k][cB];
          *(float4*)&bb[4] = *(const float4*)&X[k][cB + 4];
          float av0 = V[r0][k], av1 = V[r0 + 1][k];
          #pragma unroll
          for (int j = 0; j < 8; ++j) {
            a2[0][j] += av0 * bb[j];
            a2[1][j] += av1 * bb[j];
          }
        }
      };
      mm();
      #pragma unroll
      for (int i = 0; i < 2; ++i) {
        float4 v0 = *(const float4*)&V[r0 + i][cB];
        float4 v1 = *(const float4*)&V[r0 + i][cB + 4];
        tmp[i][0] = 13.f * v0.x - 15.f * a2[i][0];
        tmp[i][1] = 13.f * v0.y - 15.f * a2[i][1];
        tmp[i][2] = 13.f * v0.z - 15.f * a2[i][2];
        tmp[i][3] = 13.f * v0.w - 15.f * a2[i][3];
        tmp[i][4] = 13.f * v1.x - 15.f * a2[i][4];
        tmp[i][5] = 13.f * v1.y - 15.f * a2[i][5];
        tmp[i][6] = 13.f * v1.z - 15.f * a2[i][6];
        tmp[i][7] = 13.f * v1.w - 15.f * a2[i][7];
      }
      __syncthreads();
      #pragma unroll
      for (int i = 0; i < 2; ++i) {
        *(float4*)&V[r0 + i][cB] = make_float4(a2[i][0], a2[i][1], a2[i][2], a2[i][3]);
        *(float4*)&V[r0 + i][cB + 4] = make_float4(a2[i][4], a2[i][5], a2[i][6], a2[i][7]);
      }
      __syncthreads();
      mm();
      #pragma unroll
      for (int i = 0; i < 2; ++i)
        #pragma unroll
        for (int j = 0; j < 8; ++j) tmp[i][j] += 7.f * a2[i][j];
      __syncthreads();
      #pragma unroll
      for (int i = 0; i < 2; ++i) {
        *(float4*)&V[r0 + i][cB] = make_float4(a2[i][0], a2[i][1], a2[i][2], a2[i][3]);
        *(float4*)&V[r0 + i][cB + 4] = make_float4(a2[i][4], a2[i][5], a2[i][6], a2[i][7]);
      }
      __syncthreads();
      mm();
      __syncthreads();
      #pragma unroll
      for (int i = 0; i < 2; ++i) {
        float o0 = 0.25f * (tmp[i][0] - a2[i][0]);
        float o1 = 0.25f * (tmp[i][1] - a2[i][1]);
        float o2 = 0.25f * (tmp[i][2] - a2[i][2]);
        float o3 = 0.25f * (tmp[i][3] - a2[i][3]);
        float o4 = 0.25f * (tmp[i][4] - a2[i][4]);
        float o5 = 0.25f * (tmp[i][5] - a2[i][5]);
        float o6 = 0.25f * (tmp[i][6] - a2[i][6]);
        float o7 = 0.25f * (tmp[i][7] - a2[i][7]);
        *(float4*)&V[r0 + i][cB] = make_float4(o0, o1, o2, o3);
        *(float4*)&V[r0 + i][cB + 4] = make_float4(o4, o5, o6, o7);
      }
      __syncthreads();
    }
  }
  const float* kp = kv3 + (long)z * NL * VF;
  for (int idx = tid; idx < NL * VF; idx += 512)
    X[idx >> 6][idx & 63] = kp[idx];
  __syncthreads();
  int rM = wv * 16 + (l >> 4) * 4;
  int cM = (l & 15) * 4;
  float am[4][4] = {};
  for (int k = 0; k < 128; ++k) {
    float4 b4 = *(const float4*)&X[k][cM];
    #pragma unroll
    for (int i = 0; i < 4; ++i) {
      float a = V[rM + i][k];
      am[i][0] += a * b4.x; am[i][1] += a * b4.y;
      am[i][2] += a * b4.z; am[i][3] += a * b4.w;
    }
  }
  float* mp = m2 + (long)z * NL * VF;
  #pragma unroll
  for (int i = 0; i < 4; ++i)
    *(float4*)&mp[(long)(rM + i) * VF + cM] =
        make_float4(am[i][0], am[i][1], am[i][2], am[i][3]);
}

// ---------------------------------------------------------------- kernel_1 + attn + merge
__global__ __launch_bounds__(256) void k_k1attn(
    const float* __restrict__ Eq, const float* __restrict__ kland,
    const float* __restrict__ possel, const float* __restrict__ m2,
    const float* __restrict__ proj, f16* __restrict__ merged)
{
  int zz = blockIdx.x; int z = zz / (S / 16); int st = zz % (S / 16);
  int b = z / H, h = z % H;
  int s0 = st * 16;
  __shared__ float ks[NL][68];
  __shared__ float ms[NL][64];
  __shared__ float eqs[16][68];
  __shared__ float P[16][132];
  int tid = threadIdx.x;
  for (int idx = tid; idx < NL * DF; idx += 256) {
    int rr = idx >> 6, d = idx & 63;
    ks[rr][d] = kland[((long)b * NL + rr) * DF + d];
    ms[rr][d] = m2[((long)z * NL + rr) * DF + d];
  }
  for (int idx = tid; idx < 16 * DF; idx += 256) {
    int rr = idx >> 6, d = idx & 63;
    eqs[rr][d] = Eq[((long)z * S + s0 + rr) * DF + d];
  }
  __syncthreads();
  int r = tid >> 4, li = tid & 15;
  const float* pp = possel + (long)h * NL * S;
  float vals[8]; float lmax = -INFINITY;
  #pragma unroll
  for (int jj = 0; jj < 8; jj++) {
    int lm = li + jj * 16;
    float s = 0.f;
    #pragma unroll
    for (int d = 0; d < DF; d += 4) {
      float4 e = *(const float4*)&eqs[r][d];
      float4 k4 = *(const float4*)&ks[lm][d];
      s += e.x * k4.x + e.y * k4.y + e.z * k4.z + e.w * k4.w;
    }
    s += pp[(long)lm * S + s0 + r];
    vals[jj] = s; lmax = fmaxf(lmax, s);
  }
  #pragma unroll
  for (int o = 8; o; o >>= 1) lmax = fmaxf(lmax, __shfl_xor(lmax, o));
  float ssum = 0.f;
  #pragma unroll
  for (int jj = 0; jj < 8; jj++) { vals[jj] = expf(vals[jj] - lmax); ssum += vals[jj]; }
  #pragma unroll
  for (int o = 8; o; o >>= 1) ssum += __shfl_xor(ssum, o);
  float inv = 1.f / ssum;
  #pragma unroll
  for (int jj = 0; jj < 8; jj++) P[r][li + jj * 16] = vals[jj] * inv;
  __syncthreads();
  float acc[4] = {};
  for (int lm = 0; lm < NL; lm++) {
    float p = P[r][lm];
    float4 m4 = *(const float4*)&ms[lm][li * 4];
    acc[0] += p * m4.x; acc[1] += p * m4.y; acc[2] += p * m4.z; acc[3] += p * m4.w;
  }
  long srow = (long)b * S + s0 + r;
  float4 pj = *(const float4*)&proj[srow * VF + li * 4];
  f16x4 h4;
  h4[0] = (f16)(acc[0] + pj.x); h4[1] = (f16)(acc[1] + pj.y);
  h4[2] = (f16)(acc[2] + pj.z); h4[3] = (f16)(acc[3] + pj.w);
  int r7 = (int)(srow & 7);
  long off = srow * (long)HV + h * 64 + (((li >> 1) ^ r7) << 3) + ((li & 1) << 2);
  *(f16x4*)&merged[off] = h4;
}

} // namespace

extern "C" void kernel_launch(void* const* d_in, const int* in_sizes, int n_in,
                              void* d_out, int out_size, void* d_ws, size_t ws_size,
                              hipStream_t stream)
{
  const float* lat   = (const float*)d_in[0];
  const float* masks = (const float*)d_in[1];
  const float* xemb  = (const float*)d_in[2];
  const float* ccls  = (const float*)d_in[4];
  const float* qlin  = (const float*)d_in[5];
  const float* klin  = (const float*)d_in[6];
  const float* vlin  = (const float*)d_in[7];
  const float* plin  = (const float*)d_in[8];
  const float* agg   = (const float*)d_in[9];
  const float* cfeat = (const float*)d_in[10];
  float* out = (float*)d_out;
  float* ws = (float*)d_ws;

  long off = 0;
  auto allocF = [&](long n) { float* p = ws + off; off += (n + 3) & ~3L; return p; };
  auto allocH = [&](long n) { f16* p = (f16*)(ws + off); off += ((n + 1) / 2 + 3) & ~3L; return p; };

  f16* origA = allocH(ROWS * KSF);
  f16* vbufA = allocH(ROWS * KSF);
  f16* merged = allocH(ROWS * (long)HV);
  f16* WQt = allocH(16L * 64 * KSF);
  f16* WKt = allocH(2L * 64 * KSF);
  f16* WVt = allocH(16L * 64 * KSF);
  f16* WPt = allocH(2L * 64 * KSF);
  f16* WCFt = allocH((long)KSF * 512);
  f16* WCCt = allocH(64L * 512);
  f16* Ek16 = allocH((long)B * S * 64);
  f16* Ev16 = allocH((long)B * H * S * 64);
  f16* qland16 = allocH((long)B * H * NL * DF);
  float* cl     = allocF(ROWS * HS);
  float* Eq     = allocF((long)B * H * S * DF);
  float* EkB    = allocF((long)B * S * DF);
  float* projb  = allocF((long)B * S * VF);
  float* qland  = allocF((long)B * H * NL * DF);
  float* kland  = allocF((long)B * NL * DF);
  float* possel = allocF((long)H * NL * S);
  float* possel2= allocF((long)H * NL * NL);
  float* k2b    = allocF((long)B * H * NL * NL);
  float* kv3    = allocF((long)B * H * NL * VF);
  float* m2b    = allocF((long)B * H * NL * VF);
  float* colmax = allocF(64);

  k_cl<<<(int)(ROWS / 4), 256, 0, stream>>>(lat, masks, cl);
  k_cvta<<<(int)(ROWS * 168 / 256), 256, 0, stream>>>(xemb, cl, origA);

  auto cvtw = [&](const float* src, f16* dst, int K, int N, int Npad, int KS, long srcZ, int nz) {
    long total = (long)nz * Npad * (KS / 8);
    k_cvtw<<<(int)((total + 255) / 256), 256, 0, stream>>>(src, dst, K, N, Npad, KS, srcZ, total);
  };
  cvtw(qlin, WQt, FEAT, 64, 64, KSF, (long)FEATP * 64, 16);
  cvtw(klin, WKt, FEAT, 64, 64, KSF, (long)FEATP * 64, 2);
  cvtw(vlin, WVt, FEAT, 64, 64, KSF, (long)FEATP * 64, 16);
  cvtw(plin, WPt, FEAT, 64, 64, KSF, (long)FEATP * 64, 2);
  cvtw(cfeat, WCFt, 512, FEAT, KSF, 512, 0, 1);
  cvtw(ccls, WCCt, 512, HS, 64, 512, 0, 1);

  const f16* Aact = origA;
  for (int layer = 0; layer < 2; ++layer) {
    const f16* wq = WQt + (long)layer * 8 * 64 * KSF;
    const f16* wk = WKt + (long)layer * 64 * KSF;
    const f16* wvv = WVt + (long)layer * 8 * 64 * KSF;
    const f16* wp = WPt + (long)layer * 64 * KSF;
    const float* bq = qlin + (long)layer * 8 * FEATP * 64 + (long)(FEATP - 2) * 64;
    const float* bk = klin + (long)layer * FEATP * 64 + (long)(FEATP - 2) * 64;
    const float* bv = vlin + (long)layer * 8 * FEATP * 64 + (long)(FEATP - 2) * 64;
    const float* bp = plin + (long)layer * FEATP * 64 + (long)(FEATP - 2) * 64;
    const float* ag = agg + layer * H;

    dim3 gQ(8, 1, 64), gK(8, 1, 8);
    k_mgemm<<<gQ, 256, 0, stream>>>(Aact, (long)S * KSF, 8, wq, 64L * KSF, 8, 21, 0,
        Eq, (long)S * 64, 64, bq, (long)FEATP * 64, INV_SCALE, nullptr, 64, nullptr);
    k_mgemm<<<gK, 256, 0, stream>>>(Aact, (long)S * KSF, 1, wk, 0, 1, 21, 4,
        EkB, (long)S * 64, 64, bk, 0, INV_SCALE, Ek16, 64, nullptr);
    k_mgemm<<<gQ, 256, 0, stream>>>(Aact, (long)S * KSF, 8, wvv, 64L * KSF, 8, 21, 3,
        nullptr, (long)S * 64, 64, bv, (long)FEATP * 64, 1.0f, Ev16, 64, nullptr);
    k_mgemm<<<gK, 256, 0, stream>>>(origA, (long)S * KSF, 1, wp, 0, 1, 21, 0,
        projb, (long)S * 64, 64, bp, 0, 0.5f, nullptr, 64, nullptr);

    k_segmean<<<B * H * NL, 64, 0, stream>>>(Eq, qland, qland16);
    k_segmean<<<B * NL, 64, 0, stream>>>(EkB, kland, nullptr);
    k_possel<<<H * NL, 256, 0, stream>>>(ag, possel);
    k_possel2<<<H * NL, 128, 0, stream>>>(possel, possel2);

    k_kernel2<<<B * H, 256, 0, stream>>>(qland, kland, possel2, k2b, colmax);
    k_kernel3<<<B * H * 2, 256, 0, stream>>>(qland16, Ek16, Ev16, ag, masks, kv3);
    k_inverse<<<B * H, 512, 0, stream>>>(k2b, colmax, kv3, m2b);
    k_k1attn<<<B * H * (S / 16), 256, 0, stream>>>(Eq, kland, possel, m2b, projb, merged);

    if (layer == 0) {
      dim3 gC(64, 21, 1);
      k_mgemm<<<gC, 256, 0, stream>>>(merged, 0, 1, WCFt, 0, 1, 8, 1,
          nullptr, 0, 0, nullptr, 0, 1.0f, vbufA, FEAT, nullptr);
      Aact = vbufA;
    } else {
      dim3 gO(64, 1, 1);
      k_mgemm<<<gO, 256, 0, stream>>>(merged, 0, 1, WCCt, 0, 1, 8, 2,
          out, 0, HS, nullptr, 0, 1.0f, nullptr, HS, masks);
    }
  }
  (void)in_sizes; (void)n_in; (void)out_size; (void)ws_size;
}

// Round 4
// 1160.535 us; speedup vs baseline: 5.3855x; 1.4835x over previous
//
#include <hip/hip_runtime.h>
#include <math.h>

// ESMMimicryModule: B=8 S=2048 H=8 NL=128 DF=VF=64 NF=1280 HS=33 FEAT=1313
// Round 3: k_inverse rewritten as fp16 MFMA Newton-Schulz. All affine terms
// folded into B-fragment prep (Y1=X@(7I-X), Y3=X@(15I-Y1), V=V@(3.25I-.25Y3));
// dual normal/transposed swizzled fp16 LDS images (Vn/Vt/Pn/Pt, 128KB);
// key A-fragments pinned in registers across all 6 iterations.

namespace {

constexpr int B = 8, S = 2048, H = 8, NL = 128, DF = 64, VF = 64;
constexpr int NF = 1280, HS = 33, FEAT = 1313, FEATP = 1314;
constexpr int SEG = 16, HV = H * VF;            // 512
constexpr int KSF = 1344;                        // padded feature-K (21*64)
constexpr long ROWS = (long)B * S;               // 16384
constexpr float INV_SCALE = 0.35355339059327373f;

typedef _Float16 f16;
typedef _Float16 f16x8 __attribute__((ext_vector_type(8)));
typedef _Float16 f16x4 __attribute__((ext_vector_type(4)));
typedef float f32x4 __attribute__((ext_vector_type(4)));

// ---------------------------------------------------------------- cl = softmax(latent)*mask
__global__ __launch_bounds__(256) void k_cl(
    const float* __restrict__ lat, const float* __restrict__ masks,
    float* __restrict__ cl)
{
  long row = (long)blockIdx.x * 4 + (threadIdx.x >> 6);
  int l = threadIdx.x & 63;
  float v = (l < HS) ? lat[row * HS + l] : -INFINITY;
  float m = v;
  #pragma unroll
  for (int o = 32; o; o >>= 1) m = fmaxf(m, __shfl_xor(m, o));
  float e = (l < HS) ? expf(v - m) : 0.f;
  float s = e;
  #pragma unroll
  for (int o = 32; o; o >>= 1) s += __shfl_xor(s, o);
  if (l < HS) cl[row * HS + l] = e / s * masks[row];
}

// ---------------------------------------------------------------- origA fp16 arena (swizzled)
__global__ __launch_bounds__(256) void k_cvta(
    const float* __restrict__ xemb, const float* __restrict__ cl,
    f16* __restrict__ dst)
{
  long idx = (long)blockIdx.x * 256 + threadIdx.x;  // chunk id (row,c)
  long row = idx / 168;
  int c = (int)(idx - row * 168);
  int t = c >> 3, cs = c & 7;
  int cd = cs ^ ((int)row & 7);
  int k0 = t * 64 + cd * 8;
  f16x8 v;
  #pragma unroll
  for (int i = 0; i < 8; ++i) {
    int k = k0 + i;
    float f = 0.f;
    if (k < NF) f = xemb[row * NF + k];
    else if (k < FEAT) f = cl[row * HS + (k - NF)];
    v[i] = (f16)f;
  }
  *(f16x8*)&dst[idx * 8] = v;
}

// ---------------------------------------------------------------- weight -> Wt fp16 arena
__global__ __launch_bounds__(256) void k_cvtw(
    const float* __restrict__ src, f16* __restrict__ dst,
    int K, int N, int Npad, int KS, long srcZ, long total)
{
  long idx = (long)blockIdx.x * 256 + threadIdx.x;
  if (idx >= total) return;
  long cpz = (long)Npad * (KS >> 3);
  long z = idx / cpz;
  long rem = idx - z * cpz;
  int n = (int)(rem / (KS >> 3));
  int c = (int)(rem - (long)n * (KS >> 3));
  int t = c >> 3, cs = c & 7;
  int cd = cs ^ (n & 7);
  int k0 = t * 64 + cd * 8;
  const float* sp = src + z * srcZ;
  f16x8 v;
  #pragma unroll
  for (int i = 0; i < 8; ++i) {
    int k = k0 + i;
    v[i] = (f16)((k < K && n < N) ? sp[(long)k * N + n] : 0.f);
  }
  *(f16x8*)&dst[idx * 8] = v;
}

// ---------------------------------------------------------------- fp16 MFMA GEMM
// mode 0: fp32 C = (acc + bias)*scale
// mode 1: fp16 swizzled arena (KSF stride, zero-fill col>=NR)
// mode 2: fp32 out * mask, col<NR
// mode 3: fp16 row-major out (64 cols), (acc+bias)*scale
// mode 4: mode 0 fp32 + fp16 row-major copy
__global__ __launch_bounds__(256, 2) void k_mgemm(
    const f16* __restrict__ A, long aZOff, int aDiv,
    const f16* __restrict__ Wt, long wZOff, int wMod,
    int KT, int mode,
    float* __restrict__ C, long cZOff, int ldC,
    const float* __restrict__ biasBase, long biasZOff, float scale,
    f16* __restrict__ outA, int NR, const float* __restrict__ mask)
{
  const long KS = (long)KT * 64;
  int z = blockIdx.z;
  const f16* Ap = A + (long)(z / aDiv) * aZOff;
  const f16* Wp = Wt + (long)(z % wMod) * wZOff;
  long m0 = (long)blockIdx.x * 256;
  int n0 = blockIdx.y * 64;
  constexpr int BOFF = 256 * 64;
  __shared__ f16 lds[2][(256 + 64) * 64];
  int tid = threadIdx.x;
  int wv = tid >> 6, l = tid & 63;

  const f16* aW = Ap + (m0 + wv * 64 + (l >> 3)) * KS + (l & 7) * 8;
  const f16* bW = Wp + ((long)(n0 + wv * 16 + (l >> 3))) * KS + (l & 7) * 8;

  f32x4 acc[4][4];
  #pragma unroll
  for (int i = 0; i < 4; ++i)
    #pragma unroll
    for (int j = 0; j < 4; ++j) acc[i][j] = (f32x4){0.f, 0.f, 0.f, 0.f};

  auto stage = [&](int buf, int t) {
    f16* la = &lds[buf][(wv * 64) * 64];
    const f16* ga = aW + (long)t * 64;
    #pragma unroll
    for (int j = 0; j < 8; ++j)
      __builtin_amdgcn_global_load_lds(
          (const __attribute__((address_space(1))) void*)(ga + (long)j * 8 * KS),
          (__attribute__((address_space(3))) void*)(la + j * 8 * 64), 16, 0, 0);
    f16* lb = &lds[buf][BOFF + (wv * 16) * 64];
    const f16* gb = bW + (long)t * 64;
    #pragma unroll
    for (int j = 0; j < 2; ++j)
      __builtin_amdgcn_global_load_lds(
          (const __attribute__((address_space(1))) void*)(gb + (long)j * 8 * KS),
          (__attribute__((address_space(3))) void*)(lb + j * 8 * 64), 16, 0, 0);
  };

  stage(0, 0);
  int rA = (wv * 64 + (l & 15)) * 64;
  int rB = BOFF + (l & 15) * 64;
  int lc = l >> 4, lx = l & 7;
  for (int t = 0; t < KT; ++t) {
    int nb = t & 1;
    if (t + 1 < KT) {
      stage(nb ^ 1, t + 1);
      asm volatile("s_waitcnt vmcnt(10)" ::: "memory");
    } else {
      asm volatile("s_waitcnt vmcnt(0)" ::: "memory");
    }
    __syncthreads();
    const f16* base = &lds[nb][0];
    f16x8 af[4][2], bf[4][2];
    #pragma unroll
    for (int mi = 0; mi < 4; ++mi)
      #pragma unroll
      for (int kh = 0; kh < 2; ++kh)
        af[mi][kh] = *(const f16x8*)&base[rA + mi * 16 * 64 + (((kh * 4 + lc) ^ lx) << 3)];
    #pragma unroll
    for (int ni = 0; ni < 4; ++ni)
      #pragma unroll
      for (int kh = 0; kh < 2; ++kh)
        bf[ni][kh] = *(const f16x8*)&base[rB + ni * 16 * 64 + (((kh * 4 + lc) ^ lx) << 3)];
    #pragma unroll
    for (int mi = 0; mi < 4; ++mi)
      #pragma unroll
      for (int ni = 0; ni < 4; ++ni) {
        acc[mi][ni] = __builtin_amdgcn_mfma_f32_16x16x32_f16(af[mi][0], bf[ni][0], acc[mi][ni], 0, 0, 0);
        acc[mi][ni] = __builtin_amdgcn_mfma_f32_16x16x32_f16(af[mi][1], bf[ni][1], acc[mi][ni], 0, 0, 0);
      }
    __syncthreads();
  }

  int lr = (l >> 4) * 4;
  int lcn = l & 15;
  if (mode == 0) {
    float* Cp = C + (long)z * cZOff;
    const float* bp = biasBase ? biasBase + (long)(z % wMod) * biasZOff : nullptr;
    #pragma unroll
    for (int ni = 0; ni < 4; ++ni) {
      int col = n0 + ni * 16 + lcn;
      float bv = bp ? bp[col] : 0.f;
      #pragma unroll
      for (int mi = 0; mi < 4; ++mi) {
        long row = m0 + wv * 64 + mi * 16 + lr;
        #pragma unroll
        for (int r = 0; r < 4; ++r)
          Cp[(row + r) * (long)ldC + col] = (acc[mi][ni][r] + bv) * scale;
      }
    }
  } else if (mode == 1) {
    #pragma unroll
    for (int mi = 0; mi < 4; ++mi) {
      #pragma unroll
      for (int r = 0; r < 4; ++r) {
        long row = m0 + wv * 64 + mi * 16 + lr + r;
        int r7 = (int)row & 7;
        #pragma unroll
        for (int ni = 0; ni < 4; ++ni) {
          int col = n0 + ni * 16 + lcn;
          int tt = col >> 6, kk = col & 63;
          int cd = kk >> 3, wi = kk & 7;
          float v = (col < NR) ? acc[mi][ni][r] : 0.f;
          outA[row * KSF + tt * 64 + (((cd ^ r7)) << 3) + wi] = (f16)v;
        }
      }
    }
  } else if (mode == 2) {
    #pragma unroll
    for (int mi = 0; mi < 4; ++mi) {
      #pragma unroll
      for (int r = 0; r < 4; ++r) {
        long row = m0 + wv * 64 + mi * 16 + lr + r;
        float mv = mask[row];
        #pragma unroll
        for (int ni = 0; ni < 4; ++ni) {
          int col = n0 + ni * 16 + lcn;
          if (col < NR) C[row * (long)ldC + col] = acc[mi][ni][r] * mv;
        }
      }
    }
  } else {  // mode 3 / 4
    const float* bp = biasBase ? biasBase + (long)(z % wMod) * biasZOff : nullptr;
    f16* o16 = outA + (long)z * cZOff;
    float* Cp = C ? C + (long)z * cZOff : nullptr;
    #pragma unroll
    for (int ni = 0; ni < 4; ++ni) {
      int col = n0 + ni * 16 + lcn;
      float bv = bp ? bp[col] : 0.f;
      #pragma unroll
      for (int mi = 0; mi < 4; ++mi) {
        long row = m0 + wv * 64 + mi * 16 + lr;
        #pragma unroll
        for (int r = 0; r < 4; ++r) {
          float v = (acc[mi][ni][r] + bv) * scale;
          if (mode == 4) Cp[(row + r) * 64 + col] = v;
          o16[(row + r) * 64 + col] = (f16)v;
        }
      }
    }
  }
}

// ---------------------------------------------------------------- landmarks
__global__ void k_segmean(const float* __restrict__ in, float* __restrict__ out,
                          f16* __restrict__ out16)
{
  long zl = blockIdx.x;
  long z = zl / NL, lm = zl % NL;
  int d = threadIdx.x;
  const float* p = in + (z * S + lm * SEG) * (long)DF + d;
  float s = 0.f;
  #pragma unroll
  for (int i = 0; i < SEG; i++) s += p[(long)i * DF];
  float v = s * (1.f / SEG);
  out[(z * NL + lm) * (long)DF + d] = v;
  if (out16) out16[(z * NL + lm) * (long)DF + d] = (f16)v;
}

__global__ void k_possel(const float* __restrict__ agg, float* __restrict__ possel)
{
  int hl = blockIdx.x; int h = hl / NL; int lm = hl % NL;
  float sigma = fabsf(agg[h]) + 0.001f;
  int base = lm * SEG;
  for (int j = threadIdx.x; j < S; j += blockDim.x) {
    float s = 0.f;
    #pragma unroll
    for (int i = 0; i < SEG; i++) s += fabsf((float)(base + i - j));
    possel[((long)h * NL + lm) * S + j] = -sigma * s * (1.f / SEG);
  }
}

__global__ void k_possel2(const float* __restrict__ possel, float* __restrict__ possel2)
{
  int hl = blockIdx.x;
  for (int m = threadIdx.x; m < NL; m += blockDim.x) {
    const float* p = possel + (long)hl * S + m * SEG;
    float s = 0.f;
    #pragma unroll
    for (int i = 0; i < SEG; i++) s += p[i];
    possel2[(long)hl * NL + m] = s * (1.f / SEG);
  }
}

// ---------------------------------------------------------------- kernel_2
__global__ __launch_bounds__(256) void k_kernel2(
    const float* __restrict__ qland, const float* __restrict__ kland,
    const float* __restrict__ possel2, float* __restrict__ k2,
    float* __restrict__ colmax)
{
  int z = blockIdx.x; int b = z / H; int h = z % H;
  __shared__ float qs[NL][68];
  __shared__ float ks[NL][68];
  __shared__ float lg[NL][NL + 1];
  int tid = threadIdx.x;
  for (int idx = tid; idx < NL * DF; idx += 256) {
    int r = idx >> 6, d = idx & 63;
    qs[r][d] = qland[((long)z * NL + r) * DF + d];
    ks[r][d] = kland[((long)b * NL + r) * DF + d];
  }
  __syncthreads();
  int r = tid >> 1, half = tid & 1;
  const float* p2 = possel2 + ((long)h * NL + r) * NL;
  float lmax = -INFINITY;
  for (int c = 0; c < 64; c++) {
    int m = half * 64 + c;
    float s = 0.f;
    #pragma unroll
    for (int d = 0; d < DF; d += 4) {
      float4 q = *(const float4*)&qs[r][d];
      float4 k4 = *(const float4*)&ks[m][d];
      s += q.x * k4.x + q.y * k4.y + q.z * k4.z + q.w * k4.w;
    }
    s += p2[m];
    lg[r][m] = s;
    lmax = fmaxf(lmax, s);
  }
  lmax = fmaxf(lmax, __shfl_xor(lmax, 1));
  float lsum = 0.f;
  for (int c = 0; c < 64; c++) {
    int m = half * 64 + c;
    float e = expf(lg[r][m] - lmax);
    lg[r][m] = e; lsum += e;
  }
  lsum += __shfl_xor(lsum, 1);
  float inv = 1.f / lsum;
  for (int c = 0; c < 64; c++) {
    int m = half * 64 + c;
    float p = lg[r][m] * inv;
    lg[r][m] = p;
    k2[((long)z * NL + r) * NL + m] = p;
  }
  __syncthreads();
  float myc = 0.f;
  if (tid < NL) {
    for (int rr = 0; rr < NL; rr++) myc += lg[rr][tid];
  }
  float wm = myc;
  #pragma unroll
  for (int o = 32; o; o >>= 1) wm = fmaxf(wm, __shfl_xor(wm, o));
  __shared__ float wred[4];
  if ((tid & 63) == 0) wred[tid >> 6] = wm;
  __syncthreads();
  if (tid == 0)
    colmax[z] = fmaxf(fmaxf(wred[0], wred[1]), fmaxf(wred[2], wred[3]));
}

// ---------------------------------------------------------------- kernel_3 (flash MFMA)
__global__ __launch_bounds__(256, 2) void k_kernel3(
    const f16* __restrict__ qland16, const f16* __restrict__ Ek16,
    const f16* __restrict__ Ev16, const float* __restrict__ aggL,
    const float* __restrict__ masks, float* __restrict__ kv3)
{
  __shared__ __align__(16) f16 Qs[64 * 64];
  __shared__ __align__(16) f16 Ks[128 * 64];
  __shared__ __align__(16) f16 Vt[64 * 128];
  __shared__ __align__(16) f16 Pb[4 * 16 * 128];
  __shared__ float Ms[128];
  int z2 = blockIdx.x;
  int z = z2 >> 1, half = z2 & 1;
  int b = z >> 3, h = z & 7;
  int q0 = half * 64;
  int tid = threadIdx.x;
  int w = tid >> 6, l = tid & 63;
  float sigma = fabsf(aggL[h]) + 0.001f;
  float cpos = -sigma * (1.f / 16.f);

  for (int c = tid; c < 64 * 8; c += 256) {
    int q = c >> 3, kc = c & 7;
    f16x8 v = *(const f16x8*)&qland16[((long)z * NL + q0 + q) * 64 + kc * 8];
    *(f16x8*)&Qs[q * 64 + ((kc ^ (q & 7)) << 3)] = v;
  }

  f16* Pw = &Pb[w * 16 * 128];
  int l15 = l & 15, lg4 = l >> 4, l7 = l & 7;
  f32x4 Oa[4];
  #pragma unroll
  for (int i = 0; i < 4; ++i) Oa[i] = (f32x4){0.f, 0.f, 0.f, 0.f};
  float mrun[4] = {-INFINITY, -INFINITY, -INFINITY, -INFINITY};
  float lrun[4] = {0.f, 0.f, 0.f, 0.f};

  for (int t0 = 0; t0 < S / 128; ++t0) {
    __syncthreads();
    for (int c = tid; c < 1024; c += 256) {
      int k = c >> 3, kc = c & 7;
      f16x8 v = *(const f16x8*)&Ek16[((long)b * S + t0 * 128 + k) * 64 + kc * 8];
      *(f16x8*)&Ks[k * 64 + ((kc ^ (k & 7)) << 3)] = v;
    }
    for (int c = tid; c < 1024; c += 256) {
      int k = c & 127, dc = c >> 7;
      f16x8 v = *(const f16x8*)&Ev16[((long)z * S + t0 * 128 + k) * 64 + dc * 8];
      int kc = k >> 3, ki = k & 7;
      #pragma unroll
      for (int j = 0; j < 8; ++j) {
        int d = dc * 8 + j;
        Vt[d * 128 + ((kc ^ (d & 7)) << 3) + ki] = v[j];
      }
    }
    if (tid < 128)
      Ms[tid] = (masks[(long)b * S + t0 * 128 + tid] == 0.f) ? -1e6f : 0.f;
    __syncthreads();

    f16x8 af[2];
    #pragma unroll
    for (int kh = 0; kh < 2; ++kh)
      af[kh] = *(const f16x8*)&Qs[(w * 16 + l15) * 64 + (((kh * 4 + lg4) ^ l7) << 3)];
    f32x4 sc[8];
    #pragma unroll
    for (int ct = 0; ct < 8; ++ct) {
      int n = ct * 16 + l15;
      f16x8 b0 = *(const f16x8*)&Ks[n * 64 + (((lg4) ^ (n & 7)) << 3)];
      f16x8 b1 = *(const f16x8*)&Ks[n * 64 + (((4 + lg4) ^ (n & 7)) << 3)];
      f32x4 zz = (f32x4){0.f, 0.f, 0.f, 0.f};
      zz = __builtin_amdgcn_mfma_f32_16x16x32_f16(af[0], b0, zz, 0, 0, 0);
      sc[ct] = __builtin_amdgcn_mfma_f32_16x16x32_f16(af[1], b1, zz, 0, 0, 0);
    }
    float tmax[4] = {-INFINITY, -INFINITY, -INFINITY, -INFINITY};
    #pragma unroll
    for (int ct = 0; ct < 8; ++ct) {
      float mk = Ms[ct * 16 + l15];
      int key = t0 * 128 + ct * 16 + l15;
      #pragma unroll
      for (int r = 0; r < 4; ++r) {
        int qg = q0 + w * 16 + lg4 * 4 + r;
        float a = (float)(key - 16 * qg);
        float ac = fminf(fmaxf(a, 0.f), 15.f);
        float dd = fabsf(a - ac);
        float sum = ac * ac - 15.f * ac + 120.f + 16.f * dd;
        float s = sc[ct][r] + cpos * sum + mk;
        sc[ct][r] = s;
        tmax[r] = fmaxf(tmax[r], s);
      }
    }
    #pragma unroll
    for (int r = 0; r < 4; ++r) {
      #pragma unroll
      for (int o = 1; o < 16; o <<= 1)
        tmax[r] = fmaxf(tmax[r], __shfl_xor(tmax[r], o));
    }
    float fr[4], lsum[4];
    #pragma unroll
    for (int r = 0; r < 4; ++r) {
      float mnew = fmaxf(mrun[r], tmax[r]);
      fr[r] = expf(mrun[r] - mnew);
      mrun[r] = mnew;
      lsum[r] = 0.f;
    }
    #pragma unroll
    for (int ct = 0; ct < 8; ++ct) {
      #pragma unroll
      for (int r = 0; r < 4; ++r) {
        float p = expf(sc[ct][r] - mrun[r]);
        sc[ct][r] = p;
        lsum[r] += p;
      }
    }
    #pragma unroll
    for (int r = 0; r < 4; ++r) {
      #pragma unroll
      for (int o = 1; o < 16; o <<= 1)
        lsum[r] += __shfl_xor(lsum[r], o);
      lrun[r] = lrun[r] * fr[r] + lsum[r];
    }
    f32x4 fv = (f32x4){fr[0], fr[1], fr[2], fr[3]};
    #pragma unroll
    for (int dt = 0; dt < 4; ++dt) Oa[dt] *= fv;
    #pragma unroll
    for (int ct = 0; ct < 8; ++ct) {
      int kc = ct * 2 + (l15 >> 3);
      int ki = l15 & 7;
      #pragma unroll
      for (int r = 0; r < 4; ++r) {
        int row = lg4 * 4 + r;
        Pw[row * 128 + ((kc ^ (row & 7)) << 3) + ki] = (f16)sc[ct][r];
      }
    }
    #pragma unroll
    for (int ks = 0; ks < 4; ++ks) {
      f16x8 pa = *(const f16x8*)&Pw[l15 * 128 + (((ks * 4 + lg4) ^ l7) << 3)];
      #pragma unroll
      for (int dt = 0; dt < 4; ++dt) {
        int n = dt * 16 + l15;
        f16x8 bv = *(const f16x8*)&Vt[n * 128 + (((ks * 4 + lg4) ^ (n & 7)) << 3)];
        Oa[dt] = __builtin_amdgcn_mfma_f32_16x16x32_f16(pa, bv, Oa[dt], 0, 0, 0);
      }
    }
  }
  #pragma unroll
  for (int r = 0; r < 4; ++r) {
    float inv = 1.f / lrun[r];
    long qg = q0 + w * 16 + lg4 * 4 + r;
    #pragma unroll
    for (int dt = 0; dt < 4; ++dt)
      kv3[((long)z * NL + qg) * VF + dt * 16 + l15] = Oa[dt][r] * inv;
  }
}

// ---------------------------------------------------------------- inverse (MFMA fp16 NS)
// V0 = recip*key^T; 6x { X=key@V; Y1=X@(7I-X); Y3=X@(15I-Y1); V=V@(3.25I-.25Y3) }
// then m2 = V @ kv3. Dual swizzled fp16 images: Vn/Vt, Pn/Pt (X, then Y3^T);
// Y1^T transient in Vt. key A-frags pinned in registers.
__global__ __launch_bounds__(512, 1) void k_inverse(
    const float* __restrict__ k2g, const float* __restrict__ colmax,
    const float* __restrict__ kv3, float* __restrict__ m2)
{
  __shared__ __align__(16) f16 Vn[128 * 128];
  __shared__ __align__(16) f16 Vt[128 * 128];
  __shared__ __align__(16) f16 Pn[128 * 128];
  __shared__ __align__(16) f16 Pt[128 * 128];
  int z = blockIdx.x;
  int tid = threadIdx.x;
  int w = tid >> 6, l = tid & 63;
  int l15 = l & 15, lg4 = l >> 4;
  int wr = (w >> 1) * 32;      // wave row base
  int wc = (w & 1) * 64;       // wave col base

  float gmax = colmax[0];
  #pragma unroll
  for (int i = 1; i < 64; ++i) gmax = fmaxf(gmax, colmax[i]);
  float recip = 1.f / gmax;
  const float* key = k2g + (long)z * NL * NL;

  auto swz = [](int r, int c) { return r * 128 + ((((c >> 3) ^ (r & 15))) << 3) + (c & 7); };

  // init: Vt = recip*key (== V^T), Vn = transposed image (== V)
  for (int idx = tid; idx < 128 * 32; idx += 512) {
    int r = idx >> 5, c4 = (idx & 31) << 2;
    float4 kk = *(const float4*)&key[r * 128 + c4];
    f16x4 hv;
    hv[0] = (f16)(recip * kk.x); hv[1] = (f16)(recip * kk.y);
    hv[2] = (f16)(recip * kk.z); hv[3] = (f16)(recip * kk.w);
    *(f16x4*)&Vt[swz(r, c4)] = hv;
    Vn[swz(c4 + 0, r)] = hv[0];
    Vn[swz(c4 + 1, r)] = hv[1];
    Vn[swz(c4 + 2, r)] = hv[2];
    Vn[swz(c4 + 3, r)] = hv[3];
  }
  // key A-fragments (rows wr..wr+31), fixed across iterations
  f16x8 keyA[2][4];
  #pragma unroll
  for (int mi = 0; mi < 2; ++mi)
    #pragma unroll
    for (int ks = 0; ks < 4; ++ks) {
      int r = wr + mi * 16 + l15;
      int k0 = ks * 32 + lg4 * 8;
      float4 a = *(const float4*)&key[r * 128 + k0];
      float4 bq = *(const float4*)&key[r * 128 + k0 + 4];
      f16x8 v;
      v[0] = (f16)a.x; v[1] = (f16)a.y; v[2] = (f16)a.z; v[3] = (f16)a.w;
      v[4] = (f16)bq.x; v[5] = (f16)bq.y; v[6] = (f16)bq.z; v[7] = (f16)bq.w;
      keyA[mi][ks] = v;
    }
  __syncthreads();

  // B'[k][n] = alpha*Bls-image[n][k] + beta*(k==n)
  auto loadB = [&](const f16* Bls, int ni, int ks, float alpha, float beta) -> f16x8 {
    int n = wc + ni * 16 + l15;
    int k0 = ks * 32 + lg4 * 8;
    f16x8 bv = *(const f16x8*)&Bls[swz(n, k0)];
    if (alpha != 1.f) {
      #pragma unroll
      for (int j = 0; j < 8; ++j) bv[j] = (f16)(alpha * (float)bv[j]);
    }
    if (beta != 0.f) {
      int d = n - k0;
      #pragma unroll
      for (int j = 0; j < 8; ++j)
        if (d == j) bv[j] = (f16)((float)bv[j] + beta);
    }
    return bv;
  };
  auto loadA = [&](const f16* Als, int mi, int ks) -> f16x8 {
    return *(const f16x8*)&Als[swz(wr + mi * 16 + l15, ks * 32 + lg4 * 8)];
  };
  auto MM = [&](const f16* An, bool useKey, const f16* Bls,
                float alpha, float beta, f16* Nout, f16* Tout) {
    f32x4 acc[2][4];
    #pragma unroll
    for (int mi = 0; mi < 2; ++mi)
      #pragma unroll
      for (int ni = 0; ni < 4; ++ni) acc[mi][ni] = (f32x4){0.f, 0.f, 0.f, 0.f};
    #pragma unroll
    for (int ks = 0; ks < 4; ++ks) {
      f16x8 bf[4];
      #pragma unroll
      for (int ni = 0; ni < 4; ++ni) bf[ni] = loadB(Bls, ni, ks, alpha, beta);
      f16x8 af[2];
      #pragma unroll
      for (int mi = 0; mi < 2; ++mi)
        af[mi] = useKey ? keyA[mi][ks] : loadA(An, mi, ks);
      #pragma unroll
      for (int mi = 0; mi < 2; ++mi)
        #pragma unroll
        for (int ni = 0; ni < 4; ++ni)
          acc[mi][ni] = __builtin_amdgcn_mfma_f32_16x16x32_f16(af[mi], bf[ni], acc[mi][ni], 0, 0, 0);
    }
    #pragma unroll
    for (int mi = 0; mi < 2; ++mi)
      #pragma unroll
      for (int ni = 0; ni < 4; ++ni) {
        int row0 = wr + mi * 16 + lg4 * 4;
        int col = wc + ni * 16 + l15;
        #pragma unroll
        for (int r = 0; r < 4; ++r) {
          f16 hv = (f16)acc[mi][ni][r];
          if (Nout) Nout[swz(row0 + r, col)] = hv;
          if (Tout) Tout[swz(col, row0 + r)] = hv;
        }
      }
  };

  for (int it = 0; it < 6; ++it) {
    MM(nullptr, true,  Vt, 1.f,    0.f,   Pn, Pt);       // X = key@V
    __syncthreads();
    MM(Pn,     false, Pt, -1.f,   7.f,   nullptr, Vt);   // Y1 = X@(7I-X) -> Vt
    __syncthreads();
    MM(Pn,     false, Vt, -1.f,   15.f,  nullptr, Pt);   // Y3 = X@(15I-Y1) -> Pt
    __syncthreads();
    MM(Vn,     false, Pt, -0.25f, 3.25f, Vn, Vt);        // V = V@(3.25I-.25Y3)
    __syncthreads();
  }

  // m2 = V @ kv3 : stage kv3^T into Pn as [64][128]
  const float* kp = kv3 + (long)z * NL * VF;
  for (int idx = tid; idx < 128 * 16; idx += 512) {
    int k = idx >> 4, c4 = (idx & 15) << 2;
    float4 v4 = *(const float4*)&kp[k * 64 + c4];
    Pn[swz(c4 + 0, k)] = (f16)v4.x;
    Pn[swz(c4 + 1, k)] = (f16)v4.y;
    Pn[swz(c4 + 2, k)] = (f16)v4.z;
    Pn[swz(c4 + 3, k)] = (f16)v4.w;
  }
  __syncthreads();
  // wave w owns rows w*16..w*16+15
  f32x4 accF[4];
  #pragma unroll
  for (int ni = 0; ni < 4; ++ni) accF[ni] = (f32x4){0.f, 0.f, 0.f, 0.f};
  #pragma unroll
  for (int ks = 0; ks < 4; ++ks) {
    f16x8 af = *(const f16x8*)&Vn[swz(w * 16 + l15, ks * 32 + lg4 * 8)];
    #pragma unroll
    for (int ni = 0; ni < 4; ++ni) {
      f16x8 bf = *(const f16x8*)&Pn[swz(ni * 16 + l15, ks * 32 + lg4 * 8)];
      accF[ni] = __builtin_amdgcn_mfma_f32_16x16x32_f16(af, bf, accF[ni], 0, 0, 0);
    }
  }
  float* mp = m2 + (long)z * NL * VF;
  #pragma unroll
  for (int ni = 0; ni < 4; ++ni)
    #pragma unroll
    for (int r = 0; r < 4; ++r)
      mp[(long)(w * 16 + lg4 * 4 + r) * VF + ni * 16 + l15] = accF[ni][r];
}

// ---------------------------------------------------------------- kernel_1 + attn + merge
__global__ __launch_bounds__(256) void k_k1attn(
    const float* __restrict__ Eq, const float* __restrict__ kland,
    const float* __restrict__ possel, const float* __restrict__ m2,
    const float* __restrict__ proj, f16* __restrict__ merged)
{
  int zz = blockIdx.x; int z = zz / (S / 16); int st = zz % (S / 16);
  int b = z / H, h = z % H;
  int s0 = st * 16;
  __shared__ float ks[NL][68];
  __shared__ float ms[NL][64];
  __shared__ float eqs[16][68];
  __shared__ float P[16][132];
  int tid = threadIdx.x;
  for (int idx = tid; idx < NL * DF; idx += 256) {
    int rr = idx >> 6, d = idx & 63;
    ks[rr][d] = kland[((long)b * NL + rr) * DF + d];
    ms[rr][d] = m2[((long)z * NL + rr) * DF + d];
  }
  for (int idx = tid; idx < 16 * DF; idx += 256) {
    int rr = idx >> 6, d = idx & 63;
    eqs[rr][d] = Eq[((long)z * S + s0 + rr) * DF + d];
  }
  __syncthreads();
  int r = tid >> 4, li = tid & 15;
  const float* pp = possel + (long)h * NL * S;
  float vals[8]; float lmax = -INFINITY;
  #pragma unroll
  for (int jj = 0; jj < 8; jj++) {
    int lm = li + jj * 16;
    float s = 0.f;
    #pragma unroll
    for (int d = 0; d < DF; d += 4) {
      float4 e = *(const float4*)&eqs[r][d];
      float4 k4 = *(const float4*)&ks[lm][d];
      s += e.x * k4.x + e.y * k4.y + e.z * k4.z + e.w * k4.w;
    }
    s += pp[(long)lm * S + s0 + r];
    vals[jj] = s; lmax = fmaxf(lmax, s);
  }
  #pragma unroll
  for (int o = 8; o; o >>= 1) lmax = fmaxf(lmax, __shfl_xor(lmax, o));
  float ssum = 0.f;
  #pragma unroll
  for (int jj = 0; jj < 8; jj++) { vals[jj] = expf(vals[jj] - lmax); ssum += vals[jj]; }
  #pragma unroll
  for (int o = 8; o; o >>= 1) ssum += __shfl_xor(ssum, o);
  float inv = 1.f / ssum;
  #pragma unroll
  for (int jj = 0; jj < 8; jj++) P[r][li + jj * 16] = vals[jj] * inv;
  __syncthreads();
  float acc[4] = {};
  for (int lm = 0; lm < NL; lm++) {
    float p = P[r][lm];
    float4 m4 = *(const float4*)&ms[lm][li * 4];
    acc[0] += p * m4.x; acc[1] += p * m4.y; acc[2] += p * m4.z; acc[3] += p * m4.w;
  }
  long srow = (long)b * S + s0 + r;
  float4 pj = *(const float4*)&proj[srow * VF + li * 4];
  f16x4 h4;
  h4[0] = (f16)(acc[0] + pj.x); h4[1] = (f16)(acc[1] + pj.y);
  h4[2] = (f16)(acc[2] + pj.z); h4[3] = (f16)(acc[3] + pj.w);
  int r7 = (int)(srow & 7);
  long off = srow * (long)HV + h * 64 + (((li >> 1) ^ r7) << 3) + ((li & 1) << 2);
  *(f16x4*)&merged[off] = h4;
}

} // namespace

extern "C" void kernel_launch(void* const* d_in, const int* in_sizes, int n_in,
                              void* d_out, int out_size, void* d_ws, size_t ws_size,
                              hipStream_t stream)
{
  const float* lat   = (const float*)d_in[0];
  const float* masks = (const float*)d_in[1];
  const float* xemb  = (const float*)d_in[2];
  const float* ccls  = (const float*)d_in[4];
  const float* qlin  = (const float*)d_in[5];
  const float* klin  = (const float*)d_in[6];
  const float* vlin  = (const float*)d_in[7];
  const float* plin  = (const float*)d_in[8];
  const float* agg   = (const float*)d_in[9];
  const float* cfeat = (const float*)d_in[10];
  float* out = (float*)d_out;
  float* ws = (float*)d_ws;

  long off = 0;
  auto allocF = [&](long n) { float* p = ws + off; off += (n + 3) & ~3L; return p; };
  auto allocH = [&](long n) { f16* p = (f16*)(ws + off); off += ((n + 1) / 2 + 3) & ~3L; return p; };

  f16* origA = allocH(ROWS * KSF);
  f16* vbufA = allocH(ROWS * KSF);
  f16* merged = allocH(ROWS * (long)HV);
  f16* WQt = allocH(16L * 64 * KSF);
  f16* WKt = allocH(2L * 64 * KSF);
  f16* WVt = allocH(16L * 64 * KSF);
  f16* WPt = allocH(2L * 64 * KSF);
  f16* WCFt = allocH((long)KSF * 512);
  f16* WCCt = allocH(64L * 512);
  f16* Ek16 = allocH((long)B * S * 64);
  f16* Ev16 = allocH((long)B * H * S * 64);
  f16* qland16 = allocH((long)B * H * NL * DF);
  float* cl     = allocF(ROWS * HS);
  float* Eq     = allocF((long)B * H * S * DF);
  float* EkB    = allocF((long)B * S * DF);
  float* projb  = allocF((long)B * S * VF);
  float* qland  = allocF((long)B * H * NL * DF);
  float* kland  = allocF((long)B * NL * DF);
  float* possel = allocF((long)H * NL * S);
  float* possel2= allocF((long)H * NL * NL);
  float* k2b    = allocF((long)B * H * NL * NL);
  float* kv3    = allocF((long)B * H * NL * VF);
  float* m2b    = allocF((long)B * H * NL * VF);
  float* colmax = allocF(64);

  k_cl<<<(int)(ROWS / 4), 256, 0, stream>>>(lat, masks, cl);
  k_cvta<<<(int)(ROWS * 168 / 256), 256, 0, stream>>>(xemb, cl, origA);

  auto cvtw = [&](const float* src, f16* dst, int K, int N, int Npad, int KS, long srcZ, int nz) {
    long total = (long)nz * Npad * (KS / 8);
    k_cvtw<<<(int)((total + 255) / 256), 256, 0, stream>>>(src, dst, K, N, Npad, KS, srcZ, total);
  };
  cvtw(qlin, WQt, FEAT, 64, 64, KSF, (long)FEATP * 64, 16);
  cvtw(klin, WKt, FEAT, 64, 64, KSF, (long)FEATP * 64, 2);
  cvtw(vlin, WVt, FEAT, 64, 64, KSF, (long)FEATP * 64, 16);
  cvtw(plin, WPt, FEAT, 64, 64, KSF, (long)FEATP * 64, 2);
  cvtw(cfeat, WCFt, 512, FEAT, KSF, 512, 0, 1);
  cvtw(ccls, WCCt, 512, HS, 64, 512, 0, 1);

  const f16* Aact = origA;
  for (int layer = 0; layer < 2; ++layer) {
    const f16* wq = WQt + (long)layer * 8 * 64 * KSF;
    const f16* wk = WKt + (long)layer * 64 * KSF;
    const f16* wvv = WVt + (long)layer * 8 * 64 * KSF;
    const f16* wp = WPt + (long)layer * 64 * KSF;
    const float* bq = qlin + (long)layer * 8 * FEATP * 64 + (long)(FEATP - 2) * 64;
    const float* bk = klin + (long)layer * FEATP * 64 + (long)(FEATP - 2) * 64;
    const float* bv = vlin + (long)layer * 8 * FEATP * 64 + (long)(FEATP - 2) * 64;
    const float* bp = plin + (long)layer * FEATP * 64 + (long)(FEATP - 2) * 64;
    const float* ag = agg + layer * H;

    dim3 gQ(8, 1, 64), gK(8, 1, 8);
    k_mgemm<<<gQ, 256, 0, stream>>>(Aact, (long)S * KSF, 8, wq, 64L * KSF, 8, 21, 0,
        Eq, (long)S * 64, 64, bq, (long)FEATP * 64, INV_SCALE, nullptr, 64, nullptr);
    k_mgemm<<<gK, 256, 0, stream>>>(Aact, (long)S * KSF, 1, wk, 0, 1, 21, 4,
        EkB, (long)S * 64, 64, bk, 0, INV_SCALE, Ek16, 64, nullptr);
    k_mgemm<<<gQ, 256, 0, stream>>>(Aact, (long)S * KSF, 8, wvv, 64L * KSF, 8, 21, 3,
        nullptr, (long)S * 64, 64, bv, (long)FEATP * 64, 1.0f, Ev16, 64, nullptr);
    k_mgemm<<<gK, 256, 0, stream>>>(origA, (long)S * KSF, 1, wp, 0, 1, 21, 0,
        projb, (long)S * 64, 64, bp, 0, 0.5f, nullptr, 64, nullptr);

    k_segmean<<<B * H * NL, 64, 0, stream>>>(Eq, qland, qland16);
    k_segmean<<<B * NL, 64, 0, stream>>>(EkB, kland, nullptr);
    k_possel<<<H * NL, 256, 0, stream>>>(ag, possel);
    k_possel2<<<H * NL, 128, 0, stream>>>(possel, possel2);

    k_kernel2<<<B * H, 256, 0, stream>>>(qland, kland, possel2, k2b, colmax);
    k_kernel3<<<B * H * 2, 256, 0, stream>>>(qland16, Ek16, Ev16, ag, masks, kv3);
    k_inverse<<<B * H, 512, 0, stream>>>(k2b, colmax, kv3, m2b);
    k_k1attn<<<B * H * (S / 16), 256, 0, stream>>>(Eq, kland, possel, m2b, projb, merged);

    if (layer == 0) {
      dim3 gC(64, 21, 1);
      k_mgemm<<<gC, 256, 0, stream>>>(merged, 0, 1, WCFt, 0, 1, 8, 1,
          nullptr, 0, 0, nullptr, 0, 1.0f, vbufA, FEAT, nullptr);
      Aact = vbufA;
    } else {
      dim3 gO(64, 1, 1);
      k_mgemm<<<gO, 256, 0, stream>>>(merged, 0, 1, WCCt, 0, 1, 8, 2,
          out, 0, HS, nullptr, 0, 1.0f, nullptr, HS, masks);
    }
  }
  (void)in_sizes; (void)n_in; (void)out_size; (void)ws_size;
}

// Round 5
// 908.570 us; speedup vs baseline: 6.8791x; 1.2773x over previous
//
#include <hip/hip_runtime.h>
#include <math.h>

// ESMMimicryModule: B=8 S=2048 H=8 NL=128 DF=VF=64 NF=1280 HS=33 FEAT=1313
// Round 4: k_k1attn rewritten as MFMA fp16 (mirrors k_kernel3): Eq16 via mgemm
// mode 4, kland16 staged swizzled, analytic pos term (no possel gather),
// in-register 128-wide softmax, PV vs transposed m2 image, merged arena write.

namespace {

constexpr int B = 8, S = 2048, H = 8, NL = 128, DF = 64, VF = 64;
constexpr int NF = 1280, HS = 33, FEAT = 1313, FEATP = 1314;
constexpr int SEG = 16, HV = H * VF;            // 512
constexpr int KSF = 1344;                        // padded feature-K (21*64)
constexpr long ROWS = (long)B * S;               // 16384
constexpr float INV_SCALE = 0.35355339059327373f;

typedef _Float16 f16;
typedef _Float16 f16x8 __attribute__((ext_vector_type(8)));
typedef _Float16 f16x4 __attribute__((ext_vector_type(4)));
typedef float f32x4 __attribute__((ext_vector_type(4)));

// ---------------------------------------------------------------- cl = softmax(latent)*mask
__global__ __launch_bounds__(256) void k_cl(
    const float* __restrict__ lat, const float* __restrict__ masks,
    float* __restrict__ cl)
{
  long row = (long)blockIdx.x * 4 + (threadIdx.x >> 6);
  int l = threadIdx.x & 63;
  float v = (l < HS) ? lat[row * HS + l] : -INFINITY;
  float m = v;
  #pragma unroll
  for (int o = 32; o; o >>= 1) m = fmaxf(m, __shfl_xor(m, o));
  float e = (l < HS) ? expf(v - m) : 0.f;
  float s = e;
  #pragma unroll
  for (int o = 32; o; o >>= 1) s += __shfl_xor(s, o);
  if (l < HS) cl[row * HS + l] = e / s * masks[row];
}

// ---------------------------------------------------------------- origA fp16 arena (swizzled)
__global__ __launch_bounds__(256) void k_cvta(
    const float* __restrict__ xemb, const float* __restrict__ cl,
    f16* __restrict__ dst)
{
  long idx = (long)blockIdx.x * 256 + threadIdx.x;  // chunk id (row,c)
  long row = idx / 168;
  int c = (int)(idx - row * 168);
  int t = c >> 3, cs = c & 7;
  int cd = cs ^ ((int)row & 7);
  int k0 = t * 64 + cd * 8;
  f16x8 v;
  #pragma unroll
  for (int i = 0; i < 8; ++i) {
    int k = k0 + i;
    float f = 0.f;
    if (k < NF) f = xemb[row * NF + k];
    else if (k < FEAT) f = cl[row * HS + (k - NF)];
    v[i] = (f16)f;
  }
  *(f16x8*)&dst[idx * 8] = v;
}

// ---------------------------------------------------------------- weight -> Wt fp16 arena
__global__ __launch_bounds__(256) void k_cvtw(
    const float* __restrict__ src, f16* __restrict__ dst,
    int K, int N, int Npad, int KS, long srcZ, long total)
{
  long idx = (long)blockIdx.x * 256 + threadIdx.x;
  if (idx >= total) return;
  long cpz = (long)Npad * (KS >> 3);
  long z = idx / cpz;
  long rem = idx - z * cpz;
  int n = (int)(rem / (KS >> 3));
  int c = (int)(rem - (long)n * (KS >> 3));
  int t = c >> 3, cs = c & 7;
  int cd = cs ^ (n & 7);
  int k0 = t * 64 + cd * 8;
  const float* sp = src + z * srcZ;
  f16x8 v;
  #pragma unroll
  for (int i = 0; i < 8; ++i) {
    int k = k0 + i;
    v[i] = (f16)((k < K && n < N) ? sp[(long)k * N + n] : 0.f);
  }
  *(f16x8*)&dst[idx * 8] = v;
}

// ---------------------------------------------------------------- fp16 MFMA GEMM
// mode 0: fp32 C = (acc + bias)*scale
// mode 1: fp16 swizzled arena (KSF stride, zero-fill col>=NR)
// mode 2: fp32 out * mask, col<NR
// mode 3: fp16 row-major out (64 cols), (acc+bias)*scale
// mode 4: mode 0 fp32 + fp16 row-major copy
__global__ __launch_bounds__(256, 2) void k_mgemm(
    const f16* __restrict__ A, long aZOff, int aDiv,
    const f16* __restrict__ Wt, long wZOff, int wMod,
    int KT, int mode,
    float* __restrict__ C, long cZOff, int ldC,
    const float* __restrict__ biasBase, long biasZOff, float scale,
    f16* __restrict__ outA, int NR, const float* __restrict__ mask)
{
  const long KS = (long)KT * 64;
  int z = blockIdx.z;
  const f16* Ap = A + (long)(z / aDiv) * aZOff;
  const f16* Wp = Wt + (long)(z % wMod) * wZOff;
  long m0 = (long)blockIdx.x * 256;
  int n0 = blockIdx.y * 64;
  constexpr int BOFF = 256 * 64;
  __shared__ f16 lds[2][(256 + 64) * 64];
  int tid = threadIdx.x;
  int wv = tid >> 6, l = tid & 63;

  const f16* aW = Ap + (m0 + wv * 64 + (l >> 3)) * KS + (l & 7) * 8;
  const f16* bW = Wp + ((long)(n0 + wv * 16 + (l >> 3))) * KS + (l & 7) * 8;

  f32x4 acc[4][4];
  #pragma unroll
  for (int i = 0; i < 4; ++i)
    #pragma unroll
    for (int j = 0; j < 4; ++j) acc[i][j] = (f32x4){0.f, 0.f, 0.f, 0.f};

  auto stage = [&](int buf, int t) {
    f16* la = &lds[buf][(wv * 64) * 64];
    const f16* ga = aW + (long)t * 64;
    #pragma unroll
    for (int j = 0; j < 8; ++j)
      __builtin_amdgcn_global_load_lds(
          (const __attribute__((address_space(1))) void*)(ga + (long)j * 8 * KS),
          (__attribute__((address_space(3))) void*)(la + j * 8 * 64), 16, 0, 0);
    f16* lb = &lds[buf][BOFF + (wv * 16) * 64];
    const f16* gb = bW + (long)t * 64;
    #pragma unroll
    for (int j = 0; j < 2; ++j)
      __builtin_amdgcn_global_load_lds(
          (const __attribute__((address_space(1))) void*)(gb + (long)j * 8 * KS),
          (__attribute__((address_space(3))) void*)(lb + j * 8 * 64), 16, 0, 0);
  };

  stage(0, 0);
  int rA = (wv * 64 + (l & 15)) * 64;
  int rB = BOFF + (l & 15) * 64;
  int lc = l >> 4, lx = l & 7;
  for (int t = 0; t < KT; ++t) {
    int nb = t & 1;
    if (t + 1 < KT) {
      stage(nb ^ 1, t + 1);
      asm volatile("s_waitcnt vmcnt(10)" ::: "memory");
    } else {
      asm volatile("s_waitcnt vmcnt(0)" ::: "memory");
    }
    __syncthreads();
    const f16* base = &lds[nb][0];
    f16x8 af[4][2], bf[4][2];
    #pragma unroll
    for (int mi = 0; mi < 4; ++mi)
      #pragma unroll
      for (int kh = 0; kh < 2; ++kh)
        af[mi][kh] = *(const f16x8*)&base[rA + mi * 16 * 64 + (((kh * 4 + lc) ^ lx) << 3)];
    #pragma unroll
    for (int ni = 0; ni < 4; ++ni)
      #pragma unroll
      for (int kh = 0; kh < 2; ++kh)
        bf[ni][kh] = *(const f16x8*)&base[rB + ni * 16 * 64 + (((kh * 4 + lc) ^ lx) << 3)];
    #pragma unroll
    for (int mi = 0; mi < 4; ++mi)
      #pragma unroll
      for (int ni = 0; ni < 4; ++ni) {
        acc[mi][ni] = __builtin_amdgcn_mfma_f32_16x16x32_f16(af[mi][0], bf[ni][0], acc[mi][ni], 0, 0, 0);
        acc[mi][ni] = __builtin_amdgcn_mfma_f32_16x16x32_f16(af[mi][1], bf[ni][1], acc[mi][ni], 0, 0, 0);
      }
    __syncthreads();
  }

  int lr = (l >> 4) * 4;
  int lcn = l & 15;
  if (mode == 0) {
    float* Cp = C + (long)z * cZOff;
    const float* bp = biasBase ? biasBase + (long)(z % wMod) * biasZOff : nullptr;
    #pragma unroll
    for (int ni = 0; ni < 4; ++ni) {
      int col = n0 + ni * 16 + lcn;
      float bv = bp ? bp[col] : 0.f;
      #pragma unroll
      for (int mi = 0; mi < 4; ++mi) {
        long row = m0 + wv * 64 + mi * 16 + lr;
        #pragma unroll
        for (int r = 0; r < 4; ++r)
          Cp[(row + r) * (long)ldC + col] = (acc[mi][ni][r] + bv) * scale;
      }
    }
  } else if (mode == 1) {
    #pragma unroll
    for (int mi = 0; mi < 4; ++mi) {
      #pragma unroll
      for (int r = 0; r < 4; ++r) {
        long row = m0 + wv * 64 + mi * 16 + lr + r;
        int r7 = (int)row & 7;
        #pragma unroll
        for (int ni = 0; ni < 4; ++ni) {
          int col = n0 + ni * 16 + lcn;
          int tt = col >> 6, kk = col & 63;
          int cd = kk >> 3, wi = kk & 7;
          float v = (col < NR) ? acc[mi][ni][r] : 0.f;
          outA[row * KSF + tt * 64 + (((cd ^ r7)) << 3) + wi] = (f16)v;
        }
      }
    }
  } else if (mode == 2) {
    #pragma unroll
    for (int mi = 0; mi < 4; ++mi) {
      #pragma unroll
      for (int r = 0; r < 4; ++r) {
        long row = m0 + wv * 64 + mi * 16 + lr + r;
        float mv = mask[row];
        #pragma unroll
        for (int ni = 0; ni < 4; ++ni) {
          int col = n0 + ni * 16 + lcn;
          if (col < NR) C[row * (long)ldC + col] = acc[mi][ni][r] * mv;
        }
      }
    }
  } else {  // mode 3 / 4
    const float* bp = biasBase ? biasBase + (long)(z % wMod) * biasZOff : nullptr;
    f16* o16 = outA + (long)z * cZOff;
    float* Cp = C ? C + (long)z * cZOff : nullptr;
    #pragma unroll
    for (int ni = 0; ni < 4; ++ni) {
      int col = n0 + ni * 16 + lcn;
      float bv = bp ? bp[col] : 0.f;
      #pragma unroll
      for (int mi = 0; mi < 4; ++mi) {
        long row = m0 + wv * 64 + mi * 16 + lr;
        #pragma unroll
        for (int r = 0; r < 4; ++r) {
          float v = (acc[mi][ni][r] + bv) * scale;
          if (mode == 4) Cp[(row + r) * 64 + col] = v;
          o16[(row + r) * 64 + col] = (f16)v;
        }
      }
    }
  }
}

// ---------------------------------------------------------------- landmarks
__global__ void k_segmean(const float* __restrict__ in, float* __restrict__ out,
                          f16* __restrict__ out16)
{
  long zl = blockIdx.x;
  long z = zl / NL, lm = zl % NL;
  int d = threadIdx.x;
  const float* p = in + (z * S + lm * SEG) * (long)DF + d;
  float s = 0.f;
  #pragma unroll
  for (int i = 0; i < SEG; i++) s += p[(long)i * DF];
  float v = s * (1.f / SEG);
  out[(z * NL + lm) * (long)DF + d] = v;
  if (out16) out16[(z * NL + lm) * (long)DF + d] = (f16)v;
}

__global__ void k_possel(const float* __restrict__ agg, float* __restrict__ possel)
{
  int hl = blockIdx.x; int h = hl / NL; int lm = hl % NL;
  float sigma = fabsf(agg[h]) + 0.001f;
  int base = lm * SEG;
  for (int j = threadIdx.x; j < S; j += blockDim.x) {
    float s = 0.f;
    #pragma unroll
    for (int i = 0; i < SEG; i++) s += fabsf((float)(base + i - j));
    possel[((long)h * NL + lm) * S + j] = -sigma * s * (1.f / SEG);
  }
}

__global__ void k_possel2(const float* __restrict__ possel, float* __restrict__ possel2)
{
  int hl = blockIdx.x;
  for (int m = threadIdx.x; m < NL; m += blockDim.x) {
    const float* p = possel + (long)hl * S + m * SEG;
    float s = 0.f;
    #pragma unroll
    for (int i = 0; i < SEG; i++) s += p[i];
    possel2[(long)hl * NL + m] = s * (1.f / SEG);
  }
}

// ---------------------------------------------------------------- kernel_2
__global__ __launch_bounds__(256) void k_kernel2(
    const float* __restrict__ qland, const float* __restrict__ kland,
    const float* __restrict__ possel2, float* __restrict__ k2,
    float* __restrict__ colmax)
{
  int z = blockIdx.x; int b = z / H; int h = z % H;
  __shared__ float qs[NL][68];
  __shared__ float ks[NL][68];
  __shared__ float lg[NL][NL + 1];
  int tid = threadIdx.x;
  for (int idx = tid; idx < NL * DF; idx += 256) {
    int r = idx >> 6, d = idx & 63;
    qs[r][d] = qland[((long)z * NL + r) * DF + d];
    ks[r][d] = kland[((long)b * NL + r) * DF + d];
  }
  __syncthreads();
  int r = tid >> 1, half = tid & 1;
  const float* p2 = possel2 + ((long)h * NL + r) * NL;
  float lmax = -INFINITY;
  for (int c = 0; c < 64; c++) {
    int m = half * 64 + c;
    float s = 0.f;
    #pragma unroll
    for (int d = 0; d < DF; d += 4) {
      float4 q = *(const float4*)&qs[r][d];
      float4 k4 = *(const float4*)&ks[m][d];
      s += q.x * k4.x + q.y * k4.y + q.z * k4.z + q.w * k4.w;
    }
    s += p2[m];
    lg[r][m] = s;
    lmax = fmaxf(lmax, s);
  }
  lmax = fmaxf(lmax, __shfl_xor(lmax, 1));
  float lsum = 0.f;
  for (int c = 0; c < 64; c++) {
    int m = half * 64 + c;
    float e = expf(lg[r][m] - lmax);
    lg[r][m] = e; lsum += e;
  }
  lsum += __shfl_xor(lsum, 1);
  float inv = 1.f / lsum;
  for (int c = 0; c < 64; c++) {
    int m = half * 64 + c;
    float p = lg[r][m] * inv;
    lg[r][m] = p;
    k2[((long)z * NL + r) * NL + m] = p;
  }
  __syncthreads();
  float myc = 0.f;
  if (tid < NL) {
    for (int rr = 0; rr < NL; rr++) myc += lg[rr][tid];
  }
  float wm = myc;
  #pragma unroll
  for (int o = 32; o; o >>= 1) wm = fmaxf(wm, __shfl_xor(wm, o));
  __shared__ float wred[4];
  if ((tid & 63) == 0) wred[tid >> 6] = wm;
  __syncthreads();
  if (tid == 0)
    colmax[z] = fmaxf(fmaxf(wred[0], wred[1]), fmaxf(wred[2], wred[3]));
}

// ---------------------------------------------------------------- kernel_3 (flash MFMA)
__global__ __launch_bounds__(256, 2) void k_kernel3(
    const f16* __restrict__ qland16, const f16* __restrict__ Ek16,
    const f16* __restrict__ Ev16, const float* __restrict__ aggL,
    const float* __restrict__ masks, float* __restrict__ kv3)
{
  __shared__ __align__(16) f16 Qs[64 * 64];
  __shared__ __align__(16) f16 Ks[128 * 64];
  __shared__ __align__(16) f16 Vt[64 * 128];
  __shared__ __align__(16) f16 Pb[4 * 16 * 128];
  __shared__ float Ms[128];
  int z2 = blockIdx.x;
  int z = z2 >> 1, half = z2 & 1;
  int b = z >> 3, h = z & 7;
  int q0 = half * 64;
  int tid = threadIdx.x;
  int w = tid >> 6, l = tid & 63;
  float sigma = fabsf(aggL[h]) + 0.001f;
  float cpos = -sigma * (1.f / 16.f);

  for (int c = tid; c < 64 * 8; c += 256) {
    int q = c >> 3, kc = c & 7;
    f16x8 v = *(const f16x8*)&qland16[((long)z * NL + q0 + q) * 64 + kc * 8];
    *(f16x8*)&Qs[q * 64 + ((kc ^ (q & 7)) << 3)] = v;
  }

  f16* Pw = &Pb[w * 16 * 128];
  int l15 = l & 15, lg4 = l >> 4, l7 = l & 7;
  f32x4 Oa[4];
  #pragma unroll
  for (int i = 0; i < 4; ++i) Oa[i] = (f32x4){0.f, 0.f, 0.f, 0.f};
  float mrun[4] = {-INFINITY, -INFINITY, -INFINITY, -INFINITY};
  float lrun[4] = {0.f, 0.f, 0.f, 0.f};

  for (int t0 = 0; t0 < S / 128; ++t0) {
    __syncthreads();
    for (int c = tid; c < 1024; c += 256) {
      int k = c >> 3, kc = c & 7;
      f16x8 v = *(const f16x8*)&Ek16[((long)b * S + t0 * 128 + k) * 64 + kc * 8];
      *(f16x8*)&Ks[k * 64 + ((kc ^ (k & 7)) << 3)] = v;
    }
    for (int c = tid; c < 1024; c += 256) {
      int k = c & 127, dc = c >> 7;
      f16x8 v = *(const f16x8*)&Ev16[((long)z * S + t0 * 128 + k) * 64 + dc * 8];
      int kc = k >> 3, ki = k & 7;
      #pragma unroll
      for (int j = 0; j < 8; ++j) {
        int d = dc * 8 + j;
        Vt[d * 128 + ((kc ^ (d & 7)) << 3) + ki] = v[j];
      }
    }
    if (tid < 128)
      Ms[tid] = (masks[(long)b * S + t0 * 128 + tid] == 0.f) ? -1e6f : 0.f;
    __syncthreads();

    f16x8 af[2];
    #pragma unroll
    for (int kh = 0; kh < 2; ++kh)
      af[kh] = *(const f16x8*)&Qs[(w * 16 + l15) * 64 + (((kh * 4 + lg4) ^ l7) << 3)];
    f32x4 sc[8];
    #pragma unroll
    for (int ct = 0; ct < 8; ++ct) {
      int n = ct * 16 + l15;
      f16x8 b0 = *(const f16x8*)&Ks[n * 64 + (((lg4) ^ (n & 7)) << 3)];
      f16x8 b1 = *(const f16x8*)&Ks[n * 64 + (((4 + lg4) ^ (n & 7)) << 3)];
      f32x4 zz = (f32x4){0.f, 0.f, 0.f, 0.f};
      zz = __builtin_amdgcn_mfma_f32_16x16x32_f16(af[0], b0, zz, 0, 0, 0);
      sc[ct] = __builtin_amdgcn_mfma_f32_16x16x32_f16(af[1], b1, zz, 0, 0, 0);
    }
    float tmax[4] = {-INFINITY, -INFINITY, -INFINITY, -INFINITY};
    #pragma unroll
    for (int ct = 0; ct < 8; ++ct) {
      float mk = Ms[ct * 16 + l15];
      int key = t0 * 128 + ct * 16 + l15;
      #pragma unroll
      for (int r = 0; r < 4; ++r) {
        int qg = q0 + w * 16 + lg4 * 4 + r;
        float a = (float)(key - 16 * qg);
        float ac = fminf(fmaxf(a, 0.f), 15.f);
        float dd = fabsf(a - ac);
        float sum = ac * ac - 15.f * ac + 120.f + 16.f * dd;
        float s = sc[ct][r] + cpos * sum + mk;
        sc[ct][r] = s;
        tmax[r] = fmaxf(tmax[r], s);
      }
    }
    #pragma unroll
    for (int r = 0; r < 4; ++r) {
      #pragma unroll
      for (int o = 1; o < 16; o <<= 1)
        tmax[r] = fmaxf(tmax[r], __shfl_xor(tmax[r], o));
    }
    float fr[4], lsum[4];
    #pragma unroll
    for (int r = 0; r < 4; ++r) {
      float mnew = fmaxf(mrun[r], tmax[r]);
      fr[r] = expf(mrun[r] - mnew);
      mrun[r] = mnew;
      lsum[r] = 0.f;
    }
    #pragma unroll
    for (int ct = 0; ct < 8; ++ct) {
      #pragma unroll
      for (int r = 0; r < 4; ++r) {
        float p = expf(sc[ct][r] - mrun[r]);
        sc[ct][r] = p;
        lsum[r] += p;
      }
    }
    #pragma unroll
    for (int r = 0; r < 4; ++r) {
      #pragma unroll
      for (int o = 1; o < 16; o <<= 1)
        lsum[r] += __shfl_xor(lsum[r], o);
      lrun[r] = lrun[r] * fr[r] + lsum[r];
    }
    f32x4 fv = (f32x4){fr[0], fr[1], fr[2], fr[3]};
    #pragma unroll
    for (int dt = 0; dt < 4; ++dt) Oa[dt] *= fv;
    #pragma unroll
    for (int ct = 0; ct < 8; ++ct) {
      int kc = ct * 2 + (l15 >> 3);
      int ki = l15 & 7;
      #pragma unroll
      for (int r = 0; r < 4; ++r) {
        int row = lg4 * 4 + r;
        Pw[row * 128 + ((kc ^ (row & 7)) << 3) + ki] = (f16)sc[ct][r];
      }
    }
    #pragma unroll
    for (int ks = 0; ks < 4; ++ks) {
      f16x8 pa = *(const f16x8*)&Pw[l15 * 128 + (((ks * 4 + lg4) ^ l7) << 3)];
      #pragma unroll
      for (int dt = 0; dt < 4; ++dt) {
        int n = dt * 16 + l15;
        f16x8 bv = *(const f16x8*)&Vt[n * 128 + (((ks * 4 + lg4) ^ (n & 7)) << 3)];
        Oa[dt] = __builtin_amdgcn_mfma_f32_16x16x32_f16(pa, bv, Oa[dt], 0, 0, 0);
      }
    }
  }
  #pragma unroll
  for (int r = 0; r < 4; ++r) {
    float inv = 1.f / lrun[r];
    long qg = q0 + w * 16 + lg4 * 4 + r;
    #pragma unroll
    for (int dt = 0; dt < 4; ++dt)
      kv3[((long)z * NL + qg) * VF + dt * 16 + l15] = Oa[dt][r] * inv;
  }
}

// ---------------------------------------------------------------- inverse (MFMA fp16 NS)
__global__ __launch_bounds__(512, 1) void k_inverse(
    const float* __restrict__ k2g, const float* __restrict__ colmax,
    const float* __restrict__ kv3, float* __restrict__ m2)
{
  __shared__ __align__(16) f16 Vn[128 * 128];
  __shared__ __align__(16) f16 Vt[128 * 128];
  __shared__ __align__(16) f16 Pn[128 * 128];
  __shared__ __align__(16) f16 Pt[128 * 128];
  int z = blockIdx.x;
  int tid = threadIdx.x;
  int w = tid >> 6, l = tid & 63;
  int l15 = l & 15, lg4 = l >> 4;
  int wr = (w >> 1) * 32;
  int wc = (w & 1) * 64;

  float gmax = colmax[0];
  #pragma unroll
  for (int i = 1; i < 64; ++i) gmax = fmaxf(gmax, colmax[i]);
  float recip = 1.f / gmax;
  const float* key = k2g + (long)z * NL * NL;

  auto swz = [](int r, int c) { return r * 128 + ((((c >> 3) ^ (r & 15))) << 3) + (c & 7); };

  for (int idx = tid; idx < 128 * 32; idx += 512) {
    int r = idx >> 5, c4 = (idx & 31) << 2;
    float4 kk = *(const float4*)&key[r * 128 + c4];
    f16x4 hv;
    hv[0] = (f16)(recip * kk.x); hv[1] = (f16)(recip * kk.y);
    hv[2] = (f16)(recip * kk.z); hv[3] = (f16)(recip * kk.w);
    *(f16x4*)&Vt[swz(r, c4)] = hv;
    Vn[swz(c4 + 0, r)] = hv[0];
    Vn[swz(c4 + 1, r)] = hv[1];
    Vn[swz(c4 + 2, r)] = hv[2];
    Vn[swz(c4 + 3, r)] = hv[3];
  }
  f16x8 keyA[2][4];
  #pragma unroll
  for (int mi = 0; mi < 2; ++mi)
    #pragma unroll
    for (int ks = 0; ks < 4; ++ks) {
      int r = wr + mi * 16 + l15;
      int k0 = ks * 32 + lg4 * 8;
      float4 a = *(const float4*)&key[r * 128 + k0];
      float4 bq = *(const float4*)&key[r * 128 + k0 + 4];
      f16x8 v;
      v[0] = (f16)a.x; v[1] = (f16)a.y; v[2] = (f16)a.z; v[3] = (f16)a.w;
      v[4] = (f16)bq.x; v[5] = (f16)bq.y; v[6] = (f16)bq.z; v[7] = (f16)bq.w;
      keyA[mi][ks] = v;
    }
  __syncthreads();

  auto loadB = [&](const f16* Bls, int ni, int ks, float alpha, float beta) -> f16x8 {
    int n = wc + ni * 16 + l15;
    int k0 = ks * 32 + lg4 * 8;
    f16x8 bv = *(const f16x8*)&Bls[swz(n, k0)];
    if (alpha != 1.f) {
      #pragma unroll
      for (int j = 0; j < 8; ++j) bv[j] = (f16)(alpha * (float)bv[j]);
    }
    if (beta != 0.f) {
      int d = n - k0;
      #pragma unroll
      for (int j = 0; j < 8; ++j)
        if (d == j) bv[j] = (f16)((float)bv[j] + beta);
    }
    return bv;
  };
  auto loadA = [&](const f16* Als, int mi, int ks) -> f16x8 {
    return *(const f16x8*)&Als[swz(wr + mi * 16 + l15, ks * 32 + lg4 * 8)];
  };
  auto MM = [&](const f16* An, bool useKey, const f16* Bls,
                float alpha, float beta, f16* Nout, f16* Tout) {
    f32x4 acc[2][4];
    #pragma unroll
    for (int mi = 0; mi < 2; ++mi)
      #pragma unroll
      for (int ni = 0; ni < 4; ++ni) acc[mi][ni] = (f32x4){0.f, 0.f, 0.f, 0.f};
    #pragma unroll
    for (int ks = 0; ks < 4; ++ks) {
      f16x8 bf[4];
      #pragma unroll
      for (int ni = 0; ni < 4; ++ni) bf[ni] = loadB(Bls, ni, ks, alpha, beta);
      f16x8 af[2];
      #pragma unroll
      for (int mi = 0; mi < 2; ++mi)
        af[mi] = useKey ? keyA[mi][ks] : loadA(An, mi, ks);
      #pragma unroll
      for (int mi = 0; mi < 2; ++mi)
        #pragma unroll
        for (int ni = 0; ni < 4; ++ni)
          acc[mi][ni] = __builtin_amdgcn_mfma_f32_16x16x32_f16(af[mi], bf[ni], acc[mi][ni], 0, 0, 0);
    }
    #pragma unroll
    for (int mi = 0; mi < 2; ++mi)
      #pragma unroll
      for (int ni = 0; ni < 4; ++ni) {
        int row0 = wr + mi * 16 + lg4 * 4;
        int col = wc + ni * 16 + l15;
        #pragma unroll
        for (int r = 0; r < 4; ++r) {
          f16 hv = (f16)acc[mi][ni][r];
          if (Nout) Nout[swz(row0 + r, col)] = hv;
          if (Tout) Tout[swz(col, row0 + r)] = hv;
        }
      }
  };

  for (int it = 0; it < 6; ++it) {
    MM(nullptr, true,  Vt, 1.f,    0.f,   Pn, Pt);
    __syncthreads();
    MM(Pn,     false, Pt, -1.f,   7.f,   nullptr, Vt);
    __syncthreads();
    MM(Pn,     false, Vt, -1.f,   15.f,  nullptr, Pt);
    __syncthreads();
    MM(Vn,     false, Pt, -0.25f, 3.25f, Vn, Vt);
    __syncthreads();
  }

  const float* kp = kv3 + (long)z * NL * VF;
  for (int idx = tid; idx < 128 * 16; idx += 512) {
    int k = idx >> 4, c4 = (idx & 15) << 2;
    float4 v4 = *(const float4*)&kp[k * 64 + c4];
    Pn[swz(c4 + 0, k)] = (f16)v4.x;
    Pn[swz(c4 + 1, k)] = (f16)v4.y;
    Pn[swz(c4 + 2, k)] = (f16)v4.z;
    Pn[swz(c4 + 3, k)] = (f16)v4.w;
  }
  __syncthreads();
  f32x4 accF[4];
  #pragma unroll
  for (int ni = 0; ni < 4; ++ni) accF[ni] = (f32x4){0.f, 0.f, 0.f, 0.f};
  #pragma unroll
  for (int ks = 0; ks < 4; ++ks) {
    f16x8 af = *(const f16x8*)&Vn[swz(w * 16 + l15, ks * 32 + lg4 * 8)];
    #pragma unroll
    for (int ni = 0; ni < 4; ++ni) {
      f16x8 bf = *(const f16x8*)&Pn[swz(ni * 16 + l15, ks * 32 + lg4 * 8)];
      accF[ni] = __builtin_amdgcn_mfma_f32_16x16x32_f16(af, bf, accF[ni], 0, 0, 0);
    }
  }
  float* mp = m2 + (long)z * NL * VF;
  #pragma unroll
  for (int ni = 0; ni < 4; ++ni)
    #pragma unroll
    for (int r = 0; r < 4; ++r)
      mp[(long)(w * 16 + lg4 * 4 + r) * VF + ni * 16 + l15] = accF[ni][r];
}

// ---------------------------------------------------------------- kernel_1 + attn + merge (MFMA)
// block = (b,h, 64-row S tile); 4 waves x 16 rows. logits = Eq16@kland16^T +
// analytic pos; softmax over 128 in regs; P@m2T + proj -> merged arena fp16.
__global__ __launch_bounds__(256, 2) void k_k1attn(
    const f16* __restrict__ Eq16, const f16* __restrict__ kland16,
    const float* __restrict__ aggL, const float* __restrict__ m2,
    const float* __restrict__ proj, f16* __restrict__ merged)
{
  __shared__ __align__(16) f16 Kl[128 * 64];
  __shared__ __align__(16) f16 M2t[64 * 128];
  __shared__ __align__(16) f16 Pb[4 * 16 * 128];
  int zz = blockIdx.x;
  int z = zz >> 5, st = zz & 31;
  int b = z >> 3, h = z & 7;
  int s0 = st * 64;
  int tid = threadIdx.x;
  int w = tid >> 6, l = tid & 63;
  int l15 = l & 15, lg4 = l >> 4, l7 = l & 7;
  float sigma = fabsf(aggL[h]) + 0.001f;
  float cpos = -sigma * (1.f / 16.f);

  // stage kland16 (B-operand, swizzled)
  for (int c = tid; c < 128 * 8; c += 256) {
    int k = c >> 3, kc = c & 7;
    f16x8 v = *(const f16x8*)&kland16[((long)b * NL + k) * 64 + kc * 8];
    *(f16x8*)&Kl[k * 64 + ((kc ^ (k & 7)) << 3)] = v;
  }
  // stage m2 transposed [d][k]
  const float* mp = m2 + (long)z * NL * VF;
  for (int c = tid; c < 128 * 16; c += 256) {
    int k = c >> 4, c4 = (c & 15) << 2;
    float4 v4 = *(const float4*)&mp[k * 64 + c4];
    int kc = k >> 3, ki = k & 7;
    M2t[(c4 + 0) * 128 + ((kc ^ ((c4 + 0) & 7)) << 3) + ki] = (f16)v4.x;
    M2t[(c4 + 1) * 128 + ((kc ^ ((c4 + 1) & 7)) << 3) + ki] = (f16)v4.y;
    M2t[(c4 + 2) * 128 + ((kc ^ ((c4 + 2) & 7)) << 3) + ki] = (f16)v4.z;
    M2t[(c4 + 3) * 128 + ((kc ^ ((c4 + 3) & 7)) << 3) + ki] = (f16)v4.w;
  }
  __syncthreads();

  // Q fragments straight from global Eq16
  long qrow = (long)z * S + s0 + w * 16 + l15;
  f16x8 af[2];
  #pragma unroll
  for (int kh = 0; kh < 2; ++kh)
    af[kh] = *(const f16x8*)&Eq16[qrow * 64 + kh * 32 + lg4 * 8];

  // logits
  f32x4 sc[8];
  #pragma unroll
  for (int ct = 0; ct < 8; ++ct) {
    int n = ct * 16 + l15;
    f16x8 b0 = *(const f16x8*)&Kl[n * 64 + ((lg4 ^ (n & 7)) << 3)];
    f16x8 b1 = *(const f16x8*)&Kl[n * 64 + (((4 + lg4) ^ (n & 7)) << 3)];
    f32x4 zz4 = (f32x4){0.f, 0.f, 0.f, 0.f};
    zz4 = __builtin_amdgcn_mfma_f32_16x16x32_f16(af[0], b0, zz4, 0, 0, 0);
    sc[ct] = __builtin_amdgcn_mfma_f32_16x16x32_f16(af[1], b1, zz4, 0, 0, 0);
  }
  // analytic pos + row max
  float tmax[4] = {-INFINITY, -INFINITY, -INFINITY, -INFINITY};
  #pragma unroll
  for (int ct = 0; ct < 8; ++ct) {
    int lm = ct * 16 + l15;
    #pragma unroll
    for (int r = 0; r < 4; ++r) {
      int spos = s0 + w * 16 + lg4 * 4 + r;
      float a = (float)(spos - 16 * lm);
      float ac = fminf(fmaxf(a, 0.f), 15.f);
      float dd = fabsf(a - ac);
      float sum = ac * ac - 15.f * ac + 120.f + 16.f * dd;
      float s = sc[ct][r] + cpos * sum;
      sc[ct][r] = s;
      tmax[r] = fmaxf(tmax[r], s);
    }
  }
  #pragma unroll
  for (int r = 0; r < 4; ++r) {
    #pragma unroll
    for (int o = 1; o < 16; o <<= 1)
      tmax[r] = fmaxf(tmax[r], __shfl_xor(tmax[r], o));
  }
  float lsum[4] = {0.f, 0.f, 0.f, 0.f};
  #pragma unroll
  for (int ct = 0; ct < 8; ++ct) {
    #pragma unroll
    for (int r = 0; r < 4; ++r) {
      float p = expf(sc[ct][r] - tmax[r]);
      sc[ct][r] = p;
      lsum[r] += p;
    }
  }
  #pragma unroll
  for (int r = 0; r < 4; ++r) {
    #pragma unroll
    for (int o = 1; o < 16; o <<= 1)
      lsum[r] += __shfl_xor(lsum[r], o);
    lsum[r] = 1.f / lsum[r];
  }
  // P -> wave-private swizzled LDS (normalized)
  f16* Pw = &Pb[w * 16 * 128];
  #pragma unroll
  for (int ct = 0; ct < 8; ++ct) {
    int kc = ct * 2 + (l15 >> 3);
    int ki = l15 & 7;
    #pragma unroll
    for (int r = 0; r < 4; ++r) {
      int row = lg4 * 4 + r;
      Pw[row * 128 + ((kc ^ (row & 7)) << 3) + ki] = (f16)(sc[ct][r] * lsum[r]);
    }
  }
  // PV
  f32x4 Oa[4];
  #pragma unroll
  for (int i = 0; i < 4; ++i) Oa[i] = (f32x4){0.f, 0.f, 0.f, 0.f};
  #pragma unroll
  for (int ks = 0; ks < 4; ++ks) {
    f16x8 pa = *(const f16x8*)&Pw[l15 * 128 + (((ks * 4 + lg4) ^ l7) << 3)];
    #pragma unroll
    for (int dt = 0; dt < 4; ++dt) {
      int n = dt * 16 + l15;
      f16x8 bv = *(const f16x8*)&M2t[n * 128 + (((ks * 4 + lg4) ^ (n & 7)) << 3)];
      Oa[dt] = __builtin_amdgcn_mfma_f32_16x16x32_f16(pa, bv, Oa[dt], 0, 0, 0);
    }
  }
  // epilogue: +proj, write merged arena
  #pragma unroll
  for (int r = 0; r < 4; ++r) {
    long srow = (long)b * S + s0 + w * 16 + lg4 * 4 + r;
    int r7 = (int)(srow & 7);
    #pragma unroll
    for (int dt = 0; dt < 4; ++dt) {
      int col = dt * 16 + l15;
      float v = Oa[dt][r] + proj[srow * VF + col];
      merged[srow * (long)HV + h * 64 + (((col >> 3) ^ r7) << 3) + (col & 7)] = (f16)v;
    }
  }
}

} // namespace

extern "C" void kernel_launch(void* const* d_in, const int* in_sizes, int n_in,
                              void* d_out, int out_size, void* d_ws, size_t ws_size,
                              hipStream_t stream)
{
  const float* lat   = (const float*)d_in[0];
  const float* masks = (const float*)d_in[1];
  const float* xemb  = (const float*)d_in[2];
  const float* ccls  = (const float*)d_in[4];
  const float* qlin  = (const float*)d_in[5];
  const float* klin  = (const float*)d_in[6];
  const float* vlin  = (const float*)d_in[7];
  const float* plin  = (const float*)d_in[8];
  const float* agg   = (const float*)d_in[9];
  const float* cfeat = (const float*)d_in[10];
  float* out = (float*)d_out;
  float* ws = (float*)d_ws;

  long off = 0;
  auto allocF = [&](long n) { float* p = ws + off; off += (n + 3) & ~3L; return p; };
  auto allocH = [&](long n) { f16* p = (f16*)(ws + off); off += ((n + 1) / 2 + 3) & ~3L; return p; };

  f16* origA = allocH(ROWS * KSF);
  f16* vbufA = allocH(ROWS * KSF);
  f16* merged = allocH(ROWS * (long)HV);
  f16* WQt = allocH(16L * 64 * KSF);
  f16* WKt = allocH(2L * 64 * KSF);
  f16* WVt = allocH(16L * 64 * KSF);
  f16* WPt = allocH(2L * 64 * KSF);
  f16* WCFt = allocH((long)KSF * 512);
  f16* WCCt = allocH(64L * 512);
  f16* Ek16 = allocH((long)B * S * 64);
  f16* Ev16 = allocH((long)B * H * S * 64);
  f16* Eq16 = allocH((long)B * H * S * 64);
  f16* qland16 = allocH((long)B * H * NL * DF);
  f16* kland16 = allocH((long)B * NL * DF);
  float* cl     = allocF(ROWS * HS);
  float* Eq     = allocF((long)B * H * S * DF);
  float* EkB    = allocF((long)B * S * DF);
  float* projb  = allocF((long)B * S * VF);
  float* qland  = allocF((long)B * H * NL * DF);
  float* kland  = allocF((long)B * NL * DF);
  float* possel = allocF((long)H * NL * S);
  float* possel2= allocF((long)H * NL * NL);
  float* k2b    = allocF((long)B * H * NL * NL);
  float* kv3    = allocF((long)B * H * NL * VF);
  float* m2b    = allocF((long)B * H * NL * VF);
  float* colmax = allocF(64);

  k_cl<<<(int)(ROWS / 4), 256, 0, stream>>>(lat, masks, cl);
  k_cvta<<<(int)(ROWS * 168 / 256), 256, 0, stream>>>(xemb, cl, origA);

  auto cvtw = [&](const float* src, f16* dst, int K, int N, int Npad, int KS, long srcZ, int nz) {
    long total = (long)nz * Npad * (KS / 8);
    k_cvtw<<<(int)((total + 255) / 256), 256, 0, stream>>>(src, dst, K, N, Npad, KS, srcZ, total);
  };
  cvtw(qlin, WQt, FEAT, 64, 64, KSF, (long)FEATP * 64, 16);
  cvtw(klin, WKt, FEAT, 64, 64, KSF, (long)FEATP * 64, 2);
  cvtw(vlin, WVt, FEAT, 64, 64, KSF, (long)FEATP * 64, 16);
  cvtw(plin, WPt, FEAT, 64, 64, KSF, (long)FEATP * 64, 2);
  cvtw(cfeat, WCFt, 512, FEAT, KSF, 512, 0, 1);
  cvtw(ccls, WCCt, 512, HS, 64, 512, 0, 1);

  const f16* Aact = origA;
  for (int layer = 0; layer < 2; ++layer) {
    const f16* wq = WQt + (long)layer * 8 * 64 * KSF;
    const f16* wk = WKt + (long)layer * 64 * KSF;
    const f16* wvv = WVt + (long)layer * 8 * 64 * KSF;
    const f16* wp = WPt + (long)layer * 64 * KSF;
    const float* bq = qlin + (long)layer * 8 * FEATP * 64 + (long)(FEATP - 2) * 64;
    const float* bk = klin + (long)layer * FEATP * 64 + (long)(FEATP - 2) * 64;
    const float* bv = vlin + (long)layer * 8 * FEATP * 64 + (long)(FEATP - 2) * 64;
    const float* bp = plin + (long)layer * FEATP * 64 + (long)(FEATP - 2) * 64;
    const float* ag = agg + layer * H;

    dim3 gQ(8, 1, 64), gK(8, 1, 8);
    k_mgemm<<<gQ, 256, 0, stream>>>(Aact, (long)S * KSF, 8, wq, 64L * KSF, 8, 21, 4,
        Eq, (long)S * 64, 64, bq, (long)FEATP * 64, INV_SCALE, Eq16, 64, nullptr);
    k_mgemm<<<gK, 256, 0, stream>>>(Aact, (long)S * KSF, 1, wk, 0, 1, 21, 4,
        EkB, (long)S * 64, 64, bk, 0, INV_SCALE, Ek16, 64, nullptr);
    k_mgemm<<<gQ, 256, 0, stream>>>(Aact, (long)S * KSF, 8, wvv, 64L * KSF, 8, 21, 3,
        nullptr, (long)S * 64, 64, bv, (long)FEATP * 64, 1.0f, Ev16, 64, nullptr);
    k_mgemm<<<gK, 256, 0, stream>>>(origA, (long)S * KSF, 1, wp, 0, 1, 21, 0,
        projb, (long)S * 64, 64, bp, 0, 0.5f, nullptr, 64, nullptr);

    k_segmean<<<B * H * NL, 64, 0, stream>>>(Eq, qland, qland16);
    k_segmean<<<B * NL, 64, 0, stream>>>(EkB, kland, kland16);
    k_possel<<<H * NL, 256, 0, stream>>>(ag, possel);
    k_possel2<<<H * NL, 128, 0, stream>>>(possel, possel2);

    k_kernel2<<<B * H, 256, 0, stream>>>(qland, kland, possel2, k2b, colmax);
    k_kernel3<<<B * H * 2, 256, 0, stream>>>(qland16, Ek16, Ev16, ag, masks, kv3);
    k_inverse<<<B * H, 512, 0, stream>>>(k2b, colmax, kv3, m2b);
    k_k1attn<<<B * H * (S / 64), 256, 0, stream>>>(Eq16, kland16, ag, m2b, projb, merged);

    if (layer == 0) {
      dim3 gC(64, 21, 1);
      k_mgemm<<<gC, 256, 0, stream>>>(merged, 0, 1, WCFt, 0, 1, 8, 1,
          nullptr, 0, 0, nullptr, 0, 1.0f, vbufA, FEAT, nullptr);
      Aact = vbufA;
    } else {
      dim3 gO(64, 1, 1);
      k_mgemm<<<gO, 256, 0, stream>>>(merged, 0, 1, WCCt, 0, 1, 8, 2,
          out, 0, HS, nullptr, 0, 1.0f, nullptr, HS, masks);
    }
  }
  (void)in_sizes; (void)n_in; (void)out_size; (void)ws_size;
}

// Round 6
// 831.488 us; speedup vs baseline: 7.5168x; 1.0927x over previous
//
#include <hip/hip_runtime.h>
#include <math.h>

// ESMMimicryModule: B=8 S=2048 H=8 NL=128 DF=VF=64 NF=1280 HS=33 FEAT=1313
// Round 5: k_inverse -> 1024 thr / 16 waves, pre-folded affine terms at write
// (pure f16x8 B loads), f16x4 packed transposed writes, race-free V update,
// wave-reduced colmax. mgemm modes 1/3 epilogue staged via LDS (f16x8 stores);
// Eq/Ek now fp16-only (segmean reads f16). possel/possel2 replaced by the
// closed form -sigma*(l==m ? 5.3125 : 16|l-m|) inline in k_kernel2.

namespace {

constexpr int B = 8, S = 2048, H = 8, NL = 128, DF = 64, VF = 64;
constexpr int NF = 1280, HS = 33, FEAT = 1313, FEATP = 1314;
constexpr int SEG = 16, HV = H * VF;            // 512
constexpr int KSF = 1344;                        // padded feature-K (21*64)
constexpr long ROWS = (long)B * S;               // 16384
constexpr float INV_SCALE = 0.35355339059327373f;

typedef _Float16 f16;
typedef _Float16 f16x8 __attribute__((ext_vector_type(8)));
typedef _Float16 f16x4 __attribute__((ext_vector_type(4)));
typedef float f32x4 __attribute__((ext_vector_type(4)));

// ---------------------------------------------------------------- cl = softmax(latent)*mask
__global__ __launch_bounds__(256) void k_cl(
    const float* __restrict__ lat, const float* __restrict__ masks,
    float* __restrict__ cl)
{
  long row = (long)blockIdx.x * 4 + (threadIdx.x >> 6);
  int l = threadIdx.x & 63;
  float v = (l < HS) ? lat[row * HS + l] : -INFINITY;
  float m = v;
  #pragma unroll
  for (int o = 32; o; o >>= 1) m = fmaxf(m, __shfl_xor(m, o));
  float e = (l < HS) ? expf(v - m) : 0.f;
  float s = e;
  #pragma unroll
  for (int o = 32; o; o >>= 1) s += __shfl_xor(s, o);
  if (l < HS) cl[row * HS + l] = e / s * masks[row];
}

// ---------------------------------------------------------------- origA fp16 arena (swizzled)
__global__ __launch_bounds__(256) void k_cvta(
    const float* __restrict__ xemb, const float* __restrict__ cl,
    f16* __restrict__ dst)
{
  long idx = (long)blockIdx.x * 256 + threadIdx.x;  // chunk id (row,c)
  long row = idx / 168;
  int c = (int)(idx - row * 168);
  int t = c >> 3, cs = c & 7;
  int cd = cs ^ ((int)row & 7);
  int k0 = t * 64 + cd * 8;
  f16x8 v;
  #pragma unroll
  for (int i = 0; i < 8; ++i) {
    int k = k0 + i;
    float f = 0.f;
    if (k < NF) f = xemb[row * NF + k];
    else if (k < FEAT) f = cl[row * HS + (k - NF)];
    v[i] = (f16)f;
  }
  *(f16x8*)&dst[idx * 8] = v;
}

// ---------------------------------------------------------------- weight -> Wt fp16 arena
__global__ __launch_bounds__(256) void k_cvtw(
    const float* __restrict__ src, f16* __restrict__ dst,
    int K, int N, int Npad, int KS, long srcZ, long total)
{
  long idx = (long)blockIdx.x * 256 + threadIdx.x;
  if (idx >= total) return;
  long cpz = (long)Npad * (KS >> 3);
  long z = idx / cpz;
  long rem = idx - z * cpz;
  int n = (int)(rem / (KS >> 3));
  int c = (int)(rem - (long)n * (KS >> 3));
  int t = c >> 3, cs = c & 7;
  int cd = cs ^ (n & 7);
  int k0 = t * 64 + cd * 8;
  const float* sp = src + z * srcZ;
  f16x8 v;
  #pragma unroll
  for (int i = 0; i < 8; ++i) {
    int k = k0 + i;
    v[i] = (f16)((k < K && n < N) ? sp[(long)k * N + n] : 0.f);
  }
  *(f16x8*)&dst[idx * 8] = v;
}

// ---------------------------------------------------------------- fp16 MFMA GEMM
// mode 0: fp32 C = (acc + bias)*scale
// mode 1: fp16 swizzled arena (KSF stride, zero-fill col>=NR), LDS-staged
// mode 2: fp32 out * mask, col<NR
// mode 3: fp16 row-major out (64 cols), (acc+bias)*scale, LDS-staged
__global__ __launch_bounds__(256, 2) void k_mgemm(
    const f16* __restrict__ A, long aZOff, int aDiv,
    const f16* __restrict__ Wt, long wZOff, int wMod,
    int KT, int mode,
    float* __restrict__ C, long cZOff, int ldC,
    const float* __restrict__ biasBase, long biasZOff, float scale,
    f16* __restrict__ outA, int NR, const float* __restrict__ mask)
{
  const long KS = (long)KT * 64;
  int z = blockIdx.z;
  const f16* Ap = A + (long)(z / aDiv) * aZOff;
  const f16* Wp = Wt + (long)(z % wMod) * wZOff;
  long m0 = (long)blockIdx.x * 256;
  int n0 = blockIdx.y * 64;
  constexpr int BOFF = 256 * 64;
  __shared__ f16 lds[2][(256 + 64) * 64];
  int tid = threadIdx.x;
  int wv = tid >> 6, l = tid & 63;

  const f16* aW = Ap + (m0 + wv * 64 + (l >> 3)) * KS + (l & 7) * 8;
  const f16* bW = Wp + ((long)(n0 + wv * 16 + (l >> 3))) * KS + (l & 7) * 8;

  f32x4 acc[4][4];
  #pragma unroll
  for (int i = 0; i < 4; ++i)
    #pragma unroll
    for (int j = 0; j < 4; ++j) acc[i][j] = (f32x4){0.f, 0.f, 0.f, 0.f};

  auto stage = [&](int buf, int t) {
    f16* la = &lds[buf][(wv * 64) * 64];
    const f16* ga = aW + (long)t * 64;
    #pragma unroll
    for (int j = 0; j < 8; ++j)
      __builtin_amdgcn_global_load_lds(
          (const __attribute__((address_space(1))) void*)(ga + (long)j * 8 * KS),
          (__attribute__((address_space(3))) void*)(la + j * 8 * 64), 16, 0, 0);
    f16* lb = &lds[buf][BOFF + (wv * 16) * 64];
    const f16* gb = bW + (long)t * 64;
    #pragma unroll
    for (int j = 0; j < 2; ++j)
      __builtin_amdgcn_global_load_lds(
          (const __attribute__((address_space(1))) void*)(gb + (long)j * 8 * KS),
          (__attribute__((address_space(3))) void*)(lb + j * 8 * 64), 16, 0, 0);
  };

  stage(0, 0);
  int rA = (wv * 64 + (l & 15)) * 64;
  int rB = BOFF + (l & 15) * 64;
  int lc = l >> 4, lx = l & 7;
  for (int t = 0; t < KT; ++t) {
    int nb = t & 1;
    if (t + 1 < KT) {
      stage(nb ^ 1, t + 1);
      asm volatile("s_waitcnt vmcnt(10)" ::: "memory");
    } else {
      asm volatile("s_waitcnt vmcnt(0)" ::: "memory");
    }
    __syncthreads();
    const f16* base = &lds[nb][0];
    f16x8 af[4][2], bf[4][2];
    #pragma unroll
    for (int mi = 0; mi < 4; ++mi)
      #pragma unroll
      for (int kh = 0; kh < 2; ++kh)
        af[mi][kh] = *(const f16x8*)&base[rA + mi * 16 * 64 + (((kh * 4 + lc) ^ lx) << 3)];
    #pragma unroll
    for (int ni = 0; ni < 4; ++ni)
      #pragma unroll
      for (int kh = 0; kh < 2; ++kh)
        bf[ni][kh] = *(const f16x8*)&base[rB + ni * 16 * 64 + (((kh * 4 + lc) ^ lx) << 3)];
    #pragma unroll
    for (int mi = 0; mi < 4; ++mi)
      #pragma unroll
      for (int ni = 0; ni < 4; ++ni) {
        acc[mi][ni] = __builtin_amdgcn_mfma_f32_16x16x32_f16(af[mi][0], bf[ni][0], acc[mi][ni], 0, 0, 0);
        acc[mi][ni] = __builtin_amdgcn_mfma_f32_16x16x32_f16(af[mi][1], bf[ni][1], acc[mi][ni], 0, 0, 0);
      }
    __syncthreads();
  }

  int lr = (l >> 4) * 4;
  int lcn = l & 15;
  if (mode == 0) {
    float* Cp = C + (long)z * cZOff;
    const float* bp = biasBase ? biasBase + (long)(z % wMod) * biasZOff : nullptr;
    #pragma unroll
    for (int ni = 0; ni < 4; ++ni) {
      int col = n0 + ni * 16 + lcn;
      float bv = bp ? bp[col] : 0.f;
      #pragma unroll
      for (int mi = 0; mi < 4; ++mi) {
        long row = m0 + wv * 64 + mi * 16 + lr;
        #pragma unroll
        for (int r = 0; r < 4; ++r)
          Cp[(row + r) * (long)ldC + col] = (acc[mi][ni][r] + bv) * scale;
      }
    }
  } else if (mode == 2) {
    #pragma unroll
    for (int mi = 0; mi < 4; ++mi) {
      #pragma unroll
      for (int r = 0; r < 4; ++r) {
        long row = m0 + wv * 64 + mi * 16 + lr + r;
        float mv = mask[row];
        #pragma unroll
        for (int ni = 0; ni < 4; ++ni) {
          int col = n0 + ni * 16 + lcn;
          if (col < NR) C[row * (long)ldC + col] = acc[mi][ni][r] * mv;
        }
      }
    }
  } else {  // mode 1 / 3: stage f16 tile in LDS, vectorized global writes
    f16* st = &lds[0][0];
    const float* bp = biasBase ? biasBase + (long)(z % wMod) * biasZOff : nullptr;
    #pragma unroll
    for (int ni = 0; ni < 4; ++ni) {
      int coll = ni * 16 + lcn;
      int col = n0 + coll;
      float bv = bp ? bp[col] : 0.f;
      bool ok = col < NR;
      #pragma unroll
      for (int mi = 0; mi < 4; ++mi) {
        int rowl = wv * 64 + mi * 16 + lr;
        #pragma unroll
        for (int r = 0; r < 4; ++r) {
          float v = ok ? (acc[mi][ni][r] + bv) * scale : 0.f;
          st[(rowl + r) * 64 + coll] = (f16)v;
        }
      }
    }
    __syncthreads();
    if (mode == 3) {
      f16* o16 = outA + (long)z * cZOff;
      for (int c = tid; c < 2048; c += 256) {
        int row = c >> 3, cc = c & 7;
        f16x8 v = *(const f16x8*)&st[row * 64 + cc * 8];
        *(f16x8*)&o16[(m0 + row) * 64 + cc * 8] = v;
      }
    } else {
      int tt = n0 >> 6;
      for (int c = tid; c < 2048; c += 256) {
        int row = c >> 3, cd = c & 7;
        long grow = m0 + row;
        int r7 = (int)grow & 7;
        f16x8 v = *(const f16x8*)&st[row * 64 + cd * 8];
        *(f16x8*)&outA[grow * KSF + tt * 64 + ((cd ^ r7) << 3)] = v;
      }
    }
  }
}

// ---------------------------------------------------------------- landmarks (f16 input)
__global__ void k_segmean(const f16* __restrict__ in, float* __restrict__ out,
                          f16* __restrict__ out16)
{
  long zl = blockIdx.x;
  long z = zl / NL, lm = zl % NL;
  int d = threadIdx.x;
  const f16* p = in + (z * S + lm * SEG) * (long)DF + d;
  float s = 0.f;
  #pragma unroll
  for (int i = 0; i < SEG; i++) s += (float)p[(long)i * DF];
  float v = s * (1.f / SEG);
  out[(z * NL + lm) * (long)DF + d] = v;
  if (out16) out16[(z * NL + lm) * (long)DF + d] = (f16)v;
}

// ---------------------------------------------------------------- kernel_2 (analytic possel2)
__global__ __launch_bounds__(256) void k_kernel2(
    const float* __restrict__ qland, const float* __restrict__ kland,
    const float* __restrict__ aggL, float* __restrict__ k2,
    float* __restrict__ colmax)
{
  int z = blockIdx.x; int b = z / H; int h = z % H;
  float sigma = fabsf(aggL[h]) + 0.001f;
  __shared__ float qs[NL][68];
  __shared__ float ks[NL][68];
  __shared__ float lg[NL][NL + 1];
  int tid = threadIdx.x;
  for (int idx = tid; idx < NL * DF; idx += 256) {
    int r = idx >> 6, d = idx & 63;
    qs[r][d] = qland[((long)z * NL + r) * DF + d];
    ks[r][d] = kland[((long)b * NL + r) * DF + d];
  }
  __syncthreads();
  int r = tid >> 1, half = tid & 1;
  float lmax = -INFINITY;
  for (int c = 0; c < 64; c++) {
    int m = half * 64 + c;
    float s = 0.f;
    #pragma unroll
    for (int d = 0; d < DF; d += 4) {
      float4 q = *(const float4*)&qs[r][d];
      float4 k4 = *(const float4*)&ks[m][d];
      s += q.x * k4.x + q.y * k4.y + q.z * k4.z + q.w * k4.w;
    }
    // possel2[h,r,m] = -sigma * (r==m ? 5.3125 : 16|r-m|)
    float dd = fabsf((float)(r - m));
    s += -sigma * ((r == m) ? 5.3125f : 16.f * dd);
    lg[r][m] = s;
    lmax = fmaxf(lmax, s);
  }
  lmax = fmaxf(lmax, __shfl_xor(lmax, 1));
  float lsum = 0.f;
  for (int c = 0; c < 64; c++) {
    int m = half * 64 + c;
    float e = expf(lg[r][m] - lmax);
    lg[r][m] = e; lsum += e;
  }
  lsum += __shfl_xor(lsum, 1);
  float inv = 1.f / lsum;
  for (int c = 0; c < 64; c++) {
    int m = half * 64 + c;
    float p = lg[r][m] * inv;
    lg[r][m] = p;
    k2[((long)z * NL + r) * NL + m] = p;
  }
  __syncthreads();
  float myc = 0.f;
  if (tid < NL) {
    for (int rr = 0; rr < NL; rr++) myc += lg[rr][tid];
  }
  float wm = myc;
  #pragma unroll
  for (int o = 32; o; o >>= 1) wm = fmaxf(wm, __shfl_xor(wm, o));
  __shared__ float wred[4];
  if ((tid & 63) == 0) wred[tid >> 6] = wm;
  __syncthreads();
  if (tid == 0)
    colmax[z] = fmaxf(fmaxf(wred[0], wred[1]), fmaxf(wred[2], wred[3]));
}

// ---------------------------------------------------------------- kernel_3 (flash MFMA)
__global__ __launch_bounds__(256, 2) void k_kernel3(
    const f16* __restrict__ qland16, const f16* __restrict__ Ek16,
    const f16* __restrict__ Ev16, const float* __restrict__ aggL,
    const float* __restrict__ masks, float* __restrict__ kv3)
{
  __shared__ __align__(16) f16 Qs[64 * 64];
  __shared__ __align__(16) f16 Ks[128 * 64];
  __shared__ __align__(16) f16 Vt[64 * 128];
  __shared__ __align__(16) f16 Pb[4 * 16 * 128];
  __shared__ float Ms[128];
  int z2 = blockIdx.x;
  int z = z2 >> 1, half = z2 & 1;
  int b = z >> 3, h = z & 7;
  int q0 = half * 64;
  int tid = threadIdx.x;
  int w = tid >> 6, l = tid & 63;
  float sigma = fabsf(aggL[h]) + 0.001f;
  float cpos = -sigma * (1.f / 16.f);

  for (int c = tid; c < 64 * 8; c += 256) {
    int q = c >> 3, kc = c & 7;
    f16x8 v = *(const f16x8*)&qland16[((long)z * NL + q0 + q) * 64 + kc * 8];
    *(f16x8*)&Qs[q * 64 + ((kc ^ (q & 7)) << 3)] = v;
  }

  f16* Pw = &Pb[w * 16 * 128];
  int l15 = l & 15, lg4 = l >> 4, l7 = l & 7;
  f32x4 Oa[4];
  #pragma unroll
  for (int i = 0; i < 4; ++i) Oa[i] = (f32x4){0.f, 0.f, 0.f, 0.f};
  float mrun[4] = {-INFINITY, -INFINITY, -INFINITY, -INFINITY};
  float lrun[4] = {0.f, 0.f, 0.f, 0.f};

  for (int t0 = 0; t0 < S / 128; ++t0) {
    __syncthreads();
    for (int c = tid; c < 1024; c += 256) {
      int k = c >> 3, kc = c & 7;
      f16x8 v = *(const f16x8*)&Ek16[((long)b * S + t0 * 128 + k) * 64 + kc * 8];
      *(f16x8*)&Ks[k * 64 + ((kc ^ (k & 7)) << 3)] = v;
    }
    for (int c = tid; c < 1024; c += 256) {
      int k = c & 127, dc = c >> 7;
      f16x8 v = *(const f16x8*)&Ev16[((long)z * S + t0 * 128 + k) * 64 + dc * 8];
      int kc = k >> 3, ki = k & 7;
      #pragma unroll
      for (int j = 0; j < 8; ++j) {
        int d = dc * 8 + j;
        Vt[d * 128 + ((kc ^ (d & 7)) << 3) + ki] = v[j];
      }
    }
    if (tid < 128)
      Ms[tid] = (masks[(long)b * S + t0 * 128 + tid] == 0.f) ? -1e6f : 0.f;
    __syncthreads();

    f16x8 af[2];
    #pragma unroll
    for (int kh = 0; kh < 2; ++kh)
      af[kh] = *(const f16x8*)&Qs[(w * 16 + l15) * 64 + (((kh * 4 + lg4) ^ l7) << 3)];
    f32x4 sc[8];
    #pragma unroll
    for (int ct = 0; ct < 8; ++ct) {
      int n = ct * 16 + l15;
      f16x8 b0 = *(const f16x8*)&Ks[n * 64 + (((lg4) ^ (n & 7)) << 3)];
      f16x8 b1 = *(const f16x8*)&Ks[n * 64 + (((4 + lg4) ^ (n & 7)) << 3)];
      f32x4 zz = (f32x4){0.f, 0.f, 0.f, 0.f};
      zz = __builtin_amdgcn_mfma_f32_16x16x32_f16(af[0], b0, zz, 0, 0, 0);
      sc[ct] = __builtin_amdgcn_mfma_f32_16x16x32_f16(af[1], b1, zz, 0, 0, 0);
    }
    float tmax[4] = {-INFINITY, -INFINITY, -INFINITY, -INFINITY};
    #pragma unroll
    for (int ct = 0; ct < 8; ++ct) {
      float mk = Ms[ct * 16 + l15];
      int key = t0 * 128 + ct * 16 + l15;
      #pragma unroll
      for (int r = 0; r < 4; ++r) {
        int qg = q0 + w * 16 + lg4 * 4 + r;
        float a = (float)(key - 16 * qg);
        float ac = fminf(fmaxf(a, 0.f), 15.f);
        float dd = fabsf(a - ac);
        float sum = ac * ac - 15.f * ac + 120.f + 16.f * dd;
        float s = sc[ct][r] + cpos * sum + mk;
        sc[ct][r] = s;
        tmax[r] = fmaxf(tmax[r], s);
      }
    }
    #pragma unroll
    for (int r = 0; r < 4; ++r) {
      #pragma unroll
      for (int o = 1; o < 16; o <<= 1)
        tmax[r] = fmaxf(tmax[r], __shfl_xor(tmax[r], o));
    }
    float fr[4], lsum[4];
    #pragma unroll
    for (int r = 0; r < 4; ++r) {
      float mnew = fmaxf(mrun[r], tmax[r]);
      fr[r] = expf(mrun[r] - mnew);
      mrun[r] = mnew;
      lsum[r] = 0.f;
    }
    #pragma unroll
    for (int ct = 0; ct < 8; ++ct) {
      #pragma unroll
      for (int r = 0; r < 4; ++r) {
        float p = expf(sc[ct][r] - mrun[r]);
        sc[ct][r] = p;
        lsum[r] += p;
      }
    }
    #pragma unroll
    for (int r = 0; r < 4; ++r) {
      #pragma unroll
      for (int o = 1; o < 16; o <<= 1)
        lsum[r] += __shfl_xor(lsum[r], o);
      lrun[r] = lrun[r] * fr[r] + lsum[r];
    }
    f32x4 fv = (f32x4){fr[0], fr[1], fr[2], fr[3]};
    #pragma unroll
    for (int dt = 0; dt < 4; ++dt) Oa[dt] *= fv;
    #pragma unroll
    for (int ct = 0; ct < 8; ++ct) {
      int kc = ct * 2 + (l15 >> 3);
      int ki = l15 & 7;
      #pragma unroll
      for (int r = 0; r < 4; ++r) {
        int row = lg4 * 4 + r;
        Pw[row * 128 + ((kc ^ (row & 7)) << 3) + ki] = (f16)sc[ct][r];
      }
    }
    #pragma unroll
    for (int ks = 0; ks < 4; ++ks) {
      f16x8 pa = *(const f16x8*)&Pw[l15 * 128 + (((ks * 4 + lg4) ^ l7) << 3)];
      #pragma unroll
      for (int dt = 0; dt < 4; ++dt) {
        int n = dt * 16 + l15;
        f16x8 bv = *(const f16x8*)&Vt[n * 128 + (((ks * 4 + lg4) ^ (n & 7)) << 3)];
        Oa[dt] = __builtin_amdgcn_mfma_f32_16x16x32_f16(pa, bv, Oa[dt], 0, 0, 0);
      }
    }
  }
  #pragma unroll
  for (int r = 0; r < 4; ++r) {
    float inv = 1.f / lrun[r];
    long qg = q0 + w * 16 + lg4 * 4 + r;
    #pragma unroll
    for (int dt = 0; dt < 4; ++dt)
      kv3[((long)z * NL + qg) * VF + dt * 16 + l15] = Oa[dt][r] * inv;
  }
}

// ---------------------------------------------------------------- inverse (MFMA fp16 NS, 16 waves)
// 6x { X=key@V ; Y1=X@(7I-X) ; Y3=X@(15I-Y1) ; V=V@(3.25I-.25Y3) } then m2=V@kv3.
// Affine terms pre-folded into transposed writes (B loads are pure f16x8);
// V-update prefetches A rows to regs + barrier (race-free in-place update).
__global__ __launch_bounds__(1024, 4) void k_inverse(
    const float* __restrict__ k2g, const float* __restrict__ colmax,
    const float* __restrict__ kv3, float* __restrict__ m2)
{
  __shared__ __align__(16) f16 Vn[128 * 128];
  __shared__ __align__(16) f16 Vt[128 * 128];
  __shared__ __align__(16) f16 Pn[128 * 128];
  __shared__ __align__(16) f16 Pt[128 * 128];
  int z = blockIdx.x;
  int tid = threadIdx.x;
  int w = tid >> 6, l = tid & 63;
  int l15 = l & 15, lg4 = l >> 4;
  int wr = (w >> 2) * 32, wc = (w & 3) * 32;

  float cv = colmax[l];
  #pragma unroll
  for (int o = 32; o; o >>= 1) cv = fmaxf(cv, __shfl_xor(cv, o));
  float recip = 1.f / cv;

  const float* key = k2g + (long)z * NL * NL;
  auto swz = [](int r, int c) { return r * 128 + ((((c >> 3) ^ (r & 15))) << 3) + (c & 7); };

  // init: Vt = recip*key image (V^T), Vn = transpose (V)
  for (int idx = tid; idx < 128 * 32; idx += 1024) {
    int r = idx >> 5, c4 = (idx & 31) << 2;
    float4 kk = *(const float4*)&key[r * 128 + c4];
    f16x4 hv;
    hv[0] = (f16)(recip * kk.x); hv[1] = (f16)(recip * kk.y);
    hv[2] = (f16)(recip * kk.z); hv[3] = (f16)(recip * kk.w);
    *(f16x4*)&Vt[swz(r, c4)] = hv;
    Vn[swz(c4 + 0, r)] = hv[0];
    Vn[swz(c4 + 1, r)] = hv[1];
    Vn[swz(c4 + 2, r)] = hv[2];
    Vn[swz(c4 + 3, r)] = hv[3];
  }
  // key A-fragments (rows wr..wr+31), pinned across iterations
  f16x8 keyA[2][4];
  #pragma unroll
  for (int mi = 0; mi < 2; ++mi)
    #pragma unroll
    for (int ks = 0; ks < 4; ++ks) {
      int r = wr + mi * 16 + l15;
      int k0 = ks * 32 + lg4 * 8;
      float4 a = *(const float4*)&key[r * 128 + k0];
      float4 bq = *(const float4*)&key[r * 128 + k0 + 4];
      f16x8 v;
      v[0] = (f16)a.x; v[1] = (f16)a.y; v[2] = (f16)a.z; v[3] = (f16)a.w;
      v[4] = (f16)bq.x; v[5] = (f16)bq.y; v[6] = (f16)bq.z; v[7] = (f16)bq.w;
      keyA[mi][ks] = v;
    }
  __syncthreads();

  f32x4 acc[2][2];
  auto MMc = [&](const f16* Aimg, const f16* Bimg) {
    #pragma unroll
    for (int mi = 0; mi < 2; ++mi)
      #pragma unroll
      for (int ni = 0; ni < 2; ++ni) acc[mi][ni] = (f32x4){0.f, 0.f, 0.f, 0.f};
    #pragma unroll
    for (int ks = 0; ks < 4; ++ks) {
      int k0 = ks * 32 + lg4 * 8;
      f16x8 bf[2];
      bf[0] = *(const f16x8*)&Bimg[swz(wc + l15, k0)];
      bf[1] = *(const f16x8*)&Bimg[swz(wc + 16 + l15, k0)];
      f16x8 af[2];
      if (Aimg) {
        af[0] = *(const f16x8*)&Aimg[swz(wr + l15, k0)];
        af[1] = *(const f16x8*)&Aimg[swz(wr + 16 + l15, k0)];
      } else {
        af[0] = keyA[0][ks]; af[1] = keyA[1][ks];
      }
      #pragma unroll
      for (int mi = 0; mi < 2; ++mi)
        #pragma unroll
        for (int ni = 0; ni < 2; ++ni)
          acc[mi][ni] = __builtin_amdgcn_mfma_f32_16x16x32_f16(af[mi], bf[ni], acc[mi][ni], 0, 0, 0);
    }
  };
  // Nout: raw normal image (optional). Tout: transposed image with fold
  // image[col][row] = aT*acc[row][col] + bT*(row==col)  (packed f16x4 store)
  auto store = [&](f16* Nout, f16* Tout, float aT, float bT) {
    #pragma unroll
    for (int mi = 0; mi < 2; ++mi) {
      int row0 = wr + mi * 16 + lg4 * 4;
      #pragma unroll
      for (int ni = 0; ni < 2; ++ni) {
        int col = wc + ni * 16 + l15;
        f16x4 tv;
        #pragma unroll
        for (int r = 0; r < 4; ++r) {
          float v = acc[mi][ni][r];
          if (Nout) Nout[swz(row0 + r, col)] = (f16)v;
          tv[r] = (f16)(aT * v + ((row0 + r == col) ? bT : 0.f));
        }
        *(f16x4*)&Tout[col * 128 + ((((row0 >> 3) ^ (col & 15))) << 3) + (row0 & 7)] = tv;
      }
    }
  };

  for (int it = 0; it < 6; ++it) {
    MMc(nullptr, Vt);  store(Pn, Pt, -1.f, 7.f);        __syncthreads();
    MMc(Pn, Pt);       store(nullptr, Vt, -1.f, 15.f);  __syncthreads();
    MMc(Pn, Vt);       store(nullptr, Pt, -0.25f, 3.25f); __syncthreads();
    // V update: prefetch A rows of Vn, barrier, then MFMA + in-place write
    f16x8 aV[2][4];
    #pragma unroll
    for (int ks = 0; ks < 4; ++ks) {
      int k0 = ks * 32 + lg4 * 8;
      aV[0][ks] = *(const f16x8*)&Vn[swz(wr + l15, k0)];
      aV[1][ks] = *(const f16x8*)&Vn[swz(wr + 16 + l15, k0)];
    }
    __syncthreads();
    #pragma unroll
    for (int mi = 0; mi < 2; ++mi)
      #pragma unroll
      for (int ni = 0; ni < 2; ++ni) acc[mi][ni] = (f32x4){0.f, 0.f, 0.f, 0.f};
    #pragma unroll
    for (int ks = 0; ks < 4; ++ks) {
      int k0 = ks * 32 + lg4 * 8;
      f16x8 bf[2];
      bf[0] = *(const f16x8*)&Pt[swz(wc + l15, k0)];
      bf[1] = *(const f16x8*)&Pt[swz(wc + 16 + l15, k0)];
      #pragma unroll
      for (int mi = 0; mi < 2; ++mi)
        #pragma unroll
        for (int ni = 0; ni < 2; ++ni)
          acc[mi][ni] = __builtin_amdgcn_mfma_f32_16x16x32_f16(aV[mi][ks], bf[ni], acc[mi][ni], 0, 0, 0);
    }
    store(Vn, Vt, 1.f, 0.f);
    __syncthreads();
  }

  // m2 = V @ kv3 : stage kv3^T into Pn
  const float* kp = kv3 + (long)z * NL * VF;
  for (int idx = tid; idx < 128 * 16; idx += 1024) {
    int k = idx >> 4, c4 = (idx & 15) << 2;
    float4 v4 = *(const float4*)&kp[k * 64 + c4];
    Pn[swz(c4 + 0, k)] = (f16)v4.x;
    Pn[swz(c4 + 1, k)] = (f16)v4.y;
    Pn[swz(c4 + 2, k)] = (f16)v4.z;
    Pn[swz(c4 + 3, k)] = (f16)v4.w;
  }
  __syncthreads();
  // wave w: rows (w>>1)*16.., col half (w&1)*32
  int r0 = (w >> 1) * 16, ch = (w & 1) * 32;
  f32x4 accF[2];
  #pragma unroll
  for (int ni = 0; ni < 2; ++ni) accF[ni] = (f32x4){0.f, 0.f, 0.f, 0.f};
  #pragma unroll
  for (int ks = 0; ks < 4; ++ks) {
    int k0 = ks * 32 + lg4 * 8;
    f16x8 af = *(const f16x8*)&Vn[swz(r0 + l15, k0)];
    #pragma unroll
    for (int ni = 0; ni < 2; ++ni) {
      f16x8 bf = *(const f16x8*)&Pn[swz(ch + ni * 16 + l15, k0)];
      accF[ni] = __builtin_amdgcn_mfma_f32_16x16x32_f16(af, bf, accF[ni], 0, 0, 0);
    }
  }
  float* mp = m2 + (long)z * NL * VF;
  #pragma unroll
  for (int ni = 0; ni < 2; ++ni)
    #pragma unroll
    for (int r = 0; r < 4; ++r)
      mp[(long)(r0 + lg4 * 4 + r) * VF + ch + ni * 16 + l15] = accF[ni][r];
}

// ---------------------------------------------------------------- kernel_1 + attn + merge (MFMA)
__global__ __launch_bounds__(256, 2) void k_k1attn(
    const f16* __restrict__ Eq16, const f16* __restrict__ kland16,
    const float* __restrict__ aggL, const float* __restrict__ m2,
    const float* __restrict__ proj, f16* __restrict__ merged)
{
  __shared__ __align__(16) f16 Kl[128 * 64];
  __shared__ __align__(16) f16 M2t[64 * 128];
  __shared__ __align__(16) f16 Pb[4 * 16 * 128];
  int zz = blockIdx.x;
  int z = zz >> 5, st = zz & 31;
  int b = z >> 3, h = z & 7;
  int s0 = st * 64;
  int tid = threadIdx.x;
  int w = tid >> 6, l = tid & 63;
  int l15 = l & 15, lg4 = l >> 4, l7 = l & 7;
  float sigma = fabsf(aggL[h]) + 0.001f;
  float cpos = -sigma * (1.f / 16.f);

  for (int c = tid; c < 128 * 8; c += 256) {
    int k = c >> 3, kc = c & 7;
    f16x8 v = *(const f16x8*)&kland16[((long)b * NL + k) * 64 + kc * 8];
    *(f16x8*)&Kl[k * 64 + ((kc ^ (k & 7)) << 3)] = v;
  }
  const float* mp = m2 + (long)z * NL * VF;
  for (int c = tid; c < 128 * 16; c += 256) {
    int k = c >> 4, c4 = (c & 15) << 2;
    float4 v4 = *(const float4*)&mp[k * 64 + c4];
    int kc = k >> 3, ki = k & 7;
    M2t[(c4 + 0) * 128 + ((kc ^ ((c4 + 0) & 7)) << 3) + ki] = (f16)v4.x;
    M2t[(c4 + 1) * 128 + ((kc ^ ((c4 + 1) & 7)) << 3) + ki] = (f16)v4.y;
    M2t[(c4 + 2) * 128 + ((kc ^ ((c4 + 2) & 7)) << 3) + ki] = (f16)v4.z;
    M2t[(c4 + 3) * 128 + ((kc ^ ((c4 + 3) & 7)) << 3) + ki] = (f16)v4.w;
  }
  __syncthreads();

  long qrow = (long)z * S + s0 + w * 16 + l15;
  f16x8 af[2];
  #pragma unroll
  for (int kh = 0; kh < 2; ++kh)
    af[kh] = *(const f16x8*)&Eq16[qrow * 64 + kh * 32 + lg4 * 8];

  f32x4 sc[8];
  #pragma unroll
  for (int ct = 0; ct < 8; ++ct) {
    int n = ct * 16 + l15;
    f16x8 b0 = *(const f16x8*)&Kl[n * 64 + ((lg4 ^ (n & 7)) << 3)];
    f16x8 b1 = *(const f16x8*)&Kl[n * 64 + (((4 + lg4) ^ (n & 7)) << 3)];
    f32x4 zz4 = (f32x4){0.f, 0.f, 0.f, 0.f};
    zz4 = __builtin_amdgcn_mfma_f32_16x16x32_f16(af[0], b0, zz4, 0, 0, 0);
    sc[ct] = __builtin_amdgcn_mfma_f32_16x16x32_f16(af[1], b1, zz4, 0, 0, 0);
  }
  float tmax[4] = {-INFINITY, -INFINITY, -INFINITY, -INFINITY};
  #pragma unroll
  for (int ct = 0; ct < 8; ++ct) {
    int lm = ct * 16 + l15;
    #pragma unroll
    for (int r = 0; r < 4; ++r) {
      int spos = s0 + w * 16 + lg4 * 4 + r;
      float a = (float)(spos - 16 * lm);
      float ac = fminf(fmaxf(a, 0.f), 15.f);
      float dd = fabsf(a - ac);
      float sum = ac * ac - 15.f * ac + 120.f + 16.f * dd;
      float s = sc[ct][r] + cpos * sum;
      sc[ct][r] = s;
      tmax[r] = fmaxf(tmax[r], s);
    }
  }
  #pragma unroll
  for (int r = 0; r < 4; ++r) {
    #pragma unroll
    for (int o = 1; o < 16; o <<= 1)
      tmax[r] = fmaxf(tmax[r], __shfl_xor(tmax[r], o));
  }
  float lsum[4] = {0.f, 0.f, 0.f, 0.f};
  #pragma unroll
  for (int ct = 0; ct < 8; ++ct) {
    #pragma unroll
    for (int r = 0; r < 4; ++r) {
      float p = expf(sc[ct][r] - tmax[r]);
      sc[ct][r] = p;
      lsum[r] += p;
    }
  }
  #pragma unroll
  for (int r = 0; r < 4; ++r) {
    #pragma unroll
    for (int o = 1; o < 16; o <<= 1)
      lsum[r] += __shfl_xor(lsum[r], o);
    lsum[r] = 1.f / lsum[r];
  }
  f16* Pw = &Pb[w * 16 * 128];
  #pragma unroll
  for (int ct = 0; ct < 8; ++ct) {
    int kc = ct * 2 + (l15 >> 3);
    int ki = l15 & 7;
    #pragma unroll
    for (int r = 0; r < 4; ++r) {
      int row = lg4 * 4 + r;
      Pw[row * 128 + ((kc ^ (row & 7)) << 3) + ki] = (f16)(sc[ct][r] * lsum[r]);
    }
  }
  f32x4 Oa[4];
  #pragma unroll
  for (int i = 0; i < 4; ++i) Oa[i] = (f32x4){0.f, 0.f, 0.f, 0.f};
  #pragma unroll
  for (int ks = 0; ks < 4; ++ks) {
    f16x8 pa = *(const f16x8*)&Pw[l15 * 128 + (((ks * 4 + lg4) ^ l7) << 3)];
    #pragma unroll
    for (int dt = 0; dt < 4; ++dt) {
      int n = dt * 16 + l15;
      f16x8 bv = *(const f16x8*)&M2t[n * 128 + (((ks * 4 + lg4) ^ (n & 7)) << 3)];
      Oa[dt] = __builtin_amdgcn_mfma_f32_16x16x32_f16(pa, bv, Oa[dt], 0, 0, 0);
    }
  }
  #pragma unroll
  for (int r = 0; r < 4; ++r) {
    long srow = (long)b * S + s0 + w * 16 + lg4 * 4 + r;
    int r7 = (int)(srow & 7);
    #pragma unroll
    for (int dt = 0; dt < 4; ++dt) {
      int col = dt * 16 + l15;
      float v = Oa[dt][r] + proj[srow * VF + col];
      merged[srow * (long)HV + h * 64 + (((col >> 3) ^ r7) << 3) + (col & 7)] = (f16)v;
    }
  }
}

} // namespace

extern "C" void kernel_launch(void* const* d_in, const int* in_sizes, int n_in,
                              void* d_out, int out_size, void* d_ws, size_t ws_size,
                              hipStream_t stream)
{
  const float* lat   = (const float*)d_in[0];
  const float* masks = (const float*)d_in[1];
  const float* xemb  = (const float*)d_in[2];
  const float* ccls  = (const float*)d_in[4];
  const float* qlin  = (const float*)d_in[5];
  const float* klin  = (const float*)d_in[6];
  const float* vlin  = (const float*)d_in[7];
  const float* plin  = (const float*)d_in[8];
  const float* agg   = (const float*)d_in[9];
  const float* cfeat = (const float*)d_in[10];
  float* out = (float*)d_out;
  float* ws = (float*)d_ws;

  long off = 0;
  auto allocF = [&](long n) { float* p = ws + off; off += (n + 3) & ~3L; return p; };
  auto allocH = [&](long n) { f16* p = (f16*)(ws + off); off += ((n + 1) / 2 + 3) & ~3L; return p; };

  f16* origA = allocH(ROWS * KSF);
  f16* vbufA = allocH(ROWS * KSF);
  f16* merged = allocH(ROWS * (long)HV);
  f16* WQt = allocH(16L * 64 * KSF);
  f16* WKt = allocH(2L * 64 * KSF);
  f16* WVt = allocH(16L * 64 * KSF);
  f16* WPt = allocH(2L * 64 * KSF);
  f16* WCFt = allocH((long)KSF * 512);
  f16* WCCt = allocH(64L * 512);
  f16* Ek16 = allocH((long)B * S * 64);
  f16* Ev16 = allocH((long)B * H * S * 64);
  f16* Eq16 = allocH((long)B * H * S * 64);
  f16* qland16 = allocH((long)B * H * NL * DF);
  f16* kland16 = allocH((long)B * NL * DF);
  float* cl     = allocF(ROWS * HS);
  float* projb  = allocF((long)B * S * VF);
  float* qland  = allocF((long)B * H * NL * DF);
  float* kland  = allocF((long)B * NL * DF);
  float* k2b    = allocF((long)B * H * NL * NL);
  float* kv3    = allocF((long)B * H * NL * VF);
  float* m2b    = allocF((long)B * H * NL * VF);
  float* colmax = allocF(64);

  k_cl<<<(int)(ROWS / 4), 256, 0, stream>>>(lat, masks, cl);
  k_cvta<<<(int)(ROWS * 168 / 256), 256, 0, stream>>>(xemb, cl, origA);

  auto cvtw = [&](const float* src, f16* dst, int K, int N, int Npad, int KS, long srcZ, int nz) {
    long total = (long)nz * Npad * (KS / 8);
    k_cvtw<<<(int)((total + 255) / 256), 256, 0, stream>>>(src, dst, K, N, Npad, KS, srcZ, total);
  };
  cvtw(qlin, WQt, FEAT, 64, 64, KSF, (long)FEATP * 64, 16);
  cvtw(klin, WKt, FEAT, 64, 64, KSF, (long)FEATP * 64, 2);
  cvtw(vlin, WVt, FEAT, 64, 64, KSF, (long)FEATP * 64, 16);
  cvtw(plin, WPt, FEAT, 64, 64, KSF, (long)FEATP * 64, 2);
  cvtw(cfeat, WCFt, 512, FEAT, KSF, 512, 0, 1);
  cvtw(ccls, WCCt, 512, HS, 64, 512, 0, 1);

  const f16* Aact = origA;
  for (int layer = 0; layer < 2; ++layer) {
    const f16* wq = WQt + (long)layer * 8 * 64 * KSF;
    const f16* wk = WKt + (long)layer * 64 * KSF;
    const f16* wvv = WVt + (long)layer * 8 * 64 * KSF;
    const f16* wp = WPt + (long)layer * 64 * KSF;
    const float* bq = qlin + (long)layer * 8 * FEATP * 64 + (long)(FEATP - 2) * 64;
    const float* bk = klin + (long)layer * FEATP * 64 + (long)(FEATP - 2) * 64;
    const float* bv = vlin + (long)layer * 8 * FEATP * 64 + (long)(FEATP - 2) * 64;
    const float* bp = plin + (long)layer * FEATP * 64 + (long)(FEATP - 2) * 64;
    const float* ag = agg + layer * H;

    dim3 gQ(8, 1, 64), gK(8, 1, 8);
    k_mgemm<<<gQ, 256, 0, stream>>>(Aact, (long)S * KSF, 8, wq, 64L * KSF, 8, 21, 3,
        nullptr, (long)S * 64, 64, bq, (long)FEATP * 64, INV_SCALE, Eq16, 64, nullptr);
    k_mgemm<<<gK, 256, 0, stream>>>(Aact, (long)S * KSF, 1, wk, 0, 1, 21, 3,
        nullptr, (long)S * 64, 64, bk, 0, INV_SCALE, Ek16, 64, nullptr);
    k_mgemm<<<gQ, 256, 0, stream>>>(Aact, (long)S * KSF, 8, wvv, 64L * KSF, 8, 21, 3,
        nullptr, (long)S * 64, 64, bv, (long)FEATP * 64, 1.0f, Ev16, 64, nullptr);
    k_mgemm<<<gK, 256, 0, stream>>>(origA, (long)S * KSF, 1, wp, 0, 1, 21, 0,
        projb, (long)S * 64, 64, bp, 0, 0.5f, nullptr, 64, nullptr);

    k_segmean<<<B * H * NL, 64, 0, stream>>>(Eq16, qland, qland16);
    k_segmean<<<B * NL, 64, 0, stream>>>(Ek16, kland, kland16);

    k_kernel2<<<B * H, 256, 0, stream>>>(qland, kland, ag, k2b, colmax);
    k_kernel3<<<B * H * 2, 256, 0, stream>>>(qland16, Ek16, Ev16, ag, masks, kv3);
    k_inverse<<<B * H, 1024, 0, stream>>>(k2b, colmax, kv3, m2b);
    k_k1attn<<<B * H * (S / 64), 256, 0, stream>>>(Eq16, kland16, ag, m2b, projb, merged);

    if (layer == 0) {
      dim3 gC(64, 21, 1);
      k_mgemm<<<gC, 256, 0, stream>>>(merged, 0, 1, WCFt, 0, 1, 8, 1,
          nullptr, 0, 0, nullptr, 0, 1.0f, vbufA, FEAT, nullptr);
      Aact = vbufA;
    } else {
      dim3 gO(64, 1, 1);
      k_mgemm<<<gO, 256, 0, stream>>>(merged, 0, 1, WCCt, 0, 1, 8, 2,
          out, 0, HS, nullptr, 0, 1.0f, nullptr, HS, masks);
    }
  }
  (void)in_sizes; (void)n_in; (void)out_size; (void)ws_size;
}

// Round 7
// 736.913 us; speedup vs baseline: 8.4815x; 1.1283x over previous
//
#include <hip/hip_runtime.h>
#include <math.h>

// ESMMimicryModule: B=8 S=2048 H=8 NL=128 DF=VF=64 NF=1280 HS=33 FEAT=1313
// Round 6: k_kernel3 split-S flash: grid x4 over key chunks (512 keys each),
// partial (U, m, l) per chunk + k_merge combine (exact regrouping). Fixes the
// 128-blocks-on-256-CUs occupancy hole (5.6% -> ~11%, serial chain 16 -> 4).

namespace {

constexpr int B = 8, S = 2048, H = 8, NL = 128, DF = 64, VF = 64;
constexpr int NF = 1280, HS = 33, FEAT = 1313, FEATP = 1314;
constexpr int SEG = 16, HV = H * VF;            // 512
constexpr int KSF = 1344;                        // padded feature-K (21*64)
constexpr int NSPL = 4;                          // key chunks in split-S flash
constexpr long ROWS = (long)B * S;               // 16384
constexpr float INV_SCALE = 0.35355339059327373f;

typedef _Float16 f16;
typedef _Float16 f16x8 __attribute__((ext_vector_type(8)));
typedef _Float16 f16x4 __attribute__((ext_vector_type(4)));
typedef float f32x4 __attribute__((ext_vector_type(4)));

// ---------------------------------------------------------------- cl = softmax(latent)*mask
__global__ __launch_bounds__(256) void k_cl(
    const float* __restrict__ lat, const float* __restrict__ masks,
    float* __restrict__ cl)
{
  long row = (long)blockIdx.x * 4 + (threadIdx.x >> 6);
  int l = threadIdx.x & 63;
  float v = (l < HS) ? lat[row * HS + l] : -INFINITY;
  float m = v;
  #pragma unroll
  for (int o = 32; o; o >>= 1) m = fmaxf(m, __shfl_xor(m, o));
  float e = (l < HS) ? expf(v - m) : 0.f;
  float s = e;
  #pragma unroll
  for (int o = 32; o; o >>= 1) s += __shfl_xor(s, o);
  if (l < HS) cl[row * HS + l] = e / s * masks[row];
}

// ---------------------------------------------------------------- origA fp16 arena (swizzled)
__global__ __launch_bounds__(256) void k_cvta(
    const float* __restrict__ xemb, const float* __restrict__ cl,
    f16* __restrict__ dst)
{
  long idx = (long)blockIdx.x * 256 + threadIdx.x;  // chunk id (row,c)
  long row = idx / 168;
  int c = (int)(idx - row * 168);
  int t = c >> 3, cs = c & 7;
  int cd = cs ^ ((int)row & 7);
  int k0 = t * 64 + cd * 8;
  f16x8 v;
  #pragma unroll
  for (int i = 0; i < 8; ++i) {
    int k = k0 + i;
    float f = 0.f;
    if (k < NF) f = xemb[row * NF + k];
    else if (k < FEAT) f = cl[row * HS + (k - NF)];
    v[i] = (f16)f;
  }
  *(f16x8*)&dst[idx * 8] = v;
}

// ---------------------------------------------------------------- weight -> Wt fp16 arena
__global__ __launch_bounds__(256) void k_cvtw(
    const float* __restrict__ src, f16* __restrict__ dst,
    int K, int N, int Npad, int KS, long srcZ, long total)
{
  long idx = (long)blockIdx.x * 256 + threadIdx.x;
  if (idx >= total) return;
  long cpz = (long)Npad * (KS >> 3);
  long z = idx / cpz;
  long rem = idx - z * cpz;
  int n = (int)(rem / (KS >> 3));
  int c = (int)(rem - (long)n * (KS >> 3));
  int t = c >> 3, cs = c & 7;
  int cd = cs ^ (n & 7);
  int k0 = t * 64 + cd * 8;
  const float* sp = src + z * srcZ;
  f16x8 v;
  #pragma unroll
  for (int i = 0; i < 8; ++i) {
    int k = k0 + i;
    v[i] = (f16)((k < K && n < N) ? sp[(long)k * N + n] : 0.f);
  }
  *(f16x8*)&dst[idx * 8] = v;
}

// ---------------------------------------------------------------- fp16 MFMA GEMM
// mode 0: fp32 C = (acc + bias)*scale
// mode 1: fp16 swizzled arena (KSF stride, zero-fill col>=NR), LDS-staged
// mode 2: fp32 out * mask, col<NR
// mode 3: fp16 row-major out (64 cols), (acc+bias)*scale, LDS-staged
__global__ __launch_bounds__(256, 2) void k_mgemm(
    const f16* __restrict__ A, long aZOff, int aDiv,
    const f16* __restrict__ Wt, long wZOff, int wMod,
    int KT, int mode,
    float* __restrict__ C, long cZOff, int ldC,
    const float* __restrict__ biasBase, long biasZOff, float scale,
    f16* __restrict__ outA, int NR, const float* __restrict__ mask)
{
  const long KS = (long)KT * 64;
  int z = blockIdx.z;
  const f16* Ap = A + (long)(z / aDiv) * aZOff;
  const f16* Wp = Wt + (long)(z % wMod) * wZOff;
  long m0 = (long)blockIdx.x * 256;
  int n0 = blockIdx.y * 64;
  constexpr int BOFF = 256 * 64;
  __shared__ f16 lds[2][(256 + 64) * 64];
  int tid = threadIdx.x;
  int wv = tid >> 6, l = tid & 63;

  const f16* aW = Ap + (m0 + wv * 64 + (l >> 3)) * KS + (l & 7) * 8;
  const f16* bW = Wp + ((long)(n0 + wv * 16 + (l >> 3))) * KS + (l & 7) * 8;

  f32x4 acc[4][4];
  #pragma unroll
  for (int i = 0; i < 4; ++i)
    #pragma unroll
    for (int j = 0; j < 4; ++j) acc[i][j] = (f32x4){0.f, 0.f, 0.f, 0.f};

  auto stage = [&](int buf, int t) {
    f16* la = &lds[buf][(wv * 64) * 64];
    const f16* ga = aW + (long)t * 64;
    #pragma unroll
    for (int j = 0; j < 8; ++j)
      __builtin_amdgcn_global_load_lds(
          (const __attribute__((address_space(1))) void*)(ga + (long)j * 8 * KS),
          (__attribute__((address_space(3))) void*)(la + j * 8 * 64), 16, 0, 0);
    f16* lb = &lds[buf][BOFF + (wv * 16) * 64];
    const f16* gb = bW + (long)t * 64;
    #pragma unroll
    for (int j = 0; j < 2; ++j)
      __builtin_amdgcn_global_load_lds(
          (const __attribute__((address_space(1))) void*)(gb + (long)j * 8 * KS),
          (__attribute__((address_space(3))) void*)(lb + j * 8 * 64), 16, 0, 0);
  };

  stage(0, 0);
  int rA = (wv * 64 + (l & 15)) * 64;
  int rB = BOFF + (l & 15) * 64;
  int lc = l >> 4, lx = l & 7;
  for (int t = 0; t < KT; ++t) {
    int nb = t & 1;
    if (t + 1 < KT) {
      stage(nb ^ 1, t + 1);
      asm volatile("s_waitcnt vmcnt(10)" ::: "memory");
    } else {
      asm volatile("s_waitcnt vmcnt(0)" ::: "memory");
    }
    __syncthreads();
    const f16* base = &lds[nb][0];
    f16x8 af[4][2], bf[4][2];
    #pragma unroll
    for (int mi = 0; mi < 4; ++mi)
      #pragma unroll
      for (int kh = 0; kh < 2; ++kh)
        af[mi][kh] = *(const f16x8*)&base[rA + mi * 16 * 64 + (((kh * 4 + lc) ^ lx) << 3)];
    #pragma unroll
    for (int ni = 0; ni < 4; ++ni)
      #pragma unroll
      for (int kh = 0; kh < 2; ++kh)
        bf[ni][kh] = *(const f16x8*)&base[rB + ni * 16 * 64 + (((kh * 4 + lc) ^ lx) << 3)];
    #pragma unroll
    for (int mi = 0; mi < 4; ++mi)
      #pragma unroll
      for (int ni = 0; ni < 4; ++ni) {
        acc[mi][ni] = __builtin_amdgcn_mfma_f32_16x16x32_f16(af[mi][0], bf[ni][0], acc[mi][ni], 0, 0, 0);
        acc[mi][ni] = __builtin_amdgcn_mfma_f32_16x16x32_f16(af[mi][1], bf[ni][1], acc[mi][ni], 0, 0, 0);
      }
    __syncthreads();
  }

  int lr = (l >> 4) * 4;
  int lcn = l & 15;
  if (mode == 0) {
    float* Cp = C + (long)z * cZOff;
    const float* bp = biasBase ? biasBase + (long)(z % wMod) * biasZOff : nullptr;
    #pragma unroll
    for (int ni = 0; ni < 4; ++ni) {
      int col = n0 + ni * 16 + lcn;
      float bv = bp ? bp[col] : 0.f;
      #pragma unroll
      for (int mi = 0; mi < 4; ++mi) {
        long row = m0 + wv * 64 + mi * 16 + lr;
        #pragma unroll
        for (int r = 0; r < 4; ++r)
          Cp[(row + r) * (long)ldC + col] = (acc[mi][ni][r] + bv) * scale;
      }
    }
  } else if (mode == 2) {
    #pragma unroll
    for (int mi = 0; mi < 4; ++mi) {
      #pragma unroll
      for (int r = 0; r < 4; ++r) {
        long row = m0 + wv * 64 + mi * 16 + lr + r;
        float mv = mask[row];
        #pragma unroll
        for (int ni = 0; ni < 4; ++ni) {
          int col = n0 + ni * 16 + lcn;
          if (col < NR) C[row * (long)ldC + col] = acc[mi][ni][r] * mv;
        }
      }
    }
  } else {  // mode 1 / 3: stage f16 tile in LDS, vectorized global writes
    f16* st = &lds[0][0];
    const float* bp = biasBase ? biasBase + (long)(z % wMod) * biasZOff : nullptr;
    #pragma unroll
    for (int ni = 0; ni < 4; ++ni) {
      int coll = ni * 16 + lcn;
      int col = n0 + coll;
      float bv = bp ? bp[col] : 0.f;
      bool ok = col < NR;
      #pragma unroll
      for (int mi = 0; mi < 4; ++mi) {
        int rowl = wv * 64 + mi * 16 + lr;
        #pragma unroll
        for (int r = 0; r < 4; ++r) {
          float v = ok ? (acc[mi][ni][r] + bv) * scale : 0.f;
          st[(rowl + r) * 64 + coll] = (f16)v;
        }
      }
    }
    __syncthreads();
    if (mode == 3) {
      f16* o16 = outA + (long)z * cZOff;
      for (int c = tid; c < 2048; c += 256) {
        int row = c >> 3, cc = c & 7;
        f16x8 v = *(const f16x8*)&st[row * 64 + cc * 8];
        *(f16x8*)&o16[(m0 + row) * 64 + cc * 8] = v;
      }
    } else {
      int tt = n0 >> 6;
      for (int c = tid; c < 2048; c += 256) {
        int row = c >> 3, cd = c & 7;
        long grow = m0 + row;
        int r7 = (int)grow & 7;
        f16x8 v = *(const f16x8*)&st[row * 64 + cd * 8];
        *(f16x8*)&outA[grow * KSF + tt * 64 + ((cd ^ r7) << 3)] = v;
      }
    }
  }
}

// ---------------------------------------------------------------- landmarks (f16 input)
__global__ void k_segmean(const f16* __restrict__ in, float* __restrict__ out,
                          f16* __restrict__ out16)
{
  long zl = blockIdx.x;
  long z = zl / NL, lm = zl % NL;
  int d = threadIdx.x;
  const f16* p = in + (z * S + lm * SEG) * (long)DF + d;
  float s = 0.f;
  #pragma unroll
  for (int i = 0; i < SEG; i++) s += (float)p[(long)i * DF];
  float v = s * (1.f / SEG);
  out[(z * NL + lm) * (long)DF + d] = v;
  if (out16) out16[(z * NL + lm) * (long)DF + d] = (f16)v;
}

// ---------------------------------------------------------------- kernel_2 (analytic possel2)
__global__ __launch_bounds__(256) void k_kernel2(
    const float* __restrict__ qland, const float* __restrict__ kland,
    const float* __restrict__ aggL, float* __restrict__ k2,
    float* __restrict__ colmax)
{
  int z = blockIdx.x; int b = z / H; int h = z % H;
  float sigma = fabsf(aggL[h]) + 0.001f;
  __shared__ float qs[NL][68];
  __shared__ float ks[NL][68];
  __shared__ float lg[NL][NL + 1];
  int tid = threadIdx.x;
  for (int idx = tid; idx < NL * DF; idx += 256) {
    int r = idx >> 6, d = idx & 63;
    qs[r][d] = qland[((long)z * NL + r) * DF + d];
    ks[r][d] = kland[((long)b * NL + r) * DF + d];
  }
  __syncthreads();
  int r = tid >> 1, half = tid & 1;
  float lmax = -INFINITY;
  for (int c = 0; c < 64; c++) {
    int m = half * 64 + c;
    float s = 0.f;
    #pragma unroll
    for (int d = 0; d < DF; d += 4) {
      float4 q = *(const float4*)&qs[r][d];
      float4 k4 = *(const float4*)&ks[m][d];
      s += q.x * k4.x + q.y * k4.y + q.z * k4.z + q.w * k4.w;
    }
    float dd = fabsf((float)(r - m));
    s += -sigma * ((r == m) ? 5.3125f : 16.f * dd);
    lg[r][m] = s;
    lmax = fmaxf(lmax, s);
  }
  lmax = fmaxf(lmax, __shfl_xor(lmax, 1));
  float lsum = 0.f;
  for (int c = 0; c < 64; c++) {
    int m = half * 64 + c;
    float e = expf(lg[r][m] - lmax);
    lg[r][m] = e; lsum += e;
  }
  lsum += __shfl_xor(lsum, 1);
  float inv = 1.f / lsum;
  for (int c = 0; c < 64; c++) {
    int m = half * 64 + c;
    float p = lg[r][m] * inv;
    lg[r][m] = p;
    k2[((long)z * NL + r) * NL + m] = p;
  }
  __syncthreads();
  float myc = 0.f;
  if (tid < NL) {
    for (int rr = 0; rr < NL; rr++) myc += lg[rr][tid];
  }
  float wm = myc;
  #pragma unroll
  for (int o = 32; o; o >>= 1) wm = fmaxf(wm, __shfl_xor(wm, o));
  __shared__ float wred[4];
  if ((tid & 63) == 0) wred[tid >> 6] = wm;
  __syncthreads();
  if (tid == 0)
    colmax[z] = fmaxf(fmaxf(wred[0], wred[1]), fmaxf(wred[2], wred[3]));
}

// ---------------------------------------------------------------- kernel_3 (split-S flash MFMA)
// block = (b,h,qhalf,chunk): 64 queries x 512 keys (4 tiles). Writes partial
// U (unnormalized PV), m, l per chunk; k_merge combines exactly.
__global__ __launch_bounds__(256, 2) void k_kernel3(
    const f16* __restrict__ qland16, const f16* __restrict__ Ek16,
    const f16* __restrict__ Ev16, const float* __restrict__ aggL,
    const float* __restrict__ masks,
    float* __restrict__ partU, float* __restrict__ partML)
{
  __shared__ __align__(16) f16 Qs[64 * 64];
  __shared__ __align__(16) f16 Ks[128 * 64];
  __shared__ __align__(16) f16 Vt[64 * 128];
  __shared__ __align__(16) f16 Pb[4 * 16 * 128];
  __shared__ float Ms[128];
  int id = blockIdx.x;
  int chunk = id & (NSPL - 1);
  int z2 = id >> 2;
  int z = z2 >> 1, half = z2 & 1;
  int b = z >> 3, h = z & 7;
  int q0 = half * 64;
  int tid = threadIdx.x;
  int w = tid >> 6, l = tid & 63;
  float sigma = fabsf(aggL[h]) + 0.001f;
  float cpos = -sigma * (1.f / 16.f);

  for (int c = tid; c < 64 * 8; c += 256) {
    int q = c >> 3, kc = c & 7;
    f16x8 v = *(const f16x8*)&qland16[((long)z * NL + q0 + q) * 64 + kc * 8];
    *(f16x8*)&Qs[q * 64 + ((kc ^ (q & 7)) << 3)] = v;
  }

  f16* Pw = &Pb[w * 16 * 128];
  int l15 = l & 15, lg4 = l >> 4, l7 = l & 7;
  f32x4 Oa[4];
  #pragma unroll
  for (int i = 0; i < 4; ++i) Oa[i] = (f32x4){0.f, 0.f, 0.f, 0.f};
  float mrun[4] = {-INFINITY, -INFINITY, -INFINITY, -INFINITY};
  float lrun[4] = {0.f, 0.f, 0.f, 0.f};

  int t0beg = chunk * (S / 128 / NSPL), t0end = t0beg + S / 128 / NSPL;
  for (int t0 = t0beg; t0 < t0end; ++t0) {
    __syncthreads();
    for (int c = tid; c < 1024; c += 256) {
      int k = c >> 3, kc = c & 7;
      f16x8 v = *(const f16x8*)&Ek16[((long)b * S + t0 * 128 + k) * 64 + kc * 8];
      *(f16x8*)&Ks[k * 64 + ((kc ^ (k & 7)) << 3)] = v;
    }
    for (int c = tid; c < 1024; c += 256) {
      int k = c & 127, dc = c >> 7;
      f16x8 v = *(const f16x8*)&Ev16[((long)z * S + t0 * 128 + k) * 64 + dc * 8];
      int kc = k >> 3, ki = k & 7;
      #pragma unroll
      for (int j = 0; j < 8; ++j) {
        int d = dc * 8 + j;
        Vt[d * 128 + ((kc ^ (d & 7)) << 3) + ki] = v[j];
      }
    }
    if (tid < 128)
      Ms[tid] = (masks[(long)b * S + t0 * 128 + tid] == 0.f) ? -1e6f : 0.f;
    __syncthreads();

    f16x8 af[2];
    #pragma unroll
    for (int kh = 0; kh < 2; ++kh)
      af[kh] = *(const f16x8*)&Qs[(w * 16 + l15) * 64 + (((kh * 4 + lg4) ^ l7) << 3)];
    f32x4 sc[8];
    #pragma unroll
    for (int ct = 0; ct < 8; ++ct) {
      int n = ct * 16 + l15;
      f16x8 b0 = *(const f16x8*)&Ks[n * 64 + (((lg4) ^ (n & 7)) << 3)];
      f16x8 b1 = *(const f16x8*)&Ks[n * 64 + (((4 + lg4) ^ (n & 7)) << 3)];
      f32x4 zz = (f32x4){0.f, 0.f, 0.f, 0.f};
      zz = __builtin_amdgcn_mfma_f32_16x16x32_f16(af[0], b0, zz, 0, 0, 0);
      sc[ct] = __builtin_amdgcn_mfma_f32_16x16x32_f16(af[1], b1, zz, 0, 0, 0);
    }
    float tmax[4] = {-INFINITY, -INFINITY, -INFINITY, -INFINITY};
    #pragma unroll
    for (int ct = 0; ct < 8; ++ct) {
      float mk = Ms[ct * 16 + l15];
      int key = t0 * 128 + ct * 16 + l15;
      #pragma unroll
      for (int r = 0; r < 4; ++r) {
        int qg = q0 + w * 16 + lg4 * 4 + r;
        float a = (float)(key - 16 * qg);
        float ac = fminf(fmaxf(a, 0.f), 15.f);
        float dd = fabsf(a - ac);
        float sum = ac * ac - 15.f * ac + 120.f + 16.f * dd;
        float s = sc[ct][r] + cpos * sum + mk;
        sc[ct][r] = s;
        tmax[r] = fmaxf(tmax[r], s);
      }
    }
    #pragma unroll
    for (int r = 0; r < 4; ++r) {
      #pragma unroll
      for (int o = 1; o < 16; o <<= 1)
        tmax[r] = fmaxf(tmax[r], __shfl_xor(tmax[r], o));
    }
    float fr[4], lsum[4];
    #pragma unroll
    for (int r = 0; r < 4; ++r) {
      float mnew = fmaxf(mrun[r], tmax[r]);
      fr[r] = expf(mrun[r] - mnew);
      mrun[r] = mnew;
      lsum[r] = 0.f;
    }
    #pragma unroll
    for (int ct = 0; ct < 8; ++ct) {
      #pragma unroll
      for (int r = 0; r < 4; ++r) {
        float p = expf(sc[ct][r] - mrun[r]);
        sc[ct][r] = p;
        lsum[r] += p;
      }
    }
    #pragma unroll
    for (int r = 0; r < 4; ++r) {
      #pragma unroll
      for (int o = 1; o < 16; o <<= 1)
        lsum[r] += __shfl_xor(lsum[r], o);
      lrun[r] = lrun[r] * fr[r] + lsum[r];
    }
    f32x4 fv = (f32x4){fr[0], fr[1], fr[2], fr[3]};
    #pragma unroll
    for (int dt = 0; dt < 4; ++dt) Oa[dt] *= fv;
    #pragma unroll
    for (int ct = 0; ct < 8; ++ct) {
      int kc = ct * 2 + (l15 >> 3);
      int ki = l15 & 7;
      #pragma unroll
      for (int r = 0; r < 4; ++r) {
        int row = lg4 * 4 + r;
        Pw[row * 128 + ((kc ^ (row & 7)) << 3) + ki] = (f16)sc[ct][r];
      }
    }
    #pragma unroll
    for (int ks = 0; ks < 4; ++ks) {
      f16x8 pa = *(const f16x8*)&Pw[l15 * 128 + (((ks * 4 + lg4) ^ l7) << 3)];
      #pragma unroll
      for (int dt = 0; dt < 4; ++dt) {
        int n = dt * 16 + l15;
        f16x8 bv = *(const f16x8*)&Vt[n * 128 + (((ks * 4 + lg4) ^ (n & 7)) << 3)];
        Oa[dt] = __builtin_amdgcn_mfma_f32_16x16x32_f16(pa, bv, Oa[dt], 0, 0, 0);
      }
    }
  }
  // partial epilogue: U (unnormalized), m, l per chunk
  #pragma unroll
  for (int r = 0; r < 4; ++r) {
    long qg = q0 + w * 16 + lg4 * 4 + r;
    long base = ((long)z * NL + qg) * NSPL + chunk;
    #pragma unroll
    for (int dt = 0; dt < 4; ++dt)
      partU[base * 64 + dt * 16 + l15] = Oa[dt][r];
    if (l15 == 0) {
      partML[base * 2] = mrun[r];
      partML[base * 2 + 1] = lrun[r];
    }
  }
}

// ---------------------------------------------------------------- merge split-flash partials
__global__ __launch_bounds__(256) void k_merge(
    const float* __restrict__ partU, const float* __restrict__ partML,
    float* __restrict__ kv3)
{
  int id = blockIdx.x;
  int z = id >> 2, part = id & 3;
  int t = threadIdx.x;
  int q = part * 32 + (t >> 3);
  int c8 = (t & 7) * 8;
  long base = ((long)z * NL + q) * NSPL;
  float m[NSPL], lv[NSPL];
  #pragma unroll
  for (int c = 0; c < NSPL; ++c) {
    m[c] = partML[(base + c) * 2];
    lv[c] = partML[(base + c) * 2 + 1];
  }
  float M = fmaxf(fmaxf(m[0], m[1]), fmaxf(m[2], m[3]));
  float L = 0.f, sc[NSPL];
  #pragma unroll
  for (int c = 0; c < NSPL; ++c) {
    sc[c] = expf(m[c] - M);
    L += lv[c] * sc[c];
  }
  float o[8] = {};
  #pragma unroll
  for (int c = 0; c < NSPL; ++c) {
    const float* up = &partU[(base + c) * 64 + c8];
    float4 a = *(const float4*)up;
    float4 bq = *(const float4*)(up + 4);
    o[0] += sc[c] * a.x; o[1] += sc[c] * a.y; o[2] += sc[c] * a.z; o[3] += sc[c] * a.w;
    o[4] += sc[c] * bq.x; o[5] += sc[c] * bq.y; o[6] += sc[c] * bq.z; o[7] += sc[c] * bq.w;
  }
  float invL = 1.f / L;
  float* kp = &kv3[((long)z * NL + q) * 64 + c8];
  #pragma unroll
  for (int j = 0; j < 8; ++j) kp[j] = o[j] * invL;
}

// ---------------------------------------------------------------- inverse (MFMA fp16 NS, 16 waves)
__global__ __launch_bounds__(1024, 4) void k_inverse(
    const float* __restrict__ k2g, const float* __restrict__ colmax,
    const float* __restrict__ kv3, float* __restrict__ m2)
{
  __shared__ __align__(16) f16 Vn[128 * 128];
  __shared__ __align__(16) f16 Vt[128 * 128];
  __shared__ __align__(16) f16 Pn[128 * 128];
  __shared__ __align__(16) f16 Pt[128 * 128];
  int z = blockIdx.x;
  int tid = threadIdx.x;
  int w = tid >> 6, l = tid & 63;
  int l15 = l & 15, lg4 = l >> 4;
  int wr = (w >> 2) * 32, wc = (w & 3) * 32;

  float cv = colmax[l];
  #pragma unroll
  for (int o = 32; o; o >>= 1) cv = fmaxf(cv, __shfl_xor(cv, o));
  float recip = 1.f / cv;

  const float* key = k2g + (long)z * NL * NL;
  auto swz = [](int r, int c) { return r * 128 + ((((c >> 3) ^ (r & 15))) << 3) + (c & 7); };

  for (int idx = tid; idx < 128 * 32; idx += 1024) {
    int r = idx >> 5, c4 = (idx & 31) << 2;
    float4 kk = *(const float4*)&key[r * 128 + c4];
    f16x4 hv;
    hv[0] = (f16)(recip * kk.x); hv[1] = (f16)(recip * kk.y);
    hv[2] = (f16)(recip * kk.z); hv[3] = (f16)(recip * kk.w);
    *(f16x4*)&Vt[swz(r, c4)] = hv;
    Vn[swz(c4 + 0, r)] = hv[0];
    Vn[swz(c4 + 1, r)] = hv[1];
    Vn[swz(c4 + 2, r)] = hv[2];
    Vn[swz(c4 + 3, r)] = hv[3];
  }
  f16x8 keyA[2][4];
  #pragma unroll
  for (int mi = 0; mi < 2; ++mi)
    #pragma unroll
    for (int ks = 0; ks < 4; ++ks) {
      int r = wr + mi * 16 + l15;
      int k0 = ks * 32 + lg4 * 8;
      float4 a = *(const float4*)&key[r * 128 + k0];
      float4 bq = *(const float4*)&key[r * 128 + k0 + 4];
      f16x8 v;
      v[0] = (f16)a.x; v[1] = (f16)a.y; v[2] = (f16)a.z; v[3] = (f16)a.w;
      v[4] = (f16)bq.x; v[5] = (f16)bq.y; v[6] = (f16)bq.z; v[7] = (f16)bq.w;
      keyA[mi][ks] = v;
    }
  __syncthreads();

  f32x4 acc[2][2];
  auto MMc = [&](const f16* Aimg, const f16* Bimg) {
    #pragma unroll
    for (int mi = 0; mi < 2; ++mi)
      #pragma unroll
      for (int ni = 0; ni < 2; ++ni) acc[mi][ni] = (f32x4){0.f, 0.f, 0.f, 0.f};
    #pragma unroll
    for (int ks = 0; ks < 4; ++ks) {
      int k0 = ks * 32 + lg4 * 8;
      f16x8 bf[2];
      bf[0] = *(const f16x8*)&Bimg[swz(wc + l15, k0)];
      bf[1] = *(const f16x8*)&Bimg[swz(wc + 16 + l15, k0)];
      f16x8 af[2];
      if (Aimg) {
        af[0] = *(const f16x8*)&Aimg[swz(wr + l15, k0)];
        af[1] = *(const f16x8*)&Aimg[swz(wr + 16 + l15, k0)];
      } else {
        af[0] = keyA[0][ks]; af[1] = keyA[1][ks];
      }
      #pragma unroll
      for (int mi = 0; mi < 2; ++mi)
        #pragma unroll
        for (int ni = 0; ni < 2; ++ni)
          acc[mi][ni] = __builtin_amdgcn_mfma_f32_16x16x32_f16(af[mi], bf[ni], acc[mi][ni], 0, 0, 0);
    }
  };
  auto store = [&](f16* Nout, f16* Tout, float aT, float bT) {
    #pragma unroll
    for (int mi = 0; mi < 2; ++mi) {
      int row0 = wr + mi * 16 + lg4 * 4;
      #pragma unroll
      for (int ni = 0; ni < 2; ++ni) {
        int col = wc + ni * 16 + l15;
        f16x4 tv;
        #pragma unroll
        for (int r = 0; r < 4; ++r) {
          float v = acc[mi][ni][r];
          if (Nout) Nout[swz(row0 + r, col)] = (f16)v;
          tv[r] = (f16)(aT * v + ((row0 + r == col) ? bT : 0.f));
        }
        *(f16x4*)&Tout[col * 128 + ((((row0 >> 3) ^ (col & 15))) << 3) + (row0 & 7)] = tv;
      }
    }
  };

  for (int it = 0; it < 6; ++it) {
    MMc(nullptr, Vt);  store(Pn, Pt, -1.f, 7.f);        __syncthreads();
    MMc(Pn, Pt);       store(nullptr, Vt, -1.f, 15.f);  __syncthreads();
    MMc(Pn, Vt);       store(nullptr, Pt, -0.25f, 3.25f); __syncthreads();
    f16x8 aV[2][4];
    #pragma unroll
    for (int ks = 0; ks < 4; ++ks) {
      int k0 = ks * 32 + lg4 * 8;
      aV[0][ks] = *(const f16x8*)&Vn[swz(wr + l15, k0)];
      aV[1][ks] = *(const f16x8*)&Vn[swz(wr + 16 + l15, k0)];
    }
    __syncthreads();
    #pragma unroll
    for (int mi = 0; mi < 2; ++mi)
      #pragma unroll
      for (int ni = 0; ni < 2; ++ni) acc[mi][ni] = (f32x4){0.f, 0.f, 0.f, 0.f};
    #pragma unroll
    for (int ks = 0; ks < 4; ++ks) {
      int k0 = ks * 32 + lg4 * 8;
      f16x8 bf[2];
      bf[0] = *(const f16x8*)&Pt[swz(wc + l15, k0)];
      bf[1] = *(const f16x8*)&Pt[swz(wc + 16 + l15, k0)];
      #pragma unroll
      for (int mi = 0; mi < 2; ++mi)
        #pragma unroll
        for (int ni = 0; ni < 2; ++ni)
          acc[mi][ni] = __builtin_amdgcn_mfma_f32_16x16x32_f16(aV[mi][ks], bf[ni], acc[mi][ni], 0, 0, 0);
    }
    store(Vn, Vt, 1.f, 0.f);
    __syncthreads();
  }

  const float* kp = kv3 + (long)z * NL * VF;
  for (int idx = tid; idx < 128 * 16; idx += 1024) {
    int k = idx >> 4, c4 = (idx & 15) << 2;
    float4 v4 = *(const float4*)&kp[k * 64 + c4];
    Pn[swz(c4 + 0, k)] = (f16)v4.x;
    Pn[swz(c4 + 1, k)] = (f16)v4.y;
    Pn[swz(c4 + 2, k)] = (f16)v4.z;
    Pn[swz(c4 + 3, k)] = (f16)v4.w;
  }
  __syncthreads();
  int r0 = (w >> 1) * 16, ch = (w & 1) * 32;
  f32x4 accF[2];
  #pragma unroll
  for (int ni = 0; ni < 2; ++ni) accF[ni] = (f32x4){0.f, 0.f, 0.f, 0.f};
  #pragma unroll
  for (int ks = 0; ks < 4; ++ks) {
    int k0 = ks * 32 + lg4 * 8;
    f16x8 af = *(const f16x8*)&Vn[swz(r0 + l15, k0)];
    #pragma unroll
    for (int ni = 0; ni < 2; ++ni) {
      f16x8 bf = *(const f16x8*)&Pn[swz(ch + ni * 16 + l15, k0)];
      accF[ni] = __builtin_amdgcn_mfma_f32_16x16x32_f16(af, bf, accF[ni], 0, 0, 0);
    }
  }
  float* mp = m2 + (long)z * NL * VF;
  #pragma unroll
  for (int ni = 0; ni < 2; ++ni)
    #pragma unroll
    for (int r = 0; r < 4; ++r)
      mp[(long)(r0 + lg4 * 4 + r) * VF + ch + ni * 16 + l15] = accF[ni][r];
}

// ---------------------------------------------------------------- kernel_1 + attn + merge (MFMA)
__global__ __launch_bounds__(256, 2) void k_k1attn(
    const f16* __restrict__ Eq16, const f16* __restrict__ kland16,
    const float* __restrict__ aggL, const float* __restrict__ m2,
    const float* __restrict__ proj, f16* __restrict__ merged)
{
  __shared__ __align__(16) f16 Kl[128 * 64];
  __shared__ __align__(16) f16 M2t[64 * 128];
  __shared__ __align__(16) f16 Pb[4 * 16 * 128];
  int zz = blockIdx.x;
  int z = zz >> 5, st = zz & 31;
  int b = z >> 3, h = z & 7;
  int s0 = st * 64;
  int tid = threadIdx.x;
  int w = tid >> 6, l = tid & 63;
  int l15 = l & 15, lg4 = l >> 4, l7 = l & 7;
  float sigma = fabsf(aggL[h]) + 0.001f;
  float cpos = -sigma * (1.f / 16.f);

  for (int c = tid; c < 128 * 8; c += 256) {
    int k = c >> 3, kc = c & 7;
    f16x8 v = *(const f16x8*)&kland16[((long)b * NL + k) * 64 + kc * 8];
    *(f16x8*)&Kl[k * 64 + ((kc ^ (k & 7)) << 3)] = v;
  }
  const float* mp = m2 + (long)z * NL * VF;
  for (int c = tid; c < 128 * 16; c += 256) {
    int k = c >> 4, c4 = (c & 15) << 2;
    float4 v4 = *(const float4*)&mp[k * 64 + c4];
    int kc = k >> 3, ki = k & 7;
    M2t[(c4 + 0) * 128 + ((kc ^ ((c4 + 0) & 7)) << 3) + ki] = (f16)v4.x;
    M2t[(c4 + 1) * 128 + ((kc ^ ((c4 + 1) & 7)) << 3) + ki] = (f16)v4.y;
    M2t[(c4 + 2) * 128 + ((kc ^ ((c4 + 2) & 7)) << 3) + ki] = (f16)v4.z;
    M2t[(c4 + 3) * 128 + ((kc ^ ((c4 + 3) & 7)) << 3) + ki] = (f16)v4.w;
  }
  __syncthreads();

  long qrow = (long)z * S + s0 + w * 16 + l15;
  f16x8 af[2];
  #pragma unroll
  for (int kh = 0; kh < 2; ++kh)
    af[kh] = *(const f16x8*)&Eq16[qrow * 64 + kh * 32 + lg4 * 8];

  f32x4 sc[8];
  #pragma unroll
  for (int ct = 0; ct < 8; ++ct) {
    int n = ct * 16 + l15;
    f16x8 b0 = *(const f16x8*)&Kl[n * 64 + ((lg4 ^ (n & 7)) << 3)];
    f16x8 b1 = *(const f16x8*)&Kl[n * 64 + (((4 + lg4) ^ (n & 7)) << 3)];
    f32x4 zz4 = (f32x4){0.f, 0.f, 0.f, 0.f};
    zz4 = __builtin_amdgcn_mfma_f32_16x16x32_f16(af[0], b0, zz4, 0, 0, 0);
    sc[ct] = __builtin_amdgcn_mfma_f32_16x16x32_f16(af[1], b1, zz4, 0, 0, 0);
  }
  float tmax[4] = {-INFINITY, -INFINITY, -INFINITY, -INFINITY};
  #pragma unroll
  for (int ct = 0; ct < 8; ++ct) {
    int lm = ct * 16 + l15;
    #pragma unroll
    for (int r = 0; r < 4; ++r) {
      int spos = s0 + w * 16 + lg4 * 4 + r;
      float a = (float)(spos - 16 * lm);
      float ac = fminf(fmaxf(a, 0.f), 15.f);
      float dd = fabsf(a - ac);
      float sum = ac * ac - 15.f * ac + 120.f + 16.f * dd;
      float s = sc[ct][r] + cpos * sum;
      sc[ct][r] = s;
      tmax[r] = fmaxf(tmax[r], s);
    }
  }
  #pragma unroll
  for (int r = 0; r < 4; ++r) {
    #pragma unroll
    for (int o = 1; o < 16; o <<= 1)
      tmax[r] = fmaxf(tmax[r], __shfl_xor(tmax[r], o));
  }
  float lsum[4] = {0.f, 0.f, 0.f, 0.f};
  #pragma unroll
  for (int ct = 0; ct < 8; ++ct) {
    #pragma unroll
    for (int r = 0; r < 4; ++r) {
      float p = expf(sc[ct][r] - tmax[r]);
      sc[ct][r] = p;
      lsum[r] += p;
    }
  }
  #pragma unroll
  for (int r = 0; r < 4; ++r) {
    #pragma unroll
    for (int o = 1; o < 16; o <<= 1)
      lsum[r] += __shfl_xor(lsum[r], o);
    lsum[r] = 1.f / lsum[r];
  }
  f16* Pw = &Pb[w * 16 * 128];
  #pragma unroll
  for (int ct = 0; ct < 8; ++ct) {
    int kc = ct * 2 + (l15 >> 3);
    int ki = l15 & 7;
    #pragma unroll
    for (int r = 0; r < 4; ++r) {
      int row = lg4 * 4 + r;
      Pw[row * 128 + ((kc ^ (row & 7)) << 3) + ki] = (f16)(sc[ct][r] * lsum[r]);
    }
  }
  f32x4 Oa[4];
  #pragma unroll
  for (int i = 0; i < 4; ++i) Oa[i] = (f32x4){0.f, 0.f, 0.f, 0.f};
  #pragma unroll
  for (int ks = 0; ks < 4; ++ks) {
    f16x8 pa = *(const f16x8*)&Pw[l15 * 128 + (((ks * 4 + lg4) ^ l7) << 3)];
    #pragma unroll
    for (int dt = 0; dt < 4; ++dt) {
      int n = dt * 16 + l15;
      f16x8 bv = *(const f16x8*)&M2t[n * 128 + (((ks * 4 + lg4) ^ (n & 7)) << 3)];
      Oa[dt] = __builtin_amdgcn_mfma_f32_16x16x32_f16(pa, bv, Oa[dt], 0, 0, 0);
    }
  }
  #pragma unroll
  for (int r = 0; r < 4; ++r) {
    long srow = (long)b * S + s0 + w * 16 + lg4 * 4 + r;
    int r7 = (int)(srow & 7);
    #pragma unroll
    for (int dt = 0; dt < 4; ++dt) {
      int col = dt * 16 + l15;
      float v = Oa[dt][r] + proj[srow * VF + col];
      merged[srow * (long)HV + h * 64 + (((col >> 3) ^ r7) << 3) + (col & 7)] = (f16)v;
    }
  }
}

} // namespace

extern "C" void kernel_launch(void* const* d_in, const int* in_sizes, int n_in,
                              void* d_out, int out_size, void* d_ws, size_t ws_size,
                              hipStream_t stream)
{
  const float* lat   = (const float*)d_in[0];
  const float* masks = (const float*)d_in[1];
  const float* xemb  = (const float*)d_in[2];
  const float* ccls  = (const float*)d_in[4];
  const float* qlin  = (const float*)d_in[5];
  const float* klin  = (const float*)d_in[6];
  const float* vlin  = (const float*)d_in[7];
  const float* plin  = (const float*)d_in[8];
  const float* agg   = (const float*)d_in[9];
  const float* cfeat = (const float*)d_in[10];
  float* out = (float*)d_out;
  float* ws = (float*)d_ws;

  long off = 0;
  auto allocF = [&](long n) { float* p = ws + off; off += (n + 3) & ~3L; return p; };
  auto allocH = [&](long n) { f16* p = (f16*)(ws + off); off += ((n + 1) / 2 + 3) & ~3L; return p; };

  f16* origA = allocH(ROWS * KSF);
  f16* vbufA = allocH(ROWS * KSF);
  f16* merged = allocH(ROWS * (long)HV);
  f16* WQt = allocH(16L * 64 * KSF);
  f16* WKt = allocH(2L * 64 * KSF);
  f16* WVt = allocH(16L * 64 * KSF);
  f16* WPt = allocH(2L * 64 * KSF);
  f16* WCFt = allocH((long)KSF * 512);
  f16* WCCt = allocH(64L * 512);
  f16* Ek16 = allocH((long)B * S * 64);
  f16* Ev16 = allocH((long)B * H * S * 64);
  f16* Eq16 = allocH((long)B * H * S * 64);
  f16* qland16 = allocH((long)B * H * NL * DF);
  f16* kland16 = allocH((long)B * NL * DF);
  float* cl     = allocF(ROWS * HS);
  float* projb  = allocF((long)B * S * VF);
  float* qland  = allocF((long)B * H * NL * DF);
  float* kland  = allocF((long)B * NL * DF);
  float* k2b    = allocF((long)B * H * NL * NL);
  float* kv3    = allocF((long)B * H * NL * VF);
  float* m2b    = allocF((long)B * H * NL * VF);
  float* colmax = allocF(64);
  float* partU  = allocF((long)B * H * NL * NSPL * 64);
  float* partML = allocF((long)B * H * NL * NSPL * 2);

  k_cl<<<(int)(ROWS / 4), 256, 0, stream>>>(lat, masks, cl);
  k_cvta<<<(int)(ROWS * 168 / 256), 256, 0, stream>>>(xemb, cl, origA);

  auto cvtw = [&](const float* src, f16* dst, int K, int N, int Npad, int KS, long srcZ, int nz) {
    long total = (long)nz * Npad * (KS / 8);
    k_cvtw<<<(int)((total + 255) / 256), 256, 0, stream>>>(src, dst, K, N, Npad, KS, srcZ, total);
  };
  cvtw(qlin, WQt, FEAT, 64, 64, KSF, (long)FEATP * 64, 16);
  cvtw(klin, WKt, FEAT, 64, 64, KSF, (long)FEATP * 64, 2);
  cvtw(vlin, WVt, FEAT, 64, 64, KSF, (long)FEATP * 64, 16);
  cvtw(plin, WPt, FEAT, 64, 64, KSF, (long)FEATP * 64, 2);
  cvtw(cfeat, WCFt, 512, FEAT, KSF, 512, 0, 1);
  cvtw(ccls, WCCt, 512, HS, 64, 512, 0, 1);

  const f16* Aact = origA;
  for (int layer = 0; layer < 2; ++layer) {
    const f16* wq = WQt + (long)layer * 8 * 64 * KSF;
    const f16* wk = WKt + (long)layer * 64 * KSF;
    const f16* wvv = WVt + (long)layer * 8 * 64 * KSF;
    const f16* wp = WPt + (long)layer * 64 * KSF;
    const float* bq = qlin + (long)layer * 8 * FEATP * 64 + (long)(FEATP - 2) * 64;
    const float* bk = klin + (long)layer * FEATP * 64 + (long)(FEATP - 2) * 64;
    const float* bv = vlin + (long)layer * 8 * FEATP * 64 + (long)(FEATP - 2) * 64;
    const float* bp = plin + (long)layer * FEATP * 64 + (long)(FEATP - 2) * 64;
    const float* ag = agg + layer * H;

    dim3 gQ(8, 1, 64), gK(8, 1, 8);
    k_mgemm<<<gQ, 256, 0, stream>>>(Aact, (long)S * KSF, 8, wq, 64L * KSF, 8, 21, 3,
        nullptr, (long)S * 64, 64, bq, (long)FEATP * 64, INV_SCALE, Eq16, 64, nullptr);
    k_mgemm<<<gK, 256, 0, stream>>>(Aact, (long)S * KSF, 1, wk, 0, 1, 21, 3,
        nullptr, (long)S * 64, 64, bk, 0, INV_SCALE, Ek16, 64, nullptr);
    k_mgemm<<<gQ, 256, 0, stream>>>(Aact, (long)S * KSF, 8, wvv, 64L * KSF, 8, 21, 3,
        nullptr, (long)S * 64, 64, bv, (long)FEATP * 64, 1.0f, Ev16, 64, nullptr);
    k_mgemm<<<gK, 256, 0, stream>>>(origA, (long)S * KSF, 1, wp, 0, 1, 21, 0,
        projb, (long)S * 64, 64, bp, 0, 0.5f, nullptr, 64, nullptr);

    k_segmean<<<B * H * NL, 64, 0, stream>>>(Eq16, qland, qland16);
    k_segmean<<<B * NL, 64, 0, stream>>>(Ek16, kland, kland16);

    k_kernel2<<<B * H, 256, 0, stream>>>(qland, kland, ag, k2b, colmax);
    k_kernel3<<<B * H * 2 * NSPL, 256, 0, stream>>>(qland16, Ek16, Ev16, ag, masks,
        partU, partML);
    k_merge<<<B * H * 4, 256, 0, stream>>>(partU, partML, kv3);
    k_inverse<<<B * H, 1024, 0, stream>>>(k2b, colmax, kv3, m2b);
    k_k1attn<<<B * H * (S / 64), 256, 0, stream>>>(Eq16, kland16, ag, m2b, projb, merged);

    if (layer == 0) {
      dim3 gC(64, 21, 1);
      k_mgemm<<<gC, 256, 0, stream>>>(merged, 0, 1, WCFt, 0, 1, 8, 1,
          nullptr, 0, 0, nullptr, 0, 1.0f, vbufA, FEAT, nullptr);
      Aact = vbufA;
    } else {
      dim3 gO(64, 1, 1);
      k_mgemm<<<gO, 256, 0, stream>>>(merged, 0, 1, WCCt, 0, 1, 8, 2,
          out, 0, HS, nullptr, 0, 1.0f, nullptr, HS, masks);
    }
  }
  (void)in_sizes; (void)n_in; (void)out_size; (void)ws_size;
}

// Round 8
// 736.288 us; speedup vs baseline: 8.4887x; 1.0008x over previous
//
#include <hip/hip_runtime.h>
#include <math.h>

// ESMMimicryModule: B=8 S=2048 H=8 NL=128 DF=VF=64 NF=1280 HS=33 FEAT=1313
// Round 7: fix k_inverse VGPR starvation. __launch_bounds__(1024,4) capped the
// allocator at 64 VGPRs -> keyA/aV/acc spilled to scratch -> 18MB of phantom
// HBM writes per dispatch (WRITE_SIZE 20.2MB vs 2MB legit). Drop the min-waves
// hint (1 block/CU anyway at 128KB LDS). No other changes.

namespace {

constexpr int B = 8, S = 2048, H = 8, NL = 128, DF = 64, VF = 64;
constexpr int NF = 1280, HS = 33, FEAT = 1313, FEATP = 1314;
constexpr int SEG = 16, HV = H * VF;            // 512
constexpr int KSF = 1344;                        // padded feature-K (21*64)
constexpr int NSPL = 4;                          // key chunks in split-S flash
constexpr long ROWS = (long)B * S;               // 16384
constexpr float INV_SCALE = 0.35355339059327373f;

typedef _Float16 f16;
typedef _Float16 f16x8 __attribute__((ext_vector_type(8)));
typedef _Float16 f16x4 __attribute__((ext_vector_type(4)));
typedef float f32x4 __attribute__((ext_vector_type(4)));

// ---------------------------------------------------------------- cl = softmax(latent)*mask
__global__ __launch_bounds__(256) void k_cl(
    const float* __restrict__ lat, const float* __restrict__ masks,
    float* __restrict__ cl)
{
  long row = (long)blockIdx.x * 4 + (threadIdx.x >> 6);
  int l = threadIdx.x & 63;
  float v = (l < HS) ? lat[row * HS + l] : -INFINITY;
  float m = v;
  #pragma unroll
  for (int o = 32; o; o >>= 1) m = fmaxf(m, __shfl_xor(m, o));
  float e = (l < HS) ? expf(v - m) : 0.f;
  float s = e;
  #pragma unroll
  for (int o = 32; o; o >>= 1) s += __shfl_xor(s, o);
  if (l < HS) cl[row * HS + l] = e / s * masks[row];
}

// ---------------------------------------------------------------- origA fp16 arena (swizzled)
__global__ __launch_bounds__(256) void k_cvta(
    const float* __restrict__ xemb, const float* __restrict__ cl,
    f16* __restrict__ dst)
{
  long idx = (long)blockIdx.x * 256 + threadIdx.x;  // chunk id (row,c)
  long row = idx / 168;
  int c = (int)(idx - row * 168);
  int t = c >> 3, cs = c & 7;
  int cd = cs ^ ((int)row & 7);
  int k0 = t * 64 + cd * 8;
  f16x8 v;
  #pragma unroll
  for (int i = 0; i < 8; ++i) {
    int k = k0 + i;
    float f = 0.f;
    if (k < NF) f = xemb[row * NF + k];
    else if (k < FEAT) f = cl[row * HS + (k - NF)];
    v[i] = (f16)f;
  }
  *(f16x8*)&dst[idx * 8] = v;
}

// ---------------------------------------------------------------- weight -> Wt fp16 arena
__global__ __launch_bounds__(256) void k_cvtw(
    const float* __restrict__ src, f16* __restrict__ dst,
    int K, int N, int Npad, int KS, long srcZ, long total)
{
  long idx = (long)blockIdx.x * 256 + threadIdx.x;
  if (idx >= total) return;
  long cpz = (long)Npad * (KS >> 3);
  long z = idx / cpz;
  long rem = idx - z * cpz;
  int n = (int)(rem / (KS >> 3));
  int c = (int)(rem - (long)n * (KS >> 3));
  int t = c >> 3, cs = c & 7;
  int cd = cs ^ (n & 7);
  int k0 = t * 64 + cd * 8;
  const float* sp = src + z * srcZ;
  f16x8 v;
  #pragma unroll
  for (int i = 0; i < 8; ++i) {
    int k = k0 + i;
    v[i] = (f16)((k < K && n < N) ? sp[(long)k * N + n] : 0.f);
  }
  *(f16x8*)&dst[idx * 8] = v;
}

// ---------------------------------------------------------------- fp16 MFMA GEMM
// mode 0: fp32 C = (acc + bias)*scale
// mode 1: fp16 swizzled arena (KSF stride, zero-fill col>=NR), LDS-staged
// mode 2: fp32 out * mask, col<NR
// mode 3: fp16 row-major out (64 cols), (acc+bias)*scale, LDS-staged
__global__ __launch_bounds__(256, 2) void k_mgemm(
    const f16* __restrict__ A, long aZOff, int aDiv,
    const f16* __restrict__ Wt, long wZOff, int wMod,
    int KT, int mode,
    float* __restrict__ C, long cZOff, int ldC,
    const float* __restrict__ biasBase, long biasZOff, float scale,
    f16* __restrict__ outA, int NR, const float* __restrict__ mask)
{
  const long KS = (long)KT * 64;
  int z = blockIdx.z;
  const f16* Ap = A + (long)(z / aDiv) * aZOff;
  const f16* Wp = Wt + (long)(z % wMod) * wZOff;
  long m0 = (long)blockIdx.x * 256;
  int n0 = blockIdx.y * 64;
  constexpr int BOFF = 256 * 64;
  __shared__ f16 lds[2][(256 + 64) * 64];
  int tid = threadIdx.x;
  int wv = tid >> 6, l = tid & 63;

  const f16* aW = Ap + (m0 + wv * 64 + (l >> 3)) * KS + (l & 7) * 8;
  const f16* bW = Wp + ((long)(n0 + wv * 16 + (l >> 3))) * KS + (l & 7) * 8;

  f32x4 acc[4][4];
  #pragma unroll
  for (int i = 0; i < 4; ++i)
    #pragma unroll
    for (int j = 0; j < 4; ++j) acc[i][j] = (f32x4){0.f, 0.f, 0.f, 0.f};

  auto stage = [&](int buf, int t) {
    f16* la = &lds[buf][(wv * 64) * 64];
    const f16* ga = aW + (long)t * 64;
    #pragma unroll
    for (int j = 0; j < 8; ++j)
      __builtin_amdgcn_global_load_lds(
          (const __attribute__((address_space(1))) void*)(ga + (long)j * 8 * KS),
          (__attribute__((address_space(3))) void*)(la + j * 8 * 64), 16, 0, 0);
    f16* lb = &lds[buf][BOFF + (wv * 16) * 64];
    const f16* gb = bW + (long)t * 64;
    #pragma unroll
    for (int j = 0; j < 2; ++j)
      __builtin_amdgcn_global_load_lds(
          (const __attribute__((address_space(1))) void*)(gb + (long)j * 8 * KS),
          (__attribute__((address_space(3))) void*)(lb + j * 8 * 64), 16, 0, 0);
  };

  stage(0, 0);
  int rA = (wv * 64 + (l & 15)) * 64;
  int rB = BOFF + (l & 15) * 64;
  int lc = l >> 4, lx = l & 7;
  for (int t = 0; t < KT; ++t) {
    int nb = t & 1;
    if (t + 1 < KT) {
      stage(nb ^ 1, t + 1);
      asm volatile("s_waitcnt vmcnt(10)" ::: "memory");
    } else {
      asm volatile("s_waitcnt vmcnt(0)" ::: "memory");
    }
    __syncthreads();
    const f16* base = &lds[nb][0];
    f16x8 af[4][2], bf[4][2];
    #pragma unroll
    for (int mi = 0; mi < 4; ++mi)
      #pragma unroll
      for (int kh = 0; kh < 2; ++kh)
        af[mi][kh] = *(const f16x8*)&base[rA + mi * 16 * 64 + (((kh * 4 + lc) ^ lx) << 3)];
    #pragma unroll
    for (int ni = 0; ni < 4; ++ni)
      #pragma unroll
      for (int kh = 0; kh < 2; ++kh)
        bf[ni][kh] = *(const f16x8*)&base[rB + ni * 16 * 64 + (((kh * 4 + lc) ^ lx) << 3)];
    #pragma unroll
    for (int mi = 0; mi < 4; ++mi)
      #pragma unroll
      for (int ni = 0; ni < 4; ++ni) {
        acc[mi][ni] = __builtin_amdgcn_mfma_f32_16x16x32_f16(af[mi][0], bf[ni][0], acc[mi][ni], 0, 0, 0);
        acc[mi][ni] = __builtin_amdgcn_mfma_f32_16x16x32_f16(af[mi][1], bf[ni][1], acc[mi][ni], 0, 0, 0);
      }
    __syncthreads();
  }

  int lr = (l >> 4) * 4;
  int lcn = l & 15;
  if (mode == 0) {
    float* Cp = C + (long)z * cZOff;
    const float* bp = biasBase ? biasBase + (long)(z % wMod) * biasZOff : nullptr;
    #pragma unroll
    for (int ni = 0; ni < 4; ++ni) {
      int col = n0 + ni * 16 + lcn;
      float bv = bp ? bp[col] : 0.f;
      #pragma unroll
      for (int mi = 0; mi < 4; ++mi) {
        long row = m0 + wv * 64 + mi * 16 + lr;
        #pragma unroll
        for (int r = 0; r < 4; ++r)
          Cp[(row + r) * (long)ldC + col] = (acc[mi][ni][r] + bv) * scale;
      }
    }
  } else if (mode == 2) {
    #pragma unroll
    for (int mi = 0; mi < 4; ++mi) {
      #pragma unroll
      for (int r = 0; r < 4; ++r) {
        long row = m0 + wv * 64 + mi * 16 + lr + r;
        float mv = mask[row];
        #pragma unroll
        for (int ni = 0; ni < 4; ++ni) {
          int col = n0 + ni * 16 + lcn;
          if (col < NR) C[row * (long)ldC + col] = acc[mi][ni][r] * mv;
        }
      }
    }
  } else {  // mode 1 / 3: stage f16 tile in LDS, vectorized global writes
    f16* st = &lds[0][0];
    const float* bp = biasBase ? biasBase + (long)(z % wMod) * biasZOff : nullptr;
    #pragma unroll
    for (int ni = 0; ni < 4; ++ni) {
      int coll = ni * 16 + lcn;
      int col = n0 + coll;
      float bv = bp ? bp[col] : 0.f;
      bool ok = col < NR;
      #pragma unroll
      for (int mi = 0; mi < 4; ++mi) {
        int rowl = wv * 64 + mi * 16 + lr;
        #pragma unroll
        for (int r = 0; r < 4; ++r) {
          float v = ok ? (acc[mi][ni][r] + bv) * scale : 0.f;
          st[(rowl + r) * 64 + coll] = (f16)v;
        }
      }
    }
    __syncthreads();
    if (mode == 3) {
      f16* o16 = outA + (long)z * cZOff;
      for (int c = tid; c < 2048; c += 256) {
        int row = c >> 3, cc = c & 7;
        f16x8 v = *(const f16x8*)&st[row * 64 + cc * 8];
        *(f16x8*)&o16[(m0 + row) * 64 + cc * 8] = v;
      }
    } else {
      int tt = n0 >> 6;
      for (int c = tid; c < 2048; c += 256) {
        int row = c >> 3, cd = c & 7;
        long grow = m0 + row;
        int r7 = (int)grow & 7;
        f16x8 v = *(const f16x8*)&st[row * 64 + cd * 8];
        *(f16x8*)&outA[grow * KSF + tt * 64 + ((cd ^ r7) << 3)] = v;
      }
    }
  }
}

// ---------------------------------------------------------------- landmarks (f16 input)
__global__ void k_segmean(const f16* __restrict__ in, float* __restrict__ out,
                          f16* __restrict__ out16)
{
  long zl = blockIdx.x;
  long z = zl / NL, lm = zl % NL;
  int d = threadIdx.x;
  const f16* p = in + (z * S + lm * SEG) * (long)DF + d;
  float s = 0.f;
  #pragma unroll
  for (int i = 0; i < SEG; i++) s += (float)p[(long)i * DF];
  float v = s * (1.f / SEG);
  out[(z * NL + lm) * (long)DF + d] = v;
  if (out16) out16[(z * NL + lm) * (long)DF + d] = (f16)v;
}

// ---------------------------------------------------------------- kernel_2 (analytic possel2)
__global__ __launch_bounds__(256) void k_kernel2(
    const float* __restrict__ qland, const float* __restrict__ kland,
    const float* __restrict__ aggL, float* __restrict__ k2,
    float* __restrict__ colmax)
{
  int z = blockIdx.x; int b = z / H; int h = z % H;
  float sigma = fabsf(aggL[h]) + 0.001f;
  __shared__ float qs[NL][68];
  __shared__ float ks[NL][68];
  __shared__ float lg[NL][NL + 1];
  int tid = threadIdx.x;
  for (int idx = tid; idx < NL * DF; idx += 256) {
    int r = idx >> 6, d = idx & 63;
    qs[r][d] = qland[((long)z * NL + r) * DF + d];
    ks[r][d] = kland[((long)b * NL + r) * DF + d];
  }
  __syncthreads();
  int r = tid >> 1, half = tid & 1;
  float lmax = -INFINITY;
  for (int c = 0; c < 64; c++) {
    int m = half * 64 + c;
    float s = 0.f;
    #pragma unroll
    for (int d = 0; d < DF; d += 4) {
      float4 q = *(const float4*)&qs[r][d];
      float4 k4 = *(const float4*)&ks[m][d];
      s += q.x * k4.x + q.y * k4.y + q.z * k4.z + q.w * k4.w;
    }
    float dd = fabsf((float)(r - m));
    s += -sigma * ((r == m) ? 5.3125f : 16.f * dd);
    lg[r][m] = s;
    lmax = fmaxf(lmax, s);
  }
  lmax = fmaxf(lmax, __shfl_xor(lmax, 1));
  float lsum = 0.f;
  for (int c = 0; c < 64; c++) {
    int m = half * 64 + c;
    float e = expf(lg[r][m] - lmax);
    lg[r][m] = e; lsum += e;
  }
  lsum += __shfl_xor(lsum, 1);
  float inv = 1.f / lsum;
  for (int c = 0; c < 64; c++) {
    int m = half * 64 + c;
    float p = lg[r][m] * inv;
    lg[r][m] = p;
    k2[((long)z * NL + r) * NL + m] = p;
  }
  __syncthreads();
  float myc = 0.f;
  if (tid < NL) {
    for (int rr = 0; rr < NL; rr++) myc += lg[rr][tid];
  }
  float wm = myc;
  #pragma unroll
  for (int o = 32; o; o >>= 1) wm = fmaxf(wm, __shfl_xor(wm, o));
  __shared__ float wred[4];
  if ((tid & 63) == 0) wred[tid >> 6] = wm;
  __syncthreads();
  if (tid == 0)
    colmax[z] = fmaxf(fmaxf(wred[0], wred[1]), fmaxf(wred[2], wred[3]));
}

// ---------------------------------------------------------------- kernel_3 (split-S flash MFMA)
__global__ __launch_bounds__(256, 2) void k_kernel3(
    const f16* __restrict__ qland16, const f16* __restrict__ Ek16,
    const f16* __restrict__ Ev16, const float* __restrict__ aggL,
    const float* __restrict__ masks,
    float* __restrict__ partU, float* __restrict__ partML)
{
  __shared__ __align__(16) f16 Qs[64 * 64];
  __shared__ __align__(16) f16 Ks[128 * 64];
  __shared__ __align__(16) f16 Vt[64 * 128];
  __shared__ __align__(16) f16 Pb[4 * 16 * 128];
  __shared__ float Ms[128];
  int id = blockIdx.x;
  int chunk = id & (NSPL - 1);
  int z2 = id >> 2;
  int z = z2 >> 1, half = z2 & 1;
  int b = z >> 3, h = z & 7;
  int q0 = half * 64;
  int tid = threadIdx.x;
  int w = tid >> 6, l = tid & 63;
  float sigma = fabsf(aggL[h]) + 0.001f;
  float cpos = -sigma * (1.f / 16.f);

  for (int c = tid; c < 64 * 8; c += 256) {
    int q = c >> 3, kc = c & 7;
    f16x8 v = *(const f16x8*)&qland16[((long)z * NL + q0 + q) * 64 + kc * 8];
    *(f16x8*)&Qs[q * 64 + ((kc ^ (q & 7)) << 3)] = v;
  }

  f16* Pw = &Pb[w * 16 * 128];
  int l15 = l & 15, lg4 = l >> 4, l7 = l & 7;
  f32x4 Oa[4];
  #pragma unroll
  for (int i = 0; i < 4; ++i) Oa[i] = (f32x4){0.f, 0.f, 0.f, 0.f};
  float mrun[4] = {-INFINITY, -INFINITY, -INFINITY, -INFINITY};
  float lrun[4] = {0.f, 0.f, 0.f, 0.f};

  int t0beg = chunk * (S / 128 / NSPL), t0end = t0beg + S / 128 / NSPL;
  for (int t0 = t0beg; t0 < t0end; ++t0) {
    __syncthreads();
    for (int c = tid; c < 1024; c += 256) {
      int k = c >> 3, kc = c & 7;
      f16x8 v = *(const f16x8*)&Ek16[((long)b * S + t0 * 128 + k) * 64 + kc * 8];
      *(f16x8*)&Ks[k * 64 + ((kc ^ (k & 7)) << 3)] = v;
    }
    for (int c = tid; c < 1024; c += 256) {
      int k = c & 127, dc = c >> 7;
      f16x8 v = *(const f16x8*)&Ev16[((long)z * S + t0 * 128 + k) * 64 + dc * 8];
      int kc = k >> 3, ki = k & 7;
      #pragma unroll
      for (int j = 0; j < 8; ++j) {
        int d = dc * 8 + j;
        Vt[d * 128 + ((kc ^ (d & 7)) << 3) + ki] = v[j];
      }
    }
    if (tid < 128)
      Ms[tid] = (masks[(long)b * S + t0 * 128 + tid] == 0.f) ? -1e6f : 0.f;
    __syncthreads();

    f16x8 af[2];
    #pragma unroll
    for (int kh = 0; kh < 2; ++kh)
      af[kh] = *(const f16x8*)&Qs[(w * 16 + l15) * 64 + (((kh * 4 + lg4) ^ l7) << 3)];
    f32x4 sc[8];
    #pragma unroll
    for (int ct = 0; ct < 8; ++ct) {
      int n = ct * 16 + l15;
      f16x8 b0 = *(const f16x8*)&Ks[n * 64 + (((lg4) ^ (n & 7)) << 3)];
      f16x8 b1 = *(const f16x8*)&Ks[n * 64 + (((4 + lg4) ^ (n & 7)) << 3)];
      f32x4 zz = (f32x4){0.f, 0.f, 0.f, 0.f};
      zz = __builtin_amdgcn_mfma_f32_16x16x32_f16(af[0], b0, zz, 0, 0, 0);
      sc[ct] = __builtin_amdgcn_mfma_f32_16x16x32_f16(af[1], b1, zz, 0, 0, 0);
    }
    float tmax[4] = {-INFINITY, -INFINITY, -INFINITY, -INFINITY};
    #pragma unroll
    for (int ct = 0; ct < 8; ++ct) {
      float mk = Ms[ct * 16 + l15];
      int key = t0 * 128 + ct * 16 + l15;
      #pragma unroll
      for (int r = 0; r < 4; ++r) {
        int qg = q0 + w * 16 + lg4 * 4 + r;
        float a = (float)(key - 16 * qg);
        float ac = fminf(fmaxf(a, 0.f), 15.f);
        float dd = fabsf(a - ac);
        float sum = ac * ac - 15.f * ac + 120.f + 16.f * dd;
        float s = sc[ct][r] + cpos * sum + mk;
        sc[ct][r] = s;
        tmax[r] = fmaxf(tmax[r], s);
      }
    }
    #pragma unroll
    for (int r = 0; r < 4; ++r) {
      #pragma unroll
      for (int o = 1; o < 16; o <<= 1)
        tmax[r] = fmaxf(tmax[r], __shfl_xor(tmax[r], o));
    }
    float fr[4], lsum[4];
    #pragma unroll
    for (int r = 0; r < 4; ++r) {
      float mnew = fmaxf(mrun[r], tmax[r]);
      fr[r] = expf(mrun[r] - mnew);
      mrun[r] = mnew;
      lsum[r] = 0.f;
    }
    #pragma unroll
    for (int ct = 0; ct < 8; ++ct) {
      #pragma unroll
      for (int r = 0; r < 4; ++r) {
        float p = expf(sc[ct][r] - mrun[r]);
        sc[ct][r] = p;
        lsum[r] += p;
      }
    }
    #pragma unroll
    for (int r = 0; r < 4; ++r) {
      #pragma unroll
      for (int o = 1; o < 16; o <<= 1)
        lsum[r] += __shfl_xor(lsum[r], o);
      lrun[r] = lrun[r] * fr[r] + lsum[r];
    }
    f32x4 fv = (f32x4){fr[0], fr[1], fr[2], fr[3]};
    #pragma unroll
    for (int dt = 0; dt < 4; ++dt) Oa[dt] *= fv;
    #pragma unroll
    for (int ct = 0; ct < 8; ++ct) {
      int kc = ct * 2 + (l15 >> 3);
      int ki = l15 & 7;
      #pragma unroll
      for (int r = 0; r < 4; ++r) {
        int row = lg4 * 4 + r;
        Pw[row * 128 + ((kc ^ (row & 7)) << 3) + ki] = (f16)sc[ct][r];
      }
    }
    #pragma unroll
    for (int ks = 0; ks < 4; ++ks) {
      f16x8 pa = *(const f16x8*)&Pw[l15 * 128 + (((ks * 4 + lg4) ^ l7) << 3)];
      #pragma unroll
      for (int dt = 0; dt < 4; ++dt) {
        int n = dt * 16 + l15;
        f16x8 bv = *(const f16x8*)&Vt[n * 128 + (((ks * 4 + lg4) ^ (n & 7)) << 3)];
        Oa[dt] = __builtin_amdgcn_mfma_f32_16x16x32_f16(pa, bv, Oa[dt], 0, 0, 0);
      }
    }
  }
  #pragma unroll
  for (int r = 0; r < 4; ++r) {
    long qg = q0 + w * 16 + lg4 * 4 + r;
    long base = ((long)z * NL + qg) * NSPL + chunk;
    #pragma unroll
    for (int dt = 0; dt < 4; ++dt)
      partU[base * 64 + dt * 16 + l15] = Oa[dt][r];
    if (l15 == 0) {
      partML[base * 2] = mrun[r];
      partML[base * 2 + 1] = lrun[r];
    }
  }
}

// ---------------------------------------------------------------- merge split-flash partials
__global__ __launch_bounds__(256) void k_merge(
    const float* __restrict__ partU, const float* __restrict__ partML,
    float* __restrict__ kv3)
{
  int id = blockIdx.x;
  int z = id >> 2, part = id & 3;
  int t = threadIdx.x;
  int q = part * 32 + (t >> 3);
  int c8 = (t & 7) * 8;
  long base = ((long)z * NL + q) * NSPL;
  float m[NSPL], lv[NSPL];
  #pragma unroll
  for (int c = 0; c < NSPL; ++c) {
    m[c] = partML[(base + c) * 2];
    lv[c] = partML[(base + c) * 2 + 1];
  }
  float M = fmaxf(fmaxf(m[0], m[1]), fmaxf(m[2], m[3]));
  float L = 0.f, sc[NSPL];
  #pragma unroll
  for (int c = 0; c < NSPL; ++c) {
    sc[c] = expf(m[c] - M);
    L += lv[c] * sc[c];
  }
  float o[8] = {};
  #pragma unroll
  for (int c = 0; c < NSPL; ++c) {
    const float* up = &partU[(base + c) * 64 + c8];
    float4 a = *(const float4*)up;
    float4 bq = *(const float4*)(up + 4);
    o[0] += sc[c] * a.x; o[1] += sc[c] * a.y; o[2] += sc[c] * a.z; o[3] += sc[c] * a.w;
    o[4] += sc[c] * bq.x; o[5] += sc[c] * bq.y; o[6] += sc[c] * bq.z; o[7] += sc[c] * bq.w;
  }
  float invL = 1.f / L;
  float* kp = &kv3[((long)z * NL + q) * 64 + c8];
  #pragma unroll
  for (int j = 0; j < 8; ++j) kp[j] = o[j] * invL;
}

// ---------------------------------------------------------------- inverse (MFMA fp16 NS, 16 waves)
__global__ __launch_bounds__(1024) void k_inverse(
    const float* __restrict__ k2g, const float* __restrict__ colmax,
    const float* __restrict__ kv3, float* __restrict__ m2)
{
  __shared__ __align__(16) f16 Vn[128 * 128];
  __shared__ __align__(16) f16 Vt[128 * 128];
  __shared__ __align__(16) f16 Pn[128 * 128];
  __shared__ __align__(16) f16 Pt[128 * 128];
  int z = blockIdx.x;
  int tid = threadIdx.x;
  int w = tid >> 6, l = tid & 63;
  int l15 = l & 15, lg4 = l >> 4;
  int wr = (w >> 2) * 32, wc = (w & 3) * 32;

  float cv = colmax[l];
  #pragma unroll
  for (int o = 32; o; o >>= 1) cv = fmaxf(cv, __shfl_xor(cv, o));
  float recip = 1.f / cv;

  const float* key = k2g + (long)z * NL * NL;
  auto swz = [](int r, int c) { return r * 128 + ((((c >> 3) ^ (r & 15))) << 3) + (c & 7); };

  for (int idx = tid; idx < 128 * 32; idx += 1024) {
    int r = idx >> 5, c4 = (idx & 31) << 2;
    float4 kk = *(const float4*)&key[r * 128 + c4];
    f16x4 hv;
    hv[0] = (f16)(recip * kk.x); hv[1] = (f16)(recip * kk.y);
    hv[2] = (f16)(recip * kk.z); hv[3] = (f16)(recip * kk.w);
    *(f16x4*)&Vt[swz(r, c4)] = hv;
    Vn[swz(c4 + 0, r)] = hv[0];
    Vn[swz(c4 + 1, r)] = hv[1];
    Vn[swz(c4 + 2, r)] = hv[2];
    Vn[swz(c4 + 3, r)] = hv[3];
  }
  f16x8 keyA[2][4];
  #pragma unroll
  for (int mi = 0; mi < 2; ++mi)
    #pragma unroll
    for (int ks = 0; ks < 4; ++ks) {
      int r = wr + mi * 16 + l15;
      int k0 = ks * 32 + lg4 * 8;
      float4 a = *(const float4*)&key[r * 128 + k0];
      float4 bq = *(const float4*)&key[r * 128 + k0 + 4];
      f16x8 v;
      v[0] = (f16)a.x; v[1] = (f16)a.y; v[2] = (f16)a.z; v[3] = (f16)a.w;
      v[4] = (f16)bq.x; v[5] = (f16)bq.y; v[6] = (f16)bq.z; v[7] = (f16)bq.w;
      keyA[mi][ks] = v;
    }
  __syncthreads();

  f32x4 acc[2][2];
  auto MMc = [&](const f16* Aimg, const f16* Bimg) {
    #pragma unroll
    for (int mi = 0; mi < 2; ++mi)
      #pragma unroll
      for (int ni = 0; ni < 2; ++ni) acc[mi][ni] = (f32x4){0.f, 0.f, 0.f, 0.f};
    #pragma unroll
    for (int ks = 0; ks < 4; ++ks) {
      int k0 = ks * 32 + lg4 * 8;
      f16x8 bf[2];
      bf[0] = *(const f16x8*)&Bimg[swz(wc + l15, k0)];
      bf[1] = *(const f16x8*)&Bimg[swz(wc + 16 + l15, k0)];
      f16x8 af[2];
      if (Aimg) {
        af[0] = *(const f16x8*)&Aimg[swz(wr + l15, k0)];
        af[1] = *(const f16x8*)&Aimg[swz(wr + 16 + l15, k0)];
      } else {
        af[0] = keyA[0][ks]; af[1] = keyA[1][ks];
      }
      #pragma unroll
      for (int mi = 0; mi < 2; ++mi)
        #pragma unroll
        for (int ni = 0; ni < 2; ++ni)
          acc[mi][ni] = __builtin_amdgcn_mfma_f32_16x16x32_f16(af[mi], bf[ni], acc[mi][ni], 0, 0, 0);
    }
  };
  auto store = [&](f16* Nout, f16* Tout, float aT, float bT) {
    #pragma unroll
    for (int mi = 0; mi < 2; ++mi) {
      int row0 = wr + mi * 16 + lg4 * 4;
      #pragma unroll
      for (int ni = 0; ni < 2; ++ni) {
        int col = wc + ni * 16 + l15;
        f16x4 tv;
        #pragma unroll
        for (int r = 0; r < 4; ++r) {
          float v = acc[mi][ni][r];
          if (Nout) Nout[swz(row0 + r, col)] = (f16)v;
          tv[r] = (f16)(aT * v + ((row0 + r == col) ? bT : 0.f));
        }
        *(f16x4*)&Tout[col * 128 + ((((row0 >> 3) ^ (col & 15))) << 3) + (row0 & 7)] = tv;
      }
    }
  };

  for (int it = 0; it < 6; ++it) {
    MMc(nullptr, Vt);  store(Pn, Pt, -1.f, 7.f);        __syncthreads();
    MMc(Pn, Pt);       store(nullptr, Vt, -1.f, 15.f);  __syncthreads();
    MMc(Pn, Vt);       store(nullptr, Pt, -0.25f, 3.25f); __syncthreads();
    f16x8 aV[2][4];
    #pragma unroll
    for (int ks = 0; ks < 4; ++ks) {
      int k0 = ks * 32 + lg4 * 8;
      aV[0][ks] = *(const f16x8*)&Vn[swz(wr + l15, k0)];
      aV[1][ks] = *(const f16x8*)&Vn[swz(wr + 16 + l15, k0)];
    }
    __syncthreads();
    #pragma unroll
    for (int mi = 0; mi < 2; ++mi)
      #pragma unroll
      for (int ni = 0; ni < 2; ++ni) acc[mi][ni] = (f32x4){0.f, 0.f, 0.f, 0.f};
    #pragma unroll
    for (int ks = 0; ks < 4; ++ks) {
      int k0 = ks * 32 + lg4 * 8;
      f16x8 bf[2];
      bf[0] = *(const f16x8*)&Pt[swz(wc + l15, k0)];
      bf[1] = *(const f16x8*)&Pt[swz(wc + 16 + l15, k0)];
      #pragma unroll
      for (int mi = 0; mi < 2; ++mi)
        #pragma unroll
        for (int ni = 0; ni < 2; ++ni)
          acc[mi][ni] = __builtin_amdgcn_mfma_f32_16x16x32_f16(aV[mi][ks], bf[ni], acc[mi][ni], 0, 0, 0);
    }
    store(Vn, Vt, 1.f, 0.f);
    __syncthreads();
  }

  const float* kp = kv3 + (long)z * NL * VF;
  for (int idx = tid; idx < 128 * 16; idx += 1024) {
    int k = idx >> 4, c4 = (idx & 15) << 2;
    float4 v4 = *(const float4*)&kp[k * 64 + c4];
    Pn[swz(c4 + 0, k)] = (f16)v4.x;
    Pn[swz(c4 + 1, k)] = (f16)v4.y;
    Pn[swz(c4 + 2, k)] = (f16)v4.z;
    Pn[swz(c4 + 3, k)] = (f16)v4.w;
  }
  __syncthreads();
  int r0 = (w >> 1) * 16, ch = (w & 1) * 32;
  f32x4 accF[2];
  #pragma unroll
  for (int ni = 0; ni < 2; ++ni) accF[ni] = (f32x4){0.f, 0.f, 0.f, 0.f};
  #pragma unroll
  for (int ks = 0; ks < 4; ++ks) {
    int k0 = ks * 32 + lg4 * 8;
    f16x8 af = *(const f16x8*)&Vn[swz(r0 + l15, k0)];
    #pragma unroll
    for (int ni = 0; ni < 2; ++ni) {
      f16x8 bf = *(const f16x8*)&Pn[swz(ch + ni * 16 + l15, k0)];
      accF[ni] = __builtin_amdgcn_mfma_f32_16x16x32_f16(af, bf, accF[ni], 0, 0, 0);
    }
  }
  float* mp = m2 + (long)z * NL * VF;
  #pragma unroll
  for (int ni = 0; ni < 2; ++ni)
    #pragma unroll
    for (int r = 0; r < 4; ++r)
      mp[(long)(r0 + lg4 * 4 + r) * VF + ch + ni * 16 + l15] = accF[ni][r];
}

// ---------------------------------------------------------------- kernel_1 + attn + merge (MFMA)
__global__ __launch_bounds__(256, 2) void k_k1attn(
    const f16* __restrict__ Eq16, const f16* __restrict__ kland16,
    const float* __restrict__ aggL, const float* __restrict__ m2,
    const float* __restrict__ proj, f16* __restrict__ merged)
{
  __shared__ __align__(16) f16 Kl[128 * 64];
  __shared__ __align__(16) f16 M2t[64 * 128];
  __shared__ __align__(16) f16 Pb[4 * 16 * 128];
  int zz = blockIdx.x;
  int z = zz >> 5, st = zz & 31;
  int b = z >> 3, h = z & 7;
  int s0 = st * 64;
  int tid = threadIdx.x;
  int w = tid >> 6, l = tid & 63;
  int l15 = l & 15, lg4 = l >> 4, l7 = l & 7;
  float sigma = fabsf(aggL[h]) + 0.001f;
  float cpos = -sigma * (1.f / 16.f);

  for (int c = tid; c < 128 * 8; c += 256) {
    int k = c >> 3, kc = c & 7;
    f16x8 v = *(const f16x8*)&kland16[((long)b * NL + k) * 64 + kc * 8];
    *(f16x8*)&Kl[k * 64 + ((kc ^ (k & 7)) << 3)] = v;
  }
  const float* mp = m2 + (long)z * NL * VF;
  for (int c = tid; c < 128 * 16; c += 256) {
    int k = c >> 4, c4 = (c & 15) << 2;
    float4 v4 = *(const float4*)&mp[k * 64 + c4];
    int kc = k >> 3, ki = k & 7;
    M2t[(c4 + 0) * 128 + ((kc ^ ((c4 + 0) & 7)) << 3) + ki] = (f16)v4.x;
    M2t[(c4 + 1) * 128 + ((kc ^ ((c4 + 1) & 7)) << 3) + ki] = (f16)v4.y;
    M2t[(c4 + 2) * 128 + ((kc ^ ((c4 + 2) & 7)) << 3) + ki] = (f16)v4.z;
    M2t[(c4 + 3) * 128 + ((kc ^ ((c4 + 3) & 7)) << 3) + ki] = (f16)v4.w;
  }
  __syncthreads();

  long qrow = (long)z * S + s0 + w * 16 + l15;
  f16x8 af[2];
  #pragma unroll
  for (int kh = 0; kh < 2; ++kh)
    af[kh] = *(const f16x8*)&Eq16[qrow * 64 + kh * 32 + lg4 * 8];

  f32x4 sc[8];
  #pragma unroll
  for (int ct = 0; ct < 8; ++ct) {
    int n = ct * 16 + l15;
    f16x8 b0 = *(const f16x8*)&Kl[n * 64 + ((lg4 ^ (n & 7)) << 3)];
    f16x8 b1 = *(const f16x8*)&Kl[n * 64 + (((4 + lg4) ^ (n & 7)) << 3)];
    f32x4 zz4 = (f32x4){0.f, 0.f, 0.f, 0.f};
    zz4 = __builtin_amdgcn_mfma_f32_16x16x32_f16(af[0], b0, zz4, 0, 0, 0);
    sc[ct] = __builtin_amdgcn_mfma_f32_16x16x32_f16(af[1], b1, zz4, 0, 0, 0);
  }
  float tmax[4] = {-INFINITY, -INFINITY, -INFINITY, -INFINITY};
  #pragma unroll
  for (int ct = 0; ct < 8; ++ct) {
    int lm = ct * 16 + l15;
    #pragma unroll
    for (int r = 0; r < 4; ++r) {
      int spos = s0 + w * 16 + lg4 * 4 + r;
      float a = (float)(spos - 16 * lm);
      float ac = fminf(fmaxf(a, 0.f), 15.f);
      float dd = fabsf(a - ac);
      float sum = ac * ac - 15.f * ac + 120.f + 16.f * dd;
      float s = sc[ct][r] + cpos * sum;
      sc[ct][r] = s;
      tmax[r] = fmaxf(tmax[r], s);
    }
  }
  #pragma unroll
  for (int r = 0; r < 4; ++r) {
    #pragma unroll
    for (int o = 1; o < 16; o <<= 1)
      tmax[r] = fmaxf(tmax[r], __shfl_xor(tmax[r], o));
  }
  float lsum[4] = {0.f, 0.f, 0.f, 0.f};
  #pragma unroll
  for (int ct = 0; ct < 8; ++ct) {
    #pragma unroll
    for (int r = 0; r < 4; ++r) {
      float p = expf(sc[ct][r] - tmax[r]);
      sc[ct][r] = p;
      lsum[r] += p;
    }
  }
  #pragma unroll
  for (int r = 0; r < 4; ++r) {
    #pragma unroll
    for (int o = 1; o < 16; o <<= 1)
      lsum[r] += __shfl_xor(lsum[r], o);
    lsum[r] = 1.f / lsum[r];
  }
  f16* Pw = &Pb[w * 16 * 128];
  #pragma unroll
  for (int ct = 0; ct < 8; ++ct) {
    int kc = ct * 2 + (l15 >> 3);
    int ki = l15 & 7;
    #pragma unroll
    for (int r = 0; r < 4; ++r) {
      int row = lg4 * 4 + r;
      Pw[row * 128 + ((kc ^ (row & 7)) << 3) + ki] = (f16)(sc[ct][r] * lsum[r]);
    }
  }
  f32x4 Oa[4];
  #pragma unroll
  for (int i = 0; i < 4; ++i) Oa[i] = (f32x4){0.f, 0.f, 0.f, 0.f};
  #pragma unroll
  for (int ks = 0; ks < 4; ++ks) {
    f16x8 pa = *(const f16x8*)&Pw[l15 * 128 + (((ks * 4 + lg4) ^ l7) << 3)];
    #pragma unroll
    for (int dt = 0; dt < 4; ++dt) {
      int n = dt * 16 + l15;
      f16x8 bv = *(const f16x8*)&M2t[n * 128 + (((ks * 4 + lg4) ^ (n & 7)) << 3)];
      Oa[dt] = __builtin_amdgcn_mfma_f32_16x16x32_f16(pa, bv, Oa[dt], 0, 0, 0);
    }
  }
  #pragma unroll
  for (int r = 0; r < 4; ++r) {
    long srow = (long)b * S + s0 + w * 16 + lg4 * 4 + r;
    int r7 = (int)(srow & 7);
    #pragma unroll
    for (int dt = 0; dt < 4; ++dt) {
      int col = dt * 16 + l15;
      float v = Oa[dt][r] + proj[srow * VF + col];
      merged[srow * (long)HV + h * 64 + (((col >> 3) ^ r7) << 3) + (col & 7)] = (f16)v;
    }
  }
}

} // namespace

extern "C" void kernel_launch(void* const* d_in, const int* in_sizes, int n_in,
                              void* d_out, int out_size, void* d_ws, size_t ws_size,
                              hipStream_t stream)
{
  const float* lat   = (const float*)d_in[0];
  const float* masks = (const float*)d_in[1];
  const float* xemb  = (const float*)d_in[2];
  const float* ccls  = (const float*)d_in[4];
  const float* qlin  = (const float*)d_in[5];
  const float* klin  = (const float*)d_in[6];
  const float* vlin  = (const float*)d_in[7];
  const float* plin  = (const float*)d_in[8];
  const float* agg   = (const float*)d_in[9];
  const float* cfeat = (const float*)d_in[10];
  float* out = (float*)d_out;
  float* ws = (float*)d_ws;

  long off = 0;
  auto allocF = [&](long n) { float* p = ws + off; off += (n + 3) & ~3L; return p; };
  auto allocH = [&](long n) { f16* p = (f16*)(ws + off); off += ((n + 1) / 2 + 3) & ~3L; return p; };

  f16* origA = allocH(ROWS * KSF);
  f16* vbufA = allocH(ROWS * KSF);
  f16* merged = allocH(ROWS * (long)HV);
  f16* WQt = allocH(16L * 64 * KSF);
  f16* WKt = allocH(2L * 64 * KSF);
  f16* WVt = allocH(16L * 64 * KSF);
  f16* WPt = allocH(2L * 64 * KSF);
  f16* WCFt = allocH((long)KSF * 512);
  f16* WCCt = allocH(64L * 512);
  f16* Ek16 = allocH((long)B * S * 64);
  f16* Ev16 = allocH((long)B * H * S * 64);
  f16* Eq16 = allocH((long)B * H * S * 64);
  f16* qland16 = allocH((long)B * H * NL * DF);
  f16* kland16 = allocH((long)B * NL * DF);
  float* cl     = allocF(ROWS * HS);
  float* projb  = allocF((long)B * S * VF);
  float* qland  = allocF((long)B * H * NL * DF);
  float* kland  = allocF((long)B * NL * DF);
  float* k2b    = allocF((long)B * H * NL * NL);
  float* kv3    = allocF((long)B * H * NL * VF);
  float* m2b    = allocF((long)B * H * NL * VF);
  float* colmax = allocF(64);
  float* partU  = allocF((long)B * H * NL * NSPL * 64);
  float* partML = allocF((long)B * H * NL * NSPL * 2);

  k_cl<<<(int)(ROWS / 4), 256, 0, stream>>>(lat, masks, cl);
  k_cvta<<<(int)(ROWS * 168 / 256), 256, 0, stream>>>(xemb, cl, origA);

  auto cvtw = [&](const float* src, f16* dst, int K, int N, int Npad, int KS, long srcZ, int nz) {
    long total = (long)nz * Npad * (KS / 8);
    k_cvtw<<<(int)((total + 255) / 256), 256, 0, stream>>>(src, dst, K, N, Npad, KS, srcZ, total);
  };
  cvtw(qlin, WQt, FEAT, 64, 64, KSF, (long)FEATP * 64, 16);
  cvtw(klin, WKt, FEAT, 64, 64, KSF, (long)FEATP * 64, 2);
  cvtw(vlin, WVt, FEAT, 64, 64, KSF, (long)FEATP * 64, 16);
  cvtw(plin, WPt, FEAT, 64, 64, KSF, (long)FEATP * 64, 2);
  cvtw(cfeat, WCFt, 512, FEAT, KSF, 512, 0, 1);
  cvtw(ccls, WCCt, 512, HS, 64, 512, 0, 1);

  const f16* Aact = origA;
  for (int layer = 0; layer < 2; ++layer) {
    const f16* wq = WQt + (long)layer * 8 * 64 * KSF;
    const f16* wk = WKt + (long)layer * 64 * KSF;
    const f16* wvv = WVt + (long)layer * 8 * 64 * KSF;
    const f16* wp = WPt + (long)layer * 64 * KSF;
    const float* bq = qlin + (long)layer * 8 * FEATP * 64 + (long)(FEATP - 2) * 64;
    const float* bk = klin + (long)layer * FEATP * 64 + (long)(FEATP - 2) * 64;
    const float* bv = vlin + (long)layer * 8 * FEATP * 64 + (long)(FEATP - 2) * 64;
    const float* bp = plin + (long)layer * FEATP * 64 + (long)(FEATP - 2) * 64;
    const float* ag = agg + layer * H;

    dim3 gQ(8, 1, 64), gK(8, 1, 8);
    k_mgemm<<<gQ, 256, 0, stream>>>(Aact, (long)S * KSF, 8, wq, 64L * KSF, 8, 21, 3,
        nullptr, (long)S * 64, 64, bq, (long)FEATP * 64, INV_SCALE, Eq16, 64, nullptr);
    k_mgemm<<<gK, 256, 0, stream>>>(Aact, (long)S * KSF, 1, wk, 0, 1, 21, 3,
        nullptr, (long)S * 64, 64, bk, 0, INV_SCALE, Ek16, 64, nullptr);
    k_mgemm<<<gQ, 256, 0, stream>>>(Aact, (long)S * KSF, 8, wvv, 64L * KSF, 8, 21, 3,
        nullptr, (long)S * 64, 64, bv, (long)FEATP * 64, 1.0f, Ev16, 64, nullptr);
    k_mgemm<<<gK, 256, 0, stream>>>(origA, (long)S * KSF, 1, wp, 0, 1, 21, 0,
        projb, (long)S * 64, 64, bp, 0, 0.5f, nullptr, 64, nullptr);

    k_segmean<<<B * H * NL, 64, 0, stream>>>(Eq16, qland, qland16);
    k_segmean<<<B * NL, 64, 0, stream>>>(Ek16, kland, kland16);

    k_kernel2<<<B * H, 256, 0, stream>>>(qland, kland, ag, k2b, colmax);
    k_kernel3<<<B * H * 2 * NSPL, 256, 0, stream>>>(qland16, Ek16, Ev16, ag, masks,
        partU, partML);
    k_merge<<<B * H * 4, 256, 0, stream>>>(partU, partML, kv3);
    k_inverse<<<B * H, 1024, 0, stream>>>(k2b, colmax, kv3, m2b);
    k_k1attn<<<B * H * (S / 64), 256, 0, stream>>>(Eq16, kland16, ag, m2b, projb, merged);

    if (layer == 0) {
      dim3 gC(64, 21, 1);
      k_mgemm<<<gC, 256, 0, stream>>>(merged, 0, 1, WCFt, 0, 1, 8, 1,
          nullptr, 0, 0, nullptr, 0, 1.0f, vbufA, FEAT, nullptr);
      Aact = vbufA;
    } else {
      dim3 gO(64, 1, 1);
      k_mgemm<<<gO, 256, 0, stream>>>(merged, 0, 1, WCCt, 0, 1, 8, 2,
          out, 0, HS, nullptr, 0, 1.0f, nullptr, HS, masks);
    }
  }
  (void)in_sizes; (void)n_in; (void)out_size; (void)ws_size;
}

// Round 9
// 678.097 us; speedup vs baseline: 9.2171x; 1.0858x over previous
//
#include <hip/hip_runtime.h>
#include <math.h>

// ESMMimicryModule: B=8 S=2048 H=8 NL=128 DF=VF=64 NF=1280 HS=33 FEAT=1313
// Round 8: k_inverse spill removal for real. 1024-thr blocks = 4 waves/SIMD =
// 128 unified VGPR+AGPR budget (hipcc splits 64+64; hints don't change it).
// Cut register demand: (1) no keyA pinning -- k2 stored as fp16 arena, stage-1
// A-frags read from global (L2-resident); (2) no aV prefetch -- stage 4 writes
// V_new to the scratch buffer and swaps pointers (race-free, -1 barrier).

namespace {

constexpr int B = 8, S = 2048, H = 8, NL = 128, DF = 64, VF = 64;
constexpr int NF = 1280, HS = 33, FEAT = 1313, FEATP = 1314;
constexpr int SEG = 16, HV = H * VF;            // 512
constexpr int KSF = 1344;                        // padded feature-K (21*64)
constexpr int NSPL = 4;                          // key chunks in split-S flash
constexpr long ROWS = (long)B * S;               // 16384
constexpr float INV_SCALE = 0.35355339059327373f;

typedef _Float16 f16;
typedef _Float16 f16x8 __attribute__((ext_vector_type(8)));
typedef _Float16 f16x4 __attribute__((ext_vector_type(4)));
typedef float f32x4 __attribute__((ext_vector_type(4)));

// ---------------------------------------------------------------- cl = softmax(latent)*mask
__global__ __launch_bounds__(256) void k_cl(
    const float* __restrict__ lat, const float* __restrict__ masks,
    float* __restrict__ cl)
{
  long row = (long)blockIdx.x * 4 + (threadIdx.x >> 6);
  int l = threadIdx.x & 63;
  float v = (l < HS) ? lat[row * HS + l] : -INFINITY;
  float m = v;
  #pragma unroll
  for (int o = 32; o; o >>= 1) m = fmaxf(m, __shfl_xor(m, o));
  float e = (l < HS) ? expf(v - m) : 0.f;
  float s = e;
  #pragma unroll
  for (int o = 32; o; o >>= 1) s += __shfl_xor(s, o);
  if (l < HS) cl[row * HS + l] = e / s * masks[row];
}

// ---------------------------------------------------------------- origA fp16 arena (swizzled)
__global__ __launch_bounds__(256) void k_cvta(
    const float* __restrict__ xemb, const float* __restrict__ cl,
    f16* __restrict__ dst)
{
  long idx = (long)blockIdx.x * 256 + threadIdx.x;  // chunk id (row,c)
  long row = idx / 168;
  int c = (int)(idx - row * 168);
  int t = c >> 3, cs = c & 7;
  int cd = cs ^ ((int)row & 7);
  int k0 = t * 64 + cd * 8;
  f16x8 v;
  #pragma unroll
  for (int i = 0; i < 8; ++i) {
    int k = k0 + i;
    float f = 0.f;
    if (k < NF) f = xemb[row * NF + k];
    else if (k < FEAT) f = cl[row * HS + (k - NF)];
    v[i] = (f16)f;
  }
  *(f16x8*)&dst[idx * 8] = v;
}

// ---------------------------------------------------------------- weight -> Wt fp16 arena
__global__ __launch_bounds__(256) void k_cvtw(
    const float* __restrict__ src, f16* __restrict__ dst,
    int K, int N, int Npad, int KS, long srcZ, long total)
{
  long idx = (long)blockIdx.x * 256 + threadIdx.x;
  if (idx >= total) return;
  long cpz = (long)Npad * (KS >> 3);
  long z = idx / cpz;
  long rem = idx - z * cpz;
  int n = (int)(rem / (KS >> 3));
  int c = (int)(rem - (long)n * (KS >> 3));
  int t = c >> 3, cs = c & 7;
  int cd = cs ^ (n & 7);
  int k0 = t * 64 + cd * 8;
  const float* sp = src + z * srcZ;
  f16x8 v;
  #pragma unroll
  for (int i = 0; i < 8; ++i) {
    int k = k0 + i;
    v[i] = (f16)((k < K && n < N) ? sp[(long)k * N + n] : 0.f);
  }
  *(f16x8*)&dst[idx * 8] = v;
}

// ---------------------------------------------------------------- fp16 MFMA GEMM
// mode 0: fp32 C = (acc + bias)*scale
// mode 1: fp16 swizzled arena (KSF stride, zero-fill col>=NR), LDS-staged
// mode 2: fp32 out * mask, col<NR
// mode 3: fp16 row-major out (64 cols), (acc+bias)*scale, LDS-staged
__global__ __launch_bounds__(256, 2) void k_mgemm(
    const f16* __restrict__ A, long aZOff, int aDiv,
    const f16* __restrict__ Wt, long wZOff, int wMod,
    int KT, int mode,
    float* __restrict__ C, long cZOff, int ldC,
    const float* __restrict__ biasBase, long biasZOff, float scale,
    f16* __restrict__ outA, int NR, const float* __restrict__ mask)
{
  const long KS = (long)KT * 64;
  int z = blockIdx.z;
  const f16* Ap = A + (long)(z / aDiv) * aZOff;
  const f16* Wp = Wt + (long)(z % wMod) * wZOff;
  long m0 = (long)blockIdx.x * 256;
  int n0 = blockIdx.y * 64;
  constexpr int BOFF = 256 * 64;
  __shared__ f16 lds[2][(256 + 64) * 64];
  int tid = threadIdx.x;
  int wv = tid >> 6, l = tid & 63;

  const f16* aW = Ap + (m0 + wv * 64 + (l >> 3)) * KS + (l & 7) * 8;
  const f16* bW = Wp + ((long)(n0 + wv * 16 + (l >> 3))) * KS + (l & 7) * 8;

  f32x4 acc[4][4];
  #pragma unroll
  for (int i = 0; i < 4; ++i)
    #pragma unroll
    for (int j = 0; j < 4; ++j) acc[i][j] = (f32x4){0.f, 0.f, 0.f, 0.f};

  auto stage = [&](int buf, int t) {
    f16* la = &lds[buf][(wv * 64) * 64];
    const f16* ga = aW + (long)t * 64;
    #pragma unroll
    for (int j = 0; j < 8; ++j)
      __builtin_amdgcn_global_load_lds(
          (const __attribute__((address_space(1))) void*)(ga + (long)j * 8 * KS),
          (__attribute__((address_space(3))) void*)(la + j * 8 * 64), 16, 0, 0);
    f16* lb = &lds[buf][BOFF + (wv * 16) * 64];
    const f16* gb = bW + (long)t * 64;
    #pragma unroll
    for (int j = 0; j < 2; ++j)
      __builtin_amdgcn_global_load_lds(
          (const __attribute__((address_space(1))) void*)(gb + (long)j * 8 * KS),
          (__attribute__((address_space(3))) void*)(lb + j * 8 * 64), 16, 0, 0);
  };

  stage(0, 0);
  int rA = (wv * 64 + (l & 15)) * 64;
  int rB = BOFF + (l & 15) * 64;
  int lc = l >> 4, lx = l & 7;
  for (int t = 0; t < KT; ++t) {
    int nb = t & 1;
    if (t + 1 < KT) {
      stage(nb ^ 1, t + 1);
      asm volatile("s_waitcnt vmcnt(10)" ::: "memory");
    } else {
      asm volatile("s_waitcnt vmcnt(0)" ::: "memory");
    }
    __syncthreads();
    const f16* base = &lds[nb][0];
    f16x8 af[4][2], bf[4][2];
    #pragma unroll
    for (int mi = 0; mi < 4; ++mi)
      #pragma unroll
      for (int kh = 0; kh < 2; ++kh)
        af[mi][kh] = *(const f16x8*)&base[rA + mi * 16 * 64 + (((kh * 4 + lc) ^ lx) << 3)];
    #pragma unroll
    for (int ni = 0; ni < 4; ++ni)
      #pragma unroll
      for (int kh = 0; kh < 2; ++kh)
        bf[ni][kh] = *(const f16x8*)&base[rB + ni * 16 * 64 + (((kh * 4 + lc) ^ lx) << 3)];
    #pragma unroll
    for (int mi = 0; mi < 4; ++mi)
      #pragma unroll
      for (int ni = 0; ni < 4; ++ni) {
        acc[mi][ni] = __builtin_amdgcn_mfma_f32_16x16x32_f16(af[mi][0], bf[ni][0], acc[mi][ni], 0, 0, 0);
        acc[mi][ni] = __builtin_amdgcn_mfma_f32_16x16x32_f16(af[mi][1], bf[ni][1], acc[mi][ni], 0, 0, 0);
      }
    __syncthreads();
  }

  int lr = (l >> 4) * 4;
  int lcn = l & 15;
  if (mode == 0) {
    float* Cp = C + (long)z * cZOff;
    const float* bp = biasBase ? biasBase + (long)(z % wMod) * biasZOff : nullptr;
    #pragma unroll
    for (int ni = 0; ni < 4; ++ni) {
      int col = n0 + ni * 16 + lcn;
      float bv = bp ? bp[col] : 0.f;
      #pragma unroll
      for (int mi = 0; mi < 4; ++mi) {
        long row = m0 + wv * 64 + mi * 16 + lr;
        #pragma unroll
        for (int r = 0; r < 4; ++r)
          Cp[(row + r) * (long)ldC + col] = (acc[mi][ni][r] + bv) * scale;
      }
    }
  } else if (mode == 2) {
    #pragma unroll
    for (int mi = 0; mi < 4; ++mi) {
      #pragma unroll
      for (int r = 0; r < 4; ++r) {
        long row = m0 + wv * 64 + mi * 16 + lr + r;
        float mv = mask[row];
        #pragma unroll
        for (int ni = 0; ni < 4; ++ni) {
          int col = n0 + ni * 16 + lcn;
          if (col < NR) C[row * (long)ldC + col] = acc[mi][ni][r] * mv;
        }
      }
    }
  } else {  // mode 1 / 3: stage f16 tile in LDS, vectorized global writes
    f16* st = &lds[0][0];
    const float* bp = biasBase ? biasBase + (long)(z % wMod) * biasZOff : nullptr;
    #pragma unroll
    for (int ni = 0; ni < 4; ++ni) {
      int coll = ni * 16 + lcn;
      int col = n0 + coll;
      float bv = bp ? bp[col] : 0.f;
      bool ok = col < NR;
      #pragma unroll
      for (int mi = 0; mi < 4; ++mi) {
        int rowl = wv * 64 + mi * 16 + lr;
        #pragma unroll
        for (int r = 0; r < 4; ++r) {
          float v = ok ? (acc[mi][ni][r] + bv) * scale : 0.f;
          st[(rowl + r) * 64 + coll] = (f16)v;
        }
      }
    }
    __syncthreads();
    if (mode == 3) {
      f16* o16 = outA + (long)z * cZOff;
      for (int c = tid; c < 2048; c += 256) {
        int row = c >> 3, cc = c & 7;
        f16x8 v = *(const f16x8*)&st[row * 64 + cc * 8];
        *(f16x8*)&o16[(m0 + row) * 64 + cc * 8] = v;
      }
    } else {
      int tt = n0 >> 6;
      for (int c = tid; c < 2048; c += 256) {
        int row = c >> 3, cd = c & 7;
        long grow = m0 + row;
        int r7 = (int)grow & 7;
        f16x8 v = *(const f16x8*)&st[row * 64 + cd * 8];
        *(f16x8*)&outA[grow * KSF + tt * 64 + ((cd ^ r7) << 3)] = v;
      }
    }
  }
}

// ---------------------------------------------------------------- landmarks (f16 input)
__global__ void k_segmean(const f16* __restrict__ in, float* __restrict__ out,
                          f16* __restrict__ out16)
{
  long zl = blockIdx.x;
  long z = zl / NL, lm = zl % NL;
  int d = threadIdx.x;
  const f16* p = in + (z * S + lm * SEG) * (long)DF + d;
  float s = 0.f;
  #pragma unroll
  for (int i = 0; i < SEG; i++) s += (float)p[(long)i * DF];
  float v = s * (1.f / SEG);
  out[(z * NL + lm) * (long)DF + d] = v;
  if (out16) out16[(z * NL + lm) * (long)DF + d] = (f16)v;
}

// ---------------------------------------------------------------- kernel_2 (analytic possel2)
// writes k2 as fp16 row-major arena (consumed only by k_inverse)
__global__ __launch_bounds__(256) void k_kernel2(
    const float* __restrict__ qland, const float* __restrict__ kland,
    const float* __restrict__ aggL, f16* __restrict__ k2h,
    float* __restrict__ colmax)
{
  int z = blockIdx.x; int b = z / H; int h = z % H;
  float sigma = fabsf(aggL[h]) + 0.001f;
  __shared__ float qs[NL][68];
  __shared__ float ks[NL][68];
  __shared__ float lg[NL][NL + 1];
  int tid = threadIdx.x;
  for (int idx = tid; idx < NL * DF; idx += 256) {
    int r = idx >> 6, d = idx & 63;
    qs[r][d] = qland[((long)z * NL + r) * DF + d];
    ks[r][d] = kland[((long)b * NL + r) * DF + d];
  }
  __syncthreads();
  int r = tid >> 1, half = tid & 1;
  float lmax = -INFINITY;
  for (int c = 0; c < 64; c++) {
    int m = half * 64 + c;
    float s = 0.f;
    #pragma unroll
    for (int d = 0; d < DF; d += 4) {
      float4 q = *(const float4*)&qs[r][d];
      float4 k4 = *(const float4*)&ks[m][d];
      s += q.x * k4.x + q.y * k4.y + q.z * k4.z + q.w * k4.w;
    }
    float dd = fabsf((float)(r - m));
    s += -sigma * ((r == m) ? 5.3125f : 16.f * dd);
    lg[r][m] = s;
    lmax = fmaxf(lmax, s);
  }
  lmax = fmaxf(lmax, __shfl_xor(lmax, 1));
  float lsum = 0.f;
  for (int c = 0; c < 64; c++) {
    int m = half * 64 + c;
    float e = expf(lg[r][m] - lmax);
    lg[r][m] = e; lsum += e;
  }
  lsum += __shfl_xor(lsum, 1);
  float inv = 1.f / lsum;
  for (int c = 0; c < 64; c++) {
    int m = half * 64 + c;
    float p = lg[r][m] * inv;
    lg[r][m] = p;
    k2h[((long)z * NL + r) * NL + m] = (f16)p;
  }
  __syncthreads();
  float myc = 0.f;
  if (tid < NL) {
    for (int rr = 0; rr < NL; rr++) myc += lg[rr][tid];
  }
  float wm = myc;
  #pragma unroll
  for (int o = 32; o; o >>= 1) wm = fmaxf(wm, __shfl_xor(wm, o));
  __shared__ float wred[4];
  if ((tid & 63) == 0) wred[tid >> 6] = wm;
  __syncthreads();
  if (tid == 0)
    colmax[z] = fmaxf(fmaxf(wred[0], wred[1]), fmaxf(wred[2], wred[3]));
}

// ---------------------------------------------------------------- kernel_3 (split-S flash MFMA)
__global__ __launch_bounds__(256, 2) void k_kernel3(
    const f16* __restrict__ qland16, const f16* __restrict__ Ek16,
    const f16* __restrict__ Ev16, const float* __restrict__ aggL,
    const float* __restrict__ masks,
    float* __restrict__ partU, float* __restrict__ partML)
{
  __shared__ __align__(16) f16 Qs[64 * 64];
  __shared__ __align__(16) f16 Ks[128 * 64];
  __shared__ __align__(16) f16 Vt[64 * 128];
  __shared__ __align__(16) f16 Pb[4 * 16 * 128];
  __shared__ float Ms[128];
  int id = blockIdx.x;
  int chunk = id & (NSPL - 1);
  int z2 = id >> 2;
  int z = z2 >> 1, half = z2 & 1;
  int b = z >> 3, h = z & 7;
  int q0 = half * 64;
  int tid = threadIdx.x;
  int w = tid >> 6, l = tid & 63;
  float sigma = fabsf(aggL[h]) + 0.001f;
  float cpos = -sigma * (1.f / 16.f);

  for (int c = tid; c < 64 * 8; c += 256) {
    int q = c >> 3, kc = c & 7;
    f16x8 v = *(const f16x8*)&qland16[((long)z * NL + q0 + q) * 64 + kc * 8];
    *(f16x8*)&Qs[q * 64 + ((kc ^ (q & 7)) << 3)] = v;
  }

  f16* Pw = &Pb[w * 16 * 128];
  int l15 = l & 15, lg4 = l >> 4, l7 = l & 7;
  f32x4 Oa[4];
  #pragma unroll
  for (int i = 0; i < 4; ++i) Oa[i] = (f32x4){0.f, 0.f, 0.f, 0.f};
  float mrun[4] = {-INFINITY, -INFINITY, -INFINITY, -INFINITY};
  float lrun[4] = {0.f, 0.f, 0.f, 0.f};

  int t0beg = chunk * (S / 128 / NSPL), t0end = t0beg + S / 128 / NSPL;
  for (int t0 = t0beg; t0 < t0end; ++t0) {
    __syncthreads();
    for (int c = tid; c < 1024; c += 256) {
      int k = c >> 3, kc = c & 7;
      f16x8 v = *(const f16x8*)&Ek16[((long)b * S + t0 * 128 + k) * 64 + kc * 8];
      *(f16x8*)&Ks[k * 64 + ((kc ^ (k & 7)) << 3)] = v;
    }
    for (int c = tid; c < 1024; c += 256) {
      int k = c & 127, dc = c >> 7;
      f16x8 v = *(const f16x8*)&Ev16[((long)z * S + t0 * 128 + k) * 64 + dc * 8];
      int kc = k >> 3, ki = k & 7;
      #pragma unroll
      for (int j = 0; j < 8; ++j) {
        int d = dc * 8 + j;
        Vt[d * 128 + ((kc ^ (d & 7)) << 3) + ki] = v[j];
      }
    }
    if (tid < 128)
      Ms[tid] = (masks[(long)b * S + t0 * 128 + tid] == 0.f) ? -1e6f : 0.f;
    __syncthreads();

    f16x8 af[2];
    #pragma unroll
    for (int kh = 0; kh < 2; ++kh)
      af[kh] = *(const f16x8*)&Qs[(w * 16 + l15) * 64 + (((kh * 4 + lg4) ^ l7) << 3)];
    f32x4 sc[8];
    #pragma unroll
    for (int ct = 0; ct < 8; ++ct) {
      int n = ct * 16 + l15;
      f16x8 b0 = *(const f16x8*)&Ks[n * 64 + (((lg4) ^ (n & 7)) << 3)];
      f16x8 b1 = *(const f16x8*)&Ks[n * 64 + (((4 + lg4) ^ (n & 7)) << 3)];
      f32x4 zz = (f32x4){0.f, 0.f, 0.f, 0.f};
      zz = __builtin_amdgcn_mfma_f32_16x16x32_f16(af[0], b0, zz, 0, 0, 0);
      sc[ct] = __builtin_amdgcn_mfma_f32_16x16x32_f16(af[1], b1, zz, 0, 0, 0);
    }
    float tmax[4] = {-INFINITY, -INFINITY, -INFINITY, -INFINITY};
    #pragma unroll
    for (int ct = 0; ct < 8; ++ct) {
      float mk = Ms[ct * 16 + l15];
      int key = t0 * 128 + ct * 16 + l15;
      #pragma unroll
      for (int r = 0; r < 4; ++r) {
        int qg = q0 + w * 16 + lg4 * 4 + r;
        float a = (float)(key - 16 * qg);
        float ac = fminf(fmaxf(a, 0.f), 15.f);
        float dd = fabsf(a - ac);
        float sum = ac * ac - 15.f * ac + 120.f + 16.f * dd;
        float s = sc[ct][r] + cpos * sum + mk;
        sc[ct][r] = s;
        tmax[r] = fmaxf(tmax[r], s);
      }
    }
    #pragma unroll
    for (int r = 0; r < 4; ++r) {
      #pragma unroll
      for (int o = 1; o < 16; o <<= 1)
        tmax[r] = fmaxf(tmax[r], __shfl_xor(tmax[r], o));
    }
    float fr[4], lsum[4];
    #pragma unroll
    for (int r = 0; r < 4; ++r) {
      float mnew = fmaxf(mrun[r], tmax[r]);
      fr[r] = expf(mrun[r] - mnew);
      mrun[r] = mnew;
      lsum[r] = 0.f;
    }
    #pragma unroll
    for (int ct = 0; ct < 8; ++ct) {
      #pragma unroll
      for (int r = 0; r < 4; ++r) {
        float p = expf(sc[ct][r] - mrun[r]);
        sc[ct][r] = p;
        lsum[r] += p;
      }
    }
    #pragma unroll
    for (int r = 0; r < 4; ++r) {
      #pragma unroll
      for (int o = 1; o < 16; o <<= 1)
        lsum[r] += __shfl_xor(lsum[r], o);
      lrun[r] = lrun[r] * fr[r] + lsum[r];
    }
    f32x4 fv = (f32x4){fr[0], fr[1], fr[2], fr[3]};
    #pragma unroll
    for (int dt = 0; dt < 4; ++dt) Oa[dt] *= fv;
    #pragma unroll
    for (int ct = 0; ct < 8; ++ct) {
      int kc = ct * 2 + (l15 >> 3);
      int ki = l15 & 7;
      #pragma unroll
      for (int r = 0; r < 4; ++r) {
        int row = lg4 * 4 + r;
        Pw[row * 128 + ((kc ^ (row & 7)) << 3) + ki] = (f16)sc[ct][r];
      }
    }
    #pragma unroll
    for (int ks = 0; ks < 4; ++ks) {
      f16x8 pa = *(const f16x8*)&Pw[l15 * 128 + (((ks * 4 + lg4) ^ l7) << 3)];
      #pragma unroll
      for (int dt = 0; dt < 4; ++dt) {
        int n = dt * 16 + l15;
        f16x8 bv = *(const f16x8*)&Vt[n * 128 + (((ks * 4 + lg4) ^ (n & 7)) << 3)];
        Oa[dt] = __builtin_amdgcn_mfma_f32_16x16x32_f16(pa, bv, Oa[dt], 0, 0, 0);
      }
    }
  }
  #pragma unroll
  for (int r = 0; r < 4; ++r) {
    long qg = q0 + w * 16 + lg4 * 4 + r;
    long base = ((long)z * NL + qg) * NSPL + chunk;
    #pragma unroll
    for (int dt = 0; dt < 4; ++dt)
      partU[base * 64 + dt * 16 + l15] = Oa[dt][r];
    if (l15 == 0) {
      partML[base * 2] = mrun[r];
      partML[base * 2 + 1] = lrun[r];
    }
  }
}

// ---------------------------------------------------------------- merge split-flash partials
__global__ __launch_bounds__(256) void k_merge(
    const float* __restrict__ partU, const float* __restrict__ partML,
    float* __restrict__ kv3)
{
  int id = blockIdx.x;
  int z = id >> 2, part = id & 3;
  int t = threadIdx.x;
  int q = part * 32 + (t >> 3);
  int c8 = (t & 7) * 8;
  long base = ((long)z * NL + q) * NSPL;
  float m[NSPL], lv[NSPL];
  #pragma unroll
  for (int c = 0; c < NSPL; ++c) {
    m[c] = partML[(base + c) * 2];
    lv[c] = partML[(base + c) * 2 + 1];
  }
  float M = fmaxf(fmaxf(m[0], m[1]), fmaxf(m[2], m[3]));
  float L = 0.f, sc[NSPL];
  #pragma unroll
  for (int c = 0; c < NSPL; ++c) {
    sc[c] = expf(m[c] - M);
    L += lv[c] * sc[c];
  }
  float o[8] = {};
  #pragma unroll
  for (int c = 0; c < NSPL; ++c) {
    const float* up = &partU[(base + c) * 64 + c8];
    float4 a = *(const float4*)up;
    float4 bq = *(const float4*)(up + 4);
    o[0] += sc[c] * a.x; o[1] += sc[c] * a.y; o[2] += sc[c] * a.z; o[3] += sc[c] * a.w;
    o[4] += sc[c] * bq.x; o[5] += sc[c] * bq.y; o[6] += sc[c] * bq.z; o[7] += sc[c] * bq.w;
  }
  float invL = 1.f / L;
  float* kp = &kv3[((long)z * NL + q) * 64 + c8];
  #pragma unroll
  for (int j = 0; j < 8; ++j) kp[j] = o[j] * invL;
}

// ---------------------------------------------------------------- inverse (MFMA fp16 NS, 16 waves)
// key in fp16 global arena; stage-1 A-frags from global (L2-resident, no keyA
// pinning); buffer role-swap removes aV prefetch; fits 64 VGPR + 64 AGPR.
__global__ __launch_bounds__(1024) void k_inverse(
    const f16* __restrict__ k2h, const float* __restrict__ colmax,
    const float* __restrict__ kv3, float* __restrict__ m2)
{
  __shared__ __align__(16) f16 bufA[128 * 128];   // V normal (current)
  __shared__ __align__(16) f16 bufB[128 * 128];   // scratch normal (X / V_new)
  __shared__ __align__(16) f16 Vt[128 * 128];
  __shared__ __align__(16) f16 Pt[128 * 128];
  int z = blockIdx.x;
  int tid = threadIdx.x;
  int w = tid >> 6, l = tid & 63;
  int l15 = l & 15, lg4 = l >> 4;
  int wr = (w >> 2) * 32, wc = (w & 3) * 32;

  float cv = colmax[l];
  #pragma unroll
  for (int o = 32; o; o >>= 1) cv = fmaxf(cv, __shfl_xor(cv, o));
  float recip = 1.f / cv;

  const f16* key = k2h + (long)z * NL * NL;
  auto swz = [](int r, int c) { return r * 128 + ((((c >> 3) ^ (r & 15))) << 3) + (c & 7); };

  // init: Vt = recip*key image (V^T), bufA = transpose (V)
  for (int idx = tid; idx < 128 * 16; idx += 1024) {
    int r = idx >> 4, c8 = (idx & 15) << 3;
    f16x8 kk = *(const f16x8*)&key[r * 128 + c8];
    f16x8 sv;
    #pragma unroll
    for (int j = 0; j < 8; ++j) sv[j] = (f16)(recip * (float)kk[j]);
    *(f16x8*)&Vt[swz(r, c8)] = sv;
    #pragma unroll
    for (int j = 0; j < 8; ++j) bufA[swz(c8 + j, r)] = sv[j];
  }
  __syncthreads();

  f16* Vc = bufA;
  f16* Sc = bufB;

  f32x4 acc[2][2];
  auto MMc = [&](bool fromGlobal, const f16* Aimg, const f16* Bimg) {
    #pragma unroll
    for (int mi = 0; mi < 2; ++mi)
      #pragma unroll
      for (int ni = 0; ni < 2; ++ni) acc[mi][ni] = (f32x4){0.f, 0.f, 0.f, 0.f};
    #pragma unroll
    for (int ks = 0; ks < 4; ++ks) {
      int k0 = ks * 32 + lg4 * 8;
      f16x8 bf[2];
      bf[0] = *(const f16x8*)&Bimg[swz(wc + l15, k0)];
      bf[1] = *(const f16x8*)&Bimg[swz(wc + 16 + l15, k0)];
      f16x8 af[2];
      if (fromGlobal) {
        af[0] = *(const f16x8*)&key[(wr + l15) * 128 + k0];
        af[1] = *(const f16x8*)&key[(wr + 16 + l15) * 128 + k0];
      } else {
        af[0] = *(const f16x8*)&Aimg[swz(wr + l15, k0)];
        af[1] = *(const f16x8*)&Aimg[swz(wr + 16 + l15, k0)];
      }
      #pragma unroll
      for (int mi = 0; mi < 2; ++mi)
        #pragma unroll
        for (int ni = 0; ni < 2; ++ni)
          acc[mi][ni] = __builtin_amdgcn_mfma_f32_16x16x32_f16(af[mi], bf[ni], acc[mi][ni], 0, 0, 0);
    }
  };
  // Nout: raw normal image (optional). Tout: transposed image with fold
  // image[col][row] = aT*acc[row][col] + bT*(row==col)  (packed f16x4 store)
  auto store = [&](f16* Nout, f16* Tout, float aT, float bT) {
    #pragma unroll
    for (int mi = 0; mi < 2; ++mi) {
      int row0 = wr + mi * 16 + lg4 * 4;
      #pragma unroll
      for (int ni = 0; ni < 2; ++ni) {
        int col = wc + ni * 16 + l15;
        f16x4 tv;
        #pragma unroll
        for (int r = 0; r < 4; ++r) {
          float v = acc[mi][ni][r];
          if (Nout) Nout[swz(row0 + r, col)] = (f16)v;
          tv[r] = (f16)(aT * v + ((row0 + r == col) ? bT : 0.f));
        }
        *(f16x4*)&Tout[col * 128 + ((((row0 >> 3) ^ (col & 15))) << 3) + (row0 & 7)] = tv;
      }
    }
  };

  for (int it = 0; it < 6; ++it) {
    MMc(true, nullptr, Vt);  store(Sc, Pt, -1.f, 7.f);       __syncthreads();
    MMc(false, Sc, Pt);      store(nullptr, Vt, -1.f, 15.f); __syncthreads();
    MMc(false, Sc, Vt);      store(nullptr, Pt, -0.25f, 3.25f); __syncthreads();
    MMc(false, Vc, Pt);      store(Sc, Vt, 1.f, 0.f);        __syncthreads();
    f16* tsw = Vc; Vc = Sc; Sc = tsw;
  }

  // m2 = V @ kv3 : stage kv3^T into Pt as [64][128]
  const float* kp = kv3 + (long)z * NL * VF;
  for (int idx = tid; idx < 128 * 16; idx += 1024) {
    int k = idx >> 4, c4 = (idx & 15) << 2;
    float4 v4 = *(const float4*)&kp[k * 64 + c4];
    Pt[swz(c4 + 0, k)] = (f16)v4.x;
    Pt[swz(c4 + 1, k)] = (f16)v4.y;
    Pt[swz(c4 + 2, k)] = (f16)v4.z;
    Pt[swz(c4 + 3, k)] = (f16)v4.w;
  }
  __syncthreads();
  int r0 = (w >> 1) * 16, ch = (w & 1) * 32;
  f32x4 accF[2];
  #pragma unroll
  for (int ni = 0; ni < 2; ++ni) accF[ni] = (f32x4){0.f, 0.f, 0.f, 0.f};
  #pragma unroll
  for (int ks = 0; ks < 4; ++ks) {
    int k0 = ks * 32 + lg4 * 8;
    f16x8 af = *(const f16x8*)&Vc[swz(r0 + l15, k0)];
    #pragma unroll
    for (int ni = 0; ni < 2; ++ni) {
      f16x8 bf = *(const f16x8*)&Pt[swz(ch + ni * 16 + l15, k0)];
      accF[ni] = __builtin_amdgcn_mfma_f32_16x16x32_f16(af, bf, accF[ni], 0, 0, 0);
    }
  }
  float* mp = m2 + (long)z * NL * VF;
  #pragma unroll
  for (int ni = 0; ni < 2; ++ni)
    #pragma unroll
    for (int r = 0; r < 4; ++r)
      mp[(long)(r0 + lg4 * 4 + r) * VF + ch + ni * 16 + l15] = accF[ni][r];
}

// ---------------------------------------------------------------- kernel_1 + attn + merge (MFMA)
__global__ __launch_bounds__(256, 2) void k_k1attn(
    const f16* __restrict__ Eq16, const f16* __restrict__ kland16,
    const float* __restrict__ aggL, const float* __restrict__ m2,
    const float* __restrict__ proj, f16* __restrict__ merged)
{
  __shared__ __align__(16) f16 Kl[128 * 64];
  __shared__ __align__(16) f16 M2t[64 * 128];
  __shared__ __align__(16) f16 Pb[4 * 16 * 128];
  int zz = blockIdx.x;
  int z = zz >> 5, st = zz & 31;
  int b = z >> 3, h = z & 7;
  int s0 = st * 64;
  int tid = threadIdx.x;
  int w = tid >> 6, l = tid & 63;
  int l15 = l & 15, lg4 = l >> 4, l7 = l & 7;
  float sigma = fabsf(aggL[h]) + 0.001f;
  float cpos = -sigma * (1.f / 16.f);

  for (int c = tid; c < 128 * 8; c += 256) {
    int k = c >> 3, kc = c & 7;
    f16x8 v = *(const f16x8*)&kland16[((long)b * NL + k) * 64 + kc * 8];
    *(f16x8*)&Kl[k * 64 + ((kc ^ (k & 7)) << 3)] = v;
  }
  const float* mp = m2 + (long)z * NL * VF;
  for (int c = tid; c < 128 * 16; c += 256) {
    int k = c >> 4, c4 = (c & 15) << 2;
    float4 v4 = *(const float4*)&mp[k * 64 + c4];
    int kc = k >> 3, ki = k & 7;
    M2t[(c4 + 0) * 128 + ((kc ^ ((c4 + 0) & 7)) << 3) + ki] = (f16)v4.x;
    M2t[(c4 + 1) * 128 + ((kc ^ ((c4 + 1) & 7)) << 3) + ki] = (f16)v4.y;
    M2t[(c4 + 2) * 128 + ((kc ^ ((c4 + 2) & 7)) << 3) + ki] = (f16)v4.z;
    M2t[(c4 + 3) * 128 + ((kc ^ ((c4 + 3) & 7)) << 3) + ki] = (f16)v4.w;
  }
  __syncthreads();

  long qrow = (long)z * S + s0 + w * 16 + l15;
  f16x8 af[2];
  #pragma unroll
  for (int kh = 0; kh < 2; ++kh)
    af[kh] = *(const f16x8*)&Eq16[qrow * 64 + kh * 32 + lg4 * 8];

  f32x4 sc[8];
  #pragma unroll
  for (int ct = 0; ct < 8; ++ct) {
    int n = ct * 16 + l15;
    f16x8 b0 = *(const f16x8*)&Kl[n * 64 + ((lg4 ^ (n & 7)) << 3)];
    f16x8 b1 = *(const f16x8*)&Kl[n * 64 + (((4 + lg4) ^ (n & 7)) << 3)];
    f32x4 zz4 = (f32x4){0.f, 0.f, 0.f, 0.f};
    zz4 = __builtin_amdgcn_mfma_f32_16x16x32_f16(af[0], b0, zz4, 0, 0, 0);
    sc[ct] = __builtin_amdgcn_mfma_f32_16x16x32_f16(af[1], b1, zz4, 0, 0, 0);
  }
  float tmax[4] = {-INFINITY, -INFINITY, -INFINITY, -INFINITY};
  #pragma unroll
  for (int ct = 0; ct < 8; ++ct) {
    int lm = ct * 16 + l15;
    #pragma unroll
    for (int r = 0; r < 4; ++r) {
      int spos = s0 + w * 16 + lg4 * 4 + r;
      float a = (float)(spos - 16 * lm);
      float ac = fminf(fmaxf(a, 0.f), 15.f);
      float dd = fabsf(a - ac);
      float sum = ac * ac - 15.f * ac + 120.f + 16.f * dd;
      float s = sc[ct][r] + cpos * sum;
      sc[ct][r] = s;
      tmax[r] = fmaxf(tmax[r], s);
    }
  }
  #pragma unroll
  for (int r = 0; r < 4; ++r) {
    #pragma unroll
    for (int o = 1; o < 16; o <<= 1)
      tmax[r] = fmaxf(tmax[r], __shfl_xor(tmax[r], o));
  }
  float lsum[4] = {0.f, 0.f, 0.f, 0.f};
  #pragma unroll
  for (int ct = 0; ct < 8; ++ct) {
    #pragma unroll
    for (int r = 0; r < 4; ++r) {
      float p = expf(sc[ct][r] - tmax[r]);
      sc[ct][r] = p;
      lsum[r] += p;
    }
  }
  #pragma unroll
  for (int r = 0; r < 4; ++r) {
    #pragma unroll
    for (int o = 1; o < 16; o <<= 1)
      lsum[r] += __shfl_xor(lsum[r], o);
    lsum[r] = 1.f / lsum[r];
  }
  f16* Pw = &Pb[w * 16 * 128];
  #pragma unroll
  for (int ct = 0; ct < 8; ++ct) {
    int kc = ct * 2 + (l15 >> 3);
    int ki = l15 & 7;
    #pragma unroll
    for (int r = 0; r < 4; ++r) {
      int row = lg4 * 4 + r;
      Pw[row * 128 + ((kc ^ (row & 7)) << 3) + ki] = (f16)(sc[ct][r] * lsum[r]);
    }
  }
  f32x4 Oa[4];
  #pragma unroll
  for (int i = 0; i < 4; ++i) Oa[i] = (f32x4){0.f, 0.f, 0.f, 0.f};
  #pragma unroll
  for (int ks = 0; ks < 4; ++ks) {
    f16x8 pa = *(const f16x8*)&Pw[l15 * 128 + (((ks * 4 + lg4) ^ l7) << 3)];
    #pragma unroll
    for (int dt = 0; dt < 4; ++dt) {
      int n = dt * 16 + l15;
      f16x8 bv = *(const f16x8*)&M2t[n * 128 + (((ks * 4 + lg4) ^ (n & 7)) << 3)];
      Oa[dt] = __builtin_amdgcn_mfma_f32_16x16x32_f16(pa, bv, Oa[dt], 0, 0, 0);
    }
  }
  #pragma unroll
  for (int r = 0; r < 4; ++r) {
    long srow = (long)b * S + s0 + w * 16 + lg4 * 4 + r;
    int r7 = (int)(srow & 7);
    #pragma unroll
    for (int dt = 0; dt < 4; ++dt) {
      int col = dt * 16 + l15;
      float v = Oa[dt][r] + proj[srow * VF + col];
      merged[srow * (long)HV + h * 64 + (((col >> 3) ^ r7) << 3) + (col & 7)] = (f16)v;
    }
  }
}

} // namespace

extern "C" void kernel_launch(void* const* d_in, const int* in_sizes, int n_in,
                              void* d_out, int out_size, void* d_ws, size_t ws_size,
                              hipStream_t stream)
{
  const float* lat   = (const float*)d_in[0];
  const float* masks = (const float*)d_in[1];
  const float* xemb  = (const float*)d_in[2];
  const float* ccls  = (const float*)d_in[4];
  const float* qlin  = (const float*)d_in[5];
  const float* klin  = (const float*)d_in[6];
  const float* vlin  = (const float*)d_in[7];
  const float* plin  = (const float*)d_in[8];
  const float* agg   = (const float*)d_in[9];
  const float* cfeat = (const float*)d_in[10];
  float* out = (float*)d_out;
  float* ws = (float*)d_ws;

  long off = 0;
  auto allocF = [&](long n) { float* p = ws + off; off += (n + 3) & ~3L; return p; };
  auto allocH = [&](long n) { f16* p = (f16*)(ws + off); off += ((n + 1) / 2 + 3) & ~3L; return p; };

  f16* origA = allocH(ROWS * KSF);
  f16* vbufA = allocH(ROWS * KSF);
  f16* merged = allocH(ROWS * (long)HV);
  f16* WQt = allocH(16L * 64 * KSF);
  f16* WKt = allocH(2L * 64 * KSF);
  f16* WVt = allocH(16L * 64 * KSF);
  f16* WPt = allocH(2L * 64 * KSF);
  f16* WCFt = allocH((long)KSF * 512);
  f16* WCCt = allocH(64L * 512);
  f16* Ek16 = allocH((long)B * S * 64);
  f16* Ev16 = allocH((long)B * H * S * 64);
  f16* Eq16 = allocH((long)B * H * S * 64);
  f16* qland16 = allocH((long)B * H * NL * DF);
  f16* kland16 = allocH((long)B * NL * DF);
  f16* k2h = allocH((long)B * H * NL * NL);
  float* cl     = allocF(ROWS * HS);
  float* projb  = allocF((long)B * S * VF);
  float* qland  = allocF((long)B * H * NL * DF);
  float* kland  = allocF((long)B * NL * DF);
  float* kv3    = allocF((long)B * H * NL * VF);
  float* m2b    = allocF((long)B * H * NL * VF);
  float* colmax = allocF(64);
  float* partU  = allocF((long)B * H * NL * NSPL * 64);
  float* partML = allocF((long)B * H * NL * NSPL * 2);

  k_cl<<<(int)(ROWS / 4), 256, 0, stream>>>(lat, masks, cl);
  k_cvta<<<(int)(ROWS * 168 / 256), 256, 0, stream>>>(xemb, cl, origA);

  auto cvtw = [&](const float* src, f16* dst, int K, int N, int Npad, int KS, long srcZ, int nz) {
    long total = (long)nz * Npad * (KS / 8);
    k_cvtw<<<(int)((total + 255) / 256), 256, 0, stream>>>(src, dst, K, N, Npad, KS, srcZ, total);
  };
  cvtw(qlin, WQt, FEAT, 64, 64, KSF, (long)FEATP * 64, 16);
  cvtw(klin, WKt, FEAT, 64, 64, KSF, (long)FEATP * 64, 2);
  cvtw(vlin, WVt, FEAT, 64, 64, KSF, (long)FEATP * 64, 16);
  cvtw(plin, WPt, FEAT, 64, 64, KSF, (long)FEATP * 64, 2);
  cvtw(cfeat, WCFt, 512, FEAT, KSF, 512, 0, 1);
  cvtw(ccls, WCCt, 512, HS, 64, 512, 0, 1);

  const f16* Aact = origA;
  for (int layer = 0; layer < 2; ++layer) {
    const f16* wq = WQt + (long)layer * 8 * 64 * KSF;
    const f16* wk = WKt + (long)layer * 64 * KSF;
    const f16* wvv = WVt + (long)layer * 8 * 64 * KSF;
    const f16* wp = WPt + (long)layer * 64 * KSF;
    const float* bq = qlin + (long)layer * 8 * FEATP * 64 + (long)(FEATP - 2) * 64;
    const float* bk = klin + (long)layer * FEATP * 64 + (long)(FEATP - 2) * 64;
    const float* bv = vlin + (long)layer * 8 * FEATP * 64 + (long)(FEATP - 2) * 64;
    const float* bp = plin + (long)layer * FEATP * 64 + (long)(FEATP - 2) * 64;
    const float* ag = agg + layer * H;

    dim3 gQ(8, 1, 64), gK(8, 1, 8);
    k_mgemm<<<gQ, 256, 0, stream>>>(Aact, (long)S * KSF, 8, wq, 64L * KSF, 8, 21, 3,
        nullptr, (long)S * 64, 64, bq, (long)FEATP * 64, INV_SCALE, Eq16, 64, nullptr);
    k_mgemm<<<gK, 256, 0, stream>>>(Aact, (long)S * KSF, 1, wk, 0, 1, 21, 3,
        nullptr, (long)S * 64, 64, bk, 0, INV_SCALE, Ek16, 64, nullptr);
    k_mgemm<<<gQ, 256, 0, stream>>>(Aact, (long)S * KSF, 8, wvv, 64L * KSF, 8, 21, 3,
        nullptr, (long)S * 64, 64, bv, (long)FEATP * 64, 1.0f, Ev16, 64, nullptr);
    k_mgemm<<<gK, 256, 0, stream>>>(origA, (long)S * KSF, 1, wp, 0, 1, 21, 0,
        projb, (long)S * 64, 64, bp, 0, 0.5f, nullptr, 64, nullptr);

    k_segmean<<<B * H * NL, 64, 0, stream>>>(Eq16, qland, qland16);
    k_segmean<<<B * NL, 64, 0, stream>>>(Ek16, kland, kland16);

    k_kernel2<<<B * H, 256, 0, stream>>>(qland, kland, ag, k2h, colmax);
    k_kernel3<<<B * H * 2 * NSPL, 256, 0, stream>>>(qland16, Ek16, Ev16, ag, masks,
        partU, partML);
    k_merge<<<B * H * 4, 256, 0, stream>>>(partU, partML, kv3);
    k_inverse<<<B * H, 1024, 0, stream>>>(k2h, colmax, kv3, m2b);
    k_k1attn<<<B * H * (S / 64), 256, 0, stream>>>(Eq16, kland16, ag, m2b, projb, merged);

    if (layer == 0) {
      dim3 gC(64, 21, 1);
      k_mgemm<<<gC, 256, 0, stream>>>(merged, 0, 1, WCFt, 0, 1, 8, 1,
          nullptr, 0, 0, nullptr, 0, 1.0f, vbufA, FEAT, nullptr);
      Aact = vbufA;
    } else {
      dim3 gO(64, 1, 1);
      k_mgemm<<<gO, 256, 0, stream>>>(merged, 0, 1, WCCt, 0, 1, 8, 2,
          out, 0, HS, nullptr, 0, 1.0f, nullptr, HS, masks);
    }
  }
  (void)in_sizes; (void)n_in; (void)out_size; (void)ws_size;
}

// Round 10
// 636.411 us; speedup vs baseline: 9.8209x; 1.0655x over previous
//
#include <hip/hip_runtime.h>
#include <math.h>

// ESMMimicryModule: B=8 S=2048 H=8 NL=128 DF=VF=64 NF=1280 HS=33 FEAT=1313
// Round 9: k_inverse -> 512 threads / 8 waves. At 1024 thr (4 waves/SIMD) the
// unified reg budget is 128/wave (64 VGPR half) -> residual spill (WRITE_SIZE
// 10.5MB vs 2MB legit, VGPR=64). 8 waves = 2/SIMD = 256 regs/wave: spill-free.
// Per-wave tile 32x64 (acc[2][4]); everything else unchanged.

namespace {

constexpr int B = 8, S = 2048, H = 8, NL = 128, DF = 64, VF = 64;
constexpr int NF = 1280, HS = 33, FEAT = 1313, FEATP = 1314;
constexpr int SEG = 16, HV = H * VF;            // 512
constexpr int KSF = 1344;                        // padded feature-K (21*64)
constexpr int NSPL = 4;                          // key chunks in split-S flash
constexpr long ROWS = (long)B * S;               // 16384
constexpr float INV_SCALE = 0.35355339059327373f;

typedef _Float16 f16;
typedef _Float16 f16x8 __attribute__((ext_vector_type(8)));
typedef _Float16 f16x4 __attribute__((ext_vector_type(4)));
typedef float f32x4 __attribute__((ext_vector_type(4)));

// ---------------------------------------------------------------- cl = softmax(latent)*mask
__global__ __launch_bounds__(256) void k_cl(
    const float* __restrict__ lat, const float* __restrict__ masks,
    float* __restrict__ cl)
{
  long row = (long)blockIdx.x * 4 + (threadIdx.x >> 6);
  int l = threadIdx.x & 63;
  float v = (l < HS) ? lat[row * HS + l] : -INFINITY;
  float m = v;
  #pragma unroll
  for (int o = 32; o; o >>= 1) m = fmaxf(m, __shfl_xor(m, o));
  float e = (l < HS) ? expf(v - m) : 0.f;
  float s = e;
  #pragma unroll
  for (int o = 32; o; o >>= 1) s += __shfl_xor(s, o);
  if (l < HS) cl[row * HS + l] = e / s * masks[row];
}

// ---------------------------------------------------------------- origA fp16 arena (swizzled)
__global__ __launch_bounds__(256) void k_cvta(
    const float* __restrict__ xemb, const float* __restrict__ cl,
    f16* __restrict__ dst)
{
  long idx = (long)blockIdx.x * 256 + threadIdx.x;  // chunk id (row,c)
  long row = idx / 168;
  int c = (int)(idx - row * 168);
  int t = c >> 3, cs = c & 7;
  int cd = cs ^ ((int)row & 7);
  int k0 = t * 64 + cd * 8;
  f16x8 v;
  #pragma unroll
  for (int i = 0; i < 8; ++i) {
    int k = k0 + i;
    float f = 0.f;
    if (k < NF) f = xemb[row * NF + k];
    else if (k < FEAT) f = cl[row * HS + (k - NF)];
    v[i] = (f16)f;
  }
  *(f16x8*)&dst[idx * 8] = v;
}

// ---------------------------------------------------------------- weight -> Wt fp16 arena
__global__ __launch_bounds__(256) void k_cvtw(
    const float* __restrict__ src, f16* __restrict__ dst,
    int K, int N, int Npad, int KS, long srcZ, long total)
{
  long idx = (long)blockIdx.x * 256 + threadIdx.x;
  if (idx >= total) return;
  long cpz = (long)Npad * (KS >> 3);
  long z = idx / cpz;
  long rem = idx - z * cpz;
  int n = (int)(rem / (KS >> 3));
  int c = (int)(rem - (long)n * (KS >> 3));
  int t = c >> 3, cs = c & 7;
  int cd = cs ^ (n & 7);
  int k0 = t * 64 + cd * 8;
  const float* sp = src + z * srcZ;
  f16x8 v;
  #pragma unroll
  for (int i = 0; i < 8; ++i) {
    int k = k0 + i;
    v[i] = (f16)((k < K && n < N) ? sp[(long)k * N + n] : 0.f);
  }
  *(f16x8*)&dst[idx * 8] = v;
}

// ---------------------------------------------------------------- fp16 MFMA GEMM
// mode 0: fp32 C = (acc + bias)*scale
// mode 1: fp16 swizzled arena (KSF stride, zero-fill col>=NR), LDS-staged
// mode 2: fp32 out * mask, col<NR
// mode 3: fp16 row-major out (64 cols), (acc+bias)*scale, LDS-staged
__global__ __launch_bounds__(256, 2) void k_mgemm(
    const f16* __restrict__ A, long aZOff, int aDiv,
    const f16* __restrict__ Wt, long wZOff, int wMod,
    int KT, int mode,
    float* __restrict__ C, long cZOff, int ldC,
    const float* __restrict__ biasBase, long biasZOff, float scale,
    f16* __restrict__ outA, int NR, const float* __restrict__ mask)
{
  const long KS = (long)KT * 64;
  int z = blockIdx.z;
  const f16* Ap = A + (long)(z / aDiv) * aZOff;
  const f16* Wp = Wt + (long)(z % wMod) * wZOff;
  long m0 = (long)blockIdx.x * 256;
  int n0 = blockIdx.y * 64;
  constexpr int BOFF = 256 * 64;
  __shared__ f16 lds[2][(256 + 64) * 64];
  int tid = threadIdx.x;
  int wv = tid >> 6, l = tid & 63;

  const f16* aW = Ap + (m0 + wv * 64 + (l >> 3)) * KS + (l & 7) * 8;
  const f16* bW = Wp + ((long)(n0 + wv * 16 + (l >> 3))) * KS + (l & 7) * 8;

  f32x4 acc[4][4];
  #pragma unroll
  for (int i = 0; i < 4; ++i)
    #pragma unroll
    for (int j = 0; j < 4; ++j) acc[i][j] = (f32x4){0.f, 0.f, 0.f, 0.f};

  auto stage = [&](int buf, int t) {
    f16* la = &lds[buf][(wv * 64) * 64];
    const f16* ga = aW + (long)t * 64;
    #pragma unroll
    for (int j = 0; j < 8; ++j)
      __builtin_amdgcn_global_load_lds(
          (const __attribute__((address_space(1))) void*)(ga + (long)j * 8 * KS),
          (__attribute__((address_space(3))) void*)(la + j * 8 * 64), 16, 0, 0);
    f16* lb = &lds[buf][BOFF + (wv * 16) * 64];
    const f16* gb = bW + (long)t * 64;
    #pragma unroll
    for (int j = 0; j < 2; ++j)
      __builtin_amdgcn_global_load_lds(
          (const __attribute__((address_space(1))) void*)(gb + (long)j * 8 * KS),
          (__attribute__((address_space(3))) void*)(lb + j * 8 * 64), 16, 0, 0);
  };

  stage(0, 0);
  int rA = (wv * 64 + (l & 15)) * 64;
  int rB = BOFF + (l & 15) * 64;
  int lc = l >> 4, lx = l & 7;
  for (int t = 0; t < KT; ++t) {
    int nb = t & 1;
    if (t + 1 < KT) {
      stage(nb ^ 1, t + 1);
      asm volatile("s_waitcnt vmcnt(10)" ::: "memory");
    } else {
      asm volatile("s_waitcnt vmcnt(0)" ::: "memory");
    }
    __syncthreads();
    const f16* base = &lds[nb][0];
    f16x8 af[4][2], bf[4][2];
    #pragma unroll
    for (int mi = 0; mi < 4; ++mi)
      #pragma unroll
      for (int kh = 0; kh < 2; ++kh)
        af[mi][kh] = *(const f16x8*)&base[rA + mi * 16 * 64 + (((kh * 4 + lc) ^ lx) << 3)];
    #pragma unroll
    for (int ni = 0; ni < 4; ++ni)
      #pragma unroll
      for (int kh = 0; kh < 2; ++kh)
        bf[ni][kh] = *(const f16x8*)&base[rB + ni * 16 * 64 + (((kh * 4 + lc) ^ lx) << 3)];
    #pragma unroll
    for (int mi = 0; mi < 4; ++mi)
      #pragma unroll
      for (int ni = 0; ni < 4; ++ni) {
        acc[mi][ni] = __builtin_amdgcn_mfma_f32_16x16x32_f16(af[mi][0], bf[ni][0], acc[mi][ni], 0, 0, 0);
        acc[mi][ni] = __builtin_amdgcn_mfma_f32_16x16x32_f16(af[mi][1], bf[ni][1], acc[mi][ni], 0, 0, 0);
      }
    __syncthreads();
  }

  int lr = (l >> 4) * 4;
  int lcn = l & 15;
  if (mode == 0) {
    float* Cp = C + (long)z * cZOff;
    const float* bp = biasBase ? biasBase + (long)(z % wMod) * biasZOff : nullptr;
    #pragma unroll
    for (int ni = 0; ni < 4; ++ni) {
      int col = n0 + ni * 16 + lcn;
      float bv = bp ? bp[col] : 0.f;
      #pragma unroll
      for (int mi = 0; mi < 4; ++mi) {
        long row = m0 + wv * 64 + mi * 16 + lr;
        #pragma unroll
        for (int r = 0; r < 4; ++r)
          Cp[(row + r) * (long)ldC + col] = (acc[mi][ni][r] + bv) * scale;
      }
    }
  } else if (mode == 2) {
    #pragma unroll
    for (int mi = 0; mi < 4; ++mi) {
      #pragma unroll
      for (int r = 0; r < 4; ++r) {
        long row = m0 + wv * 64 + mi * 16 + lr + r;
        float mv = mask[row];
        #pragma unroll
        for (int ni = 0; ni < 4; ++ni) {
          int col = n0 + ni * 16 + lcn;
          if (col < NR) C[row * (long)ldC + col] = acc[mi][ni][r] * mv;
        }
      }
    }
  } else {  // mode 1 / 3: stage f16 tile in LDS, vectorized global writes
    f16* st = &lds[0][0];
    const float* bp = biasBase ? biasBase + (long)(z % wMod) * biasZOff : nullptr;
    #pragma unroll
    for (int ni = 0; ni < 4; ++ni) {
      int coll = ni * 16 + lcn;
      int col = n0 + coll;
      float bv = bp ? bp[col] : 0.f;
      bool ok = col < NR;
      #pragma unroll
      for (int mi = 0; mi < 4; ++mi) {
        int rowl = wv * 64 + mi * 16 + lr;
        #pragma unroll
        for (int r = 0; r < 4; ++r) {
          float v = ok ? (acc[mi][ni][r] + bv) * scale : 0.f;
          st[(rowl + r) * 64 + coll] = (f16)v;
        }
      }
    }
    __syncthreads();
    if (mode == 3) {
      f16* o16 = outA + (long)z * cZOff;
      for (int c = tid; c < 2048; c += 256) {
        int row = c >> 3, cc = c & 7;
        f16x8 v = *(const f16x8*)&st[row * 64 + cc * 8];
        *(f16x8*)&o16[(m0 + row) * 64 + cc * 8] = v;
      }
    } else {
      int tt = n0 >> 6;
      for (int c = tid; c < 2048; c += 256) {
        int row = c >> 3, cd = c & 7;
        long grow = m0 + row;
        int r7 = (int)grow & 7;
        f16x8 v = *(const f16x8*)&st[row * 64 + cd * 8];
        *(f16x8*)&outA[grow * KSF + tt * 64 + ((cd ^ r7) << 3)] = v;
      }
    }
  }
}

// ---------------------------------------------------------------- landmarks (f16 input)
__global__ void k_segmean(const f16* __restrict__ in, float* __restrict__ out,
                          f16* __restrict__ out16)
{
  long zl = blockIdx.x;
  long z = zl / NL, lm = zl % NL;
  int d = threadIdx.x;
  const f16* p = in + (z * S + lm * SEG) * (long)DF + d;
  float s = 0.f;
  #pragma unroll
  for (int i = 0; i < SEG; i++) s += (float)p[(long)i * DF];
  float v = s * (1.f / SEG);
  out[(z * NL + lm) * (long)DF + d] = v;
  if (out16) out16[(z * NL + lm) * (long)DF + d] = (f16)v;
}

// ---------------------------------------------------------------- kernel_2 (analytic possel2)
// writes k2 as fp16 row-major arena (consumed only by k_inverse)
__global__ __launch_bounds__(256) void k_kernel2(
    const float* __restrict__ qland, const float* __restrict__ kland,
    const float* __restrict__ aggL, f16* __restrict__ k2h,
    float* __restrict__ colmax)
{
  int z = blockIdx.x; int b = z / H; int h = z % H;
  float sigma = fabsf(aggL[h]) + 0.001f;
  __shared__ float qs[NL][68];
  __shared__ float ks[NL][68];
  __shared__ float lg[NL][NL + 1];
  int tid = threadIdx.x;
  for (int idx = tid; idx < NL * DF; idx += 256) {
    int r = idx >> 6, d = idx & 63;
    qs[r][d] = qland[((long)z * NL + r) * DF + d];
    ks[r][d] = kland[((long)b * NL + r) * DF + d];
  }
  __syncthreads();
  int r = tid >> 1, half = tid & 1;
  float lmax = -INFINITY;
  for (int c = 0; c < 64; c++) {
    int m = half * 64 + c;
    float s = 0.f;
    #pragma unroll
    for (int d = 0; d < DF; d += 4) {
      float4 q = *(const float4*)&qs[r][d];
      float4 k4 = *(const float4*)&ks[m][d];
      s += q.x * k4.x + q.y * k4.y + q.z * k4.z + q.w * k4.w;
    }
    float dd = fabsf((float)(r - m));
    s += -sigma * ((r == m) ? 5.3125f : 16.f * dd);
    lg[r][m] = s;
    lmax = fmaxf(lmax, s);
  }
  lmax = fmaxf(lmax, __shfl_xor(lmax, 1));
  float lsum = 0.f;
  for (int c = 0; c < 64; c++) {
    int m = half * 64 + c;
    float e = expf(lg[r][m] - lmax);
    lg[r][m] = e; lsum += e;
  }
  lsum += __shfl_xor(lsum, 1);
  float inv = 1.f / lsum;
  for (int c = 0; c < 64; c++) {
    int m = half * 64 + c;
    float p = lg[r][m] * inv;
    lg[r][m] = p;
    k2h[((long)z * NL + r) * NL + m] = (f16)p;
  }
  __syncthreads();
  float myc = 0.f;
  if (tid < NL) {
    for (int rr = 0; rr < NL; rr++) myc += lg[rr][tid];
  }
  float wm = myc;
  #pragma unroll
  for (int o = 32; o; o >>= 1) wm = fmaxf(wm, __shfl_xor(wm, o));
  __shared__ float wred[4];
  if ((tid & 63) == 0) wred[tid >> 6] = wm;
  __syncthreads();
  if (tid == 0)
    colmax[z] = fmaxf(fmaxf(wred[0], wred[1]), fmaxf(wred[2], wred[3]));
}

// ---------------------------------------------------------------- kernel_3 (split-S flash MFMA)
__global__ __launch_bounds__(256, 2) void k_kernel3(
    const f16* __restrict__ qland16, const f16* __restrict__ Ek16,
    const f16* __restrict__ Ev16, const float* __restrict__ aggL,
    const float* __restrict__ masks,
    float* __restrict__ partU, float* __restrict__ partML)
{
  __shared__ __align__(16) f16 Qs[64 * 64];
  __shared__ __align__(16) f16 Ks[128 * 64];
  __shared__ __align__(16) f16 Vt[64 * 128];
  __shared__ __align__(16) f16 Pb[4 * 16 * 128];
  __shared__ float Ms[128];
  int id = blockIdx.x;
  int chunk = id & (NSPL - 1);
  int z2 = id >> 2;
  int z = z2 >> 1, half = z2 & 1;
  int b = z >> 3, h = z & 7;
  int q0 = half * 64;
  int tid = threadIdx.x;
  int w = tid >> 6, l = tid & 63;
  float sigma = fabsf(aggL[h]) + 0.001f;
  float cpos = -sigma * (1.f / 16.f);

  for (int c = tid; c < 64 * 8; c += 256) {
    int q = c >> 3, kc = c & 7;
    f16x8 v = *(const f16x8*)&qland16[((long)z * NL + q0 + q) * 64 + kc * 8];
    *(f16x8*)&Qs[q * 64 + ((kc ^ (q & 7)) << 3)] = v;
  }

  f16* Pw = &Pb[w * 16 * 128];
  int l15 = l & 15, lg4 = l >> 4, l7 = l & 7;
  f32x4 Oa[4];
  #pragma unroll
  for (int i = 0; i < 4; ++i) Oa[i] = (f32x4){0.f, 0.f, 0.f, 0.f};
  float mrun[4] = {-INFINITY, -INFINITY, -INFINITY, -INFINITY};
  float lrun[4] = {0.f, 0.f, 0.f, 0.f};

  int t0beg = chunk * (S / 128 / NSPL), t0end = t0beg + S / 128 / NSPL;
  for (int t0 = t0beg; t0 < t0end; ++t0) {
    __syncthreads();
    for (int c = tid; c < 1024; c += 256) {
      int k = c >> 3, kc = c & 7;
      f16x8 v = *(const f16x8*)&Ek16[((long)b * S + t0 * 128 + k) * 64 + kc * 8];
      *(f16x8*)&Ks[k * 64 + ((kc ^ (k & 7)) << 3)] = v;
    }
    for (int c = tid; c < 1024; c += 256) {
      int k = c & 127, dc = c >> 7;
      f16x8 v = *(const f16x8*)&Ev16[((long)z * S + t0 * 128 + k) * 64 + dc * 8];
      int kc = k >> 3, ki = k & 7;
      #pragma unroll
      for (int j = 0; j < 8; ++j) {
        int d = dc * 8 + j;
        Vt[d * 128 + ((kc ^ (d & 7)) << 3) + ki] = v[j];
      }
    }
    if (tid < 128)
      Ms[tid] = (masks[(long)b * S + t0 * 128 + tid] == 0.f) ? -1e6f : 0.f;
    __syncthreads();

    f16x8 af[2];
    #pragma unroll
    for (int kh = 0; kh < 2; ++kh)
      af[kh] = *(const f16x8*)&Qs[(w * 16 + l15) * 64 + (((kh * 4 + lg4) ^ l7) << 3)];
    f32x4 sc[8];
    #pragma unroll
    for (int ct = 0; ct < 8; ++ct) {
      int n = ct * 16 + l15;
      f16x8 b0 = *(const f16x8*)&Ks[n * 64 + (((lg4) ^ (n & 7)) << 3)];
      f16x8 b1 = *(const f16x8*)&Ks[n * 64 + (((4 + lg4) ^ (n & 7)) << 3)];
      f32x4 zz = (f32x4){0.f, 0.f, 0.f, 0.f};
      zz = __builtin_amdgcn_mfma_f32_16x16x32_f16(af[0], b0, zz, 0, 0, 0);
      sc[ct] = __builtin_amdgcn_mfma_f32_16x16x32_f16(af[1], b1, zz, 0, 0, 0);
    }
    float tmax[4] = {-INFINITY, -INFINITY, -INFINITY, -INFINITY};
    #pragma unroll
    for (int ct = 0; ct < 8; ++ct) {
      float mk = Ms[ct * 16 + l15];
      int key = t0 * 128 + ct * 16 + l15;
      #pragma unroll
      for (int r = 0; r < 4; ++r) {
        int qg = q0 + w * 16 + lg4 * 4 + r;
        float a = (float)(key - 16 * qg);
        float ac = fminf(fmaxf(a, 0.f), 15.f);
        float dd = fabsf(a - ac);
        float sum = ac * ac - 15.f * ac + 120.f + 16.f * dd;
        float s = sc[ct][r] + cpos * sum + mk;
        sc[ct][r] = s;
        tmax[r] = fmaxf(tmax[r], s);
      }
    }
    #pragma unroll
    for (int r = 0; r < 4; ++r) {
      #pragma unroll
      for (int o = 1; o < 16; o <<= 1)
        tmax[r] = fmaxf(tmax[r], __shfl_xor(tmax[r], o));
    }
    float fr[4], lsum[4];
    #pragma unroll
    for (int r = 0; r < 4; ++r) {
      float mnew = fmaxf(mrun[r], tmax[r]);
      fr[r] = expf(mrun[r] - mnew);
      mrun[r] = mnew;
      lsum[r] = 0.f;
    }
    #pragma unroll
    for (int ct = 0; ct < 8; ++ct) {
      #pragma unroll
      for (int r = 0; r < 4; ++r) {
        float p = expf(sc[ct][r] - mrun[r]);
        sc[ct][r] = p;
        lsum[r] += p;
      }
    }
    #pragma unroll
    for (int r = 0; r < 4; ++r) {
      #pragma unroll
      for (int o = 1; o < 16; o <<= 1)
        lsum[r] += __shfl_xor(lsum[r], o);
      lrun[r] = lrun[r] * fr[r] + lsum[r];
    }
    f32x4 fv = (f32x4){fr[0], fr[1], fr[2], fr[3]};
    #pragma unroll
    for (int dt = 0; dt < 4; ++dt) Oa[dt] *= fv;
    #pragma unroll
    for (int ct = 0; ct < 8; ++ct) {
      int kc = ct * 2 + (l15 >> 3);
      int ki = l15 & 7;
      #pragma unroll
      for (int r = 0; r < 4; ++r) {
        int row = lg4 * 4 + r;
        Pw[row * 128 + ((kc ^ (row & 7)) << 3) + ki] = (f16)sc[ct][r];
      }
    }
    #pragma unroll
    for (int ks = 0; ks < 4; ++ks) {
      f16x8 pa = *(const f16x8*)&Pw[l15 * 128 + (((ks * 4 + lg4) ^ l7) << 3)];
      #pragma unroll
      for (int dt = 0; dt < 4; ++dt) {
        int n = dt * 16 + l15;
        f16x8 bv = *(const f16x8*)&Vt[n * 128 + (((ks * 4 + lg4) ^ (n & 7)) << 3)];
        Oa[dt] = __builtin_amdgcn_mfma_f32_16x16x32_f16(pa, bv, Oa[dt], 0, 0, 0);
      }
    }
  }
  #pragma unroll
  for (int r = 0; r < 4; ++r) {
    long qg = q0 + w * 16 + lg4 * 4 + r;
    long base = ((long)z * NL + qg) * NSPL + chunk;
    #pragma unroll
    for (int dt = 0; dt < 4; ++dt)
      partU[base * 64 + dt * 16 + l15] = Oa[dt][r];
    if (l15 == 0) {
      partML[base * 2] = mrun[r];
      partML[base * 2 + 1] = lrun[r];
    }
  }
}

// ---------------------------------------------------------------- merge split-flash partials
__global__ __launch_bounds__(256) void k_merge(
    const float* __restrict__ partU, const float* __restrict__ partML,
    float* __restrict__ kv3)
{
  int id = blockIdx.x;
  int z = id >> 2, part = id & 3;
  int t = threadIdx.x;
  int q = part * 32 + (t >> 3);
  int c8 = (t & 7) * 8;
  long base = ((long)z * NL + q) * NSPL;
  float m[NSPL], lv[NSPL];
  #pragma unroll
  for (int c = 0; c < NSPL; ++c) {
    m[c] = partML[(base + c) * 2];
    lv[c] = partML[(base + c) * 2 + 1];
  }
  float M = fmaxf(fmaxf(m[0], m[1]), fmaxf(m[2], m[3]));
  float L = 0.f, sc[NSPL];
  #pragma unroll
  for (int c = 0; c < NSPL; ++c) {
    sc[c] = expf(m[c] - M);
    L += lv[c] * sc[c];
  }
  float o[8] = {};
  #pragma unroll
  for (int c = 0; c < NSPL; ++c) {
    const float* up = &partU[(base + c) * 64 + c8];
    float4 a = *(const float4*)up;
    float4 bq = *(const float4*)(up + 4);
    o[0] += sc[c] * a.x; o[1] += sc[c] * a.y; o[2] += sc[c] * a.z; o[3] += sc[c] * a.w;
    o[4] += sc[c] * bq.x; o[5] += sc[c] * bq.y; o[6] += sc[c] * bq.z; o[7] += sc[c] * bq.w;
  }
  float invL = 1.f / L;
  float* kp = &kv3[((long)z * NL + q) * 64 + c8];
  #pragma unroll
  for (int j = 0; j < 8; ++j) kp[j] = o[j] * invL;
}

// ---------------------------------------------------------------- inverse (MFMA fp16 NS, 8 waves)
// key in fp16 global arena; stage-1 A-frags from global (L2-resident);
// buffer role-swap; 512 thr = 2 waves/SIMD = 256 unified regs/wave (no spill).
__global__ __launch_bounds__(512) void k_inverse(
    const f16* __restrict__ k2h, const float* __restrict__ colmax,
    const float* __restrict__ kv3, float* __restrict__ m2)
{
  __shared__ __align__(16) f16 bufA[128 * 128];   // V normal (current)
  __shared__ __align__(16) f16 bufB[128 * 128];   // scratch normal (X / V_new)
  __shared__ __align__(16) f16 Vt[128 * 128];
  __shared__ __align__(16) f16 Pt[128 * 128];
  int z = blockIdx.x;
  int tid = threadIdx.x;
  int w = tid >> 6, l = tid & 63;
  int l15 = l & 15, lg4 = l >> 4;
  int wr = (w >> 1) * 32, wc = (w & 1) * 64;   // 4x2 wave grid: 32x64 tiles

  float cv = colmax[l];
  #pragma unroll
  for (int o = 32; o; o >>= 1) cv = fmaxf(cv, __shfl_xor(cv, o));
  float recip = 1.f / cv;

  const f16* key = k2h + (long)z * NL * NL;
  auto swz = [](int r, int c) { return r * 128 + ((((c >> 3) ^ (r & 15))) << 3) + (c & 7); };

  // init: Vt = recip*key image (V^T), bufA = transpose (V)
  for (int idx = tid; idx < 128 * 16; idx += 512) {
    int r = idx >> 4, c8 = (idx & 15) << 3;
    f16x8 kk = *(const f16x8*)&key[r * 128 + c8];
    f16x8 sv;
    #pragma unroll
    for (int j = 0; j < 8; ++j) sv[j] = (f16)(recip * (float)kk[j]);
    *(f16x8*)&Vt[swz(r, c8)] = sv;
    #pragma unroll
    for (int j = 0; j < 8; ++j) bufA[swz(c8 + j, r)] = sv[j];
  }
  __syncthreads();

  f16* Vc = bufA;
  f16* Sc = bufB;

  f32x4 acc[2][4];
  auto MMc = [&](bool fromGlobal, const f16* Aimg, const f16* Bimg) {
    #pragma unroll
    for (int mi = 0; mi < 2; ++mi)
      #pragma unroll
      for (int ni = 0; ni < 4; ++ni) acc[mi][ni] = (f32x4){0.f, 0.f, 0.f, 0.f};
    #pragma unroll
    for (int ks = 0; ks < 4; ++ks) {
      int k0 = ks * 32 + lg4 * 8;
      f16x8 bf[4];
      #pragma unroll
      for (int ni = 0; ni < 4; ++ni)
        bf[ni] = *(const f16x8*)&Bimg[swz(wc + ni * 16 + l15, k0)];
      f16x8 af[2];
      if (fromGlobal) {
        af[0] = *(const f16x8*)&key[(wr + l15) * 128 + k0];
        af[1] = *(const f16x8*)&key[(wr + 16 + l15) * 128 + k0];
      } else {
        af[0] = *(const f16x8*)&Aimg[swz(wr + l15, k0)];
        af[1] = *(const f16x8*)&Aimg[swz(wr + 16 + l15, k0)];
      }
      #pragma unroll
      for (int mi = 0; mi < 2; ++mi)
        #pragma unroll
        for (int ni = 0; ni < 4; ++ni)
          acc[mi][ni] = __builtin_amdgcn_mfma_f32_16x16x32_f16(af[mi], bf[ni], acc[mi][ni], 0, 0, 0);
    }
  };
  // Nout: raw normal image (optional). Tout: transposed image with fold
  // image[col][row] = aT*acc[row][col] + bT*(row==col)  (packed f16x4 store)
  auto store = [&](f16* Nout, f16* Tout, float aT, float bT) {
    #pragma unroll
    for (int mi = 0; mi < 2; ++mi) {
      int row0 = wr + mi * 16 + lg4 * 4;
      #pragma unroll
      for (int ni = 0; ni < 4; ++ni) {
        int col = wc + ni * 16 + l15;
        f16x4 tv;
        #pragma unroll
        for (int r = 0; r < 4; ++r) {
          float v = acc[mi][ni][r];
          if (Nout) Nout[swz(row0 + r, col)] = (f16)v;
          tv[r] = (f16)(aT * v + ((row0 + r == col) ? bT : 0.f));
        }
        *(f16x4*)&Tout[col * 128 + ((((row0 >> 3) ^ (col & 15))) << 3) + (row0 & 7)] = tv;
      }
    }
  };

  for (int it = 0; it < 6; ++it) {
    MMc(true, nullptr, Vt);  store(Sc, Pt, -1.f, 7.f);       __syncthreads();
    MMc(false, Sc, Pt);      store(nullptr, Vt, -1.f, 15.f); __syncthreads();
    MMc(false, Sc, Vt);      store(nullptr, Pt, -0.25f, 3.25f); __syncthreads();
    MMc(false, Vc, Pt);      store(Sc, Vt, 1.f, 0.f);        __syncthreads();
    f16* tsw = Vc; Vc = Sc; Sc = tsw;
  }

  // m2 = V @ kv3 : stage kv3^T into Pt as [64][128]
  const float* kp = kv3 + (long)z * NL * VF;
  for (int idx = tid; idx < 128 * 16; idx += 512) {
    int k = idx >> 4, c4 = (idx & 15) << 2;
    float4 v4 = *(const float4*)&kp[k * 64 + c4];
    Pt[swz(c4 + 0, k)] = (f16)v4.x;
    Pt[swz(c4 + 1, k)] = (f16)v4.y;
    Pt[swz(c4 + 2, k)] = (f16)v4.z;
    Pt[swz(c4 + 3, k)] = (f16)v4.w;
  }
  __syncthreads();
  // wave w owns rows w*16..w*16+15, all 64 cols
  f32x4 accF[4];
  #pragma unroll
  for (int ni = 0; ni < 4; ++ni) accF[ni] = (f32x4){0.f, 0.f, 0.f, 0.f};
  #pragma unroll
  for (int ks = 0; ks < 4; ++ks) {
    int k0 = ks * 32 + lg4 * 8;
    f16x8 af = *(const f16x8*)&Vc[swz(w * 16 + l15, k0)];
    #pragma unroll
    for (int ni = 0; ni < 4; ++ni) {
      f16x8 bf = *(const f16x8*)&Pt[swz(ni * 16 + l15, k0)];
      accF[ni] = __builtin_amdgcn_mfma_f32_16x16x32_f16(af, bf, accF[ni], 0, 0, 0);
    }
  }
  float* mp = m2 + (long)z * NL * VF;
  #pragma unroll
  for (int ni = 0; ni < 4; ++ni)
    #pragma unroll
    for (int r = 0; r < 4; ++r)
      mp[(long)(w * 16 + lg4 * 4 + r) * VF + ni * 16 + l15] = accF[ni][r];
}

// ---------------------------------------------------------------- kernel_1 + attn + merge (MFMA)
__global__ __launch_bounds__(256, 2) void k_k1attn(
    const f16* __restrict__ Eq16, const f16* __restrict__ kland16,
    const float* __restrict__ aggL, const float* __restrict__ m2,
    const float* __restrict__ proj, f16* __restrict__ merged)
{
  __shared__ __align__(16) f16 Kl[128 * 64];
  __shared__ __align__(16) f16 M2t[64 * 128];
  __shared__ __align__(16) f16 Pb[4 * 16 * 128];
  int zz = blockIdx.x;
  int z = zz >> 5, st = zz & 31;
  int b = z >> 3, h = z & 7;
  int s0 = st * 64;
  int tid = threadIdx.x;
  int w = tid >> 6, l = tid & 63;
  int l15 = l & 15, lg4 = l >> 4, l7 = l & 7;
  float sigma = fabsf(aggL[h]) + 0.001f;
  float cpos = -sigma * (1.f / 16.f);

  for (int c = tid; c < 128 * 8; c += 256) {
    int k = c >> 3, kc = c & 7;
    f16x8 v = *(const f16x8*)&kland16[((long)b * NL + k) * 64 + kc * 8];
    *(f16x8*)&Kl[k * 64 + ((kc ^ (k & 7)) << 3)] = v;
  }
  const float* mp = m2 + (long)z * NL * VF;
  for (int c = tid; c < 128 * 16; c += 256) {
    int k = c >> 4, c4 = (c & 15) << 2;
    float4 v4 = *(const float4*)&mp[k * 64 + c4];
    int kc = k >> 3, ki = k & 7;
    M2t[(c4 + 0) * 128 + ((kc ^ ((c4 + 0) & 7)) << 3) + ki] = (f16)v4.x;
    M2t[(c4 + 1) * 128 + ((kc ^ ((c4 + 1) & 7)) << 3) + ki] = (f16)v4.y;
    M2t[(c4 + 2) * 128 + ((kc ^ ((c4 + 2) & 7)) << 3) + ki] = (f16)v4.z;
    M2t[(c4 + 3) * 128 + ((kc ^ ((c4 + 3) & 7)) << 3) + ki] = (f16)v4.w;
  }
  __syncthreads();

  long qrow = (long)z * S + s0 + w * 16 + l15;
  f16x8 af[2];
  #pragma unroll
  for (int kh = 0; kh < 2; ++kh)
    af[kh] = *(const f16x8*)&Eq16[qrow * 64 + kh * 32 + lg4 * 8];

  f32x4 sc[8];
  #pragma unroll
  for (int ct = 0; ct < 8; ++ct) {
    int n = ct * 16 + l15;
    f16x8 b0 = *(const f16x8*)&Kl[n * 64 + ((lg4 ^ (n & 7)) << 3)];
    f16x8 b1 = *(const f16x8*)&Kl[n * 64 + (((4 + lg4) ^ (n & 7)) << 3)];
    f32x4 zz4 = (f32x4){0.f, 0.f, 0.f, 0.f};
    zz4 = __builtin_amdgcn_mfma_f32_16x16x32_f16(af[0], b0, zz4, 0, 0, 0);
    sc[ct] = __builtin_amdgcn_mfma_f32_16x16x32_f16(af[1], b1, zz4, 0, 0, 0);
  }
  float tmax[4] = {-INFINITY, -INFINITY, -INFINITY, -INFINITY};
  #pragma unroll
  for (int ct = 0; ct < 8; ++ct) {
    int lm = ct * 16 + l15;
    #pragma unroll
    for (int r = 0; r < 4; ++r) {
      int spos = s0 + w * 16 + lg4 * 4 + r;
      float a = (float)(spos - 16 * lm);
      float ac = fminf(fmaxf(a, 0.f), 15.f);
      float dd = fabsf(a - ac);
      float sum = ac * ac - 15.f * ac + 120.f + 16.f * dd;
      float s = sc[ct][r] + cpos * sum;
      sc[ct][r] = s;
      tmax[r] = fmaxf(tmax[r], s);
    }
  }
  #pragma unroll
  for (int r = 0; r < 4; ++r) {
    #pragma unroll
    for (int o = 1; o < 16; o <<= 1)
      tmax[r] = fmaxf(tmax[r], __shfl_xor(tmax[r], o));
  }
  float lsum[4] = {0.f, 0.f, 0.f, 0.f};
  #pragma unroll
  for (int ct = 0; ct < 8; ++ct) {
    #pragma unroll
    for (int r = 0; r < 4; ++r) {
      float p = expf(sc[ct][r] - tmax[r]);
      sc[ct][r] = p;
      lsum[r] += p;
    }
  }
  #pragma unroll
  for (int r = 0; r < 4; ++r) {
    #pragma unroll
    for (int o = 1; o < 16; o <<= 1)
      lsum[r] += __shfl_xor(lsum[r], o);
    lsum[r] = 1.f / lsum[r];
  }
  f16* Pw = &Pb[w * 16 * 128];
  #pragma unroll
  for (int ct = 0; ct < 8; ++ct) {
    int kc = ct * 2 + (l15 >> 3);
    int ki = l15 & 7;
    #pragma unroll
    for (int r = 0; r < 4; ++r) {
      int row = lg4 * 4 + r;
      Pw[row * 128 + ((kc ^ (row & 7)) << 3) + ki] = (f16)(sc[ct][r] * lsum[r]);
    }
  }
  f32x4 Oa[4];
  #pragma unroll
  for (int i = 0; i < 4; ++i) Oa[i] = (f32x4){0.f, 0.f, 0.f, 0.f};
  #pragma unroll
  for (int ks = 0; ks < 4; ++ks) {
    f16x8 pa = *(const f16x8*)&Pw[l15 * 128 + (((ks * 4 + lg4) ^ l7) << 3)];
    #pragma unroll
    for (int dt = 0; dt < 4; ++dt) {
      int n = dt * 16 + l15;
      f16x8 bv = *(const f16x8*)&M2t[n * 128 + (((ks * 4 + lg4) ^ (n & 7)) << 3)];
      Oa[dt] = __builtin_amdgcn_mfma_f32_16x16x32_f16(pa, bv, Oa[dt], 0, 0, 0);
    }
  }
  #pragma unroll
  for (int r = 0; r < 4; ++r) {
    long srow = (long)b * S + s0 + w * 16 + lg4 * 4 + r;
    int r7 = (int)(srow & 7);
    #pragma unroll
    for (int dt = 0; dt < 4; ++dt) {
      int col = dt * 16 + l15;
      float v = Oa[dt][r] + proj[srow * VF + col];
      merged[srow * (long)HV + h * 64 + (((col >> 3) ^ r7) << 3) + (col & 7)] = (f16)v;
    }
  }
}

} // namespace

extern "C" void kernel_launch(void* const* d_in, const int* in_sizes, int n_in,
                              void* d_out, int out_size, void* d_ws, size_t ws_size,
                              hipStream_t stream)
{
  const float* lat   = (const float*)d_in[0];
  const float* masks = (const float*)d_in[1];
  const float* xemb  = (const float*)d_in[2];
  const float* ccls  = (const float*)d_in[4];
  const float* qlin  = (const float*)d_in[5];
  const float* klin  = (const float*)d_in[6];
  const float* vlin  = (const float*)d_in[7];
  const float* plin  = (const float*)d_in[8];
  const float* agg   = (const float*)d_in[9];
  const float* cfeat = (const float*)d_in[10];
  float* out = (float*)d_out;
  float* ws = (float*)d_ws;

  long off = 0;
  auto allocF = [&](long n) { float* p = ws + off; off += (n + 3) & ~3L; return p; };
  auto allocH = [&](long n) { f16* p = (f16*)(ws + off); off += ((n + 1) / 2 + 3) & ~3L; return p; };

  f16* origA = allocH(ROWS * KSF);
  f16* vbufA = allocH(ROWS * KSF);
  f16* merged = allocH(ROWS * (long)HV);
  f16* WQt = allocH(16L * 64 * KSF);
  f16* WKt = allocH(2L * 64 * KSF);
  f16* WVt = allocH(16L * 64 * KSF);
  f16* WPt = allocH(2L * 64 * KSF);
  f16* WCFt = allocH((long)KSF * 512);
  f16* WCCt = allocH(64L * 512);
  f16* Ek16 = allocH((long)B * S * 64);
  f16* Ev16 = allocH((long)B * H * S * 64);
  f16* Eq16 = allocH((long)B * H * S * 64);
  f16* qland16 = allocH((long)B * H * NL * DF);
  f16* kland16 = allocH((long)B * NL * DF);
  f16* k2h = allocH((long)B * H * NL * NL);
  float* cl     = allocF(ROWS * HS);
  float* projb  = allocF((long)B * S * VF);
  float* qland  = allocF((long)B * H * NL * DF);
  float* kland  = allocF((long)B * NL * DF);
  float* kv3    = allocF((long)B * H * NL * VF);
  float* m2b    = allocF((long)B * H * NL * VF);
  float* colmax = allocF(64);
  float* partU  = allocF((long)B * H * NL * NSPL * 64);
  float* partML = allocF((long)B * H * NL * NSPL * 2);

  k_cl<<<(int)(ROWS / 4), 256, 0, stream>>>(lat, masks, cl);
  k_cvta<<<(int)(ROWS * 168 / 256), 256, 0, stream>>>(xemb, cl, origA);

  auto cvtw = [&](const float* src, f16* dst, int K, int N, int Npad, int KS, long srcZ, int nz) {
    long total = (long)nz * Npad * (KS / 8);
    k_cvtw<<<(int)((total + 255) / 256), 256, 0, stream>>>(src, dst, K, N, Npad, KS, srcZ, total);
  };
  cvtw(qlin, WQt, FEAT, 64, 64, KSF, (long)FEATP * 64, 16);
  cvtw(klin, WKt, FEAT, 64, 64, KSF, (long)FEATP * 64, 2);
  cvtw(vlin, WVt, FEAT, 64, 64, KSF, (long)FEATP * 64, 16);
  cvtw(plin, WPt, FEAT, 64, 64, KSF, (long)FEATP * 64, 2);
  cvtw(cfeat, WCFt, 512, FEAT, KSF, 512, 0, 1);
  cvtw(ccls, WCCt, 512, HS, 64, 512, 0, 1);

  const f16* Aact = origA;
  for (int layer = 0; layer < 2; ++layer) {
    const f16* wq = WQt + (long)layer * 8 * 64 * KSF;
    const f16* wk = WKt + (long)layer * 64 * KSF;
    const f16* wvv = WVt + (long)layer * 8 * 64 * KSF;
    const f16* wp = WPt + (long)layer * 64 * KSF;
    const float* bq = qlin + (long)layer * 8 * FEATP * 64 + (long)(FEATP - 2) * 64;
    const float* bk = klin + (long)layer * FEATP * 64 + (long)(FEATP - 2) * 64;
    const float* bv = vlin + (long)layer * 8 * FEATP * 64 + (long)(FEATP - 2) * 64;
    const float* bp = plin + (long)layer * FEATP * 64 + (long)(FEATP - 2) * 64;
    const float* ag = agg + layer * H;

    dim3 gQ(8, 1, 64), gK(8, 1, 8);
    k_mgemm<<<gQ, 256, 0, stream>>>(Aact, (long)S * KSF, 8, wq, 64L * KSF, 8, 21, 3,
        nullptr, (long)S * 64, 64, bq, (long)FEATP * 64, INV_SCALE, Eq16, 64, nullptr);
    k_mgemm<<<gK, 256, 0, stream>>>(Aact, (long)S * KSF, 1, wk, 0, 1, 21, 3,
        nullptr, (long)S * 64, 64, bk, 0, INV_SCALE, Ek16, 64, nullptr);
    k_mgemm<<<gQ, 256, 0, stream>>>(Aact, (long)S * KSF, 8, wvv, 64L * KSF, 8, 21, 3,
        nullptr, (long)S * 64, 64, bv, (long)FEATP * 64, 1.0f, Ev16, 64, nullptr);
    k_mgemm<<<gK, 256, 0, stream>>>(origA, (long)S * KSF, 1, wp, 0, 1, 21, 0,
        projb, (long)S * 64, 64, bp, 0, 0.5f, nullptr, 64, nullptr);

    k_segmean<<<B * H * NL, 64, 0, stream>>>(Eq16, qland, qland16);
    k_segmean<<<B * NL, 64, 0, stream>>>(Ek16, kland, kland16);

    k_kernel2<<<B * H, 256, 0, stream>>>(qland, kland, ag, k2h, colmax);
    k_kernel3<<<B * H * 2 * NSPL, 256, 0, stream>>>(qland16, Ek16, Ev16, ag, masks,
        partU, partML);
    k_merge<<<B * H * 4, 256, 0, stream>>>(partU, partML, kv3);
    k_inverse<<<B * H, 512, 0, stream>>>(k2h, colmax, kv3, m2b);
    k_k1attn<<<B * H * (S / 64), 256, 0, stream>>>(Eq16, kland16, ag, m2b, projb, merged);

    if (layer == 0) {
      dim3 gC(64, 21, 1);
      k_mgemm<<<gC, 256, 0, stream>>>(merged, 0, 1, WCFt, 0, 1, 8, 1,
          nullptr, 0, 0, nullptr, 0, 1.0f, vbufA, FEAT, nullptr);
      Aact = vbufA;
    } else {
      dim3 gO(64, 1, 1);
      k_mgemm<<<gO, 256, 0, stream>>>(merged, 0, 1, WCCt, 0, 1, 8, 2,
          out, 0, HS, nullptr, 0, 1.0f, nullptr, HS, masks);
    }
  }
  (void)in_sizes; (void)n_in; (void)out_size; (void)ws_size;
}

// Round 11
// 600.182 us; speedup vs baseline: 10.4137x; 1.0604x over previous
//
#include <hip/hip_runtime.h>
#include <math.h>

// ESMMimicryModule: B=8 S=2048 H=8 NL=128 DF=VF=64 NF=1280 HS=33 FEAT=1313
// Round 10: (a) k_cvta vectorized: swizzle moved to write side, float4 reads
// (scalar only for the t=20 boundary tile) -- was 8 scalar dword loads/thread
// at 1.6 TB/s. (b) k_qv: fused Eq+Ev GEMM, BM=128 BN=128 (wq|wv panels),
// A staged once for both outputs, acc[2][8], 64KB LDS, 2 blocks/CU.

namespace {

constexpr int B = 8, S = 2048, H = 8, NL = 128, DF = 64, VF = 64;
constexpr int NF = 1280, HS = 33, FEAT = 1313, FEATP = 1314;
constexpr int SEG = 16, HV = H * VF;            // 512
constexpr int KSF = 1344;                        // padded feature-K (21*64)
constexpr int NSPL = 4;                          // key chunks in split-S flash
constexpr long ROWS = (long)B * S;               // 16384
constexpr float INV_SCALE = 0.35355339059327373f;

typedef _Float16 f16;
typedef _Float16 f16x8 __attribute__((ext_vector_type(8)));
typedef _Float16 f16x4 __attribute__((ext_vector_type(4)));
typedef float f32x4 __attribute__((ext_vector_type(4)));

// ---------------------------------------------------------------- cl = softmax(latent)*mask
__global__ __launch_bounds__(256) void k_cl(
    const float* __restrict__ lat, const float* __restrict__ masks,
    float* __restrict__ cl)
{
  long row = (long)blockIdx.x * 4 + (threadIdx.x >> 6);
  int l = threadIdx.x & 63;
  float v = (l < HS) ? lat[row * HS + l] : -INFINITY;
  float m = v;
  #pragma unroll
  for (int o = 32; o; o >>= 1) m = fmaxf(m, __shfl_xor(m, o));
  float e = (l < HS) ? expf(v - m) : 0.f;
  float s = e;
  #pragma unroll
  for (int o = 32; o; o >>= 1) s += __shfl_xor(s, o);
  if (l < HS) cl[row * HS + l] = e / s * masks[row];
}

// ---------------------------------------------------------------- origA fp16 arena (swizzled)
// reads contiguous source chunks (float4x2), writes XOR-swizzled dest chunk
__global__ __launch_bounds__(256) void k_cvta(
    const float* __restrict__ xemb, const float* __restrict__ cl,
    f16* __restrict__ dst)
{
  long idx = (long)blockIdx.x * 256 + threadIdx.x;  // chunk id (row, c)
  long row = idx / 168;
  int c = (int)(idx - row * 168);
  int t = c >> 3, cs = c & 7;                       // SOURCE chunk
  int k0 = t * 64 + cs * 8;
  f16x8 v;
  if (t < 20) {
    float4 a = *(const float4*)&xemb[row * NF + k0];
    float4 b = *(const float4*)&xemb[row * NF + k0 + 4];
    v[0] = (f16)a.x; v[1] = (f16)a.y; v[2] = (f16)a.z; v[3] = (f16)a.w;
    v[4] = (f16)b.x; v[5] = (f16)b.y; v[6] = (f16)b.z; v[7] = (f16)b.w;
  } else {
    #pragma unroll
    for (int i = 0; i < 8; ++i) {
      int k = k0 + i;
      float f = 0.f;
      if (k < NF) f = xemb[row * NF + k];
      else if (k < FEAT) f = cl[row * HS + (k - NF)];
      v[i] = (f16)f;
    }
  }
  int cd = cs ^ ((int)row & 7);                     // DEST chunk (involution)
  *(f16x8*)&dst[row * KSF + t * 64 + cd * 8] = v;
}

// ---------------------------------------------------------------- weight -> Wt fp16 arena
__global__ __launch_bounds__(256) void k_cvtw(
    const float* __restrict__ src, f16* __restrict__ dst,
    int K, int N, int Npad, int KS, long srcZ, long total)
{
  long idx = (long)blockIdx.x * 256 + threadIdx.x;
  if (idx >= total) return;
  long cpz = (long)Npad * (KS >> 3);
  long z = idx / cpz;
  long rem = idx - z * cpz;
  int n = (int)(rem / (KS >> 3));
  int c = (int)(rem - (long)n * (KS >> 3));
  int t = c >> 3, cs = c & 7;
  int cd = cs ^ (n & 7);
  int k0 = t * 64 + cd * 8;
  const float* sp = src + z * srcZ;
  f16x8 v;
  #pragma unroll
  for (int i = 0; i < 8; ++i) {
    int k = k0 + i;
    v[i] = (f16)((k < K && n < N) ? sp[(long)k * N + n] : 0.f);
  }
  *(f16x8*)&dst[idx * 8] = v;
}

// ---------------------------------------------------------------- fp16 MFMA GEMM (generic)
// mode 0: fp32 C = (acc + bias)*scale
// mode 1: fp16 swizzled arena (KSF stride, zero-fill col>=NR), LDS-staged
// mode 2: fp32 out * mask, col<NR
// mode 3: fp16 row-major out (64 cols), (acc+bias)*scale, LDS-staged
__global__ __launch_bounds__(256, 2) void k_mgemm(
    const f16* __restrict__ A, long aZOff, int aDiv,
    const f16* __restrict__ Wt, long wZOff, int wMod,
    int KT, int mode,
    float* __restrict__ C, long cZOff, int ldC,
    const float* __restrict__ biasBase, long biasZOff, float scale,
    f16* __restrict__ outA, int NR, const float* __restrict__ mask)
{
  const long KS = (long)KT * 64;
  int z = blockIdx.z;
  const f16* Ap = A + (long)(z / aDiv) * aZOff;
  const f16* Wp = Wt + (long)(z % wMod) * wZOff;
  long m0 = (long)blockIdx.x * 256;
  int n0 = blockIdx.y * 64;
  constexpr int BOFF = 256 * 64;
  __shared__ f16 lds[2][(256 + 64) * 64];
  int tid = threadIdx.x;
  int wv = tid >> 6, l = tid & 63;

  const f16* aW = Ap + (m0 + wv * 64 + (l >> 3)) * KS + (l & 7) * 8;
  const f16* bW = Wp + ((long)(n0 + wv * 16 + (l >> 3))) * KS + (l & 7) * 8;

  f32x4 acc[4][4];
  #pragma unroll
  for (int i = 0; i < 4; ++i)
    #pragma unroll
    for (int j = 0; j < 4; ++j) acc[i][j] = (f32x4){0.f, 0.f, 0.f, 0.f};

  auto stage = [&](int buf, int t) {
    f16* la = &lds[buf][(wv * 64) * 64];
    const f16* ga = aW + (long)t * 64;
    #pragma unroll
    for (int j = 0; j < 8; ++j)
      __builtin_amdgcn_global_load_lds(
          (const __attribute__((address_space(1))) void*)(ga + (long)j * 8 * KS),
          (__attribute__((address_space(3))) void*)(la + j * 8 * 64), 16, 0, 0);
    f16* lb = &lds[buf][BOFF + (wv * 16) * 64];
    const f16* gb = bW + (long)t * 64;
    #pragma unroll
    for (int j = 0; j < 2; ++j)
      __builtin_amdgcn_global_load_lds(
          (const __attribute__((address_space(1))) void*)(gb + (long)j * 8 * KS),
          (__attribute__((address_space(3))) void*)(lb + j * 8 * 64), 16, 0, 0);
  };

  stage(0, 0);
  int rA = (wv * 64 + (l & 15)) * 64;
  int rB = BOFF + (l & 15) * 64;
  int lc = l >> 4, lx = l & 7;
  for (int t = 0; t < KT; ++t) {
    int nb = t & 1;
    if (t + 1 < KT) {
      stage(nb ^ 1, t + 1);
      asm volatile("s_waitcnt vmcnt(10)" ::: "memory");
    } else {
      asm volatile("s_waitcnt vmcnt(0)" ::: "memory");
    }
    __syncthreads();
    const f16* base = &lds[nb][0];
    f16x8 af[4][2], bf[4][2];
    #pragma unroll
    for (int mi = 0; mi < 4; ++mi)
      #pragma unroll
      for (int kh = 0; kh < 2; ++kh)
        af[mi][kh] = *(const f16x8*)&base[rA + mi * 16 * 64 + (((kh * 4 + lc) ^ lx) << 3)];
    #pragma unroll
    for (int ni = 0; ni < 4; ++ni)
      #pragma unroll
      for (int kh = 0; kh < 2; ++kh)
        bf[ni][kh] = *(const f16x8*)&base[rB + ni * 16 * 64 + (((kh * 4 + lc) ^ lx) << 3)];
    #pragma unroll
    for (int mi = 0; mi < 4; ++mi)
      #pragma unroll
      for (int ni = 0; ni < 4; ++ni) {
        acc[mi][ni] = __builtin_amdgcn_mfma_f32_16x16x32_f16(af[mi][0], bf[ni][0], acc[mi][ni], 0, 0, 0);
        acc[mi][ni] = __builtin_amdgcn_mfma_f32_16x16x32_f16(af[mi][1], bf[ni][1], acc[mi][ni], 0, 0, 0);
      }
    __syncthreads();
  }

  int lr = (l >> 4) * 4;
  int lcn = l & 15;
  if (mode == 0) {
    float* Cp = C + (long)z * cZOff;
    const float* bp = biasBase ? biasBase + (long)(z % wMod) * biasZOff : nullptr;
    #pragma unroll
    for (int ni = 0; ni < 4; ++ni) {
      int col = n0 + ni * 16 + lcn;
      float bv = bp ? bp[col] : 0.f;
      #pragma unroll
      for (int mi = 0; mi < 4; ++mi) {
        long row = m0 + wv * 64 + mi * 16 + lr;
        #pragma unroll
        for (int r = 0; r < 4; ++r)
          Cp[(row + r) * (long)ldC + col] = (acc[mi][ni][r] + bv) * scale;
      }
    }
  } else if (mode == 2) {
    #pragma unroll
    for (int mi = 0; mi < 4; ++mi) {
      #pragma unroll
      for (int r = 0; r < 4; ++r) {
        long row = m0 + wv * 64 + mi * 16 + lr + r;
        float mv = mask[row];
        #pragma unroll
        for (int ni = 0; ni < 4; ++ni) {
          int col = n0 + ni * 16 + lcn;
          if (col < NR) C[row * (long)ldC + col] = acc[mi][ni][r] * mv;
        }
      }
    }
  } else {  // mode 1 / 3: stage f16 tile in LDS, vectorized global writes
    f16* st = &lds[0][0];
    const float* bp = biasBase ? biasBase + (long)(z % wMod) * biasZOff : nullptr;
    #pragma unroll
    for (int ni = 0; ni < 4; ++ni) {
      int coll = ni * 16 + lcn;
      int col = n0 + coll;
      float bv = bp ? bp[col] : 0.f;
      bool ok = col < NR;
      #pragma unroll
      for (int mi = 0; mi < 4; ++mi) {
        int rowl = wv * 64 + mi * 16 + lr;
        #pragma unroll
        for (int r = 0; r < 4; ++r) {
          float v = ok ? (acc[mi][ni][r] + bv) * scale : 0.f;
          st[(rowl + r) * 64 + coll] = (f16)v;
        }
      }
    }
    __syncthreads();
    if (mode == 3) {
      f16* o16 = outA + (long)z * cZOff;
      for (int c = tid; c < 2048; c += 256) {
        int row = c >> 3, cc = c & 7;
        f16x8 v = *(const f16x8*)&st[row * 64 + cc * 8];
        *(f16x8*)&o16[(m0 + row) * 64 + cc * 8] = v;
      }
    } else {
      int tt = n0 >> 6;
      for (int c = tid; c < 2048; c += 256) {
        int row = c >> 3, cd = c & 7;
        long grow = m0 + row;
        int r7 = (int)grow & 7;
        f16x8 v = *(const f16x8*)&st[row * 64 + cd * 8];
        *(f16x8*)&outA[grow * KSF + tt * 64 + ((cd ^ r7) << 3)] = v;
      }
    }
  }
}

// ---------------------------------------------------------------- fused Eq+Ev GEMM
// BM=128, BN=128 (cols 0-63 = wq -> Eq16 *INV_SCALE+bq ; 64-127 = wv -> Ev16
// +bv). 4 waves x (32x128). A staged once for both outputs.
__global__ __launch_bounds__(256, 2) void k_qv(
    const f16* __restrict__ A,
    const f16* __restrict__ WQl, const f16* __restrict__ WVl,
    const float* __restrict__ bqBase, const float* __restrict__ bvBase,
    f16* __restrict__ Eq16, f16* __restrict__ Ev16)
{
  constexpr int KT = 21;
  constexpr int BOFF = 128 * 64;
  __shared__ f16 lds[2][(128 + 128) * 64];
  int z = blockIdx.z;                 // b*H + h
  int h = z & 7;
  const f16* Ap = A + (long)(z >> 3) * S * KSF;
  const f16* wqp = WQl + (long)h * 64 * KSF;
  const f16* wvp = WVl + (long)h * 64 * KSF;
  const float* bq = bqBase + (long)h * FEATP * 64;
  const float* bv = bvBase + (long)h * FEATP * 64;
  long m0 = (long)blockIdx.x * 128;
  int tid = threadIdx.x;
  int wv = tid >> 6, l = tid & 63;
  int l15 = l & 15, lc = l >> 4, lx = l & 7;

  const f16* aW = Ap + (m0 + wv * 32 + (l >> 3)) * KSF + (l & 7) * 8;

  f32x4 acc[2][8];
  #pragma unroll
  for (int i = 0; i < 2; ++i)
    #pragma unroll
    for (int j = 0; j < 8; ++j) acc[i][j] = (f32x4){0.f, 0.f, 0.f, 0.f};

  auto stage = [&](int buf, int t) {
    f16* la = &lds[buf][(wv * 32) * 64];
    const f16* ga = aW + (long)t * 64;
    #pragma unroll
    for (int j = 0; j < 4; ++j)
      __builtin_amdgcn_global_load_lds(
          (const __attribute__((address_space(1))) void*)(ga + (long)j * 8 * KSF),
          (__attribute__((address_space(3))) void*)(la + j * 512), 16, 0, 0);
    f16* lb = &lds[buf][BOFF + (wv * 32) * 64];
    #pragma unroll
    for (int j = 0; j < 4; ++j) {
      int brow = wv * 32 + j * 8 + (l >> 3);
      const f16* src = (brow < 64 ? wqp + (long)brow * KSF
                                  : wvp + (long)(brow - 64) * KSF)
                       + (l & 7) * 8 + (long)t * 64;
      __builtin_amdgcn_global_load_lds(
          (const __attribute__((address_space(1))) void*)src,
          (__attribute__((address_space(3))) void*)(lb + j * 512), 16, 0, 0);
    }
  };

  stage(0, 0);
  for (int t = 0; t < KT; ++t) {
    int nb = t & 1;
    if (t + 1 < KT) {
      stage(nb ^ 1, t + 1);
      asm volatile("s_waitcnt vmcnt(8)" ::: "memory");
    } else {
      asm volatile("s_waitcnt vmcnt(0)" ::: "memory");
    }
    __syncthreads();
    const f16* base = &lds[nb][0];
    f16x8 af[2][2], bf[8][2];
    #pragma unroll
    for (int mi = 0; mi < 2; ++mi)
      #pragma unroll
      for (int kh = 0; kh < 2; ++kh)
        af[mi][kh] = *(const f16x8*)&base[(wv * 32 + mi * 16 + l15) * 64 + (((kh * 4 + lc) ^ lx) << 3)];
    #pragma unroll
    for (int ni = 0; ni < 8; ++ni) {
      int n = ni * 16 + l15;
      #pragma unroll
      for (int kh = 0; kh < 2; ++kh)
        bf[ni][kh] = *(const f16x8*)&base[BOFF + n * 64 + (((kh * 4 + lc) ^ (n & 7)) << 3)];
    }
    #pragma unroll
    for (int mi = 0; mi < 2; ++mi)
      #pragma unroll
      for (int ni = 0; ni < 8; ++ni) {
        acc[mi][ni] = __builtin_amdgcn_mfma_f32_16x16x32_f16(af[mi][0], bf[ni][0], acc[mi][ni], 0, 0, 0);
        acc[mi][ni] = __builtin_amdgcn_mfma_f32_16x16x32_f16(af[mi][1], bf[ni][1], acc[mi][ni], 0, 0, 0);
      }
    __syncthreads();
  }

  // epilogue: stage 128x128 f16 tile (bias+scale applied), vector stores
  f16* st = &lds[0][0];
  int lr = (l >> 4) * 4;
  #pragma unroll
  for (int ni = 0; ni < 8; ++ni) {
    int col = ni * 16 + l15;
    float bvv = (col < 64) ? bq[col] : bv[col - 64];
    float scl = (col < 64) ? INV_SCALE : 1.f;
    #pragma unroll
    for (int mi = 0; mi < 2; ++mi) {
      int rowl = wv * 32 + mi * 16 + lr;
      #pragma unroll
      for (int r = 0; r < 4; ++r)
        st[(rowl + r) * 128 + col] = (f16)((acc[mi][ni][r] + bvv) * scl);
    }
  }
  __syncthreads();
  f16* oq = Eq16 + (long)z * S * 64;
  f16* ov = Ev16 + (long)z * S * 64;
  for (int c = tid; c < 1024; c += 256) {
    int rw = c >> 3, cc = c & 7;
    *(f16x8*)&oq[(m0 + rw) * 64 + cc * 8] = *(const f16x8*)&st[rw * 128 + cc * 8];
    *(f16x8*)&ov[(m0 + rw) * 64 + cc * 8] = *(const f16x8*)&st[rw * 128 + 64 + cc * 8];
  }
}

// ---------------------------------------------------------------- landmarks (f16 input)
__global__ void k_segmean(const f16* __restrict__ in, float* __restrict__ out,
                          f16* __restrict__ out16)
{
  long zl = blockIdx.x;
  long z = zl / NL, lm = zl % NL;
  int d = threadIdx.x;
  const f16* p = in + (z * S + lm * SEG) * (long)DF + d;
  float s = 0.f;
  #pragma unroll
  for (int i = 0; i < SEG; i++) s += (float)p[(long)i * DF];
  float v = s * (1.f / SEG);
  out[(z * NL + lm) * (long)DF + d] = v;
  if (out16) out16[(z * NL + lm) * (long)DF + d] = (f16)v;
}

// ---------------------------------------------------------------- kernel_2 (analytic possel2)
__global__ __launch_bounds__(256) void k_kernel2(
    const float* __restrict__ qland, const float* __restrict__ kland,
    const float* __restrict__ aggL, f16* __restrict__ k2h,
    float* __restrict__ colmax)
{
  int z = blockIdx.x; int b = z / H; int h = z % H;
  float sigma = fabsf(aggL[h]) + 0.001f;
  __shared__ float qs[NL][68];
  __shared__ float ks[NL][68];
  __shared__ float lg[NL][NL + 1];
  int tid = threadIdx.x;
  for (int idx = tid; idx < NL * DF; idx += 256) {
    int r = idx >> 6, d = idx & 63;
    qs[r][d] = qland[((long)z * NL + r) * DF + d];
    ks[r][d] = kland[((long)b * NL + r) * DF + d];
  }
  __syncthreads();
  int r = tid >> 1, half = tid & 1;
  float lmax = -INFINITY;
  for (int c = 0; c < 64; c++) {
    int m = half * 64 + c;
    float s = 0.f;
    #pragma unroll
    for (int d = 0; d < DF; d += 4) {
      float4 q = *(const float4*)&qs[r][d];
      float4 k4 = *(const float4*)&ks[m][d];
      s += q.x * k4.x + q.y * k4.y + q.z * k4.z + q.w * k4.w;
    }
    float dd = fabsf((float)(r - m));
    s += -sigma * ((r == m) ? 5.3125f : 16.f * dd);
    lg[r][m] = s;
    lmax = fmaxf(lmax, s);
  }
  lmax = fmaxf(lmax, __shfl_xor(lmax, 1));
  float lsum = 0.f;
  for (int c = 0; c < 64; c++) {
    int m = half * 64 + c;
    float e = expf(lg[r][m] - lmax);
    lg[r][m] = e; lsum += e;
  }
  lsum += __shfl_xor(lsum, 1);
  float inv = 1.f / lsum;
  for (int c = 0; c < 64; c++) {
    int m = half * 64 + c;
    float p = lg[r][m] * inv;
    lg[r][m] = p;
    k2h[((long)z * NL + r) * NL + m] = (f16)p;
  }
  __syncthreads();
  float myc = 0.f;
  if (tid < NL) {
    for (int rr = 0; rr < NL; rr++) myc += lg[rr][tid];
  }
  float wm = myc;
  #pragma unroll
  for (int o = 32; o; o >>= 1) wm = fmaxf(wm, __shfl_xor(wm, o));
  __shared__ float wred[4];
  if ((tid & 63) == 0) wred[tid >> 6] = wm;
  __syncthreads();
  if (tid == 0)
    colmax[z] = fmaxf(fmaxf(wred[0], wred[1]), fmaxf(wred[2], wred[3]));
}

// ---------------------------------------------------------------- kernel_3 (split-S flash MFMA)
__global__ __launch_bounds__(256, 2) void k_kernel3(
    const f16* __restrict__ qland16, const f16* __restrict__ Ek16,
    const f16* __restrict__ Ev16, const float* __restrict__ aggL,
    const float* __restrict__ masks,
    float* __restrict__ partU, float* __restrict__ partML)
{
  __shared__ __align__(16) f16 Qs[64 * 64];
  __shared__ __align__(16) f16 Ks[128 * 64];
  __shared__ __align__(16) f16 Vt[64 * 128];
  __shared__ __align__(16) f16 Pb[4 * 16 * 128];
  __shared__ float Ms[128];
  int id = blockIdx.x;
  int chunk = id & (NSPL - 1);
  int z2 = id >> 2;
  int z = z2 >> 1, half = z2 & 1;
  int b = z >> 3, h = z & 7;
  int q0 = half * 64;
  int tid = threadIdx.x;
  int w = tid >> 6, l = tid & 63;
  float sigma = fabsf(aggL[h]) + 0.001f;
  float cpos = -sigma * (1.f / 16.f);

  for (int c = tid; c < 64 * 8; c += 256) {
    int q = c >> 3, kc = c & 7;
    f16x8 v = *(const f16x8*)&qland16[((long)z * NL + q0 + q) * 64 + kc * 8];
    *(f16x8*)&Qs[q * 64 + ((kc ^ (q & 7)) << 3)] = v;
  }

  f16* Pw = &Pb[w * 16 * 128];
  int l15 = l & 15, lg4 = l >> 4, l7 = l & 7;
  f32x4 Oa[4];
  #pragma unroll
  for (int i = 0; i < 4; ++i) Oa[i] = (f32x4){0.f, 0.f, 0.f, 0.f};
  float mrun[4] = {-INFINITY, -INFINITY, -INFINITY, -INFINITY};
  float lrun[4] = {0.f, 0.f, 0.f, 0.f};

  int t0beg = chunk * (S / 128 / NSPL), t0end = t0beg + S / 128 / NSPL;
  for (int t0 = t0beg; t0 < t0end; ++t0) {
    __syncthreads();
    for (int c = tid; c < 1024; c += 256) {
      int k = c >> 3, kc = c & 7;
      f16x8 v = *(const f16x8*)&Ek16[((long)b * S + t0 * 128 + k) * 64 + kc * 8];
      *(f16x8*)&Ks[k * 64 + ((kc ^ (k & 7)) << 3)] = v;
    }
    for (int c = tid; c < 1024; c += 256) {
      int k = c & 127, dc = c >> 7;
      f16x8 v = *(const f16x8*)&Ev16[((long)z * S + t0 * 128 + k) * 64 + dc * 8];
      int kc = k >> 3, ki = k & 7;
      #pragma unroll
      for (int j = 0; j < 8; ++j) {
        int d = dc * 8 + j;
        Vt[d * 128 + ((kc ^ (d & 7)) << 3) + ki] = v[j];
      }
    }
    if (tid < 128)
      Ms[tid] = (masks[(long)b * S + t0 * 128 + tid] == 0.f) ? -1e6f : 0.f;
    __syncthreads();

    f16x8 af[2];
    #pragma unroll
    for (int kh = 0; kh < 2; ++kh)
      af[kh] = *(const f16x8*)&Qs[(w * 16 + l15) * 64 + (((kh * 4 + lg4) ^ l7) << 3)];
    f32x4 sc[8];
    #pragma unroll
    for (int ct = 0; ct < 8; ++ct) {
      int n = ct * 16 + l15;
      f16x8 b0 = *(const f16x8*)&Ks[n * 64 + (((lg4) ^ (n & 7)) << 3)];
      f16x8 b1 = *(const f16x8*)&Ks[n * 64 + (((4 + lg4) ^ (n & 7)) << 3)];
      f32x4 zz = (f32x4){0.f, 0.f, 0.f, 0.f};
      zz = __builtin_amdgcn_mfma_f32_16x16x32_f16(af[0], b0, zz, 0, 0, 0);
      sc[ct] = __builtin_amdgcn_mfma_f32_16x16x32_f16(af[1], b1, zz, 0, 0, 0);
    }
    float tmax[4] = {-INFINITY, -INFINITY, -INFINITY, -INFINITY};
    #pragma unroll
    for (int ct = 0; ct < 8; ++ct) {
      float mk = Ms[ct * 16 + l15];
      int key = t0 * 128 + ct * 16 + l15;
      #pragma unroll
      for (int r = 0; r < 4; ++r) {
        int qg = q0 + w * 16 + lg4 * 4 + r;
        float a = (float)(key - 16 * qg);
        float ac = fminf(fmaxf(a, 0.f), 15.f);
        float dd = fabsf(a - ac);
        float sum = ac * ac - 15.f * ac + 120.f + 16.f * dd;
        float s = sc[ct][r] + cpos * sum + mk;
        sc[ct][r] = s;
        tmax[r] = fmaxf(tmax[r], s);
      }
    }
    #pragma unroll
    for (int r = 0; r < 4; ++r) {
      #pragma unroll
      for (int o = 1; o < 16; o <<= 1)
        tmax[r] = fmaxf(tmax[r], __shfl_xor(tmax[r], o));
    }
    float fr[4], lsum[4];
    #pragma unroll
    for (int r = 0; r < 4; ++r) {
      float mnew = fmaxf(mrun[r], tmax[r]);
      fr[r] = expf(mrun[r] - mnew);
      mrun[r] = mnew;
      lsum[r] = 0.f;
    }
    #pragma unroll
    for (int ct = 0; ct < 8; ++ct) {
      #pragma unroll
      for (int r = 0; r < 4; ++r) {
        float p = expf(sc[ct][r] - mrun[r]);
        sc[ct][r] = p;
        lsum[r] += p;
      }
    }
    #pragma unroll
    for (int r = 0; r < 4; ++r) {
      #pragma unroll
      for (int o = 1; o < 16; o <<= 1)
        lsum[r] += __shfl_xor(lsum[r], o);
      lrun[r] = lrun[r] * fr[r] + lsum[r];
    }
    f32x4 fv = (f32x4){fr[0], fr[1], fr[2], fr[3]};
    #pragma unroll
    for (int dt = 0; dt < 4; ++dt) Oa[dt] *= fv;
    #pragma unroll
    for (int ct = 0; ct < 8; ++ct) {
      int kc = ct * 2 + (l15 >> 3);
      int ki = l15 & 7;
      #pragma unroll
      for (int r = 0; r < 4; ++r) {
        int row = lg4 * 4 + r;
        Pw[row * 128 + ((kc ^ (row & 7)) << 3) + ki] = (f16)sc[ct][r];
      }
    }
    #pragma unroll
    for (int ks = 0; ks < 4; ++ks) {
      f16x8 pa = *(const f16x8*)&Pw[l15 * 128 + (((ks * 4 + lg4) ^ l7) << 3)];
      #pragma unroll
      for (int dt = 0; dt < 4; ++dt) {
        int n = dt * 16 + l15;
        f16x8 bv = *(const f16x8*)&Vt[n * 128 + (((ks * 4 + lg4) ^ (n & 7)) << 3)];
        Oa[dt] = __builtin_amdgcn_mfma_f32_16x16x32_f16(pa, bv, Oa[dt], 0, 0, 0);
      }
    }
  }
  #pragma unroll
  for (int r = 0; r < 4; ++r) {
    long qg = q0 + w * 16 + lg4 * 4 + r;
    long base = ((long)z * NL + qg) * NSPL + chunk;
    #pragma unroll
    for (int dt = 0; dt < 4; ++dt)
      partU[base * 64 + dt * 16 + l15] = Oa[dt][r];
    if (l15 == 0) {
      partML[base * 2] = mrun[r];
      partML[base * 2 + 1] = lrun[r];
    }
  }
}

// ---------------------------------------------------------------- merge split-flash partials
__global__ __launch_bounds__(256) void k_merge(
    const float* __restrict__ partU, const float* __restrict__ partML,
    float* __restrict__ kv3)
{
  int id = blockIdx.x;
  int z = id >> 2, part = id & 3;
  int t = threadIdx.x;
  int q = part * 32 + (t >> 3);
  int c8 = (t & 7) * 8;
  long base = ((long)z * NL + q) * NSPL;
  float m[NSPL], lv[NSPL];
  #pragma unroll
  for (int c = 0; c < NSPL; ++c) {
    m[c] = partML[(base + c) * 2];
    lv[c] = partML[(base + c) * 2 + 1];
  }
  float M = fmaxf(fmaxf(m[0], m[1]), fmaxf(m[2], m[3]));
  float L = 0.f, sc[NSPL];
  #pragma unroll
  for (int c = 0; c < NSPL; ++c) {
    sc[c] = expf(m[c] - M);
    L += lv[c] * sc[c];
  }
  float o[8] = {};
  #pragma unroll
  for (int c = 0; c < NSPL; ++c) {
    const float* up = &partU[(base + c) * 64 + c8];
    float4 a = *(const float4*)up;
    float4 bq = *(const float4*)(up + 4);
    o[0] += sc[c] * a.x; o[1] += sc[c] * a.y; o[2] += sc[c] * a.z; o[3] += sc[c] * a.w;
    o[4] += sc[c] * bq.x; o[5] += sc[c] * bq.y; o[6] += sc[c] * bq.z; o[7] += sc[c] * bq.w;
  }
  float invL = 1.f / L;
  float* kp = &kv3[((long)z * NL + q) * 64 + c8];
  #pragma unroll
  for (int j = 0; j < 8; ++j) kp[j] = o[j] * invL;
}

// ---------------------------------------------------------------- inverse (MFMA fp16 NS, 8 waves)
__global__ __launch_bounds__(512) void k_inverse(
    const f16* __restrict__ k2h, const float* __restrict__ colmax,
    const float* __restrict__ kv3, float* __restrict__ m2)
{
  __shared__ __align__(16) f16 bufA[128 * 128];
  __shared__ __align__(16) f16 bufB[128 * 128];
  __shared__ __align__(16) f16 Vt[128 * 128];
  __shared__ __align__(16) f16 Pt[128 * 128];
  int z = blockIdx.x;
  int tid = threadIdx.x;
  int w = tid >> 6, l = tid & 63;
  int l15 = l & 15, lg4 = l >> 4;
  int wr = (w >> 1) * 32, wc = (w & 1) * 64;

  float cv = colmax[l];
  #pragma unroll
  for (int o = 32; o; o >>= 1) cv = fmaxf(cv, __shfl_xor(cv, o));
  float recip = 1.f / cv;

  const f16* key = k2h + (long)z * NL * NL;
  auto swz = [](int r, int c) { return r * 128 + ((((c >> 3) ^ (r & 15))) << 3) + (c & 7); };

  for (int idx = tid; idx < 128 * 16; idx += 512) {
    int r = idx >> 4, c8 = (idx & 15) << 3;
    f16x8 kk = *(const f16x8*)&key[r * 128 + c8];
    f16x8 sv;
    #pragma unroll
    for (int j = 0; j < 8; ++j) sv[j] = (f16)(recip * (float)kk[j]);
    *(f16x8*)&Vt[swz(r, c8)] = sv;
    #pragma unroll
    for (int j = 0; j < 8; ++j) bufA[swz(c8 + j, r)] = sv[j];
  }
  __syncthreads();

  f16* Vc = bufA;
  f16* Sc = bufB;

  f32x4 acc[2][4];
  auto MMc = [&](bool fromGlobal, const f16* Aimg, const f16* Bimg) {
    #pragma unroll
    for (int mi = 0; mi < 2; ++mi)
      #pragma unroll
      for (int ni = 0; ni < 4; ++ni) acc[mi][ni] = (f32x4){0.f, 0.f, 0.f, 0.f};
    #pragma unroll
    for (int ks = 0; ks < 4; ++ks) {
      int k0 = ks * 32 + lg4 * 8;
      f16x8 bf[4];
      #pragma unroll
      for (int ni = 0; ni < 4; ++ni)
        bf[ni] = *(const f16x8*)&Bimg[swz(wc + ni * 16 + l15, k0)];
      f16x8 af[2];
      if (fromGlobal) {
        af[0] = *(const f16x8*)&key[(wr + l15) * 128 + k0];
        af[1] = *(const f16x8*)&key[(wr + 16 + l15) * 128 + k0];
      } else {
        af[0] = *(const f16x8*)&Aimg[swz(wr + l15, k0)];
        af[1] = *(const f16x8*)&Aimg[swz(wr + 16 + l15, k0)];
      }
      #pragma unroll
      for (int mi = 0; mi < 2; ++mi)
        #pragma unroll
        for (int ni = 0; ni < 4; ++ni)
          acc[mi][ni] = __builtin_amdgcn_mfma_f32_16x16x32_f16(af[mi], bf[ni], acc[mi][ni], 0, 0, 0);
    }
  };
  auto store = [&](f16* Nout, f16* Tout, float aT, float bT) {
    #pragma unroll
    for (int mi = 0; mi < 2; ++mi) {
      int row0 = wr + mi * 16 + lg4 * 4;
      #pragma unroll
      for (int ni = 0; ni < 4; ++ni) {
        int col = wc + ni * 16 + l15;
        f16x4 tv;
        #pragma unroll
        for (int r = 0; r < 4; ++r) {
          float v = acc[mi][ni][r];
          if (Nout) Nout[swz(row0 + r, col)] = (f16)v;
          tv[r] = (f16)(aT * v + ((row0 + r == col) ? bT : 0.f));
        }
        *(f16x4*)&Tout[col * 128 + ((((row0 >> 3) ^ (col & 15))) << 3) + (row0 & 7)] = tv;
      }
    }
  };

  for (int it = 0; it < 6; ++it) {
    MMc(true, nullptr, Vt);  store(Sc, Pt, -1.f, 7.f);       __syncthreads();
    MMc(false, Sc, Pt);      store(nullptr, Vt, -1.f, 15.f); __syncthreads();
    MMc(false, Sc, Vt);      store(nullptr, Pt, -0.25f, 3.25f); __syncthreads();
    MMc(false, Vc, Pt);      store(Sc, Vt, 1.f, 0.f);        __syncthreads();
    f16* tsw = Vc; Vc = Sc; Sc = tsw;
  }

  const float* kp = kv3 + (long)z * NL * VF;
  for (int idx = tid; idx < 128 * 16; idx += 512) {
    int k = idx >> 4, c4 = (idx & 15) << 2;
    float4 v4 = *(const float4*)&kp[k * 64 + c4];
    Pt[swz(c4 + 0, k)] = (f16)v4.x;
    Pt[swz(c4 + 1, k)] = (f16)v4.y;
    Pt[swz(c4 + 2, k)] = (f16)v4.z;
    Pt[swz(c4 + 3, k)] = (f16)v4.w;
  }
  __syncthreads();
  f32x4 accF[4];
  #pragma unroll
  for (int ni = 0; ni < 4; ++ni) accF[ni] = (f32x4){0.f, 0.f, 0.f, 0.f};
  #pragma unroll
  for (int ks = 0; ks < 4; ++ks) {
    int k0 = ks * 32 + lg4 * 8;
    f16x8 af = *(const f16x8*)&Vc[swz(w * 16 + l15, k0)];
    #pragma unroll
    for (int ni = 0; ni < 4; ++ni) {
      f16x8 bf = *(const f16x8*)&Pt[swz(ni * 16 + l15, k0)];
      accF[ni] = __builtin_amdgcn_mfma_f32_16x16x32_f16(af, bf, accF[ni], 0, 0, 0);
    }
  }
  float* mp = m2 + (long)z * NL * VF;
  #pragma unroll
  for (int ni = 0; ni < 4; ++ni)
    #pragma unroll
    for (int r = 0; r < 4; ++r)
      mp[(long)(w * 16 + lg4 * 4 + r) * VF + ni * 16 + l15] = accF[ni][r];
}

// ---------------------------------------------------------------- kernel_1 + attn + merge (MFMA)
__global__ __launch_bounds__(256, 2) void k_k1attn(
    const f16* __restrict__ Eq16, const f16* __restrict__ kland16,
    const float* __restrict__ aggL, const float* __restrict__ m2,
    const float* __restrict__ proj, f16* __restrict__ merged)
{
  __shared__ __align__(16) f16 Kl[128 * 64];
  __shared__ __align__(16) f16 M2t[64 * 128];
  __shared__ __align__(16) f16 Pb[4 * 16 * 128];
  int zz = blockIdx.x;
  int z = zz >> 5, st = zz & 31;
  int b = z >> 3, h = z & 7;
  int s0 = st * 64;
  int tid = threadIdx.x;
  int w = tid >> 6, l = tid & 63;
  int l15 = l & 15, lg4 = l >> 4, l7 = l & 7;
  float sigma = fabsf(aggL[h]) + 0.001f;
  float cpos = -sigma * (1.f / 16.f);

  for (int c = tid; c < 128 * 8; c += 256) {
    int k = c >> 3, kc = c & 7;
    f16x8 v = *(const f16x8*)&kland16[((long)b * NL + k) * 64 + kc * 8];
    *(f16x8*)&Kl[k * 64 + ((kc ^ (k & 7)) << 3)] = v;
  }
  const float* mp = m2 + (long)z * NL * VF;
  for (int c = tid; c < 128 * 16; c += 256) {
    int k = c >> 4, c4 = (c & 15) << 2;
    float4 v4 = *(const float4*)&mp[k * 64 + c4];
    int kc = k >> 3, ki = k & 7;
    M2t[(c4 + 0) * 128 + ((kc ^ ((c4 + 0) & 7)) << 3) + ki] = (f16)v4.x;
    M2t[(c4 + 1) * 128 + ((kc ^ ((c4 + 1) & 7)) << 3) + ki] = (f16)v4.y;
    M2t[(c4 + 2) * 128 + ((kc ^ ((c4 + 2) & 7)) << 3) + ki] = (f16)v4.z;
    M2t[(c4 + 3) * 128 + ((kc ^ ((c4 + 3) & 7)) << 3) + ki] = (f16)v4.w;
  }
  __syncthreads();

  long qrow = (long)z * S + s0 + w * 16 + l15;
  f16x8 af[2];
  #pragma unroll
  for (int kh = 0; kh < 2; ++kh)
    af[kh] = *(const f16x8*)&Eq16[qrow * 64 + kh * 32 + lg4 * 8];

  f32x4 sc[8];
  #pragma unroll
  for (int ct = 0; ct < 8; ++ct) {
    int n = ct * 16 + l15;
    f16x8 b0 = *(const f16x8*)&Kl[n * 64 + ((lg4 ^ (n & 7)) << 3)];
    f16x8 b1 = *(const f16x8*)&Kl[n * 64 + (((4 + lg4) ^ (n & 7)) << 3)];
    f32x4 zz4 = (f32x4){0.f, 0.f, 0.f, 0.f};
    zz4 = __builtin_amdgcn_mfma_f32_16x16x32_f16(af[0], b0, zz4, 0, 0, 0);
    sc[ct] = __builtin_amdgcn_mfma_f32_16x16x32_f16(af[1], b1, zz4, 0, 0, 0);
  }
  float tmax[4] = {-INFINITY, -INFINITY, -INFINITY, -INFINITY};
  #pragma unroll
  for (int ct = 0; ct < 8; ++ct) {
    int lm = ct * 16 + l15;
    #pragma unroll
    for (int r = 0; r < 4; ++r) {
      int spos = s0 + w * 16 + lg4 * 4 + r;
      float a = (float)(spos - 16 * lm);
      float ac = fminf(fmaxf(a, 0.f), 15.f);
      float dd = fabsf(a - ac);
      float sum = ac * ac - 15.f * ac + 120.f + 16.f * dd;
      float s = sc[ct][r] + cpos * sum;
      sc[ct][r] = s;
      tmax[r] = fmaxf(tmax[r], s);
    }
  }
  #pragma unroll
  for (int r = 0; r < 4; ++r) {
    #pragma unroll
    for (int o = 1; o < 16; o <<= 1)
      tmax[r] = fmaxf(tmax[r], __shfl_xor(tmax[r], o));
  }
  float lsum[4] = {0.f, 0.f, 0.f, 0.f};
  #pragma unroll
  for (int ct = 0; ct < 8; ++ct) {
    #pragma unroll
    for (int r = 0; r < 4; ++r) {
      float p = expf(sc[ct][r] - tmax[r]);
      sc[ct][r] = p;
      lsum[r] += p;
    }
  }
  #pragma unroll
  for (int r = 0; r < 4; ++r) {
    #pragma unroll
    for (int o = 1; o < 16; o <<= 1)
      lsum[r] += __shfl_xor(lsum[r], o);
    lsum[r] = 1.f / lsum[r];
  }
  f16* Pw = &Pb[w * 16 * 128];
  #pragma unroll
  for (int ct = 0; ct < 8; ++ct) {
    int kc = ct * 2 + (l15 >> 3);
    int ki = l15 & 7;
    #pragma unroll
    for (int r = 0; r < 4; ++r) {
      int row = lg4 * 4 + r;
      Pw[row * 128 + ((kc ^ (row & 7)) << 3) + ki] = (f16)(sc[ct][r] * lsum[r]);
    }
  }
  f32x4 Oa[4];
  #pragma unroll
  for (int i = 0; i < 4; ++i) Oa[i] = (f32x4){0.f, 0.f, 0.f, 0.f};
  #pragma unroll
  for (int ks = 0; ks < 4; ++ks) {
    f16x8 pa = *(const f16x8*)&Pw[l15 * 128 + (((ks * 4 + lg4) ^ l7) << 3)];
    #pragma unroll
    for (int dt = 0; dt < 4; ++dt) {
      int n = dt * 16 + l15;
      f16x8 bv = *(const f16x8*)&M2t[n * 128 + (((ks * 4 + lg4) ^ (n & 7)) << 3)];
      Oa[dt] = __builtin_amdgcn_mfma_f32_16x16x32_f16(pa, bv, Oa[dt], 0, 0, 0);
    }
  }
  #pragma unroll
  for (int r = 0; r < 4; ++r) {
    long srow = (long)b * S + s0 + w * 16 + lg4 * 4 + r;
    int r7 = (int)(srow & 7);
    #pragma unroll
    for (int dt = 0; dt < 4; ++dt) {
      int col = dt * 16 + l15;
      float v = Oa[dt][r] + proj[srow * VF + col];
      merged[srow * (long)HV + h * 64 + (((col >> 3) ^ r7) << 3) + (col & 7)] = (f16)v;
    }
  }
}

} // namespace

extern "C" void kernel_launch(void* const* d_in, const int* in_sizes, int n_in,
                              void* d_out, int out_size, void* d_ws, size_t ws_size,
                              hipStream_t stream)
{
  const float* lat   = (const float*)d_in[0];
  const float* masks = (const float*)d_in[1];
  const float* xemb  = (const float*)d_in[2];
  const float* ccls  = (const float*)d_in[4];
  const float* qlin  = (const float*)d_in[5];
  const float* klin  = (const float*)d_in[6];
  const float* vlin  = (const float*)d_in[7];
  const float* plin  = (const float*)d_in[8];
  const float* agg   = (const float*)d_in[9];
  const float* cfeat = (const float*)d_in[10];
  float* out = (float*)d_out;
  float* ws = (float*)d_ws;

  long off = 0;
  auto allocF = [&](long n) { float* p = ws + off; off += (n + 3) & ~3L; return p; };
  auto allocH = [&](long n) { f16* p = (f16*)(ws + off); off += ((n + 1) / 2 + 3) & ~3L; return p; };

  f16* origA = allocH(ROWS * KSF);
  f16* vbufA = allocH(ROWS * KSF);
  f16* merged = allocH(ROWS * (long)HV);
  f16* WQt = allocH(16L * 64 * KSF);
  f16* WKt = allocH(2L * 64 * KSF);
  f16* WVt = allocH(16L * 64 * KSF);
  f16* WPt = allocH(2L * 64 * KSF);
  f16* WCFt = allocH((long)KSF * 512);
  f16* WCCt = allocH(64L * 512);
  f16* Ek16 = allocH((long)B * S * 64);
  f16* Ev16 = allocH((long)B * H * S * 64);
  f16* Eq16 = allocH((long)B * H * S * 64);
  f16* qland16 = allocH((long)B * H * NL * DF);
  f16* kland16 = allocH((long)B * NL * DF);
  f16* k2h = allocH((long)B * H * NL * NL);
  float* cl     = allocF(ROWS * HS);
  float* projb  = allocF((long)B * S * VF);
  float* qland  = allocF((long)B * H * NL * DF);
  float* kland  = allocF((long)B * NL * DF);
  float* kv3    = allocF((long)B * H * NL * VF);
  float* m2b    = allocF((long)B * H * NL * VF);
  float* colmax = allocF(64);
  float* partU  = allocF((long)B * H * NL * NSPL * 64);
  float* partML = allocF((long)B * H * NL * NSPL * 2);

  k_cl<<<(int)(ROWS / 4), 256, 0, stream>>>(lat, masks, cl);
  k_cvta<<<(int)(ROWS * 168 / 256), 256, 0, stream>>>(xemb, cl, origA);

  auto cvtw = [&](const float* src, f16* dst, int K, int N, int Npad, int KS, long srcZ, int nz) {
    long total = (long)nz * Npad * (KS / 8);
    k_cvtw<<<(int)((total + 255) / 256), 256, 0, stream>>>(src, dst, K, N, Npad, KS, srcZ, total);
  };
  cvtw(qlin, WQt, FEAT, 64, 64, KSF, (long)FEATP * 64, 16);
  cvtw(klin, WKt, FEAT, 64, 64, KSF, (long)FEATP * 64, 2);
  cvtw(vlin, WVt, FEAT, 64, 64, KSF, (long)FEATP * 64, 16);
  cvtw(plin, WPt, FEAT, 64, 64, KSF, (long)FEATP * 64, 2);
  cvtw(cfeat, WCFt, 512, FEAT, KSF, 512, 0, 1);
  cvtw(ccls, WCCt, 512, HS, 64, 512, 0, 1);

  const f16* Aact = origA;
  for (int layer = 0; layer < 2; ++layer) {
    const f16* wq = WQt + (long)layer * 8 * 64 * KSF;
    const f16* wk = WKt + (long)layer * 64 * KSF;
    const f16* wvv = WVt + (long)layer * 8 * 64 * KSF;
    const f16* wp = WPt + (long)layer * 64 * KSF;
    const float* bq = qlin + (long)layer * 8 * FEATP * 64 + (long)(FEATP - 2) * 64;
    const float* bk = klin + (long)layer * FEATP * 64 + (long)(FEATP - 2) * 64;
    const float* bv = vlin + (long)layer * 8 * FEATP * 64 + (long)(FEATP - 2) * 64;
    const float* bp = plin + (long)layer * FEATP * 64 + (long)(FEATP - 2) * 64;
    const float* ag = agg + layer * H;

    dim3 gQV(16, 1, 64), gK(8, 1, 8);
    k_qv<<<gQV, 256, 0, stream>>>(Aact, wq, wvv, bq, bv, Eq16, Ev16);
    k_mgemm<<<gK, 256, 0, stream>>>(Aact, (long)S * KSF, 1, wk, 0, 1, 21, 3,
        nullptr, (long)S * 64, 64, bk, 0, INV_SCALE, Ek16, 64, nullptr);
    k_mgemm<<<gK, 256, 0, stream>>>(origA, (long)S * KSF, 1, wp, 0, 1, 21, 0,
        projb, (long)S * 64, 64, bp, 0, 0.5f, nullptr, 64, nullptr);

    k_segmean<<<B * H * NL, 64, 0, stream>>>(Eq16, qland, qland16);
    k_segmean<<<B * NL, 64, 0, stream>>>(Ek16, kland, kland16);

    k_kernel2<<<B * H, 256, 0, stream>>>(qland, kland, ag, k2h, colmax);
    k_kernel3<<<B * H * 2 * NSPL, 256, 0, stream>>>(qland16, Ek16, Ev16, ag, masks,
        partU, partML);
    k_merge<<<B * H * 4, 256, 0, stream>>>(partU, partML, kv3);
    k_inverse<<<B * H, 512, 0, stream>>>(k2h, colmax, kv3, m2b);
    k_k1attn<<<B * H * (S / 64), 256, 0, stream>>>(Eq16, kland16, ag, m2b, projb, merged);

    if (layer == 0) {
      dim3 gC(64, 21, 1);
      k_mgemm<<<gC, 256, 0, stream>>>(merged, 0, 1, WCFt, 0, 1, 8, 1,
          nullptr, 0, 0, nullptr, 0, 1.0f, vbufA, FEAT, nullptr);
      Aact = vbufA;
    } else {
      dim3 gO(64, 1, 1);
      k_mgemm<<<gO, 256, 0, stream>>>(merged, 0, 1, WCCt, 0, 1, 8, 2,
          out, 0, HS, nullptr, 0, 1.0f, nullptr, HS, masks);
    }
  }
  (void)in_sizes; (void)n_in; (void)out_size; (void)ws_size;
}

// Round 12
// 550.047 us; speedup vs baseline: 11.3629x; 1.0911x over previous
//
#include <hip/hip_runtime.h>
#include <math.h>

// ESMMimicryModule: B=8 S=2048 H=8 NL=128 DF=VF=64 NF=1280 HS=33 FEAT=1313
// Round 11: k_ekproj -- batch the two 64-block GEMMs (Ek, proj) into one
// 128-block dispatch (z<8: Ek from Aact/wk f16-out; z>=8: proj from origA/wp
// fp32-out). Two serial quarter-machine passes -> one half-machine pass.

namespace {

constexpr int B = 8, S = 2048, H = 8, NL = 128, DF = 64, VF = 64;
constexpr int NF = 1280, HS = 33, FEAT = 1313, FEATP = 1314;
constexpr int SEG = 16, HV = H * VF;            // 512
constexpr int KSF = 1344;                        // padded feature-K (21*64)
constexpr int NSPL = 4;                          // key chunks in split-S flash
constexpr long ROWS = (long)B * S;               // 16384
constexpr float INV_SCALE = 0.35355339059327373f;

typedef _Float16 f16;
typedef _Float16 f16x8 __attribute__((ext_vector_type(8)));
typedef _Float16 f16x4 __attribute__((ext_vector_type(4)));
typedef float f32x4 __attribute__((ext_vector_type(4)));

// ---------------------------------------------------------------- cl = softmax(latent)*mask
__global__ __launch_bounds__(256) void k_cl(
    const float* __restrict__ lat, const float* __restrict__ masks,
    float* __restrict__ cl)
{
  long row = (long)blockIdx.x * 4 + (threadIdx.x >> 6);
  int l = threadIdx.x & 63;
  float v = (l < HS) ? lat[row * HS + l] : -INFINITY;
  float m = v;
  #pragma unroll
  for (int o = 32; o; o >>= 1) m = fmaxf(m, __shfl_xor(m, o));
  float e = (l < HS) ? expf(v - m) : 0.f;
  float s = e;
  #pragma unroll
  for (int o = 32; o; o >>= 1) s += __shfl_xor(s, o);
  if (l < HS) cl[row * HS + l] = e / s * masks[row];
}

// ---------------------------------------------------------------- origA fp16 arena (swizzled)
__global__ __launch_bounds__(256) void k_cvta(
    const float* __restrict__ xemb, const float* __restrict__ cl,
    f16* __restrict__ dst)
{
  long idx = (long)blockIdx.x * 256 + threadIdx.x;  // chunk id (row, c)
  long row = idx / 168;
  int c = (int)(idx - row * 168);
  int t = c >> 3, cs = c & 7;                       // SOURCE chunk
  int k0 = t * 64 + cs * 8;
  f16x8 v;
  if (t < 20) {
    float4 a = *(const float4*)&xemb[row * NF + k0];
    float4 b = *(const float4*)&xemb[row * NF + k0 + 4];
    v[0] = (f16)a.x; v[1] = (f16)a.y; v[2] = (f16)a.z; v[3] = (f16)a.w;
    v[4] = (f16)b.x; v[5] = (f16)b.y; v[6] = (f16)b.z; v[7] = (f16)b.w;
  } else {
    #pragma unroll
    for (int i = 0; i < 8; ++i) {
      int k = k0 + i;
      float f = 0.f;
      if (k < NF) f = xemb[row * NF + k];
      else if (k < FEAT) f = cl[row * HS + (k - NF)];
      v[i] = (f16)f;
    }
  }
  int cd = cs ^ ((int)row & 7);                     // DEST chunk (involution)
  *(f16x8*)&dst[row * KSF + t * 64 + cd * 8] = v;
}

// ---------------------------------------------------------------- weight -> Wt fp16 arena
__global__ __launch_bounds__(256) void k_cvtw(
    const float* __restrict__ src, f16* __restrict__ dst,
    int K, int N, int Npad, int KS, long srcZ, long total)
{
  long idx = (long)blockIdx.x * 256 + threadIdx.x;
  if (idx >= total) return;
  long cpz = (long)Npad * (KS >> 3);
  long z = idx / cpz;
  long rem = idx - z * cpz;
  int n = (int)(rem / (KS >> 3));
  int c = (int)(rem - (long)n * (KS >> 3));
  int t = c >> 3, cs = c & 7;
  int cd = cs ^ (n & 7);
  int k0 = t * 64 + cd * 8;
  const float* sp = src + z * srcZ;
  f16x8 v;
  #pragma unroll
  for (int i = 0; i < 8; ++i) {
    int k = k0 + i;
    v[i] = (f16)((k < K && n < N) ? sp[(long)k * N + n] : 0.f);
  }
  *(f16x8*)&dst[idx * 8] = v;
}

// ---------------------------------------------------------------- fp16 MFMA GEMM (generic)
// mode 1: fp16 swizzled arena (KSF stride, zero-fill col>=NR), LDS-staged
// mode 2: fp32 out * mask, col<NR
__global__ __launch_bounds__(256, 2) void k_mgemm(
    const f16* __restrict__ A, long aZOff, int aDiv,
    const f16* __restrict__ Wt, long wZOff, int wMod,
    int KT, int mode,
    float* __restrict__ C, long cZOff, int ldC,
    const float* __restrict__ biasBase, long biasZOff, float scale,
    f16* __restrict__ outA, int NR, const float* __restrict__ mask)
{
  const long KS = (long)KT * 64;
  int z = blockIdx.z;
  const f16* Ap = A + (long)(z / aDiv) * aZOff;
  const f16* Wp = Wt + (long)(z % wMod) * wZOff;
  long m0 = (long)blockIdx.x * 256;
  int n0 = blockIdx.y * 64;
  constexpr int BOFF = 256 * 64;
  __shared__ f16 lds[2][(256 + 64) * 64];
  int tid = threadIdx.x;
  int wv = tid >> 6, l = tid & 63;

  const f16* aW = Ap + (m0 + wv * 64 + (l >> 3)) * KS + (l & 7) * 8;
  const f16* bW = Wp + ((long)(n0 + wv * 16 + (l >> 3))) * KS + (l & 7) * 8;

  f32x4 acc[4][4];
  #pragma unroll
  for (int i = 0; i < 4; ++i)
    #pragma unroll
    for (int j = 0; j < 4; ++j) acc[i][j] = (f32x4){0.f, 0.f, 0.f, 0.f};

  auto stage = [&](int buf, int t) {
    f16* la = &lds[buf][(wv * 64) * 64];
    const f16* ga = aW + (long)t * 64;
    #pragma unroll
    for (int j = 0; j < 8; ++j)
      __builtin_amdgcn_global_load_lds(
          (const __attribute__((address_space(1))) void*)(ga + (long)j * 8 * KS),
          (__attribute__((address_space(3))) void*)(la + j * 8 * 64), 16, 0, 0);
    f16* lb = &lds[buf][BOFF + (wv * 16) * 64];
    const f16* gb = bW + (long)t * 64;
    #pragma unroll
    for (int j = 0; j < 2; ++j)
      __builtin_amdgcn_global_load_lds(
          (const __attribute__((address_space(1))) void*)(gb + (long)j * 8 * KS),
          (__attribute__((address_space(3))) void*)(lb + j * 8 * 64), 16, 0, 0);
  };

  stage(0, 0);
  int rA = (wv * 64 + (l & 15)) * 64;
  int rB = BOFF + (l & 15) * 64;
  int lc = l >> 4, lx = l & 7;
  for (int t = 0; t < KT; ++t) {
    int nb = t & 1;
    if (t + 1 < KT) {
      stage(nb ^ 1, t + 1);
      asm volatile("s_waitcnt vmcnt(10)" ::: "memory");
    } else {
      asm volatile("s_waitcnt vmcnt(0)" ::: "memory");
    }
    __syncthreads();
    const f16* base = &lds[nb][0];
    f16x8 af[4][2], bf[4][2];
    #pragma unroll
    for (int mi = 0; mi < 4; ++mi)
      #pragma unroll
      for (int kh = 0; kh < 2; ++kh)
        af[mi][kh] = *(const f16x8*)&base[rA + mi * 16 * 64 + (((kh * 4 + lc) ^ lx) << 3)];
    #pragma unroll
    for (int ni = 0; ni < 4; ++ni)
      #pragma unroll
      for (int kh = 0; kh < 2; ++kh)
        bf[ni][kh] = *(const f16x8*)&base[rB + ni * 16 * 64 + (((kh * 4 + lc) ^ lx) << 3)];
    #pragma unroll
    for (int mi = 0; mi < 4; ++mi)
      #pragma unroll
      for (int ni = 0; ni < 4; ++ni) {
        acc[mi][ni] = __builtin_amdgcn_mfma_f32_16x16x32_f16(af[mi][0], bf[ni][0], acc[mi][ni], 0, 0, 0);
        acc[mi][ni] = __builtin_amdgcn_mfma_f32_16x16x32_f16(af[mi][1], bf[ni][1], acc[mi][ni], 0, 0, 0);
      }
    __syncthreads();
  }

  int lr = (l >> 4) * 4;
  int lcn = l & 15;
  if (mode == 2) {
    #pragma unroll
    for (int mi = 0; mi < 4; ++mi) {
      #pragma unroll
      for (int r = 0; r < 4; ++r) {
        long row = m0 + wv * 64 + mi * 16 + lr + r;
        float mv = mask[row];
        #pragma unroll
        for (int ni = 0; ni < 4; ++ni) {
          int col = n0 + ni * 16 + lcn;
          if (col < NR) C[row * (long)ldC + col] = acc[mi][ni][r] * mv;
        }
      }
    }
  } else {  // mode 1: stage f16 tile in LDS, vectorized swizzled-arena writes
    f16* st = &lds[0][0];
    #pragma unroll
    for (int ni = 0; ni < 4; ++ni) {
      int coll = ni * 16 + lcn;
      int col = n0 + coll;
      bool ok = col < NR;
      #pragma unroll
      for (int mi = 0; mi < 4; ++mi) {
        int rowl = wv * 64 + mi * 16 + lr;
        #pragma unroll
        for (int r = 0; r < 4; ++r) {
          float v = ok ? acc[mi][ni][r] * scale : 0.f;
          st[(rowl + r) * 64 + coll] = (f16)v;
        }
      }
    }
    __syncthreads();
    int tt = n0 >> 6;
    for (int c = tid; c < 2048; c += 256) {
      int row = c >> 3, cd = c & 7;
      long grow = m0 + row;
      int r7 = (int)grow & 7;
      f16x8 v = *(const f16x8*)&st[row * 64 + cd * 8];
      *(f16x8*)&outA[grow * KSF + tt * 64 + ((cd ^ r7) << 3)] = v;
    }
  }
}

// ---------------------------------------------------------------- batched Ek + proj GEMM
// grid z in [0,16): z<8 -> Ek (A=Aact, wk, *INV_SCALE+bk, f16 out);
// z>=8 -> proj (A=origA, wp, (acc+bp)*0.5, fp32 out). BM=256 BN=64.
__global__ __launch_bounds__(256, 2) void k_ekproj(
    const f16* __restrict__ Aact, const f16* __restrict__ Aorig,
    const f16* __restrict__ wk, const f16* __restrict__ wp,
    const float* __restrict__ bk, const float* __restrict__ bp,
    f16* __restrict__ Ek16, float* __restrict__ projb)
{
  constexpr int KT = 21;
  constexpr int BOFF = 256 * 64;
  __shared__ f16 lds[2][(256 + 64) * 64];
  int z = blockIdx.z;
  int prob = z >> 3, b = z & 7;
  const f16* Ap = (prob ? Aorig : Aact) + (long)b * S * KSF;
  const f16* Wp = prob ? wp : wk;
  long m0 = (long)blockIdx.x * 256;
  int tid = threadIdx.x;
  int wv = tid >> 6, l = tid & 63;

  const f16* aW = Ap + (m0 + wv * 64 + (l >> 3)) * KSF + (l & 7) * 8;
  const f16* bW = Wp + ((long)(wv * 16 + (l >> 3))) * KSF + (l & 7) * 8;

  f32x4 acc[4][4];
  #pragma unroll
  for (int i = 0; i < 4; ++i)
    #pragma unroll
    for (int j = 0; j < 4; ++j) acc[i][j] = (f32x4){0.f, 0.f, 0.f, 0.f};

  auto stage = [&](int buf, int t) {
    f16* la = &lds[buf][(wv * 64) * 64];
    const f16* ga = aW + (long)t * 64;
    #pragma unroll
    for (int j = 0; j < 8; ++j)
      __builtin_amdgcn_global_load_lds(
          (const __attribute__((address_space(1))) void*)(ga + (long)j * 8 * KSF),
          (__attribute__((address_space(3))) void*)(la + j * 8 * 64), 16, 0, 0);
    f16* lb = &lds[buf][BOFF + (wv * 16) * 64];
    const f16* gb = bW + (long)t * 64;
    #pragma unroll
    for (int j = 0; j < 2; ++j)
      __builtin_amdgcn_global_load_lds(
          (const __attribute__((address_space(1))) void*)(gb + (long)j * 8 * KSF),
          (__attribute__((address_space(3))) void*)(lb + j * 8 * 64), 16, 0, 0);
  };

  stage(0, 0);
  int rA = (wv * 64 + (l & 15)) * 64;
  int rB = BOFF + (l & 15) * 64;
  int lc = l >> 4, lx = l & 7;
  for (int t = 0; t < KT; ++t) {
    int nb = t & 1;
    if (t + 1 < KT) {
      stage(nb ^ 1, t + 1);
      asm volatile("s_waitcnt vmcnt(10)" ::: "memory");
    } else {
      asm volatile("s_waitcnt vmcnt(0)" ::: "memory");
    }
    __syncthreads();
    const f16* base = &lds[nb][0];
    f16x8 af[4][2], bf[4][2];
    #pragma unroll
    for (int mi = 0; mi < 4; ++mi)
      #pragma unroll
      for (int kh = 0; kh < 2; ++kh)
        af[mi][kh] = *(const f16x8*)&base[rA + mi * 16 * 64 + (((kh * 4 + lc) ^ lx) << 3)];
    #pragma unroll
    for (int ni = 0; ni < 4; ++ni)
      #pragma unroll
      for (int kh = 0; kh < 2; ++kh)
        bf[ni][kh] = *(const f16x8*)&base[rB + ni * 16 * 64 + (((kh * 4 + lc) ^ lx) << 3)];
    #pragma unroll
    for (int mi = 0; mi < 4; ++mi)
      #pragma unroll
      for (int ni = 0; ni < 4; ++ni) {
        acc[mi][ni] = __builtin_amdgcn_mfma_f32_16x16x32_f16(af[mi][0], bf[ni][0], acc[mi][ni], 0, 0, 0);
        acc[mi][ni] = __builtin_amdgcn_mfma_f32_16x16x32_f16(af[mi][1], bf[ni][1], acc[mi][ni], 0, 0, 0);
      }
    __syncthreads();
  }

  int lr = (l >> 4) * 4;
  int lcn = l & 15;
  if (prob == 0) {
    // Ek: f16 LDS-staged, (acc+bk)*INV_SCALE
    f16* st = &lds[0][0];
    #pragma unroll
    for (int ni = 0; ni < 4; ++ni) {
      int col = ni * 16 + lcn;
      float bv = bk[col];
      #pragma unroll
      for (int mi = 0; mi < 4; ++mi) {
        int rowl = wv * 64 + mi * 16 + lr;
        #pragma unroll
        for (int r = 0; r < 4; ++r)
          st[(rowl + r) * 64 + col] = (f16)((acc[mi][ni][r] + bv) * INV_SCALE);
      }
    }
    __syncthreads();
    f16* o16 = Ek16 + (long)b * S * 64;
    for (int c = tid; c < 2048; c += 256) {
      int row = c >> 3, cc = c & 7;
      f16x8 v = *(const f16x8*)&st[row * 64 + cc * 8];
      *(f16x8*)&o16[(m0 + row) * 64 + cc * 8] = v;
    }
  } else {
    // proj: fp32 direct, (acc+bp)*0.5
    float* Cp = projb + (long)b * S * 64;
    #pragma unroll
    for (int ni = 0; ni < 4; ++ni) {
      int col = ni * 16 + lcn;
      float bv = bp[col];
      #pragma unroll
      for (int mi = 0; mi < 4; ++mi) {
        long row = m0 + wv * 64 + mi * 16 + lr;
        #pragma unroll
        for (int r = 0; r < 4; ++r)
          Cp[(row + r) * 64 + col] = (acc[mi][ni][r] + bv) * 0.5f;
      }
    }
  }
}

// ---------------------------------------------------------------- fused Eq+Ev GEMM
__global__ __launch_bounds__(256, 2) void k_qv(
    const f16* __restrict__ A,
    const f16* __restrict__ WQl, const f16* __restrict__ WVl,
    const float* __restrict__ bqBase, const float* __restrict__ bvBase,
    f16* __restrict__ Eq16, f16* __restrict__ Ev16)
{
  constexpr int KT = 21;
  constexpr int BOFF = 128 * 64;
  __shared__ f16 lds[2][(128 + 128) * 64];
  int z = blockIdx.z;                 // b*H + h
  int h = z & 7;
  const f16* Ap = A + (long)(z >> 3) * S * KSF;
  const f16* wqp = WQl + (long)h * 64 * KSF;
  const f16* wvp = WVl + (long)h * 64 * KSF;
  const float* bq = bqBase + (long)h * FEATP * 64;
  const float* bv = bvBase + (long)h * FEATP * 64;
  long m0 = (long)blockIdx.x * 128;
  int tid = threadIdx.x;
  int wv = tid >> 6, l = tid & 63;
  int l15 = l & 15, lc = l >> 4, lx = l & 7;

  const f16* aW = Ap + (m0 + wv * 32 + (l >> 3)) * KSF + (l & 7) * 8;

  f32x4 acc[2][8];
  #pragma unroll
  for (int i = 0; i < 2; ++i)
    #pragma unroll
    for (int j = 0; j < 8; ++j) acc[i][j] = (f32x4){0.f, 0.f, 0.f, 0.f};

  auto stage = [&](int buf, int t) {
    f16* la = &lds[buf][(wv * 32) * 64];
    const f16* ga = aW + (long)t * 64;
    #pragma unroll
    for (int j = 0; j < 4; ++j)
      __builtin_amdgcn_global_load_lds(
          (const __attribute__((address_space(1))) void*)(ga + (long)j * 8 * KSF),
          (__attribute__((address_space(3))) void*)(la + j * 512), 16, 0, 0);
    f16* lb = &lds[buf][BOFF + (wv * 32) * 64];
    #pragma unroll
    for (int j = 0; j < 4; ++j) {
      int brow = wv * 32 + j * 8 + (l >> 3);
      const f16* src = (brow < 64 ? wqp + (long)brow * KSF
                                  : wvp + (long)(brow - 64) * KSF)
                       + (l & 7) * 8 + (long)t * 64;
      __builtin_amdgcn_global_load_lds(
          (const __attribute__((address_space(1))) void*)src,
          (__attribute__((address_space(3))) void*)(lb + j * 512), 16, 0, 0);
    }
  };

  stage(0, 0);
  for (int t = 0; t < KT; ++t) {
    int nb = t & 1;
    if (t + 1 < KT) {
      stage(nb ^ 1, t + 1);
      asm volatile("s_waitcnt vmcnt(8)" ::: "memory");
    } else {
      asm volatile("s_waitcnt vmcnt(0)" ::: "memory");
    }
    __syncthreads();
    const f16* base = &lds[nb][0];
    f16x8 af[2][2], bf[8][2];
    #pragma unroll
    for (int mi = 0; mi < 2; ++mi)
      #pragma unroll
      for (int kh = 0; kh < 2; ++kh)
        af[mi][kh] = *(const f16x8*)&base[(wv * 32 + mi * 16 + l15) * 64 + (((kh * 4 + lc) ^ lx) << 3)];
    #pragma unroll
    for (int ni = 0; ni < 8; ++ni) {
      int n = ni * 16 + l15;
      #pragma unroll
      for (int kh = 0; kh < 2; ++kh)
        bf[ni][kh] = *(const f16x8*)&base[BOFF + n * 64 + (((kh * 4 + lc) ^ (n & 7)) << 3)];
    }
    #pragma unroll
    for (int mi = 0; mi < 2; ++mi)
      #pragma unroll
      for (int ni = 0; ni < 8; ++ni) {
        acc[mi][ni] = __builtin_amdgcn_mfma_f32_16x16x32_f16(af[mi][0], bf[ni][0], acc[mi][ni], 0, 0, 0);
        acc[mi][ni] = __builtin_amdgcn_mfma_f32_16x16x32_f16(af[mi][1], bf[ni][1], acc[mi][ni], 0, 0, 0);
      }
    __syncthreads();
  }

  f16* st = &lds[0][0];
  int lr = (l >> 4) * 4;
  #pragma unroll
  for (int ni = 0; ni < 8; ++ni) {
    int col = ni * 16 + l15;
    float bvv = (col < 64) ? bq[col] : bv[col - 64];
    float scl = (col < 64) ? INV_SCALE : 1.f;
    #pragma unroll
    for (int mi = 0; mi < 2; ++mi) {
      int rowl = wv * 32 + mi * 16 + lr;
      #pragma unroll
      for (int r = 0; r < 4; ++r)
        st[(rowl + r) * 128 + col] = (f16)((acc[mi][ni][r] + bvv) * scl);
    }
  }
  __syncthreads();
  f16* oq = Eq16 + (long)z * S * 64;
  f16* ov = Ev16 + (long)z * S * 64;
  for (int c = tid; c < 1024; c += 256) {
    int rw = c >> 3, cc = c & 7;
    *(f16x8*)&oq[(m0 + rw) * 64 + cc * 8] = *(const f16x8*)&st[rw * 128 + cc * 8];
    *(f16x8*)&ov[(m0 + rw) * 64 + cc * 8] = *(const f16x8*)&st[rw * 128 + 64 + cc * 8];
  }
}

// ---------------------------------------------------------------- landmarks (f16 input)
__global__ void k_segmean(const f16* __restrict__ in, float* __restrict__ out,
                          f16* __restrict__ out16)
{
  long zl = blockIdx.x;
  long z = zl / NL, lm = zl % NL;
  int d = threadIdx.x;
  const f16* p = in + (z * S + lm * SEG) * (long)DF + d;
  float s = 0.f;
  #pragma unroll
  for (int i = 0; i < SEG; i++) s += (float)p[(long)i * DF];
  float v = s * (1.f / SEG);
  out[(z * NL + lm) * (long)DF + d] = v;
  if (out16) out16[(z * NL + lm) * (long)DF + d] = (f16)v;
}

// ---------------------------------------------------------------- kernel_2 (analytic possel2)
__global__ __launch_bounds__(256) void k_kernel2(
    const float* __restrict__ qland, const float* __restrict__ kland,
    const float* __restrict__ aggL, f16* __restrict__ k2h,
    float* __restrict__ colmax)
{
  int z = blockIdx.x; int b = z / H; int h = z % H;
  float sigma = fabsf(aggL[h]) + 0.001f;
  __shared__ float qs[NL][68];
  __shared__ float ks[NL][68];
  __shared__ float lg[NL][NL + 1];
  int tid = threadIdx.x;
  for (int idx = tid; idx < NL * DF; idx += 256) {
    int r = idx >> 6, d = idx & 63;
    qs[r][d] = qland[((long)z * NL + r) * DF + d];
    ks[r][d] = kland[((long)b * NL + r) * DF + d];
  }
  __syncthreads();
  int r = tid >> 1, half = tid & 1;
  float lmax = -INFINITY;
  for (int c = 0; c < 64; c++) {
    int m = half * 64 + c;
    float s = 0.f;
    #pragma unroll
    for (int d = 0; d < DF; d += 4) {
      float4 q = *(const float4*)&qs[r][d];
      float4 k4 = *(const float4*)&ks[m][d];
      s += q.x * k4.x + q.y * k4.y + q.z * k4.z + q.w * k4.w;
    }
    float dd = fabsf((float)(r - m));
    s += -sigma * ((r == m) ? 5.3125f : 16.f * dd);
    lg[r][m] = s;
    lmax = fmaxf(lmax, s);
  }
  lmax = fmaxf(lmax, __shfl_xor(lmax, 1));
  float lsum = 0.f;
  for (int c = 0; c < 64; c++) {
    int m = half * 64 + c;
    float e = expf(lg[r][m] - lmax);
    lg[r][m] = e; lsum += e;
  }
  lsum += __shfl_xor(lsum, 1);
  float inv = 1.f / lsum;
  for (int c = 0; c < 64; c++) {
    int m = half * 64 + c;
    float p = lg[r][m] * inv;
    lg[r][m] = p;
    k2h[((long)z * NL + r) * NL + m] = (f16)p;
  }
  __syncthreads();
  float myc = 0.f;
  if (tid < NL) {
    for (int rr = 0; rr < NL; rr++) myc += lg[rr][tid];
  }
  float wm = myc;
  #pragma unroll
  for (int o = 32; o; o >>= 1) wm = fmaxf(wm, __shfl_xor(wm, o));
  __shared__ float wred[4];
  if ((tid & 63) == 0) wred[tid >> 6] = wm;
  __syncthreads();
  if (tid == 0)
    colmax[z] = fmaxf(fmaxf(wred[0], wred[1]), fmaxf(wred[2], wred[3]));
}

// ---------------------------------------------------------------- kernel_3 (split-S flash MFMA)
__global__ __launch_bounds__(256, 2) void k_kernel3(
    const f16* __restrict__ qland16, const f16* __restrict__ Ek16,
    const f16* __restrict__ Ev16, const float* __restrict__ aggL,
    const float* __restrict__ masks,
    float* __restrict__ partU, float* __restrict__ partML)
{
  __shared__ __align__(16) f16 Qs[64 * 64];
  __shared__ __align__(16) f16 Ks[128 * 64];
  __shared__ __align__(16) f16 Vt[64 * 128];
  __shared__ __align__(16) f16 Pb[4 * 16 * 128];
  __shared__ float Ms[128];
  int id = blockIdx.x;
  int chunk = id & (NSPL - 1);
  int z2 = id >> 2;
  int z = z2 >> 1, half = z2 & 1;
  int b = z >> 3, h = z & 7;
  int q0 = half * 64;
  int tid = threadIdx.x;
  int w = tid >> 6, l = tid & 63;
  float sigma = fabsf(aggL[h]) + 0.001f;
  float cpos = -sigma * (1.f / 16.f);

  for (int c = tid; c < 64 * 8; c += 256) {
    int q = c >> 3, kc = c & 7;
    f16x8 v = *(const f16x8*)&qland16[((long)z * NL + q0 + q) * 64 + kc * 8];
    *(f16x8*)&Qs[q * 64 + ((kc ^ (q & 7)) << 3)] = v;
  }

  f16* Pw = &Pb[w * 16 * 128];
  int l15 = l & 15, lg4 = l >> 4, l7 = l & 7;
  f32x4 Oa[4];
  #pragma unroll
  for (int i = 0; i < 4; ++i) Oa[i] = (f32x4){0.f, 0.f, 0.f, 0.f};
  float mrun[4] = {-INFINITY, -INFINITY, -INFINITY, -INFINITY};
  float lrun[4] = {0.f, 0.f, 0.f, 0.f};

  int t0beg = chunk * (S / 128 / NSPL), t0end = t0beg + S / 128 / NSPL;
  for (int t0 = t0beg; t0 < t0end; ++t0) {
    __syncthreads();
    for (int c = tid; c < 1024; c += 256) {
      int k = c >> 3, kc = c & 7;
      f16x8 v = *(const f16x8*)&Ek16[((long)b * S + t0 * 128 + k) * 64 + kc * 8];
      *(f16x8*)&Ks[k * 64 + ((kc ^ (k & 7)) << 3)] = v;
    }
    for (int c = tid; c < 1024; c += 256) {
      int k = c & 127, dc = c >> 7;
      f16x8 v = *(const f16x8*)&Ev16[((long)z * S + t0 * 128 + k) * 64 + dc * 8];
      int kc = k >> 3, ki = k & 7;
      #pragma unroll
      for (int j = 0; j < 8; ++j) {
        int d = dc * 8 + j;
        Vt[d * 128 + ((kc ^ (d & 7)) << 3) + ki] = v[j];
      }
    }
    if (tid < 128)
      Ms[tid] = (masks[(long)b * S + t0 * 128 + tid] == 0.f) ? -1e6f : 0.f;
    __syncthreads();

    f16x8 af[2];
    #pragma unroll
    for (int kh = 0; kh < 2; ++kh)
      af[kh] = *(const f16x8*)&Qs[(w * 16 + l15) * 64 + (((kh * 4 + lg4) ^ l7) << 3)];
    f32x4 sc[8];
    #pragma unroll
    for (int ct = 0; ct < 8; ++ct) {
      int n = ct * 16 + l15;
      f16x8 b0 = *(const f16x8*)&Ks[n * 64 + (((lg4) ^ (n & 7)) << 3)];
      f16x8 b1 = *(const f16x8*)&Ks[n * 64 + (((4 + lg4) ^ (n & 7)) << 3)];
      f32x4 zz = (f32x4){0.f, 0.f, 0.f, 0.f};
      zz = __builtin_amdgcn_mfma_f32_16x16x32_f16(af[0], b0, zz, 0, 0, 0);
      sc[ct] = __builtin_amdgcn_mfma_f32_16x16x32_f16(af[1], b1, zz, 0, 0, 0);
    }
    float tmax[4] = {-INFINITY, -INFINITY, -INFINITY, -INFINITY};
    #pragma unroll
    for (int ct = 0; ct < 8; ++ct) {
      float mk = Ms[ct * 16 + l15];
      int key = t0 * 128 + ct * 16 + l15;
      #pragma unroll
      for (int r = 0; r < 4; ++r) {
        int qg = q0 + w * 16 + lg4 * 4 + r;
        float a = (float)(key - 16 * qg);
        float ac = fminf(fmaxf(a, 0.f), 15.f);
        float dd = fabsf(a - ac);
        float sum = ac * ac - 15.f * ac + 120.f + 16.f * dd;
        float s = sc[ct][r] + cpos * sum + mk;
        sc[ct][r] = s;
        tmax[r] = fmaxf(tmax[r], s);
      }
    }
    #pragma unroll
    for (int r = 0; r < 4; ++r) {
      #pragma unroll
      for (int o = 1; o < 16; o <<= 1)
        tmax[r] = fmaxf(tmax[r], __shfl_xor(tmax[r], o));
    }
    float fr[4], lsum[4];
    #pragma unroll
    for (int r = 0; r < 4; ++r) {
      float mnew = fmaxf(mrun[r], tmax[r]);
      fr[r] = expf(mrun[r] - mnew);
      mrun[r] = mnew;
      lsum[r] = 0.f;
    }
    #pragma unroll
    for (int ct = 0; ct < 8; ++ct) {
      #pragma unroll
      for (int r = 0; r < 4; ++r) {
        float p = expf(sc[ct][r] - mrun[r]);
        sc[ct][r] = p;
        lsum[r] += p;
      }
    }
    #pragma unroll
    for (int r = 0; r < 4; ++r) {
      #pragma unroll
      for (int o = 1; o < 16; o <<= 1)
        lsum[r] += __shfl_xor(lsum[r], o);
      lrun[r] = lrun[r] * fr[r] + lsum[r];
    }
    f32x4 fv = (f32x4){fr[0], fr[1], fr[2], fr[3]};
    #pragma unroll
    for (int dt = 0; dt < 4; ++dt) Oa[dt] *= fv;
    #pragma unroll
    for (int ct = 0; ct < 8; ++ct) {
      int kc = ct * 2 + (l15 >> 3);
      int ki = l15 & 7;
      #pragma unroll
      for (int r = 0; r < 4; ++r) {
        int row = lg4 * 4 + r;
        Pw[row * 128 + ((kc ^ (row & 7)) << 3) + ki] = (f16)sc[ct][r];
      }
    }
    #pragma unroll
    for (int ks = 0; ks < 4; ++ks) {
      f16x8 pa = *(const f16x8*)&Pw[l15 * 128 + (((ks * 4 + lg4) ^ l7) << 3)];
      #pragma unroll
      for (int dt = 0; dt < 4; ++dt) {
        int n = dt * 16 + l15;
        f16x8 bv = *(const f16x8*)&Vt[n * 128 + (((ks * 4 + lg4) ^ (n & 7)) << 3)];
        Oa[dt] = __builtin_amdgcn_mfma_f32_16x16x32_f16(pa, bv, Oa[dt], 0, 0, 0);
      }
    }
  }
  #pragma unroll
  for (int r = 0; r < 4; ++r) {
    long qg = q0 + w * 16 + lg4 * 4 + r;
    long base = ((long)z * NL + qg) * NSPL + chunk;
    #pragma unroll
    for (int dt = 0; dt < 4; ++dt)
      partU[base * 64 + dt * 16 + l15] = Oa[dt][r];
    if (l15 == 0) {
      partML[base * 2] = mrun[r];
      partML[base * 2 + 1] = lrun[r];
    }
  }
}

// ---------------------------------------------------------------- merge split-flash partials
__global__ __launch_bounds__(256) void k_merge(
    const float* __restrict__ partU, const float* __restrict__ partML,
    float* __restrict__ kv3)
{
  int id = blockIdx.x;
  int z = id >> 2, part = id & 3;
  int t = threadIdx.x;
  int q = part * 32 + (t >> 3);
  int c8 = (t & 7) * 8;
  long base = ((long)z * NL + q) * NSPL;
  float m[NSPL], lv[NSPL];
  #pragma unroll
  for (int c = 0; c < NSPL; ++c) {
    m[c] = partML[(base + c) * 2];
    lv[c] = partML[(base + c) * 2 + 1];
  }
  float M = fmaxf(fmaxf(m[0], m[1]), fmaxf(m[2], m[3]));
  float L = 0.f, sc[NSPL];
  #pragma unroll
  for (int c = 0; c < NSPL; ++c) {
    sc[c] = expf(m[c] - M);
    L += lv[c] * sc[c];
  }
  float o[8] = {};
  #pragma unroll
  for (int c = 0; c < NSPL; ++c) {
    const float* up = &partU[(base + c) * 64 + c8];
    float4 a = *(const float4*)up;
    float4 bq = *(const float4*)(up + 4);
    o[0] += sc[c] * a.x; o[1] += sc[c] * a.y; o[2] += sc[c] * a.z; o[3] += sc[c] * a.w;
    o[4] += sc[c] * bq.x; o[5] += sc[c] * bq.y; o[6] += sc[c] * bq.z; o[7] += sc[c] * bq.w;
  }
  float invL = 1.f / L;
  float* kp = &kv3[((long)z * NL + q) * 64 + c8];
  #pragma unroll
  for (int j = 0; j < 8; ++j) kp[j] = o[j] * invL;
}

// ---------------------------------------------------------------- inverse (MFMA fp16 NS, 8 waves)
__global__ __launch_bounds__(512) void k_inverse(
    const f16* __restrict__ k2h, const float* __restrict__ colmax,
    const float* __restrict__ kv3, float* __restrict__ m2)
{
  __shared__ __align__(16) f16 bufA[128 * 128];
  __shared__ __align__(16) f16 bufB[128 * 128];
  __shared__ __align__(16) f16 Vt[128 * 128];
  __shared__ __align__(16) f16 Pt[128 * 128];
  int z = blockIdx.x;
  int tid = threadIdx.x;
  int w = tid >> 6, l = tid & 63;
  int l15 = l & 15, lg4 = l >> 4;
  int wr = (w >> 1) * 32, wc = (w & 1) * 64;

  float cv = colmax[l];
  #pragma unroll
  for (int o = 32; o; o >>= 1) cv = fmaxf(cv, __shfl_xor(cv, o));
  float recip = 1.f / cv;

  const f16* key = k2h + (long)z * NL * NL;
  auto swz = [](int r, int c) { return r * 128 + ((((c >> 3) ^ (r & 15))) << 3) + (c & 7); };

  for (int idx = tid; idx < 128 * 16; idx += 512) {
    int r = idx >> 4, c8 = (idx & 15) << 3;
    f16x8 kk = *(const f16x8*)&key[r * 128 + c8];
    f16x8 sv;
    #pragma unroll
    for (int j = 0; j < 8; ++j) sv[j] = (f16)(recip * (float)kk[j]);
    *(f16x8*)&Vt[swz(r, c8)] = sv;
    #pragma unroll
    for (int j = 0; j < 8; ++j) bufA[swz(c8 + j, r)] = sv[j];
  }
  __syncthreads();

  f16* Vc = bufA;
  f16* Sc = bufB;

  f32x4 acc[2][4];
  auto MMc = [&](bool fromGlobal, const f16* Aimg, const f16* Bimg) {
    #pragma unroll
    for (int mi = 0; mi < 2; ++mi)
      #pragma unroll
      for (int ni = 0; ni < 4; ++ni) acc[mi][ni] = (f32x4){0.f, 0.f, 0.f, 0.f};
    #pragma unroll
    for (int ks = 0; ks < 4; ++ks) {
      int k0 = ks * 32 + lg4 * 8;
      f16x8 bf[4];
      #pragma unroll
      for (int ni = 0; ni < 4; ++ni)
        bf[ni] = *(const f16x8*)&Bimg[swz(wc + ni * 16 + l15, k0)];
      f16x8 af[2];
      if (fromGlobal) {
        af[0] = *(const f16x8*)&key[(wr + l15) * 128 + k0];
        af[1] = *(const f16x8*)&key[(wr + 16 + l15) * 128 + k0];
      } else {
        af[0] = *(const f16x8*)&Aimg[swz(wr + l15, k0)];
        af[1] = *(const f16x8*)&Aimg[swz(wr + 16 + l15, k0)];
      }
      #pragma unroll
      for (int mi = 0; mi < 2; ++mi)
        #pragma unroll
        for (int ni = 0; ni < 4; ++ni)
          acc[mi][ni] = __builtin_amdgcn_mfma_f32_16x16x32_f16(af[mi], bf[ni], acc[mi][ni], 0, 0, 0);
    }
  };
  auto store = [&](f16* Nout, f16* Tout, float aT, float bT) {
    #pragma unroll
    for (int mi = 0; mi < 2; ++mi) {
      int row0 = wr + mi * 16 + lg4 * 4;
      #pragma unroll
      for (int ni = 0; ni < 4; ++ni) {
        int col = wc + ni * 16 + l15;
        f16x4 tv;
        #pragma unroll
        for (int r = 0; r < 4; ++r) {
          float v = acc[mi][ni][r];
          if (Nout) Nout[swz(row0 + r, col)] = (f16)v;
          tv[r] = (f16)(aT * v + ((row0 + r == col) ? bT : 0.f));
        }
        *(f16x4*)&Tout[col * 128 + ((((row0 >> 3) ^ (col & 15))) << 3) + (row0 & 7)] = tv;
      }
    }
  };

  for (int it = 0; it < 6; ++it) {
    MMc(true, nullptr, Vt);  store(Sc, Pt, -1.f, 7.f);       __syncthreads();
    MMc(false, Sc, Pt);      store(nullptr, Vt, -1.f, 15.f); __syncthreads();
    MMc(false, Sc, Vt);      store(nullptr, Pt, -0.25f, 3.25f); __syncthreads();
    MMc(false, Vc, Pt);      store(Sc, Vt, 1.f, 0.f);        __syncthreads();
    f16* tsw = Vc; Vc = Sc; Sc = tsw;
  }

  const float* kp = kv3 + (long)z * NL * VF;
  for (int idx = tid; idx < 128 * 16; idx += 512) {
    int k = idx >> 4, c4 = (idx & 15) << 2;
    float4 v4 = *(const float4*)&kp[k * 64 + c4];
    Pt[swz(c4 + 0, k)] = (f16)v4.x;
    Pt[swz(c4 + 1, k)] = (f16)v4.y;
    Pt[swz(c4 + 2, k)] = (f16)v4.z;
    Pt[swz(c4 + 3, k)] = (f16)v4.w;
  }
  __syncthreads();
  f32x4 accF[4];
  #pragma unroll
  for (int ni = 0; ni < 4; ++ni) accF[ni] = (f32x4){0.f, 0.f, 0.f, 0.f};
  #pragma unroll
  for (int ks = 0; ks < 4; ++ks) {
    int k0 = ks * 32 + lg4 * 8;
    f16x8 af = *(const f16x8*)&Vc[swz(w * 16 + l15, k0)];
    #pragma unroll
    for (int ni = 0; ni < 4; ++ni) {
      f16x8 bf = *(const f16x8*)&Pt[swz(ni * 16 + l15, k0)];
      accF[ni] = __builtin_amdgcn_mfma_f32_16x16x32_f16(af, bf, accF[ni], 0, 0, 0);
    }
  }
  float* mp = m2 + (long)z * NL * VF;
  #pragma unroll
  for (int ni = 0; ni < 4; ++ni)
    #pragma unroll
    for (int r = 0; r < 4; ++r)
      mp[(long)(w * 16 + lg4 * 4 + r) * VF + ni * 16 + l15] = accF[ni][r];
}

// ---------------------------------------------------------------- kernel_1 + attn + merge (MFMA)
__global__ __launch_bounds__(256, 2) void k_k1attn(
    const f16* __restrict__ Eq16, const f16* __restrict__ kland16,
    const float* __restrict__ aggL, const float* __restrict__ m2,
    const float* __restrict__ proj, f16* __restrict__ merged)
{
  __shared__ __align__(16) f16 Kl[128 * 64];
  __shared__ __align__(16) f16 M2t[64 * 128];
  __shared__ __align__(16) f16 Pb[4 * 16 * 128];
  int zz = blockIdx.x;
  int z = zz >> 5, st = zz & 31;
  int b = z >> 3, h = z & 7;
  int s0 = st * 64;
  int tid = threadIdx.x;
  int w = tid >> 6, l = tid & 63;
  int l15 = l & 15, lg4 = l >> 4, l7 = l & 7;
  float sigma = fabsf(aggL[h]) + 0.001f;
  float cpos = -sigma * (1.f / 16.f);

  for (int c = tid; c < 128 * 8; c += 256) {
    int k = c >> 3, kc = c & 7;
    f16x8 v = *(const f16x8*)&kland16[((long)b * NL + k) * 64 + kc * 8];
    *(f16x8*)&Kl[k * 64 + ((kc ^ (k & 7)) << 3)] = v;
  }
  const float* mp = m2 + (long)z * NL * VF;
  for (int c = tid; c < 128 * 16; c += 256) {
    int k = c >> 4, c4 = (c & 15) << 2;
    float4 v4 = *(const float4*)&mp[k * 64 + c4];
    int kc = k >> 3, ki = k & 7;
    M2t[(c4 + 0) * 128 + ((kc ^ ((c4 + 0) & 7)) << 3) + ki] = (f16)v4.x;
    M2t[(c4 + 1) * 128 + ((kc ^ ((c4 + 1) & 7)) << 3) + ki] = (f16)v4.y;
    M2t[(c4 + 2) * 128 + ((kc ^ ((c4 + 2) & 7)) << 3) + ki] = (f16)v4.z;
    M2t[(c4 + 3) * 128 + ((kc ^ ((c4 + 3) & 7)) << 3) + ki] = (f16)v4.w;
  }
  __syncthreads();

  long qrow = (long)z * S + s0 + w * 16 + l15;
  f16x8 af[2];
  #pragma unroll
  for (int kh = 0; kh < 2; ++kh)
    af[kh] = *(const f16x8*)&Eq16[qrow * 64 + kh * 32 + lg4 * 8];

  f32x4 sc[8];
  #pragma unroll
  for (int ct = 0; ct < 8; ++ct) {
    int n = ct * 16 + l15;
    f16x8 b0 = *(const f16x8*)&Kl[n * 64 + ((lg4 ^ (n & 7)) << 3)];
    f16x8 b1 = *(const f16x8*)&Kl[n * 64 + (((4 + lg4) ^ (n & 7)) << 3)];
    f32x4 zz4 = (f32x4){0.f, 0.f, 0.f, 0.f};
    zz4 = __builtin_amdgcn_mfma_f32_16x16x32_f16(af[0], b0, zz4, 0, 0, 0);
    sc[ct] = __builtin_amdgcn_mfma_f32_16x16x32_f16(af[1], b1, zz4, 0, 0, 0);
  }
  float tmax[4] = {-INFINITY, -INFINITY, -INFINITY, -INFINITY};
  #pragma unroll
  for (int ct = 0; ct < 8; ++ct) {
    int lm = ct * 16 + l15;
    #pragma unroll
    for (int r = 0; r < 4; ++r) {
      int spos = s0 + w * 16 + lg4 * 4 + r;
      float a = (float)(spos - 16 * lm);
      float ac = fminf(fmaxf(a, 0.f), 15.f);
      float dd = fabsf(a - ac);
      float sum = ac * ac - 15.f * ac + 120.f + 16.f * dd;
      float s = sc[ct][r] + cpos * sum;
      sc[ct][r] = s;
      tmax[r] = fmaxf(tmax[r], s);
    }
  }
  #pragma unroll
  for (int r = 0; r < 4; ++r) {
    #pragma unroll
    for (int o = 1; o < 16; o <<= 1)
      tmax[r] = fmaxf(tmax[r], __shfl_xor(tmax[r], o));
  }
  float lsum[4] = {0.f, 0.f, 0.f, 0.f};
  #pragma unroll
  for (int ct = 0; ct < 8; ++ct) {
    #pragma unroll
    for (int r = 0; r < 4; ++r) {
      float p = expf(sc[ct][r] - tmax[r]);
      sc[ct][r] = p;
      lsum[r] += p;
    }
  }
  #pragma unroll
  for (int r = 0; r < 4; ++r) {
    #pragma unroll
    for (int o = 1; o < 16; o <<= 1)
      lsum[r] += __shfl_xor(lsum[r], o);
    lsum[r] = 1.f / lsum[r];
  }
  f16* Pw = &Pb[w * 16 * 128];
  #pragma unroll
  for (int ct = 0; ct < 8; ++ct) {
    int kc = ct * 2 + (l15 >> 3);
    int ki = l15 & 7;
    #pragma unroll
    for (int r = 0; r < 4; ++r) {
      int row = lg4 * 4 + r;
      Pw[row * 128 + ((kc ^ (row & 7)) << 3) + ki] = (f16)(sc[ct][r] * lsum[r]);
    }
  }
  f32x4 Oa[4];
  #pragma unroll
  for (int i = 0; i < 4; ++i) Oa[i] = (f32x4){0.f, 0.f, 0.f, 0.f};
  #pragma unroll
  for (int ks = 0; ks < 4; ++ks) {
    f16x8 pa = *(const f16x8*)&Pw[l15 * 128 + (((ks * 4 + lg4) ^ l7) << 3)];
    #pragma unroll
    for (int dt = 0; dt < 4; ++dt) {
      int n = dt * 16 + l15;
      f16x8 bv = *(const f16x8*)&M2t[n * 128 + (((ks * 4 + lg4) ^ (n & 7)) << 3)];
      Oa[dt] = __builtin_amdgcn_mfma_f32_16x16x32_f16(pa, bv, Oa[dt], 0, 0, 0);
    }
  }
  #pragma unroll
  for (int r = 0; r < 4; ++r) {
    long srow = (long)b * S + s0 + w * 16 + lg4 * 4 + r;
    int r7 = (int)(srow & 7);
    #pragma unroll
    for (int dt = 0; dt < 4; ++dt) {
      int col = dt * 16 + l15;
      float v = Oa[dt][r] + proj[srow * VF + col];
      merged[srow * (long)HV + h * 64 + (((col >> 3) ^ r7) << 3) + (col & 7)] = (f16)v;
    }
  }
}

} // namespace

extern "C" void kernel_launch(void* const* d_in, const int* in_sizes, int n_in,
                              void* d_out, int out_size, void* d_ws, size_t ws_size,
                              hipStream_t stream)
{
  const float* lat   = (const float*)d_in[0];
  const float* masks = (const float*)d_in[1];
  const float* xemb  = (const float*)d_in[2];
  const float* ccls  = (const float*)d_in[4];
  const float* qlin  = (const float*)d_in[5];
  const float* klin  = (const float*)d_in[6];
  const float* vlin  = (const float*)d_in[7];
  const float* plin  = (const float*)d_in[8];
  const float* agg   = (const float*)d_in[9];
  const float* cfeat = (const float*)d_in[10];
  float* out = (float*)d_out;
  float* ws = (float*)d_ws;

  long off = 0;
  auto allocF = [&](long n) { float* p = ws + off; off += (n + 3) & ~3L; return p; };
  auto allocH = [&](long n) { f16* p = (f16*)(ws + off); off += ((n + 1) / 2 + 3) & ~3L; return p; };

  f16* origA = allocH(ROWS * KSF);
  f16* vbufA = allocH(ROWS * KSF);
  f16* merged = allocH(ROWS * (long)HV);
  f16* WQt = allocH(16L * 64 * KSF);
  f16* WKt = allocH(2L * 64 * KSF);
  f16* WVt = allocH(16L * 64 * KSF);
  f16* WPt = allocH(2L * 64 * KSF);
  f16* WCFt = allocH((long)KSF * 512);
  f16* WCCt = allocH(64L * 512);
  f16* Ek16 = allocH((long)B * S * 64);
  f16* Ev16 = allocH((long)B * H * S * 64);
  f16* Eq16 = allocH((long)B * H * S * 64);
  f16* qland16 = allocH((long)B * H * NL * DF);
  f16* kland16 = allocH((long)B * NL * DF);
  f16* k2h = allocH((long)B * H * NL * NL);
  float* cl     = allocF(ROWS * HS);
  float* projb  = allocF((long)B * S * VF);
  float* qland  = allocF((long)B * H * NL * DF);
  float* kland  = allocF((long)B * NL * DF);
  float* kv3    = allocF((long)B * H * NL * VF);
  float* m2b    = allocF((long)B * H * NL * VF);
  float* colmax = allocF(64);
  float* partU  = allocF((long)B * H * NL * NSPL * 64);
  float* partML = allocF((long)B * H * NL * NSPL * 2);

  k_cl<<<(int)(ROWS / 4), 256, 0, stream>>>(lat, masks, cl);
  k_cvta<<<(int)(ROWS * 168 / 256), 256, 0, stream>>>(xemb, cl, origA);

  auto cvtw = [&](const float* src, f16* dst, int K, int N, int Npad, int KS, long srcZ, int nz) {
    long total = (long)nz * Npad * (KS / 8);
    k_cvtw<<<(int)((total + 255) / 256), 256, 0, stream>>>(src, dst, K, N, Npad, KS, srcZ, total);
  };
  cvtw(qlin, WQt, FEAT, 64, 64, KSF, (long)FEATP * 64, 16);
  cvtw(klin, WKt, FEAT, 64, 64, KSF, (long)FEATP * 64, 2);
  cvtw(vlin, WVt, FEAT, 64, 64, KSF, (long)FEATP * 64, 16);
  cvtw(plin, WPt, FEAT, 64, 64, KSF, (long)FEATP * 64, 2);
  cvtw(cfeat, WCFt, 512, FEAT, KSF, 512, 0, 1);
  cvtw(ccls, WCCt, 512, HS, 64, 512, 0, 1);

  const f16* Aact = origA;
  for (int layer = 0; layer < 2; ++layer) {
    const f16* wq = WQt + (long)layer * 8 * 64 * KSF;
    const f16* wk = WKt + (long)layer * 64 * KSF;
    const f16* wvv = WVt + (long)layer * 8 * 64 * KSF;
    const f16* wp = WPt + (long)layer * 64 * KSF;
    const float* bq = qlin + (long)layer * 8 * FEATP * 64 + (long)(FEATP - 2) * 64;
    const float* bk = klin + (long)layer * FEATP * 64 + (long)(FEATP - 2) * 64;
    const float* bv = vlin + (long)layer * 8 * FEATP * 64 + (long)(FEATP - 2) * 64;
    const float* bp = plin + (long)layer * FEATP * 64 + (long)(FEATP - 2) * 64;
    const float* ag = agg + layer * H;

    dim3 gQV(16, 1, 64);
    k_qv<<<gQV, 256, 0, stream>>>(Aact, wq, wvv, bq, bv, Eq16, Ev16);
    k_ekproj<<<dim3(8, 1, 16), 256, 0, stream>>>(Aact, origA, wk, wp, bk, bp,
        Ek16, projb);

    k_segmean<<<B * H * NL, 64, 0, stream>>>(Eq16, qland, qland16);
    k_segmean<<<B * NL, 64, 0, stream>>>(Ek16, kland, kland16);

    k_kernel2<<<B * H, 256, 0, stream>>>(qland, kland, ag, k2h, colmax);
    k_kernel3<<<B * H * 2 * NSPL, 256, 0, stream>>>(qland16, Ek16, Ev16, ag, masks,
        partU, partML);
    k_merge<<<B * H * 4, 256, 0, stream>>>(partU, partML, kv3);
    k_inverse<<<B * H, 512, 0, stream>>>(k2h, colmax, kv3, m2b);
    k_k1attn<<<B * H * (S / 64), 256, 0, stream>>>(Eq16, kland16, ag, m2b, projb, merged);

    if (layer == 0) {
      dim3 gC(64, 21, 1);
      k_mgemm<<<gC, 256, 0, stream>>>(merged, 0, 1, WCFt, 0, 1, 8, 1,
          nullptr, 0, 0, nullptr, 0, 1.0f, vbufA, FEAT, nullptr);
      Aact = vbufA;
    } else {
      dim3 gO(64, 1, 1);
      k_mgemm<<<gO, 256, 0, stream>>>(merged, 0, 1, WCCt, 0, 1, 8, 2,
          out, 0, HS, nullptr, 0, 1.0f, nullptr, HS, masks);
    }
  }
  (void)in_sizes; (void)n_in; (void)out_size; (void)ws_size;
}